// Round 1
// baseline (493.888 us; speedup 1.0000x reference)
//
#include <hip/hip_runtime.h>
#include <hip/hip_bf16.h>
#include <math.h>

typedef __hip_bfloat16 bf16;
typedef __attribute__((ext_vector_type(8))) short short8;   // 8 bf16 (4 VGPRs)
typedef __attribute__((ext_vector_type(4))) float f32x4;
#define DEVINL __device__ __forceinline__

constexpr int Bc  = 2;
constexpr int Nc  = 768;
constexpr int Dc  = 512;
constexpr int Hc  = 8;
constexpr int DKc = 64;
constexpr int BHc = Bc * Hc;
constexpr float SCALE    = 0.125f;   // 1/sqrt(64)
constexpr float EPSF     = 1e-6f;
constexpr float BETA_NOT = 0.5f;

DEVINL float ldf(const float* p, long i) { return p[i]; }
DEVINL float ldf(const bf16* p, long i) { return __bfloat162float(p[i]); }
DEVINL void stf(float* p, long i, float v) { p[i] = v; }
DEVINL void stf(bf16* p, long i, float v) { p[i] = __float2bfloat16(v); }

DEVINL float sigf(float x) { return __fdividef(1.f, 1.f + __expf(-x)); }

// async global->LDS, 16B per lane; LDS dest = wave-uniform base + lane*16.
DEVINL void gl_lds16(const void* g, void* l) {
    __builtin_amdgcn_global_load_lds(
        (const __attribute__((address_space(1))) void*)g,
        (__attribute__((address_space(3))) void*)l, 16, 0, 0);
}

// ---------------------------------------------------------------------------
// Dtype sniffer — vectorized (validated round 9).
// ---------------------------------------------------------------------------
DEVINL int sniff_is_fp32(const void* xraw) {
    const uint4* p4 = (const uint4*)xraw;
    float mx = 0.f;
#pragma unroll
    for (int j = 0; j < 16; ++j) {
        const uint4 u = p4[j];
        const unsigned w[4] = {u.x, u.y, u.z, u.w};
#pragma unroll
        for (int t = 0; t < 4; ++t) {
            mx = fmaxf(mx, fabsf(__uint_as_float((w[t] & 0xffffu) << 16)));
            mx = fmaxf(mx, fabsf(__uint_as_float(w[t] & 0xffff0000u)));
        }
    }
    return mx > 1000.f ? 1 : 0;
}

DEVINL float cvt_elem(const void* s, long j, int is32) {
    return is32 ? ((const float*)s)[j]
                : __bfloat162float(((const bf16*)s)[j]);
}

// smallf layout (round 12 repack — 3x ds_read_b128 per u in gates_smix):
//   [  0..127]  u*8 + {w1[u][0..5], b1[u], 0}
//   [128..191]  u*4 + o : conv2_w[o][u]   (transposed)
//   [192..195]  conv2_b[0..3]
//   [196]       chain_logit
__global__ __launch_bounds__(256) void convert_all(
    const void* x, const void* w1, const void* w2, const void* pw,
    const void* c1w, const void* c1b, const void* c2w, const void* c2b,
    const void* ch,
    bf16* xb, bf16* w1b, bf16* w2b, bf16* pwb, float* smallf)
{
    __shared__ int is32s;
    if (threadIdx.x == 0) is32s = sniff_is_fp32(x);
    __syncthreads();
    const int is32 = is32s;
    const long i = (long)blockIdx.x * 256 + threadIdx.x;
    if (i < (long)Bc * Nc * Dc) {
        xb[i]  = __float2bfloat16(cvt_elem(x,  i, is32));
        w1b[i] = __float2bfloat16(cvt_elem(w1, i, is32));
        w2b[i] = __float2bfloat16(cvt_elem(w2, i, is32));
    }
    if (i < (long)Dc * Dc) pwb[i] = __float2bfloat16(cvt_elem(pw, i, is32));
    if (i < 128) {
        const int u = (int)i >> 3, k = (int)i & 7;
        smallf[i] = (k < 6) ? cvt_elem(c1w, u * 6 + k, is32)
                  : (k == 6 ? cvt_elem(c1b, u, is32) : 0.f);
    } else if (i < 192) {
        const int t = (int)i - 128;
        smallf[i] = cvt_elem(c2w, (long)(t & 3) * 16 + (t >> 2), is32);
    } else if (i < 196) smallf[i] = cvt_elem(c2b, i - 192, is32);
    else if (i == 196) smallf[196] = cvt_elem(ch, 0, is32);
    else if (i < 208)  smallf[i] = 0.f;
}

__global__ __launch_bounds__(256) void fill_sentinel(unsigned short* o) {
    const long i = (long)blockIdx.x * 256 + threadIdx.x;
    if (i < (long)Bc * Nc * Dc) o[i] = 0x40E0;  // bf16 7.0
}

// ---------------------------------------------------------------------------
// Generic bf16 transpose, 64x64 tiles: dst[c][r] = src[r][c]; src is (R,C).
// ---------------------------------------------------------------------------
__global__ __launch_bounds__(256) void transpose_bf16(
    const unsigned short* __restrict__ src, unsigned short* __restrict__ dst,
    int R, int C, long sS, long sD)
{
    __shared__ unsigned short tile[64][68];
    const unsigned short* s = src + (long)blockIdx.z * sS;
    unsigned short* d = dst + (long)blockIdx.z * sD;
    const int r0 = blockIdx.y * 64, c0 = blockIdx.x * 64;
    const int t = threadIdx.x;
    const int lr = t >> 4, lc4 = (t & 15) * 4;
#pragma unroll
    for (int i = 0; i < 4; ++i) {
        int r = lr + i * 16;
        *(uint2*)&tile[r][lc4] = *(const uint2*)&s[(long)(r0 + r) * C + c0 + lc4];
    }
    __syncthreads();
#pragma unroll
    for (int i = 0; i < 4; ++i) {
        int r = lr + i * 16;
        unsigned short v[4];
#pragma unroll
        for (int j = 0; j < 4; ++j) v[j] = tile[lc4 + j][r];
        *(uint2*)&d[(long)(c0 + r) * R + r0 + lc4] = *(uint2*)v;
    }
}

// ---------------------------------------------------------------------------
// MFMA bf16 NT GEMM with global_load_lds staging (validated rounds 6-11):
// C = A(M,K) @ Bt(N,K)^T. 128x128 tile, BK=32.
// XORB: B batch index = z^16 (merged Cr/Cl trick; adjacency-dependent).
// ---------------------------------------------------------------------------
template <int EPI, typename TC, int XORB = 0>
__global__ __launch_bounds__(256) void gemm_nt_mfma(
    const bf16* __restrict__ Ag, const bf16* __restrict__ Btg,
    TC* __restrict__ Cg, int M, int N, int K,
    long sA, long sB, long sC, float alpha)
{
    __shared__ unsigned short Asm[128 * 32];
    __shared__ unsigned short Bsm[128 * 32];

    const int tid  = threadIdx.x;
    const int wv   = tid >> 6;
    const int lane = tid & 63;
    const int q    = lane >> 4;
    const int ln   = lane & 15;
    const int wm   = wv & 1;
    const int wn   = wv >> 1;

    const int zb = XORB ? ((int)blockIdx.z ^ 16) : (int)blockIdx.z;
    const bf16* A  = Ag  + (long)blockIdx.z * sA + (long)(blockIdx.y * 128) * K;
    const bf16* Bt = Btg + (long)zb * sB + (long)(blockIdx.x * 128) * K;
    TC*         C  = Cg  + (long)blockIdx.z * sC;

    const int sr = lane >> 2, sc = lane & 3;
    const bf16* gA0 = A  + (long)(wv * 32 + sr)      * K + sc * 8;
    const bf16* gA1 = A  + (long)(wv * 32 + 16 + sr) * K + sc * 8;
    const bf16* gB0 = Bt + (long)(wv * 32 + sr)      * K + sc * 8;
    const bf16* gB1 = Bt + (long)(wv * 32 + 16 + sr) * K + sc * 8;
    unsigned short* lA0 = &Asm[(wv * 32)      * 32];
    unsigned short* lA1 = &Asm[(wv * 32 + 16) * 32];
    unsigned short* lB0 = &Bsm[(wv * 32)      * 32];
    unsigned short* lB1 = &Bsm[(wv * 32 + 16) * 32];

    f32x4 acc[4][4];
#pragma unroll
    for (int i = 0; i < 4; ++i)
#pragma unroll
        for (int j = 0; j < 4; ++j)
            acc[i][j] = (f32x4){0.f, 0.f, 0.f, 0.f};

    for (int k0 = 0; k0 < K; k0 += 32) {
        __syncthreads();
        gl_lds16(gA0 + k0, lA0);
        gl_lds16(gA1 + k0, lA1);
        gl_lds16(gB0 + k0, lB0);
        gl_lds16(gB1 + k0, lB1);
        __syncthreads();

        short8 af[4], bfr[4];
#pragma unroll
        for (int mt = 0; mt < 4; ++mt) {
            int m = wm * 64 + mt * 16 + ln;
            af[mt] = *(const short8*)&Asm[m * 32 + q * 8];
        }
#pragma unroll
        for (int nt = 0; nt < 4; ++nt) {
            int n = wn * 64 + nt * 16 + ln;
            bfr[nt] = *(const short8*)&Bsm[n * 32 + q * 8];
        }
#pragma unroll
        for (int mt = 0; mt < 4; ++mt)
#pragma unroll
            for (int nt = 0; nt < 4; ++nt)
                acc[mt][nt] = __builtin_amdgcn_mfma_f32_16x16x32_bf16(
                    af[mt], bfr[nt], acc[mt][nt], 0, 0, 0);
    }

#pragma unroll
    for (int mt = 0; mt < 4; ++mt) {
#pragma unroll
        for (int nt = 0; nt < 4; ++nt) {
            const int col = blockIdx.x * 128 + wn * 64 + nt * 16 + ln;
            const int rowb = blockIdx.y * 128 + wm * 64 + mt * 16 + q * 4;
#pragma unroll
            for (int r = 0; r < 4; ++r) {
                float v = acc[mt][nt][r] * alpha;
                if (EPI == 1) v = __logf(fmaxf(v, 0.f) + EPSF);
                stf(C, (long)(rowb + r) * N + col, v);
            }
        }
    }
}

// ---------------------------------------------------------------------------
// QKV via MFMA, merged sets (validated rounds 6-11).
// ---------------------------------------------------------------------------
__global__ __launch_bounds__(256) void qkv_mfma(
    const bf16* __restrict__ X,
    const bf16* __restrict__ w1t, const bf16* __restrict__ w2t,
    bf16* __restrict__ q1, bf16* __restrict__ k1, bf16* __restrict__ v1,
    bf16* __restrict__ q2, bf16* __restrict__ k2, bf16* __restrict__ v2)
{
    constexpr int K = Dc;  // 512
    __shared__ unsigned short Asm[128 * 32];
    __shared__ unsigned short Bsm[128 * 32];

    const int tid  = threadIdx.x;
    const int wv   = tid >> 6;
    const int lane = tid & 63;
    const int q    = lane >> 4;
    const int ln   = lane & 15;
    const int wm   = wv & 1;
    const int wn   = wv >> 1;
    const int set  = blockIdx.z;

    const bf16* Wt = set ? w2t : w1t;
    bf16* Q  = set ? q2 : q1;
    bf16* Ko = set ? k2 : k1;
    bf16* V  = set ? v2 : v1;

    const bf16* A  = X  + (long)(blockIdx.y * 128) * K;
    const bf16* Bt = Wt + (long)(blockIdx.x * 128) * K;

    const int sr = lane >> 2, sc = lane & 3;
    const bf16* gA0 = A  + (long)(wv * 32 + sr)      * K + sc * 8;
    const bf16* gA1 = A  + (long)(wv * 32 + 16 + sr) * K + sc * 8;
    const bf16* gB0 = Bt + (long)(wv * 32 + sr)      * K + sc * 8;
    const bf16* gB1 = Bt + (long)(wv * 32 + 16 + sr) * K + sc * 8;
    unsigned short* lA0 = &Asm[(wv * 32)      * 32];
    unsigned short* lA1 = &Asm[(wv * 32 + 16) * 32];
    unsigned short* lB0 = &Bsm[(wv * 32)      * 32];
    unsigned short* lB1 = &Bsm[(wv * 32 + 16) * 32];

    f32x4 acc[4][4];
#pragma unroll
    for (int i = 0; i < 4; ++i)
#pragma unroll
        for (int j = 0; j < 4; ++j)
            acc[i][j] = (f32x4){0.f, 0.f, 0.f, 0.f};

    for (int k0 = 0; k0 < K; k0 += 32) {
        __syncthreads();
        gl_lds16(gA0 + k0, lA0);
        gl_lds16(gA1 + k0, lA1);
        gl_lds16(gB0 + k0, lB0);
        gl_lds16(gB1 + k0, lB1);
        __syncthreads();

        short8 af[4], bfr[4];
#pragma unroll
        for (int mt = 0; mt < 4; ++mt) {
            int m = wm * 64 + mt * 16 + ln;
            af[mt] = *(const short8*)&Asm[m * 32 + q * 8];
        }
#pragma unroll
        for (int nt = 0; nt < 4; ++nt) {
            int n = wn * 64 + nt * 16 + ln;
            bfr[nt] = *(const short8*)&Bsm[n * 32 + q * 8];
        }
#pragma unroll
        for (int mt = 0; mt < 4; ++mt)
#pragma unroll
            for (int nt = 0; nt < 4; ++nt)
                acc[mt][nt] = __builtin_amdgcn_mfma_f32_16x16x32_bf16(
                    af[mt], bfr[nt], acc[mt][nt], 0, 0, 0);
    }

#pragma unroll
    for (int mt = 0; mt < 4; ++mt) {
#pragma unroll
        for (int nt = 0; nt < 4; ++nt) {
            const int col  = blockIdx.x * 128 + wn * 64 + nt * 16 + ln;
            const int rowb = blockIdx.y * 128 + wm * 64 + mt * 16 + q * 4;
            const int t = col >> 9;
            const int h = (col >> 6) & 7;
            const int dk = col & 63;
            bf16* dst = (t == 0) ? Q : (t == 1) ? Ko : V;
#pragma unroll
            for (int r = 0; r < 4; ++r) {
                const int row = rowb + r;
                const int b = row >= Nc ? 1 : 0;
                const int n = row - b * Nc;
                dst[(((long)b * Hc + h) * Nc + n) * DKc + dk] =
                    __float2bfloat16(acc[mt][nt][r]);
            }
        }
    }
}

// ---------------------------------------------------------------------------
// MFMA bf16 NT narrow GEMM core (validated): acc = A(128,K) @ Bt(64,K)^T.
// ---------------------------------------------------------------------------
struct N64Acc { f32x4 acc[2][4]; };

template <typename DUMMY = void>
DEVINL void n64_core(const bf16* A, const bf16* Bt, int K,
                     unsigned short* Asm, unsigned short* Bsm, N64Acc& R)
{
    const int tid  = threadIdx.x;
    const int wave = tid >> 6;
    const int lane = tid & 63;
    const int q    = lane >> 4;
    const int ln   = lane & 15;

    const int sr = tid >> 3, k8 = tid & 7;
    const bf16* pa[4];
    const bf16* pb[2];
    int wa[4], wb[2];
#pragma unroll
    for (int i = 0; i < 4; ++i) {
        pa[i] = A + (long)(sr + i * 32) * K + k8 * 8;
        wa[i] = (sr + i * 32) * 72 + k8 * 8;
    }
#pragma unroll
    for (int i = 0; i < 2; ++i) {
        pb[i] = Bt + (long)(sr + i * 32) * K + k8 * 8;
        wb[i] = (sr + i * 32) * 72 + k8 * 8;
    }

#pragma unroll
    for (int i = 0; i < 2; ++i)
#pragma unroll
        for (int j = 0; j < 4; ++j)
            R.acc[i][j] = (f32x4){0.f, 0.f, 0.f, 0.f};

    for (int k0 = 0; k0 < K; k0 += 64) {
        uint4 va[4], vb[2];
#pragma unroll
        for (int i = 0; i < 4; ++i) va[i] = *(const uint4*)(pa[i] + k0);
#pragma unroll
        for (int i = 0; i < 2; ++i) vb[i] = *(const uint4*)(pb[i] + k0);
        __syncthreads();
#pragma unroll
        for (int i = 0; i < 4; ++i) *(uint4*)&Asm[wa[i]] = va[i];
#pragma unroll
        for (int i = 0; i < 2; ++i) *(uint4*)&Bsm[wb[i]] = vb[i];
        __syncthreads();

#pragma unroll
        for (int kc = 0; kc < 2; ++kc) {
            short8 af[2], bfr[4];
#pragma unroll
            for (int mt = 0; mt < 2; ++mt) {
                int m = wave * 32 + mt * 16 + ln;
                af[mt] = *(const short8*)&Asm[m * 72 + kc * 32 + q * 8];
            }
#pragma unroll
            for (int nt = 0; nt < 4; ++nt) {
                int n = nt * 16 + ln;
                bfr[nt] = *(const short8*)&Bsm[n * 72 + kc * 32 + q * 8];
            }
#pragma unroll
            for (int mt = 0; mt < 2; ++mt)
#pragma unroll
                for (int nt = 0; nt < 4; ++nt)
                    R.acc[mt][nt] = __builtin_amdgcn_mfma_f32_16x16x32_bf16(
                        af[mt], bfr[nt], R.acc[mt][nt], 0, 0, 0);
        }
    }
}

// ---------------------------------------------------------------------------
// Merged pair launch (validated round 11):
//   z <  16: transport = A2 @ v2t -> written TRANSPOSED (64 x Nc) straight to
//            trt via an LDS transpose in the epilogue.
//   z >= 16: y_base = A @ v1t -> normal (Nc x 64) write to yb1.
// ---------------------------------------------------------------------------
__global__ __launch_bounds__(256) void gemm_n64_pair(
    const bf16* __restrict__ A0g, const bf16* __restrict__ B0g, bf16* __restrict__ C0tg,
    const bf16* __restrict__ A1g, const bf16* __restrict__ B1g, bf16* __restrict__ C1g,
    int M, int K, long sA, long sB, long sC)
{
    __shared__ unsigned short Asm[128 * 72];
    __shared__ unsigned short Bsm[64 * 72];

    const int zz = blockIdx.z & 15;
    const int second = blockIdx.z >> 4;
    const bf16* A  = (second ? A1g : A0g) + (long)zz * sA + (long)(blockIdx.y * 128) * K;
    const bf16* Bt = (second ? B1g : B0g) + (long)zz * sB;

    N64Acc R;
    n64_core(A, Bt, K, Asm, Bsm, R);

    const int tid = threadIdx.x;
    const int wave = tid >> 6, lane = tid & 63, q = lane >> 4, ln = lane & 15;

    if (second) {
        bf16* C = C1g + (long)zz * sC;
#pragma unroll
        for (int mt = 0; mt < 2; ++mt) {
#pragma unroll
            for (int nt = 0; nt < 4; ++nt) {
                const int col  = nt * 16 + ln;
                const int rowb = blockIdx.y * 128 + wave * 32 + mt * 16 + q * 4;
#pragma unroll
                for (int r = 0; r < 4; ++r)
                    C[(long)(rowb + r) * 64 + col] = __float2bfloat16(R.acc[mt][nt][r]);
            }
        }
    } else {
        // stage C tile into Asm as [dk][n] (stride 136 -> 16B-aligned rows)
        __syncthreads();   // all waves done reading Asm from the K loop
#pragma unroll
        for (int mt = 0; mt < 2; ++mt) {
#pragma unroll
            for (int nt = 0; nt < 4; ++nt) {
                const int col = nt * 16 + ln;                 // dk
                const int rwb = wave * 32 + mt * 16 + q * 4;  // n within tile
#pragma unroll
                for (int r = 0; r < 4; ++r)
                    *(bf16*)&Asm[col * 136 + rwb + r] = __float2bfloat16(R.acc[mt][nt][r]);
            }
        }
        __syncthreads();
        bf16* Ct = C0tg + (long)zz * sC;
        const int dk  = tid >> 2;
        const int nc0 = (tid & 3) * 32;
        const int gn0 = blockIdx.y * 128;
#pragma unroll
        for (int c8 = 0; c8 < 4; ++c8) {
            uint4 v = *(const uint4*)&Asm[dk * 136 + nc0 + c8 * 8];
            *(uint4*)&Ct[(long)dk * Nc + gn0 + nc0 + c8 * 8] = v;
        }
    }
}

// y_chain GEMM with fused combine + permute (validated rounds 9-11).
__global__ __launch_bounds__(256) void gemm_n64_combine(
    const bf16* __restrict__ A1b, const bf16* __restrict__ trt,
    const bf16* __restrict__ yb1, const float* __restrict__ smallf,
    bf16* __restrict__ yc, int M, int K, long sA, long sB)
{
    __shared__ unsigned short Asm[128 * 72];
    __shared__ unsigned short Bsm[64 * 72];

    const int bh = blockIdx.z;
    const bf16* A  = A1b + (long)bh * sA + (long)(blockIdx.y * 128) * K;
    const bf16* Bt = trt + (long)bh * sB;

    N64Acc R;
    n64_core(A, Bt, K, Asm, Bsm, R);

    const float w = sigf(smallf[196]);
    const int b = bh >> 3, h = bh & 7;
    const long yb1base = (long)bh * Nc * DKc;

    const int tid = threadIdx.x;
    const int wave = tid >> 6, lane = tid & 63, q = lane >> 4, ln = lane & 15;
#pragma unroll
    for (int mt = 0; mt < 2; ++mt) {
#pragma unroll
        for (int nt = 0; nt < 4; ++nt) {
            const int col  = nt * 16 + ln;
            const int rowb = blockIdx.y * 128 + wave * 32 + mt * 16 + q * 4;
#pragma unroll
            for (int r = 0; r < 4; ++r) {
                const int n = rowb + r;
                const float base = __bfloat162float(yb1[yb1base + (long)n * 64 + col]);
                yc[((long)(b * Nc + n)) * Dc + h * DKc + col] =
                    __float2bfloat16(base + w * R.acc[mt][nt][r]);
            }
        }
    }
}

// ---------------------------------------------------------------------------
// Row softmax over width 768 (validated).
// ---------------------------------------------------------------------------
template <typename TO>
__global__ __launch_bounds__(256) void softmax_rows(const float* src, TO* dst)
{
    __shared__ float red[4];
    const long row = blockIdx.x;
    const float* s = src + row * Nc;
    TO* d = dst + row * Nc;
    const int tid = threadIdx.x;

    float v[3];
    float m = -1e30f;
#pragma unroll
    for (int i = 0; i < 3; ++i) { v[i] = s[tid + i * 256]; m = fmaxf(m, v[i]); }

#pragma unroll
    for (int off = 32; off > 0; off >>= 1) m = fmaxf(m, __shfl_down(m, off, 64));
    if ((tid & 63) == 0) red[tid >> 6] = m;
    __syncthreads();
    if (tid == 0) {
        float mm = red[0];
        for (int w = 1; w < 4; ++w) mm = fmaxf(mm, red[w]);
        red[0] = mm;
    }
    __syncthreads();
    m = red[0];
    __syncthreads();

    float e[3];
    float sum = 0.f;
#pragma unroll
    for (int i = 0; i < 3; ++i) { e[i] = __expf(v[i] - m); sum += e[i]; }
#pragma unroll
    for (int off = 32; off > 0; off >>= 1) sum += __shfl_down(sum, off, 64);
    if ((tid & 63) == 0) red[tid >> 6] = sum;
    __syncthreads();
    if (tid == 0) red[0] = red[0] + red[1] + red[2] + red[3];
    __syncthreads();
    const float inv = 1.f / fmaxf(red[0], 1e-30f);
#pragma unroll
    for (int i = 0; i < 3; ++i) stf(d, tid + i * 256, e[i] * inv);
}

// ---------------------------------------------------------------------------
// Gate network + Smix — round 12: 4 elem/thread (64-wide m tile), repacked
// weights so each u-iteration is 3x ds_read_b128 (was ~11 ds_read_b32),
// exp2-folded gelu. Math identical to round-9 body otherwise.
// ---------------------------------------------------------------------------
__global__ __launch_bounds__(256) void gates_smix(
    const float* __restrict__ S1g, const float* __restrict__ S2g,
    const bf16* __restrict__ Crg, const bf16* __restrict__ Clg,
    float* __restrict__ Smixg, const float* __restrict__ smallf)
{
    __shared__ float t1t[64][17], t2t[64][17];
    __shared__ float cs[208];

    const long mat = (long)blockIdx.z * Nc * Nc;
    const float* S1 = S1g + mat;
    const float* S2 = S2g + mat;
    const unsigned short* Cr = (const unsigned short*)Crg + mat;
    const unsigned short* Cl = (const unsigned short*)Clg + mat;
    float* Smix = Smixg + mat;

    const int tid = threadIdx.x;
    if (tid < 208) cs[tid] = smallf[tid];

    const int n0 = blockIdx.y * 16, m0 = blockIdx.x * 64;
    {   // transposed tiles: S[m0..m0+63][n0..n0+15], coalesced float4 loads
        const int r = tid >> 2, c4 = (tid & 3) * 4;
        const float4 a = *(const float4*)&S1[(long)(m0 + r) * Nc + n0 + c4];
        const float4 b = *(const float4*)&S2[(long)(m0 + r) * Nc + n0 + c4];
        t1t[r][c4] = a.x; t1t[r][c4 + 1] = a.y; t1t[r][c4 + 2] = a.z; t1t[r][c4 + 3] = a.w;
        t2t[r][c4] = b.x; t2t[r][c4 + 1] = b.y; t2t[r][c4 + 2] = b.z; t2t[r][c4 + 3] = b.w;
    }
    __syncthreads();

    const int tx = tid & 15, ty = tid >> 4;
    const int n = n0 + ty;
    const long idx = (long)n * Nc + m0 + tx * 4;

    const float4 s1v = *(const float4*)&S1[idx];
    const float4 s2v = *(const float4*)&S2[idx];
    const uint2 cru = *(const uint2*)&Cr[idx];   // idx mult of 4 -> 8B aligned
    const uint2 clu = *(const uint2*)&Cl[idx];

    float s1a[4] = {s1v.x, s1v.y, s1v.z, s1v.w};
    float s2a[4] = {s2v.x, s2v.y, s2v.z, s2v.w};
    float cra[4] = {__uint_as_float((cru.x & 0xffffu) << 16),
                    __uint_as_float(cru.x & 0xffff0000u),
                    __uint_as_float((cru.y & 0xffffu) << 16),
                    __uint_as_float(cru.y & 0xffff0000u)};
    float cla[4] = {__uint_as_float((clu.x & 0xffffu) << 16),
                    __uint_as_float(clu.x & 0xffff0000u),
                    __uint_as_float((clu.y & 0xffffu) << 16),
                    __uint_as_float(clu.y & 0xffff0000u)};
    float s1t[4], s2t[4];
#pragma unroll
    for (int j = 0; j < 4; ++j) {
        s1t[j] = t1t[tx * 4 + j][ty];
        s2t[j] = t2t[tx * 4 + j][ty];
    }

    float g[4][4];
#pragma unroll
    for (int o = 0; o < 4; ++o)
#pragma unroll
        for (int j = 0; j < 4; ++j) g[o][j] = cs[192 + o];

#pragma unroll
    for (int u = 0; u < 16; ++u) {
        const float4 wa = *(const float4*)&cs[u * 8];        // w0..w3
        const float4 wb = *(const float4*)&cs[u * 8 + 4];    // w4,w5,b1,pad
        const float4 w2 = *(const float4*)&cs[128 + u * 4];  // w2t[o=0..3]
#pragma unroll
        for (int j = 0; j < 4; ++j) {
            float h = wb.z;
            h = fmaf(s1a[j], wa.x, h);
            h = fmaf(s2a[j], wa.y, h);
            h = fmaf(s1t[j], wa.z, h);
            h = fmaf(s2t[j], wa.w, h);
            h = fmaf(cra[j], wb.x, h);
            h = fmaf(cla[j], wb.y, h);
            // gelu-tanh via exp2: constants pre-multiplied by log2(e)
            const float hh = h * h;
            const float z2 = h * fmaf(hh, -0.10294357f, -2.30220902f);
            const float e = exp2f(z2);
            const float hid = h * __fdividef(1.f, 1.f + e);
            g[0][j] = fmaf(hid, w2.x, g[0][j]);
            g[1][j] = fmaf(hid, w2.y, g[1][j]);
            g[2][j] = fmaf(hid, w2.z, g[2][j]);
            g[3][j] = fmaf(hid, w2.w, g[3][j]);
        }
    }

    float out[4];
#pragma unroll
    for (int j = 0; j < 4; ++j) {
        const float ga = sigf(g[0][j]);
        const float go = sigf(g[1][j]);
        const float gn = sigf(g[2][j]);
        const float gc = sigf(g[3][j]);
        const float s1 = s1a[j], s2 = s2a[j];
        const float mx = fmaxf(s1, s2);
        const float lae = mx + __logf(1.f + __expf(-fabsf(s1 - s2)));
        out[j] = s1 + ga * s2 + go * (lae - s1) - gn * (BETA_NOT * s2) + gc * cra[j];
    }
    *(float4*)&Smix[idx] = make_float4(out[0], out[1], out[2], out[3]);
}

// ---------------------------------------------------------------------------
// Final projection via n64 core, 128x64 tiles (round 12: 96 blocks instead
// of 48 — proj_mfma left 81% of CUs idle).
// ---------------------------------------------------------------------------
__global__ __launch_bounds__(256) void proj_n64(
    const bf16* __restrict__ yc, const bf16* __restrict__ pwt,
    const void* __restrict__ xraw, void* __restrict__ out)
{
    constexpr int K = Dc;  // 512
    constexpr int N = Dc;  // 512
    __shared__ unsigned short Asm[128 * 72];
    __shared__ unsigned short Bsm[64 * 72];
    __shared__ int is32s;
    if (threadIdx.x == 0) is32s = sniff_is_fp32(xraw);

    const bf16* A  = yc  + (long)(blockIdx.y * 128) * K;
    const bf16* Bt = pwt + (long)(blockIdx.x * 64) * K;

    N64Acc R;
    n64_core(A, Bt, K, Asm, Bsm, R);   // internal barriers publish is32s

    const int is32 = is32s;
    const int tid = threadIdx.x;
    const int wave = tid >> 6, lane = tid & 63, q = lane >> 4, ln = lane & 15;
#pragma unroll
    for (int mt = 0; mt < 2; ++mt) {
#pragma unroll
        for (int nt = 0; nt < 4; ++nt) {
            const int col  = blockIdx.x * 64 + nt * 16 + ln;
            const int rowb = blockIdx.y * 128 + wave * 32 + mt * 16 + q * 4;
#pragma unroll
            for (int r = 0; r < 4; ++r) {
                const long o = (long)(rowb + r) * N + col;
                if (is32) ((float*)out)[o] = R.acc[mt][nt][r];
                else      ((bf16*)out)[o] = __float2bfloat16(R.acc[mt][nt][r]);
            }
        }
    }
}

// ---------------------------------------------------------------------------
extern "C" void kernel_launch(void* const* d_in, const int* in_sizes, int n_in,
                              void* d_out, int out_size, void* d_ws, size_t ws_size,
                              hipStream_t stream)
{
    const size_t HD   = (size_t)BHc * Nc * DKc;   // 786432
    const size_t HDh  = HD / 2;                   // float-slots for HD bf16
    const size_t MAT  = (size_t)Nc * Nc;          // 589824
    const size_t MATS = (size_t)BHc * MAT;        // 9437184
    const long   HSTR = (long)Nc * DKc;           // 49152 per-head stride

    float* ws = (float*)d_ws;
    size_t off = 0;
    auto alloc = [&](size_t n) { float* p = ws + off; off += n; return p; };

    bf16* xb  = (bf16*)alloc(HDh);
    bf16* w1b = (bf16*)alloc(HDh);   // w1b/w2b adjacent -> merged transpose
    bf16* w2b = (bf16*)alloc(HDh);
    bf16* w1t = (bf16*)alloc(HDh);
    bf16* w2t = (bf16*)alloc(HDh);
    bf16* pwb = (bf16*)alloc((size_t)Dc * Dc / 2);
    bf16* pwt = (bf16*)alloc((size_t)Dc * Dc / 2);
    float* smallf = alloc(256);
    // q1|q2 and k1|k2 adjacent -> single merged S-GEMM launch (32 heads)
    bf16* q1b = (bf16*)alloc(HDh); bf16* q2b = (bf16*)alloc(HDh);
    bf16* k1b = (bf16*)alloc(HDh); bf16* k2b = (bf16*)alloc(HDh);
    bf16* v1b = (bf16*)alloc(HDh); bf16* v2b = (bf16*)alloc(HDh);  // adjacent
    bf16* v1t = (bf16*)alloc(HDh); bf16* v2t = (bf16*)alloc(HDh);  // adjacent
    bf16* trt = (bf16*)alloc(HDh);
    float* S1   = alloc(MATS);       // S1/S2 adjacent -> merged softmax + S-GEMM
    float* S2   = alloc(MATS);
    float* Smix = alloc(MATS);       // region reused: A1tb|A2tb, then Smix
    bf16* A1b = (bf16*)alloc(MATS / 2);  // A1b/A2b adjacent
    bf16* A2b = (bf16*)alloc(MATS / 2);
    bf16* Crb = (bf16*)alloc(MATS / 2);  // Crb/Clb adjacent (merged launch)
    bf16* Clb = (bf16*)alloc(MATS / 2);
    bf16* yb1 = (bf16*)alloc(HDh);
    bf16* yc  = (bf16*)alloc(HDh);

    // aliases into dead regions
    bf16* A1tb = (bf16*)Smix;            // live steps 3-4 (dead once gates writes Smix)
    bf16* A2tb = ((bf16*)Smix) + MATS;
    bf16* Ab   = (bf16*)S1;              // S1 dead after gates

    const size_t NEED_BYTES = off * sizeof(float);
    if (ws_size < NEED_BYTES) {
        fill_sentinel<<<dim3(3072), 256, 0, stream>>>((unsigned short*)d_out);
        return;
    }

    // 0. normalize inputs
    convert_all<<<dim3(3072), 256, 0, stream>>>(
        d_in[0], d_in[1], d_in[2], d_in[3], d_in[4], d_in[5], d_in[6], d_in[7],
        d_in[8], xb, w1b, w2b, pwb, smallf);

    // 1. merged W transposes; pw transpose; merged QKV; merged v transposes
    transpose_bf16<<<dim3(24, 8, 2), 256, 0, stream>>>(
        (const unsigned short*)w1b, (unsigned short*)w1t, Dc, 3 * Dc, (long)HD, (long)HD);
    transpose_bf16<<<dim3(8, 8, 1), 256, 0, stream>>>(
        (const unsigned short*)pwb, (unsigned short*)pwt, Dc, Dc, 0, 0);
    qkv_mfma<<<dim3(12, 12, 2), 256, 0, stream>>>(
        xb, w1t, w2t, q1b, k1b, v1b, q2b, k2b, v2b);
    transpose_bf16<<<dim3(1, 12, 2 * BHc), 256, 0, stream>>>(
        (const unsigned short*)v1b, (unsigned short*)v1t, Nc, DKc, HSTR, HSTR);

    // 2. S = scale * q @ k^T — single 32-batch launch
    gemm_nt_mfma<0, float><<<dim3(6, 6, 2 * BHc), 256, 0, stream>>>(
        q1b, k1b, S1, Nc, Nc, DKc, HSTR, HSTR, (long)MAT, SCALE);

    // 3. merged softmax S1|S2 -> A1b|A2b; merged transposes -> A1tb|A2tb
    softmax_rows<bf16><<<2 * BHc * Nc, 256, 0, stream>>>(S1, A1b);
    transpose_bf16<<<dim3(12, 12, 2 * BHc), 256, 0, stream>>>(
        (const unsigned short*)A1b, (unsigned short*)A1tb, Nc, Nc, (long)MAT, (long)MAT);

    // 4. Cr|Cl in ONE 32-batch launch (Bt batch = z^16; C regions adjacent)
    gemm_nt_mfma<1, bf16, 1><<<dim3(6, 6, 2 * BHc), 256, 0, stream>>>(
        A1b, A1tb, Crb, Nc, Nc, Nc, (long)MAT, (long)MAT, (long)MAT, 1.f);

    // 5. gates + Smix (4 elem/thread, repacked weights)
    gates_smix<<<dim3(12, 48, BHc), 256, 0, stream>>>(S1, S2, Crb, Clb, Smix, smallf);

    // 6. A = softmax(Smix) -> bf16 (into S1 alias)
    softmax_rows<bf16><<<BHc * Nc, 256, 0, stream>>>(Smix, Ab);

    // 7. merged: transport = A2 @ v2 -> trt (transposed epilogue, z<16)
    //            y_base   = A  @ v1 -> yb1 (z>=16)
    gemm_n64_pair<<<dim3(1, 6, 2 * BHc), 256, 0, stream>>>(
        A2b, v2t, trt, Ab, v1t, yb1, Nc, Nc, (long)MAT, HSTR, HSTR);

    // 8. y_chain GEMM with fused combine + permute -> yc
    gemm_n64_combine<<<dim3(1, 6, BHc), 256, 0, stream>>>(
        A1b, trt, yb1, smallf, yc, Nc, Nc, (long)MAT, HSTR);

    // 9. proj via n64 core, 128x64 tiles (96 blocks)
    proj_n64<<<dim3(8, 12, 1), 256, 0, stream>>>(yc, pwt, d_in[0], d_out);
}

// Round 2
// 488.162 us; speedup vs baseline: 1.0117x; 1.0117x over previous
//
#include <hip/hip_runtime.h>
#include <hip/hip_bf16.h>
#include <math.h>

typedef __hip_bfloat16 bf16;
typedef __attribute__((ext_vector_type(8))) short short8;   // 8 bf16 (4 VGPRs)
typedef __attribute__((ext_vector_type(4))) float f32x4;
#define DEVINL __device__ __forceinline__

constexpr int Bc  = 2;
constexpr int Nc  = 768;
constexpr int Dc  = 512;
constexpr int Hc  = 8;
constexpr int DKc = 64;
constexpr int BHc = Bc * Hc;
constexpr float SCALE    = 0.125f;   // 1/sqrt(64)
constexpr float EPSF     = 1e-6f;
constexpr float BETA_NOT = 0.5f;

DEVINL float ldf(const float* p, long i) { return p[i]; }
DEVINL float ldf(const bf16* p, long i) { return __bfloat162float(p[i]); }
DEVINL void stf(float* p, long i, float v) { p[i] = v; }
DEVINL void stf(bf16* p, long i, float v) { p[i] = __float2bfloat16(v); }

DEVINL float sigf(float x) { return __fdividef(1.f, 1.f + __expf(-x)); }

// async global->LDS, 16B per lane; LDS dest = wave-uniform base + lane*16.
DEVINL void gl_lds16(const void* g, void* l) {
    __builtin_amdgcn_global_load_lds(
        (const __attribute__((address_space(1))) void*)g,
        (__attribute__((address_space(3))) void*)l, 16, 0, 0);
}

// ---------------------------------------------------------------------------
// Dtype sniffer — vectorized (validated round 9).
// ---------------------------------------------------------------------------
DEVINL int sniff_is_fp32(const void* xraw) {
    const uint4* p4 = (const uint4*)xraw;
    float mx = 0.f;
#pragma unroll
    for (int j = 0; j < 16; ++j) {
        const uint4 u = p4[j];
        const unsigned w[4] = {u.x, u.y, u.z, u.w};
#pragma unroll
        for (int t = 0; t < 4; ++t) {
            mx = fmaxf(mx, fabsf(__uint_as_float((w[t] & 0xffffu) << 16)));
            mx = fmaxf(mx, fabsf(__uint_as_float(w[t] & 0xffff0000u)));
        }
    }
    return mx > 1000.f ? 1 : 0;
}

DEVINL float cvt_elem(const void* s, long j, int is32) {
    return is32 ? ((const float*)s)[j]
                : __bfloat162float(((const bf16*)s)[j]);
}

// smallf layout (validated round 12 repack; round-13 keeps it):
//   [  0..127]  u*8 + {w1[u][0..5], b1[u], 0}
//   [128..191]  u*4 + o : conv2_w[o][u]   (transposed)
//   [192..195]  conv2_b[0..3]
//   [196]       chain_logit
__global__ __launch_bounds__(256) void convert_all(
    const void* x, const void* w1, const void* w2, const void* pw,
    const void* c1w, const void* c1b, const void* c2w, const void* c2b,
    const void* ch,
    bf16* xb, bf16* w1b, bf16* w2b, bf16* pwb, float* smallf)
{
    __shared__ int is32s;
    if (threadIdx.x == 0) is32s = sniff_is_fp32(x);
    __syncthreads();
    const int is32 = is32s;
    const long i = (long)blockIdx.x * 256 + threadIdx.x;
    if (i < (long)Bc * Nc * Dc) {
        xb[i]  = __float2bfloat16(cvt_elem(x,  i, is32));
        w1b[i] = __float2bfloat16(cvt_elem(w1, i, is32));
        w2b[i] = __float2bfloat16(cvt_elem(w2, i, is32));
    }
    if (i < (long)Dc * Dc) pwb[i] = __float2bfloat16(cvt_elem(pw, i, is32));
    if (i < 128) {
        const int u = (int)i >> 3, k = (int)i & 7;
        smallf[i] = (k < 6) ? cvt_elem(c1w, u * 6 + k, is32)
                  : (k == 6 ? cvt_elem(c1b, u, is32) : 0.f);
    } else if (i < 192) {
        const int t = (int)i - 128;
        smallf[i] = cvt_elem(c2w, (long)(t & 3) * 16 + (t >> 2), is32);
    } else if (i < 196) smallf[i] = cvt_elem(c2b, i - 192, is32);
    else if (i == 196) smallf[196] = cvt_elem(ch, 0, is32);
    else if (i < 208)  smallf[i] = 0.f;
}

__global__ __launch_bounds__(256) void fill_sentinel(unsigned short* o) {
    const long i = (long)blockIdx.x * 256 + threadIdx.x;
    if (i < (long)Bc * Nc * Dc) o[i] = 0x40E0;  // bf16 7.0
}

// ---------------------------------------------------------------------------
// Generic bf16 transpose, 64x64 tiles: dst[c][r] = src[r][c]; src is (R,C).
// ---------------------------------------------------------------------------
__global__ __launch_bounds__(256) void transpose_bf16(
    const unsigned short* __restrict__ src, unsigned short* __restrict__ dst,
    int R, int C, long sS, long sD)
{
    __shared__ unsigned short tile[64][68];
    const unsigned short* s = src + (long)blockIdx.z * sS;
    unsigned short* d = dst + (long)blockIdx.z * sD;
    const int r0 = blockIdx.y * 64, c0 = blockIdx.x * 64;
    const int t = threadIdx.x;
    const int lr = t >> 4, lc4 = (t & 15) * 4;
#pragma unroll
    for (int i = 0; i < 4; ++i) {
        int r = lr + i * 16;
        *(uint2*)&tile[r][lc4] = *(const uint2*)&s[(long)(r0 + r) * C + c0 + lc4];
    }
    __syncthreads();
#pragma unroll
    for (int i = 0; i < 4; ++i) {
        int r = lr + i * 16;
        unsigned short v[4];
#pragma unroll
        for (int j = 0; j < 4; ++j) v[j] = tile[lc4 + j][r];
        *(uint2*)&d[(long)(c0 + r) * R + r0 + lc4] = *(uint2*)v;
    }
}

// ---------------------------------------------------------------------------
// MFMA bf16 NT GEMM with global_load_lds staging (validated rounds 6-11):
// C = A(M,K) @ Bt(N,K)^T. 128x128 tile, BK=32.
// XORB: B batch index = z^16 (merged Cr/Cl trick; adjacency-dependent).
// ---------------------------------------------------------------------------
template <int EPI, typename TC, int XORB = 0>
__global__ __launch_bounds__(256) void gemm_nt_mfma(
    const bf16* __restrict__ Ag, const bf16* __restrict__ Btg,
    TC* __restrict__ Cg, int M, int N, int K,
    long sA, long sB, long sC, float alpha)
{
    __shared__ unsigned short Asm[128 * 32];
    __shared__ unsigned short Bsm[128 * 32];

    const int tid  = threadIdx.x;
    const int wv   = tid >> 6;
    const int lane = tid & 63;
    const int q    = lane >> 4;
    const int ln   = lane & 15;
    const int wm   = wv & 1;
    const int wn   = wv >> 1;

    const int zb = XORB ? ((int)blockIdx.z ^ 16) : (int)blockIdx.z;
    const bf16* A  = Ag  + (long)blockIdx.z * sA + (long)(blockIdx.y * 128) * K;
    const bf16* Bt = Btg + (long)zb * sB + (long)(blockIdx.x * 128) * K;
    TC*         C  = Cg  + (long)blockIdx.z * sC;

    const int sr = lane >> 2, sc = lane & 3;
    const bf16* gA0 = A  + (long)(wv * 32 + sr)      * K + sc * 8;
    const bf16* gA1 = A  + (long)(wv * 32 + 16 + sr) * K + sc * 8;
    const bf16* gB0 = Bt + (long)(wv * 32 + sr)      * K + sc * 8;
    const bf16* gB1 = Bt + (long)(wv * 32 + 16 + sr) * K + sc * 8;
    unsigned short* lA0 = &Asm[(wv * 32)      * 32];
    unsigned short* lA1 = &Asm[(wv * 32 + 16) * 32];
    unsigned short* lB0 = &Bsm[(wv * 32)      * 32];
    unsigned short* lB1 = &Bsm[(wv * 32 + 16) * 32];

    f32x4 acc[4][4];
#pragma unroll
    for (int i = 0; i < 4; ++i)
#pragma unroll
        for (int j = 0; j < 4; ++j)
            acc[i][j] = (f32x4){0.f, 0.f, 0.f, 0.f};

    for (int k0 = 0; k0 < K; k0 += 32) {
        __syncthreads();
        gl_lds16(gA0 + k0, lA0);
        gl_lds16(gA1 + k0, lA1);
        gl_lds16(gB0 + k0, lB0);
        gl_lds16(gB1 + k0, lB1);
        __syncthreads();

        short8 af[4], bfr[4];
#pragma unroll
        for (int mt = 0; mt < 4; ++mt) {
            int m = wm * 64 + mt * 16 + ln;
            af[mt] = *(const short8*)&Asm[m * 32 + q * 8];
        }
#pragma unroll
        for (int nt = 0; nt < 4; ++nt) {
            int n = wn * 64 + nt * 16 + ln;
            bfr[nt] = *(const short8*)&Bsm[n * 32 + q * 8];
        }
#pragma unroll
        for (int mt = 0; mt < 4; ++mt)
#pragma unroll
            for (int nt = 0; nt < 4; ++nt)
                acc[mt][nt] = __builtin_amdgcn_mfma_f32_16x16x32_bf16(
                    af[mt], bfr[nt], acc[mt][nt], 0, 0, 0);
    }

#pragma unroll
    for (int mt = 0; mt < 4; ++mt) {
#pragma unroll
        for (int nt = 0; nt < 4; ++nt) {
            const int col = blockIdx.x * 128 + wn * 64 + nt * 16 + ln;
            const int rowb = blockIdx.y * 128 + wm * 64 + mt * 16 + q * 4;
#pragma unroll
            for (int r = 0; r < 4; ++r) {
                float v = acc[mt][nt][r] * alpha;
                if (EPI == 1) v = __logf(fmaxf(v, 0.f) + EPSF);
                stf(C, (long)(rowb + r) * N + col, v);
            }
        }
    }
}

// ---------------------------------------------------------------------------
// QKV via MFMA, merged sets (validated rounds 6-11).
// ---------------------------------------------------------------------------
__global__ __launch_bounds__(256) void qkv_mfma(
    const bf16* __restrict__ X,
    const bf16* __restrict__ w1t, const bf16* __restrict__ w2t,
    bf16* __restrict__ q1, bf16* __restrict__ k1, bf16* __restrict__ v1,
    bf16* __restrict__ q2, bf16* __restrict__ k2, bf16* __restrict__ v2)
{
    constexpr int K = Dc;  // 512
    __shared__ unsigned short Asm[128 * 32];
    __shared__ unsigned short Bsm[128 * 32];

    const int tid  = threadIdx.x;
    const int wv   = tid >> 6;
    const int lane = tid & 63;
    const int q    = lane >> 4;
    const int ln   = lane & 15;
    const int wm   = wv & 1;
    const int wn   = wv >> 1;
    const int set  = blockIdx.z;

    const bf16* Wt = set ? w2t : w1t;
    bf16* Q  = set ? q2 : q1;
    bf16* Ko = set ? k2 : k1;
    bf16* V  = set ? v2 : v1;

    const bf16* A  = X  + (long)(blockIdx.y * 128) * K;
    const bf16* Bt = Wt + (long)(blockIdx.x * 128) * K;

    const int sr = lane >> 2, sc = lane & 3;
    const bf16* gA0 = A  + (long)(wv * 32 + sr)      * K + sc * 8;
    const bf16* gA1 = A  + (long)(wv * 32 + 16 + sr) * K + sc * 8;
    const bf16* gB0 = Bt + (long)(wv * 32 + sr)      * K + sc * 8;
    const bf16* gB1 = Bt + (long)(wv * 32 + 16 + sr) * K + sc * 8;
    unsigned short* lA0 = &Asm[(wv * 32)      * 32];
    unsigned short* lA1 = &Asm[(wv * 32 + 16) * 32];
    unsigned short* lB0 = &Bsm[(wv * 32)      * 32];
    unsigned short* lB1 = &Bsm[(wv * 32 + 16) * 32];

    f32x4 acc[4][4];
#pragma unroll
    for (int i = 0; i < 4; ++i)
#pragma unroll
        for (int j = 0; j < 4; ++j)
            acc[i][j] = (f32x4){0.f, 0.f, 0.f, 0.f};

    for (int k0 = 0; k0 < K; k0 += 32) {
        __syncthreads();
        gl_lds16(gA0 + k0, lA0);
        gl_lds16(gA1 + k0, lA1);
        gl_lds16(gB0 + k0, lB0);
        gl_lds16(gB1 + k0, lB1);
        __syncthreads();

        short8 af[4], bfr[4];
#pragma unroll
        for (int mt = 0; mt < 4; ++mt) {
            int m = wm * 64 + mt * 16 + ln;
            af[mt] = *(const short8*)&Asm[m * 32 + q * 8];
        }
#pragma unroll
        for (int nt = 0; nt < 4; ++nt) {
            int n = wn * 64 + nt * 16 + ln;
            bfr[nt] = *(const short8*)&Bsm[n * 32 + q * 8];
        }
#pragma unroll
        for (int mt = 0; mt < 4; ++mt)
#pragma unroll
            for (int nt = 0; nt < 4; ++nt)
                acc[mt][nt] = __builtin_amdgcn_mfma_f32_16x16x32_bf16(
                    af[mt], bfr[nt], acc[mt][nt], 0, 0, 0);
    }

#pragma unroll
    for (int mt = 0; mt < 4; ++mt) {
#pragma unroll
        for (int nt = 0; nt < 4; ++nt) {
            const int col  = blockIdx.x * 128 + wn * 64 + nt * 16 + ln;
            const int rowb = blockIdx.y * 128 + wm * 64 + mt * 16 + q * 4;
            const int t = col >> 9;
            const int h = (col >> 6) & 7;
            const int dk = col & 63;
            bf16* dst = (t == 0) ? Q : (t == 1) ? Ko : V;
#pragma unroll
            for (int r = 0; r < 4; ++r) {
                const int row = rowb + r;
                const int b = row >= Nc ? 1 : 0;
                const int n = row - b * Nc;
                dst[(((long)b * Hc + h) * Nc + n) * DKc + dk] =
                    __float2bfloat16(acc[mt][nt][r]);
            }
        }
    }
}

// ---------------------------------------------------------------------------
// MFMA bf16 NT narrow GEMM core (validated): acc = A(128,K) @ Bt(64,K)^T.
// ---------------------------------------------------------------------------
struct N64Acc { f32x4 acc[2][4]; };

template <typename DUMMY = void>
DEVINL void n64_core(const bf16* A, const bf16* Bt, int K,
                     unsigned short* Asm, unsigned short* Bsm, N64Acc& R)
{
    const int tid  = threadIdx.x;
    const int wave = tid >> 6;
    const int lane = tid & 63;
    const int q    = lane >> 4;
    const int ln   = lane & 15;

    const int sr = tid >> 3, k8 = tid & 7;
    const bf16* pa[4];
    const bf16* pb[2];
    int wa[4], wb[2];
#pragma unroll
    for (int i = 0; i < 4; ++i) {
        pa[i] = A + (long)(sr + i * 32) * K + k8 * 8;
        wa[i] = (sr + i * 32) * 72 + k8 * 8;
    }
#pragma unroll
    for (int i = 0; i < 2; ++i) {
        pb[i] = Bt + (long)(sr + i * 32) * K + k8 * 8;
        wb[i] = (sr + i * 32) * 72 + k8 * 8;
    }

#pragma unroll
    for (int i = 0; i < 2; ++i)
#pragma unroll
        for (int j = 0; j < 4; ++j)
            R.acc[i][j] = (f32x4){0.f, 0.f, 0.f, 0.f};

    for (int k0 = 0; k0 < K; k0 += 64) {
        uint4 va[4], vb[2];
#pragma unroll
        for (int i = 0; i < 4; ++i) va[i] = *(const uint4*)(pa[i] + k0);
#pragma unroll
        for (int i = 0; i < 2; ++i) vb[i] = *(const uint4*)(pb[i] + k0);
        __syncthreads();
#pragma unroll
        for (int i = 0; i < 4; ++i) *(uint4*)&Asm[wa[i]] = va[i];
#pragma unroll
        for (int i = 0; i < 2; ++i) *(uint4*)&Bsm[wb[i]] = vb[i];
        __syncthreads();

#pragma unroll
        for (int kc = 0; kc < 2; ++kc) {
            short8 af[2], bfr[4];
#pragma unroll
            for (int mt = 0; mt < 2; ++mt) {
                int m = wave * 32 + mt * 16 + ln;
                af[mt] = *(const short8*)&Asm[m * 72 + kc * 32 + q * 8];
            }
#pragma unroll
            for (int nt = 0; nt < 4; ++nt) {
                int n = nt * 16 + ln;
                bfr[nt] = *(const short8*)&Bsm[n * 72 + kc * 32 + q * 8];
            }
#pragma unroll
            for (int mt = 0; mt < 2; ++mt)
#pragma unroll
                for (int nt = 0; nt < 4; ++nt)
                    R.acc[mt][nt] = __builtin_amdgcn_mfma_f32_16x16x32_bf16(
                        af[mt], bfr[nt], R.acc[mt][nt], 0, 0, 0);
        }
    }
}

// ---------------------------------------------------------------------------
// Merged pair launch (validated round 11):
//   z <  16: transport = A2 @ v2t -> written TRANSPOSED (64 x Nc) straight to
//            trt via an LDS transpose in the epilogue.
//   z >= 16: y_base = A @ v1t -> normal (Nc x 64) write to yb1.
// ---------------------------------------------------------------------------
__global__ __launch_bounds__(256) void gemm_n64_pair(
    const bf16* __restrict__ A0g, const bf16* __restrict__ B0g, bf16* __restrict__ C0tg,
    const bf16* __restrict__ A1g, const bf16* __restrict__ B1g, bf16* __restrict__ C1g,
    int M, int K, long sA, long sB, long sC)
{
    __shared__ unsigned short Asm[128 * 72];
    __shared__ unsigned short Bsm[64 * 72];

    const int zz = blockIdx.z & 15;
    const int second = blockIdx.z >> 4;
    const bf16* A  = (second ? A1g : A0g) + (long)zz * sA + (long)(blockIdx.y * 128) * K;
    const bf16* Bt = (second ? B1g : B0g) + (long)zz * sB;

    N64Acc R;
    n64_core(A, Bt, K, Asm, Bsm, R);

    const int tid = threadIdx.x;
    const int wave = tid >> 6, lane = tid & 63, q = lane >> 4, ln = lane & 15;

    if (second) {
        bf16* C = C1g + (long)zz * sC;
#pragma unroll
        for (int mt = 0; mt < 2; ++mt) {
#pragma unroll
            for (int nt = 0; nt < 4; ++nt) {
                const int col  = nt * 16 + ln;
                const int rowb = blockIdx.y * 128 + wave * 32 + mt * 16 + q * 4;
#pragma unroll
                for (int r = 0; r < 4; ++r)
                    C[(long)(rowb + r) * 64 + col] = __float2bfloat16(R.acc[mt][nt][r]);
            }
        }
    } else {
        // stage C tile into Asm as [dk][n] (stride 136 -> 16B-aligned rows)
        __syncthreads();   // all waves done reading Asm from the K loop
#pragma unroll
        for (int mt = 0; mt < 2; ++mt) {
#pragma unroll
            for (int nt = 0; nt < 4; ++nt) {
                const int col = nt * 16 + ln;                 // dk
                const int rwb = wave * 32 + mt * 16 + q * 4;  // n within tile
#pragma unroll
                for (int r = 0; r < 4; ++r)
                    *(bf16*)&Asm[col * 136 + rwb + r] = __float2bfloat16(R.acc[mt][nt][r]);
            }
        }
        __syncthreads();
        bf16* Ct = C0tg + (long)zz * sC;
        const int dk  = tid >> 2;
        const int nc0 = (tid & 3) * 32;
        const int gn0 = blockIdx.y * 128;
#pragma unroll
        for (int c8 = 0; c8 < 4; ++c8) {
            uint4 v = *(const uint4*)&Asm[dk * 136 + nc0 + c8 * 8];
            *(uint4*)&Ct[(long)dk * Nc + gn0 + nc0 + c8 * 8] = v;
        }
    }
}

// y_chain GEMM with fused combine + permute (validated rounds 9-11).
__global__ __launch_bounds__(256) void gemm_n64_combine(
    const bf16* __restrict__ A1b, const bf16* __restrict__ trt,
    const bf16* __restrict__ yb1, const float* __restrict__ smallf,
    bf16* __restrict__ yc, int M, int K, long sA, long sB)
{
    __shared__ unsigned short Asm[128 * 72];
    __shared__ unsigned short Bsm[64 * 72];

    const int bh = blockIdx.z;
    const bf16* A  = A1b + (long)bh * sA + (long)(blockIdx.y * 128) * K;
    const bf16* Bt = trt + (long)bh * sB;

    N64Acc R;
    n64_core(A, Bt, K, Asm, Bsm, R);

    const float w = sigf(smallf[196]);
    const int b = bh >> 3, h = bh & 7;
    const long yb1base = (long)bh * Nc * DKc;

    const int tid = threadIdx.x;
    const int wave = tid >> 6, lane = tid & 63, q = lane >> 4, ln = lane & 15;
#pragma unroll
    for (int mt = 0; mt < 2; ++mt) {
#pragma unroll
        for (int nt = 0; nt < 4; ++nt) {
            const int col  = nt * 16 + ln;
            const int rowb = blockIdx.y * 128 + wave * 32 + mt * 16 + q * 4;
#pragma unroll
            for (int r = 0; r < 4; ++r) {
                const int n = rowb + r;
                const float base = __bfloat162float(yb1[yb1base + (long)n * 64 + col]);
                yc[((long)(b * Nc + n)) * Dc + h * DKc + col] =
                    __float2bfloat16(base + w * R.acc[mt][nt][r]);
            }
        }
    }
}

// ---------------------------------------------------------------------------
// Row softmax over width 768 (validated).
// ---------------------------------------------------------------------------
template <typename TO>
__global__ __launch_bounds__(256) void softmax_rows(const float* src, TO* dst)
{
    __shared__ float red[4];
    const long row = blockIdx.x;
    const float* s = src + row * Nc;
    TO* d = dst + row * Nc;
    const int tid = threadIdx.x;

    float v[3];
    float m = -1e30f;
#pragma unroll
    for (int i = 0; i < 3; ++i) { v[i] = s[tid + i * 256]; m = fmaxf(m, v[i]); }

#pragma unroll
    for (int off = 32; off > 0; off >>= 1) m = fmaxf(m, __shfl_down(m, off, 64));
    if ((tid & 63) == 0) red[tid >> 6] = m;
    __syncthreads();
    if (tid == 0) {
        float mm = red[0];
        for (int w = 1; w < 4; ++w) mm = fmaxf(mm, red[w]);
        red[0] = mm;
    }
    __syncthreads();
    m = red[0];
    __syncthreads();

    float e[3];
    float sum = 0.f;
#pragma unroll
    for (int i = 0; i < 3; ++i) { e[i] = __expf(v[i] - m); sum += e[i]; }
#pragma unroll
    for (int off = 32; off > 0; off >>= 1) sum += __shfl_down(sum, off, 64);
    if ((tid & 63) == 0) red[tid >> 6] = sum;
    __syncthreads();
    if (tid == 0) red[0] = red[0] + red[1] + red[2] + red[3];
    __syncthreads();
    const float inv = 1.f / fmaxf(red[0], 1e-30f);
#pragma unroll
    for (int i = 0; i < 3; ++i) stf(d, tid + i * 256, e[i] * inv);
}

// ---------------------------------------------------------------------------
// Gate network + Smix — round 13: EXACT round-9 structure (2 elem/thread,
// 32x17 tiles, VGPR-32 / occ-83% regime — the validated 138-142 µs floor),
// with two VALU-neutral deltas riding on it:
//   (a) repacked weights -> 3x ds_read_b128 per u (was ~11 ds_read_b32)
//   (b) exp2-folded gelu constants (validated bit-compatible in round 12)
// Round-12's 4-elem/thread variant regressed (VGPR 92, occ 22%) — reverted.
// ---------------------------------------------------------------------------
__global__ __launch_bounds__(256) void gates_smix(
    const float* __restrict__ S1g, const float* __restrict__ S2g,
    const bf16* __restrict__ Crg, const bf16* __restrict__ Clg,
    float* __restrict__ Smixg, const float* __restrict__ smallf)
{
    __shared__ float t1t[32][17], t2t[32][17];
    __shared__ float cs[208];

    const long mat = (long)blockIdx.z * Nc * Nc;
    const float* S1 = S1g + mat;
    const float* S2 = S2g + mat;
    const unsigned short* Cr = (const unsigned short*)Crg + mat;
    const unsigned short* Cl = (const unsigned short*)Clg + mat;
    float* Smix = Smixg + mat;

    const int tid = threadIdx.x;
    if (tid < 208) cs[tid] = smallf[tid];

    const int n0 = blockIdx.y * 16, m0 = blockIdx.x * 32;
    {   // transposed tiles: S[m0..m0+31][n0..n0+15], coalesced float2 loads
        const int r = tid >> 3, c2 = (tid & 7) * 2;
        const float2 a = *(const float2*)&S1[(long)(m0 + r) * Nc + n0 + c2];
        const float2 b = *(const float2*)&S2[(long)(m0 + r) * Nc + n0 + c2];
        t1t[r][c2] = a.x; t1t[r][c2 + 1] = a.y;
        t2t[r][c2] = b.x; t2t[r][c2 + 1] = b.y;
    }
    __syncthreads();

    const int tx = tid & 15, ty = tid >> 4;
    const int n = n0 + ty;
    const long idx = (long)n * Nc + m0 + tx * 2;

    const float2 s1v = *(const float2*)&S1[idx];
    const float2 s2v = *(const float2*)&S2[idx];
    const unsigned cru = *(const unsigned*)&Cr[idx];   // idx even -> 4B aligned
    const unsigned clu = *(const unsigned*)&Cl[idx];

    float s1a[2] = {s1v.x, s1v.y};
    float s2a[2] = {s2v.x, s2v.y};
    float cra[2] = {__uint_as_float((cru & 0xffffu) << 16),
                    __uint_as_float(cru & 0xffff0000u)};
    float cla[2] = {__uint_as_float((clu & 0xffffu) << 16),
                    __uint_as_float(clu & 0xffff0000u)};
    float s1t[2], s2t[2];
#pragma unroll
    for (int j = 0; j < 2; ++j) {
        s1t[j] = t1t[tx * 2 + j][ty];
        s2t[j] = t2t[tx * 2 + j][ty];
    }

    float g[4][2];
#pragma unroll
    for (int o = 0; o < 4; ++o)
#pragma unroll
        for (int j = 0; j < 2; ++j) g[o][j] = cs[192 + o];

#pragma unroll
    for (int u = 0; u < 16; ++u) {
        const float4 wa = *(const float4*)&cs[u * 8];        // w0..w3
        const float4 wb = *(const float4*)&cs[u * 8 + 4];    // w4,w5,b1,pad
        const float4 w2 = *(const float4*)&cs[128 + u * 4];  // w2t[o=0..3]
        float hid[2];
#pragma unroll
        for (int j = 0; j < 2; ++j) {
            float h = wb.z;
            h = fmaf(s1a[j], wa.x, h);
            h = fmaf(s2a[j], wa.y, h);
            h = fmaf(s1t[j], wa.z, h);
            h = fmaf(s2t[j], wa.w, h);
            h = fmaf(cra[j], wb.x, h);
            h = fmaf(cla[j], wb.y, h);
            // gelu-tanh via exp2: constants pre-multiplied by log2(e)
            const float hh = h * h;
            const float z2 = h * fmaf(hh, -0.10294357f, -2.30220902f);
            const float e = exp2f(z2);
            hid[j] = h * __fdividef(1.f, 1.f + e);
        }
#pragma unroll
        for (int j = 0; j < 2; ++j) {
            g[0][j] = fmaf(hid[j], w2.x, g[0][j]);
            g[1][j] = fmaf(hid[j], w2.y, g[1][j]);
            g[2][j] = fmaf(hid[j], w2.z, g[2][j]);
            g[3][j] = fmaf(hid[j], w2.w, g[3][j]);
        }
    }

    float out[2];
#pragma unroll
    for (int j = 0; j < 2; ++j) {
        const float ga = sigf(g[0][j]);
        const float go = sigf(g[1][j]);
        const float gn = sigf(g[2][j]);
        const float gc = sigf(g[3][j]);
        const float s1 = s1a[j], s2 = s2a[j];
        const float mx = fmaxf(s1, s2);
        const float lae = mx + __logf(1.f + __expf(-fabsf(s1 - s2)));
        out[j] = s1 + ga * s2 + go * (lae - s1) - gn * (BETA_NOT * s2) + gc * cra[j];
    }
    *(float2*)&Smix[idx] = (float2){out[0], out[1]};
}

// ---------------------------------------------------------------------------
// Final projection via n64 core, 128x64 tiles (validated round 12: 96 blocks
// instead of 48 — proj_mfma left 81% of CUs idle; net ~ -16 µs).
// ---------------------------------------------------------------------------
__global__ __launch_bounds__(256) void proj_n64(
    const bf16* __restrict__ yc, const bf16* __restrict__ pwt,
    const void* __restrict__ xraw, void* __restrict__ out)
{
    constexpr int K = Dc;  // 512
    constexpr int N = Dc;  // 512
    __shared__ unsigned short Asm[128 * 72];
    __shared__ unsigned short Bsm[64 * 72];
    __shared__ int is32s;
    if (threadIdx.x == 0) is32s = sniff_is_fp32(xraw);

    const bf16* A  = yc  + (long)(blockIdx.y * 128) * K;
    const bf16* Bt = pwt + (long)(blockIdx.x * 64) * K;

    N64Acc R;
    n64_core(A, Bt, K, Asm, Bsm, R);   // internal barriers publish is32s

    const int is32 = is32s;
    const int tid = threadIdx.x;
    const int wave = tid >> 6, lane = tid & 63, q = lane >> 4, ln = lane & 15;
#pragma unroll
    for (int mt = 0; mt < 2; ++mt) {
#pragma unroll
        for (int nt = 0; nt < 4; ++nt) {
            const int col  = blockIdx.x * 64 + nt * 16 + ln;
            const int rowb = blockIdx.y * 128 + wave * 32 + mt * 16 + q * 4;
#pragma unroll
            for (int r = 0; r < 4; ++r) {
                const long o = (long)(rowb + r) * N + col;
                if (is32) ((float*)out)[o] = R.acc[mt][nt][r];
                else      ((bf16*)out)[o] = __float2bfloat16(R.acc[mt][nt][r]);
            }
        }
    }
}

// ---------------------------------------------------------------------------
extern "C" void kernel_launch(void* const* d_in, const int* in_sizes, int n_in,
                              void* d_out, int out_size, void* d_ws, size_t ws_size,
                              hipStream_t stream)
{
    const size_t HD   = (size_t)BHc * Nc * DKc;   // 786432
    const size_t HDh  = HD / 2;                   // float-slots for HD bf16
    const size_t MAT  = (size_t)Nc * Nc;          // 589824
    const size_t MATS = (size_t)BHc * MAT;        // 9437184
    const long   HSTR = (long)Nc * DKc;           // 49152 per-head stride

    float* ws = (float*)d_ws;
    size_t off = 0;
    auto alloc = [&](size_t n) { float* p = ws + off; off += n; return p; };

    bf16* xb  = (bf16*)alloc(HDh);
    bf16* w1b = (bf16*)alloc(HDh);   // w1b/w2b adjacent -> merged transpose
    bf16* w2b = (bf16*)alloc(HDh);
    bf16* w1t = (bf16*)alloc(HDh);
    bf16* w2t = (bf16*)alloc(HDh);
    bf16* pwb = (bf16*)alloc((size_t)Dc * Dc / 2);
    bf16* pwt = (bf16*)alloc((size_t)Dc * Dc / 2);
    float* smallf = alloc(256);
    // q1|q2 and k1|k2 adjacent -> single merged S-GEMM launch (32 heads)
    bf16* q1b = (bf16*)alloc(HDh); bf16* q2b = (bf16*)alloc(HDh);
    bf16* k1b = (bf16*)alloc(HDh); bf16* k2b = (bf16*)alloc(HDh);
    bf16* v1b = (bf16*)alloc(HDh); bf16* v2b = (bf16*)alloc(HDh);  // adjacent
    bf16* v1t = (bf16*)alloc(HDh); bf16* v2t = (bf16*)alloc(HDh);  // adjacent
    bf16* trt = (bf16*)alloc(HDh);
    float* S1   = alloc(MATS);       // S1/S2 adjacent -> merged softmax + S-GEMM
    float* S2   = alloc(MATS);
    float* Smix = alloc(MATS);       // region reused: A1tb|A2tb, then Smix
    bf16* A1b = (bf16*)alloc(MATS / 2);  // A1b/A2b adjacent
    bf16* A2b = (bf16*)alloc(MATS / 2);
    bf16* Crb = (bf16*)alloc(MATS / 2);  // Crb/Clb adjacent (merged launch)
    bf16* Clb = (bf16*)alloc(MATS / 2);
    bf16* yb1 = (bf16*)alloc(HDh);
    bf16* yc  = (bf16*)alloc(HDh);

    // aliases into dead regions
    bf16* A1tb = (bf16*)Smix;            // live steps 3-4 (dead once gates writes Smix)
    bf16* A2tb = ((bf16*)Smix) + MATS;
    bf16* Ab   = (bf16*)S1;              // S1 dead after gates

    const size_t NEED_BYTES = off * sizeof(float);
    if (ws_size < NEED_BYTES) {
        fill_sentinel<<<dim3(3072), 256, 0, stream>>>((unsigned short*)d_out);
        return;
    }

    // 0. normalize inputs
    convert_all<<<dim3(3072), 256, 0, stream>>>(
        d_in[0], d_in[1], d_in[2], d_in[3], d_in[4], d_in[5], d_in[6], d_in[7],
        d_in[8], xb, w1b, w2b, pwb, smallf);

    // 1. merged W transposes; pw transpose; merged QKV; merged v transposes
    transpose_bf16<<<dim3(24, 8, 2), 256, 0, stream>>>(
        (const unsigned short*)w1b, (unsigned short*)w1t, Dc, 3 * Dc, (long)HD, (long)HD);
    transpose_bf16<<<dim3(8, 8, 1), 256, 0, stream>>>(
        (const unsigned short*)pwb, (unsigned short*)pwt, Dc, Dc, 0, 0);
    qkv_mfma<<<dim3(12, 12, 2), 256, 0, stream>>>(
        xb, w1t, w2t, q1b, k1b, v1b, q2b, k2b, v2b);
    transpose_bf16<<<dim3(1, 12, 2 * BHc), 256, 0, stream>>>(
        (const unsigned short*)v1b, (unsigned short*)v1t, Nc, DKc, HSTR, HSTR);

    // 2. S = scale * q @ k^T — single 32-batch launch
    gemm_nt_mfma<0, float><<<dim3(6, 6, 2 * BHc), 256, 0, stream>>>(
        q1b, k1b, S1, Nc, Nc, DKc, HSTR, HSTR, (long)MAT, SCALE);

    // 3. merged softmax S1|S2 -> A1b|A2b; merged transposes -> A1tb|A2tb
    softmax_rows<bf16><<<2 * BHc * Nc, 256, 0, stream>>>(S1, A1b);
    transpose_bf16<<<dim3(12, 12, 2 * BHc), 256, 0, stream>>>(
        (const unsigned short*)A1b, (unsigned short*)A1tb, Nc, Nc, (long)MAT, (long)MAT);

    // 4. Cr|Cl in ONE 32-batch launch (Bt batch = z^16; C regions adjacent)
    gemm_nt_mfma<1, bf16, 1><<<dim3(6, 6, 2 * BHc), 256, 0, stream>>>(
        A1b, A1tb, Crb, Nc, Nc, Nc, (long)MAT, (long)MAT, (long)MAT, 1.f);

    // 5. gates + Smix (round-9 structure, repacked weight reads)
    gates_smix<<<dim3(24, 48, BHc), 256, 0, stream>>>(S1, S2, Crb, Clb, Smix, smallf);

    // 6. A = softmax(Smix) -> bf16 (into S1 alias)
    softmax_rows<bf16><<<BHc * Nc, 256, 0, stream>>>(Smix, Ab);

    // 7. merged: transport = A2 @ v2 -> trt (transposed epilogue, z<16)
    //            y_base   = A  @ v1 -> yb1 (z>=16)
    gemm_n64_pair<<<dim3(1, 6, 2 * BHc), 256, 0, stream>>>(
        A2b, v2t, trt, Ab, v1t, yb1, Nc, Nc, (long)MAT, HSTR, HSTR);

    // 8. y_chain GEMM with fused combine + permute -> yc
    gemm_n64_combine<<<dim3(1, 6, BHc), 256, 0, stream>>>(
        A1b, trt, yb1, smallf, yc, Nc, Nc, (long)MAT, HSTR);

    // 9. proj via n64 core, 128x64 tiles (96 blocks)
    proj_n64<<<dim3(8, 12, 1), 256, 0, stream>>>(yc, pwt, d_in[0], d_out);
}

// Round 3
// 431.146 us; speedup vs baseline: 1.1455x; 1.1322x over previous
//
#include <hip/hip_runtime.h>
#include <hip/hip_bf16.h>
#include <math.h>

typedef __hip_bfloat16 bf16;
typedef __attribute__((ext_vector_type(8))) short short8;   // 8 bf16 (4 VGPRs)
typedef __attribute__((ext_vector_type(4))) float f32x4;
typedef __attribute__((ext_vector_type(2))) float f32x2;
#define DEVINL __device__ __forceinline__

constexpr int Bc  = 2;
constexpr int Nc  = 768;
constexpr int Dc  = 512;
constexpr int Hc  = 8;
constexpr int DKc = 64;
constexpr int BHc = Bc * Hc;
constexpr float SCALE    = 0.125f;   // 1/sqrt(64)
constexpr float EPSF     = 1e-6f;
constexpr float BETA_NOT = 0.5f;

DEVINL float ldf(const float* p, long i) { return p[i]; }
DEVINL float ldf(const bf16* p, long i) { return __bfloat162float(p[i]); }
DEVINL void stf(float* p, long i, float v) { p[i] = v; }
DEVINL void stf(bf16* p, long i, float v) { p[i] = __float2bfloat16(v); }

DEVINL float sigf(float x) { return __fdividef(1.f, 1.f + __expf(-x)); }

// packed fp32 pair helpers — backend selects v_pk_fma_f32/v_pk_mul_f32 on
// CDNA (gfx90a+); legalizes to 2 scalar ops if unsupported (no-regression).
DEVINL f32x2 fma2(f32x2 a, f32x2 b, f32x2 c) { return __builtin_elementwise_fma(a, b, c); }
DEVINL f32x2 splat2(float x) { return (f32x2){x, x}; }
// guard-free transcendentals (libm exp2f adds a denormal guard: +13% in r2)
DEVINL float vexp2(float x) { float r; asm("v_exp_f32 %0, %1" : "=v"(r) : "v"(x)); return r; }
DEVINL float vrcp(float x)  { float r; asm("v_rcp_f32 %0, %1" : "=v"(r) : "v"(x)); return r; }

// async global->LDS, 16B per lane; LDS dest = wave-uniform base + lane*16.
DEVINL void gl_lds16(const void* g, void* l) {
    __builtin_amdgcn_global_load_lds(
        (const __attribute__((address_space(1))) void*)g,
        (__attribute__((address_space(3))) void*)l, 16, 0, 0);
}

// ---------------------------------------------------------------------------
// Dtype sniffer — vectorized (validated round 9).
// ---------------------------------------------------------------------------
DEVINL int sniff_is_fp32(const void* xraw) {
    const uint4* p4 = (const uint4*)xraw;
    float mx = 0.f;
#pragma unroll
    for (int j = 0; j < 16; ++j) {
        const uint4 u = p4[j];
        const unsigned w[4] = {u.x, u.y, u.z, u.w};
#pragma unroll
        for (int t = 0; t < 4; ++t) {
            mx = fmaxf(mx, fabsf(__uint_as_float((w[t] & 0xffffu) << 16)));
            mx = fmaxf(mx, fabsf(__uint_as_float(w[t] & 0xffff0000u)));
        }
    }
    return mx > 1000.f ? 1 : 0;
}

DEVINL float cvt_elem(const void* s, long j, int is32) {
    return is32 ? ((const float*)s)[j]
                : __bfloat162float(((const bf16*)s)[j]);
}

// smallf layout (validated round 12 repack):
//   [  0..127]  u*8 + {w1[u][0..5], b1[u], 0}
//   [128..191]  u*4 + o : conv2_w[o][u]   (transposed)
//   [192..195]  conv2_b[0..3]
//   [196]       chain_logit
__global__ __launch_bounds__(256) void convert_all(
    const void* x, const void* w1, const void* w2, const void* pw,
    const void* c1w, const void* c1b, const void* c2w, const void* c2b,
    const void* ch,
    bf16* xb, bf16* w1b, bf16* w2b, bf16* pwb, float* smallf)
{
    __shared__ int is32s;
    if (threadIdx.x == 0) is32s = sniff_is_fp32(x);
    __syncthreads();
    const int is32 = is32s;
    const long i = (long)blockIdx.x * 256 + threadIdx.x;
    if (i < (long)Bc * Nc * Dc) {
        xb[i]  = __float2bfloat16(cvt_elem(x,  i, is32));
        w1b[i] = __float2bfloat16(cvt_elem(w1, i, is32));
        w2b[i] = __float2bfloat16(cvt_elem(w2, i, is32));
    }
    if (i < (long)Dc * Dc) pwb[i] = __float2bfloat16(cvt_elem(pw, i, is32));
    if (i < 128) {
        const int u = (int)i >> 3, k = (int)i & 7;
        smallf[i] = (k < 6) ? cvt_elem(c1w, u * 6 + k, is32)
                  : (k == 6 ? cvt_elem(c1b, u, is32) : 0.f);
    } else if (i < 192) {
        const int t = (int)i - 128;
        smallf[i] = cvt_elem(c2w, (long)(t & 3) * 16 + (t >> 2), is32);
    } else if (i < 196) smallf[i] = cvt_elem(c2b, i - 192, is32);
    else if (i == 196) smallf[196] = cvt_elem(ch, 0, is32);
    else if (i < 208)  smallf[i] = 0.f;
}

__global__ __launch_bounds__(256) void fill_sentinel(unsigned short* o) {
    const long i = (long)blockIdx.x * 256 + threadIdx.x;
    if (i < (long)Bc * Nc * Dc) o[i] = 0x40E0;  // bf16 7.0
}

// ---------------------------------------------------------------------------
// Generic bf16 transpose, 64x64 tiles: dst[c][r] = src[r][c]; src is (R,C).
// ---------------------------------------------------------------------------
__global__ __launch_bounds__(256) void transpose_bf16(
    const unsigned short* __restrict__ src, unsigned short* __restrict__ dst,
    int R, int C, long sS, long sD)
{
    __shared__ unsigned short tile[64][68];
    const unsigned short* s = src + (long)blockIdx.z * sS;
    unsigned short* d = dst + (long)blockIdx.z * sD;
    const int r0 = blockIdx.y * 64, c0 = blockIdx.x * 64;
    const int t = threadIdx.x;
    const int lr = t >> 4, lc4 = (t & 15) * 4;
#pragma unroll
    for (int i = 0; i < 4; ++i) {
        int r = lr + i * 16;
        *(uint2*)&tile[r][lc4] = *(const uint2*)&s[(long)(r0 + r) * C + c0 + lc4];
    }
    __syncthreads();
#pragma unroll
    for (int i = 0; i < 4; ++i) {
        int r = lr + i * 16;
        unsigned short v[4];
#pragma unroll
        for (int j = 0; j < 4; ++j) v[j] = tile[lc4 + j][r];
        *(uint2*)&d[(long)(c0 + r) * R + r0 + lc4] = *(uint2*)v;
    }
}

// ---------------------------------------------------------------------------
// MFMA bf16 NT GEMM with global_load_lds staging (validated rounds 6-11):
// C = A(M,K) @ Bt(N,K)^T. 128x128 tile, BK=32.
// XORB: B batch index = z^16 (merged Cr/Cl trick; adjacency-dependent).
// ---------------------------------------------------------------------------
template <int EPI, typename TC, int XORB = 0>
__global__ __launch_bounds__(256) void gemm_nt_mfma(
    const bf16* __restrict__ Ag, const bf16* __restrict__ Btg,
    TC* __restrict__ Cg, int M, int N, int K,
    long sA, long sB, long sC, float alpha)
{
    __shared__ unsigned short Asm[128 * 32];
    __shared__ unsigned short Bsm[128 * 32];

    const int tid  = threadIdx.x;
    const int wv   = tid >> 6;
    const int lane = tid & 63;
    const int q    = lane >> 4;
    const int ln   = lane & 15;
    const int wm   = wv & 1;
    const int wn   = wv >> 1;

    const int zb = XORB ? ((int)blockIdx.z ^ 16) : (int)blockIdx.z;
    const bf16* A  = Ag  + (long)blockIdx.z * sA + (long)(blockIdx.y * 128) * K;
    const bf16* Bt = Btg + (long)zb * sB + (long)(blockIdx.x * 128) * K;
    TC*         C  = Cg  + (long)blockIdx.z * sC;

    const int sr = lane >> 2, sc = lane & 3;
    const bf16* gA0 = A  + (long)(wv * 32 + sr)      * K + sc * 8;
    const bf16* gA1 = A  + (long)(wv * 32 + 16 + sr) * K + sc * 8;
    const bf16* gB0 = Bt + (long)(wv * 32 + sr)      * K + sc * 8;
    const bf16* gB1 = Bt + (long)(wv * 32 + 16 + sr) * K + sc * 8;
    unsigned short* lA0 = &Asm[(wv * 32)      * 32];
    unsigned short* lA1 = &Asm[(wv * 32 + 16) * 32];
    unsigned short* lB0 = &Bsm[(wv * 32)      * 32];
    unsigned short* lB1 = &Bsm[(wv * 32 + 16) * 32];

    f32x4 acc[4][4];
#pragma unroll
    for (int i = 0; i < 4; ++i)
#pragma unroll
        for (int j = 0; j < 4; ++j)
            acc[i][j] = (f32x4){0.f, 0.f, 0.f, 0.f};

    for (int k0 = 0; k0 < K; k0 += 32) {
        __syncthreads();
        gl_lds16(gA0 + k0, lA0);
        gl_lds16(gA1 + k0, lA1);
        gl_lds16(gB0 + k0, lB0);
        gl_lds16(gB1 + k0, lB1);
        __syncthreads();

        short8 af[4], bfr[4];
#pragma unroll
        for (int mt = 0; mt < 4; ++mt) {
            int m = wm * 64 + mt * 16 + ln;
            af[mt] = *(const short8*)&Asm[m * 32 + q * 8];
        }
#pragma unroll
        for (int nt = 0; nt < 4; ++nt) {
            int n = wn * 64 + nt * 16 + ln;
            bfr[nt] = *(const short8*)&Bsm[n * 32 + q * 8];
        }
#pragma unroll
        for (int mt = 0; mt < 4; ++mt)
#pragma unroll
            for (int nt = 0; nt < 4; ++nt)
                acc[mt][nt] = __builtin_amdgcn_mfma_f32_16x16x32_bf16(
                    af[mt], bfr[nt], acc[mt][nt], 0, 0, 0);
    }

#pragma unroll
    for (int mt = 0; mt < 4; ++mt) {
#pragma unroll
        for (int nt = 0; nt < 4; ++nt) {
            const int col = blockIdx.x * 128 + wn * 64 + nt * 16 + ln;
            const int rowb = blockIdx.y * 128 + wm * 64 + mt * 16 + q * 4;
#pragma unroll
            for (int r = 0; r < 4; ++r) {
                float v = acc[mt][nt][r] * alpha;
                if (EPI == 1) v = __logf(fmaxf(v, 0.f) + EPSF);
                stf(C, (long)(rowb + r) * N + col, v);
            }
        }
    }
}

// ---------------------------------------------------------------------------
// QKV via MFMA, merged sets (validated rounds 6-11).
// ---------------------------------------------------------------------------
__global__ __launch_bounds__(256) void qkv_mfma(
    const bf16* __restrict__ X,
    const bf16* __restrict__ w1t, const bf16* __restrict__ w2t,
    bf16* __restrict__ q1, bf16* __restrict__ k1, bf16* __restrict__ v1,
    bf16* __restrict__ q2, bf16* __restrict__ k2, bf16* __restrict__ v2)
{
    constexpr int K = Dc;  // 512
    __shared__ unsigned short Asm[128 * 32];
    __shared__ unsigned short Bsm[128 * 32];

    const int tid  = threadIdx.x;
    const int wv   = tid >> 6;
    const int lane = tid & 63;
    const int q    = lane >> 4;
    const int ln   = lane & 15;
    const int wm   = wv & 1;
    const int wn   = wv >> 1;
    const int set  = blockIdx.z;

    const bf16* Wt = set ? w2t : w1t;
    bf16* Q  = set ? q2 : q1;
    bf16* Ko = set ? k2 : k1;
    bf16* V  = set ? v2 : v1;

    const bf16* A  = X  + (long)(blockIdx.y * 128) * K;
    const bf16* Bt = Wt + (long)(blockIdx.x * 128) * K;

    const int sr = lane >> 2, sc = lane & 3;
    const bf16* gA0 = A  + (long)(wv * 32 + sr)      * K + sc * 8;
    const bf16* gA1 = A  + (long)(wv * 32 + 16 + sr) * K + sc * 8;
    const bf16* gB0 = Bt + (long)(wv * 32 + sr)      * K + sc * 8;
    const bf16* gB1 = Bt + (long)(wv * 32 + 16 + sr) * K + sc * 8;
    unsigned short* lA0 = &Asm[(wv * 32)      * 32];
    unsigned short* lA1 = &Asm[(wv * 32 + 16) * 32];
    unsigned short* lB0 = &Bsm[(wv * 32)      * 32];
    unsigned short* lB1 = &Bsm[(wv * 32 + 16) * 32];

    f32x4 acc[4][4];
#pragma unroll
    for (int i = 0; i < 4; ++i)
#pragma unroll
        for (int j = 0; j < 4; ++j)
            acc[i][j] = (f32x4){0.f, 0.f, 0.f, 0.f};

    for (int k0 = 0; k0 < K; k0 += 32) {
        __syncthreads();
        gl_lds16(gA0 + k0, lA0);
        gl_lds16(gA1 + k0, lA1);
        gl_lds16(gB0 + k0, lB0);
        gl_lds16(gB1 + k0, lB1);
        __syncthreads();

        short8 af[4], bfr[4];
#pragma unroll
        for (int mt = 0; mt < 4; ++mt) {
            int m = wm * 64 + mt * 16 + ln;
            af[mt] = *(const short8*)&Asm[m * 32 + q * 8];
        }
#pragma unroll
        for (int nt = 0; nt < 4; ++nt) {
            int n = wn * 64 + nt * 16 + ln;
            bfr[nt] = *(const short8*)&Bsm[n * 32 + q * 8];
        }
#pragma unroll
        for (int mt = 0; mt < 4; ++mt)
#pragma unroll
            for (int nt = 0; nt < 4; ++nt)
                acc[mt][nt] = __builtin_amdgcn_mfma_f32_16x16x32_bf16(
                    af[mt], bfr[nt], acc[mt][nt], 0, 0, 0);
    }

#pragma unroll
    for (int mt = 0; mt < 4; ++mt) {
#pragma unroll
        for (int nt = 0; nt < 4; ++nt) {
            const int col  = blockIdx.x * 128 + wn * 64 + nt * 16 + ln;
            const int rowb = blockIdx.y * 128 + wm * 64 + mt * 16 + q * 4;
            const int t = col >> 9;
            const int h = (col >> 6) & 7;
            const int dk = col & 63;
            bf16* dst = (t == 0) ? Q : (t == 1) ? Ko : V;
#pragma unroll
            for (int r = 0; r < 4; ++r) {
                const int row = rowb + r;
                const int b = row >= Nc ? 1 : 0;
                const int n = row - b * Nc;
                dst[(((long)b * Hc + h) * Nc + n) * DKc + dk] =
                    __float2bfloat16(acc[mt][nt][r]);
            }
        }
    }
}

// ---------------------------------------------------------------------------
// MFMA bf16 NT narrow GEMM core (validated): acc = A(128,K) @ Bt(64,K)^T.
// ---------------------------------------------------------------------------
struct N64Acc { f32x4 acc[2][4]; };

template <typename DUMMY = void>
DEVINL void n64_core(const bf16* A, const bf16* Bt, int K,
                     unsigned short* Asm, unsigned short* Bsm, N64Acc& R)
{
    const int tid  = threadIdx.x;
    const int wave = tid >> 6;
    const int lane = tid & 63;
    const int q    = lane >> 4;
    const int ln   = lane & 15;

    const int sr = tid >> 3, k8 = tid & 7;
    const bf16* pa[4];
    const bf16* pb[2];
    int wa[4], wb[2];
#pragma unroll
    for (int i = 0; i < 4; ++i) {
        pa[i] = A + (long)(sr + i * 32) * K + k8 * 8;
        wa[i] = (sr + i * 32) * 72 + k8 * 8;
    }
#pragma unroll
    for (int i = 0; i < 2; ++i) {
        pb[i] = Bt + (long)(sr + i * 32) * K + k8 * 8;
        wb[i] = (sr + i * 32) * 72 + k8 * 8;
    }

#pragma unroll
    for (int i = 0; i < 2; ++i)
#pragma unroll
        for (int j = 0; j < 4; ++j)
            R.acc[i][j] = (f32x4){0.f, 0.f, 0.f, 0.f};

    for (int k0 = 0; k0 < K; k0 += 64) {
        uint4 va[4], vb[2];
#pragma unroll
        for (int i = 0; i < 4; ++i) va[i] = *(const uint4*)(pa[i] + k0);
#pragma unroll
        for (int i = 0; i < 2; ++i) vb[i] = *(const uint4*)(pb[i] + k0);
        __syncthreads();
#pragma unroll
        for (int i = 0; i < 4; ++i) *(uint4*)&Asm[wa[i]] = va[i];
#pragma unroll
        for (int i = 0; i < 2; ++i) *(uint4*)&Bsm[wb[i]] = vb[i];
        __syncthreads();

#pragma unroll
        for (int kc = 0; kc < 2; ++kc) {
            short8 af[2], bfr[4];
#pragma unroll
            for (int mt = 0; mt < 2; ++mt) {
                int m = wave * 32 + mt * 16 + ln;
                af[mt] = *(const short8*)&Asm[m * 72 + kc * 32 + q * 8];
            }
#pragma unroll
            for (int nt = 0; nt < 4; ++nt) {
                int n = nt * 16 + ln;
                bfr[nt] = *(const short8*)&Bsm[n * 72 + kc * 32 + q * 8];
            }
#pragma unroll
            for (int mt = 0; mt < 2; ++mt)
#pragma unroll
                for (int nt = 0; nt < 4; ++nt)
                    R.acc[mt][nt] = __builtin_amdgcn_mfma_f32_16x16x32_bf16(
                        af[mt], bfr[nt], R.acc[mt][nt], 0, 0, 0);
        }
    }
}

// ---------------------------------------------------------------------------
// Merged pair launch (validated round 11):
//   z <  16: transport = A2 @ v2t -> written TRANSPOSED (64 x Nc) straight to
//            trt via an LDS transpose in the epilogue.
//   z >= 16: y_base = A @ v1t -> normal (Nc x 64) write to yb1.
// ---------------------------------------------------------------------------
__global__ __launch_bounds__(256) void gemm_n64_pair(
    const bf16* __restrict__ A0g, const bf16* __restrict__ B0g, bf16* __restrict__ C0tg,
    const bf16* __restrict__ A1g, const bf16* __restrict__ B1g, bf16* __restrict__ C1g,
    int M, int K, long sA, long sB, long sC)
{
    __shared__ unsigned short Asm[128 * 72];
    __shared__ unsigned short Bsm[64 * 72];

    const int zz = blockIdx.z & 15;
    const int second = blockIdx.z >> 4;
    const bf16* A  = (second ? A1g : A0g) + (long)zz * sA + (long)(blockIdx.y * 128) * K;
    const bf16* Bt = (second ? B1g : B0g) + (long)zz * sB;

    N64Acc R;
    n64_core(A, Bt, K, Asm, Bsm, R);

    const int tid = threadIdx.x;
    const int wave = tid >> 6, lane = tid & 63, q = lane >> 4, ln = lane & 15;

    if (second) {
        bf16* C = C1g + (long)zz * sC;
#pragma unroll
        for (int mt = 0; mt < 2; ++mt) {
#pragma unroll
            for (int nt = 0; nt < 4; ++nt) {
                const int col  = nt * 16 + ln;
                const int rowb = blockIdx.y * 128 + wave * 32 + mt * 16 + q * 4;
#pragma unroll
                for (int r = 0; r < 4; ++r)
                    C[(long)(rowb + r) * 64 + col] = __float2bfloat16(R.acc[mt][nt][r]);
            }
        }
    } else {
        // stage C tile into Asm as [dk][n] (stride 136 -> 16B-aligned rows)
        __syncthreads();   // all waves done reading Asm from the K loop
#pragma unroll
        for (int mt = 0; mt < 2; ++mt) {
#pragma unroll
            for (int nt = 0; nt < 4; ++nt) {
                const int col = nt * 16 + ln;                 // dk
                const int rwb = wave * 32 + mt * 16 + q * 4;  // n within tile
#pragma unroll
                for (int r = 0; r < 4; ++r)
                    *(bf16*)&Asm[col * 136 + rwb + r] = __float2bfloat16(R.acc[mt][nt][r]);
            }
        }
        __syncthreads();
        bf16* Ct = C0tg + (long)zz * sC;
        const int dk  = tid >> 2;
        const int nc0 = (tid & 3) * 32;
        const int gn0 = blockIdx.y * 128;
#pragma unroll
        for (int c8 = 0; c8 < 4; ++c8) {
            uint4 v = *(const uint4*)&Asm[dk * 136 + nc0 + c8 * 8];
            *(uint4*)&Ct[(long)dk * Nc + gn0 + nc0 + c8 * 8] = v;
        }
    }
}

// y_chain GEMM with fused combine + permute (validated rounds 9-11).
__global__ __launch_bounds__(256) void gemm_n64_combine(
    const bf16* __restrict__ A1b, const bf16* __restrict__ trt,
    const bf16* __restrict__ yb1, const float* __restrict__ smallf,
    bf16* __restrict__ yc, int M, int K, long sA, long sB)
{
    __shared__ unsigned short Asm[128 * 72];
    __shared__ unsigned short Bsm[64 * 72];

    const int bh = blockIdx.z;
    const bf16* A  = A1b + (long)bh * sA + (long)(blockIdx.y * 128) * K;
    const bf16* Bt = trt + (long)bh * sB;

    N64Acc R;
    n64_core(A, Bt, K, Asm, Bsm, R);

    const float w = sigf(smallf[196]);
    const int b = bh >> 3, h = bh & 7;
    const long yb1base = (long)bh * Nc * DKc;

    const int tid = threadIdx.x;
    const int wave = tid >> 6, lane = tid & 63, q = lane >> 4, ln = lane & 15;
#pragma unroll
    for (int mt = 0; mt < 2; ++mt) {
#pragma unroll
        for (int nt = 0; nt < 4; ++nt) {
            const int col  = nt * 16 + ln;
            const int rowb = blockIdx.y * 128 + wave * 32 + mt * 16 + q * 4;
#pragma unroll
            for (int r = 0; r < 4; ++r) {
                const int n = rowb + r;
                const float base = __bfloat162float(yb1[yb1base + (long)n * 64 + col]);
                yc[((long)(b * Nc + n)) * Dc + h * DKc + col] =
                    __float2bfloat16(base + w * R.acc[mt][nt][r]);
            }
        }
    }
}

// ---------------------------------------------------------------------------
// Row softmax over width 768 (validated).
// ---------------------------------------------------------------------------
template <typename TO>
__global__ __launch_bounds__(256) void softmax_rows(const float* src, TO* dst)
{
    __shared__ float red[4];
    const long row = blockIdx.x;
    const float* s = src + row * Nc;
    TO* d = dst + row * Nc;
    const int tid = threadIdx.x;

    float v[3];
    float m = -1e30f;
#pragma unroll
    for (int i = 0; i < 3; ++i) { v[i] = s[tid + i * 256]; m = fmaxf(m, v[i]); }

#pragma unroll
    for (int off = 32; off > 0; off >>= 1) m = fmaxf(m, __shfl_down(m, off, 64));
    if ((tid & 63) == 0) red[tid >> 6] = m;
    __syncthreads();
    if (tid == 0) {
        float mm = red[0];
        for (int w = 1; w < 4; ++w) mm = fmaxf(mm, red[w]);
        red[0] = mm;
    }
    __syncthreads();
    m = red[0];
    __syncthreads();

    float e[3];
    float sum = 0.f;
#pragma unroll
    for (int i = 0; i < 3; ++i) { e[i] = __expf(v[i] - m); sum += e[i]; }
#pragma unroll
    for (int off = 32; off > 0; off >>= 1) sum += __shfl_down(sum, off, 64);
    if ((tid & 63) == 0) red[tid >> 6] = sum;
    __syncthreads();
    if (tid == 0) red[0] = red[0] + red[1] + red[2] + red[3];
    __syncthreads();
    const float inv = 1.f / fmaxf(red[0], 1e-30f);
#pragma unroll
    for (int i = 0; i < 3; ++i) stf(d, tid + i * 256, e[i] * inv);
}

// ---------------------------------------------------------------------------
// Gate network + Smix — round 14: round-9 structure (2 elem/thread, 32x17
// tiles — the validated VGPR-32/occ-83% regime) with the j=0/1 pair expressed
// as <2 x float> so the backend can select v_pk_fma_f32/v_pk_mul_f32 (VOP3P,
// 2 fp32 ops per issue slot; legalizes to scalar if unsupported). gelu exp is
// guard-free v_exp_f32 asm with base-2-folded constants (r2 lesson: libm
// exp2f's denormal guard cost +13%). Kernel is VALU-issue-bound (r0/r2 A/B).
// ---------------------------------------------------------------------------
__global__ __launch_bounds__(256) void gates_smix(
    const float* __restrict__ S1g, const float* __restrict__ S2g,
    const bf16* __restrict__ Crg, const bf16* __restrict__ Clg,
    float* __restrict__ Smixg, const float* __restrict__ smallf)
{
    __shared__ float t1t[32][17], t2t[32][17];
    __shared__ float cs[208];

    const long mat = (long)blockIdx.z * Nc * Nc;
    const float* S1 = S1g + mat;
    const float* S2 = S2g + mat;
    const unsigned short* Cr = (const unsigned short*)Crg + mat;
    const unsigned short* Cl = (const unsigned short*)Clg + mat;
    float* Smix = Smixg + mat;

    const int tid = threadIdx.x;
    if (tid < 208) cs[tid] = smallf[tid];

    const int n0 = blockIdx.y * 16, m0 = blockIdx.x * 32;
    {   // transposed tiles: S[m0..m0+31][n0..n0+15], coalesced float2 loads
        const int r = tid >> 3, c2 = (tid & 7) * 2;
        const float2 a = *(const float2*)&S1[(long)(m0 + r) * Nc + n0 + c2];
        const float2 b = *(const float2*)&S2[(long)(m0 + r) * Nc + n0 + c2];
        t1t[r][c2] = a.x; t1t[r][c2 + 1] = a.y;
        t2t[r][c2] = b.x; t2t[r][c2 + 1] = b.y;
    }
    __syncthreads();

    const int tx = tid & 15, ty = tid >> 4;
    const int n = n0 + ty;
    const long idx = (long)n * Nc + m0 + tx * 2;

    const float2 s1v = *(const float2*)&S1[idx];
    const float2 s2v = *(const float2*)&S2[idx];
    const unsigned cru = *(const unsigned*)&Cr[idx];   // idx even -> 4B aligned
    const unsigned clu = *(const unsigned*)&Cl[idx];

    const f32x2 s1a = {s1v.x, s1v.y};
    const f32x2 s2a = {s2v.x, s2v.y};
    const f32x2 cra = {__uint_as_float((cru & 0xffffu) << 16),
                       __uint_as_float(cru & 0xffff0000u)};
    const f32x2 cla = {__uint_as_float((clu & 0xffffu) << 16),
                       __uint_as_float(clu & 0xffff0000u)};
    const f32x2 s1t = {t1t[tx * 2][ty], t1t[tx * 2 + 1][ty]};
    const f32x2 s2t = {t2t[tx * 2][ty], t2t[tx * 2 + 1][ty]};

    f32x2 g0 = splat2(cs[192]);
    f32x2 g1 = splat2(cs[193]);
    f32x2 g2 = splat2(cs[194]);
    f32x2 g3 = splat2(cs[195]);

#pragma unroll
    for (int u = 0; u < 16; ++u) {
        const float4 wa = *(const float4*)&cs[u * 8];        // w0..w3
        const float4 wb = *(const float4*)&cs[u * 8 + 4];    // w4,w5,b1,pad
        const float4 w2 = *(const float4*)&cs[128 + u * 4];  // w2t[o=0..3]
        f32x2 h = splat2(wb.z);
        h = fma2(s1a, splat2(wa.x), h);
        h = fma2(s2a, splat2(wa.y), h);
        h = fma2(s1t, splat2(wa.z), h);
        h = fma2(s2t, splat2(wa.w), h);
        h = fma2(cra, splat2(wb.x), h);
        h = fma2(cla, splat2(wb.y), h);
        // gelu-tanh: z2 = h*(c1 + c3*h^2) in base-2 (log2e folded), e = 2^z2
        const f32x2 hh = h * h;
        const f32x2 z2 = h * fma2(hh, splat2(-0.10294357f), splat2(-2.30220902f));
        f32x2 e;
        e[0] = vexp2(z2[0]);
        e[1] = vexp2(z2[1]);
        f32x2 d = splat2(1.f) + e;
        f32x2 rc;
        rc[0] = vrcp(d[0]);
        rc[1] = vrcp(d[1]);
        const f32x2 hid = h * rc;
        g0 = fma2(hid, splat2(w2.x), g0);
        g1 = fma2(hid, splat2(w2.y), g1);
        g2 = fma2(hid, splat2(w2.z), g2);
        g3 = fma2(hid, splat2(w2.w), g3);
    }

    float out[2];
#pragma unroll
    for (int j = 0; j < 2; ++j) {
        const float ga = sigf(g0[j]);
        const float go = sigf(g1[j]);
        const float gn = sigf(g2[j]);
        const float gc = sigf(g3[j]);
        const float s1 = s1a[j], s2 = s2a[j];
        const float mx = fmaxf(s1, s2);
        const float lae = mx + __logf(1.f + __expf(-fabsf(s1 - s2)));
        out[j] = s1 + ga * s2 + go * (lae - s1) - gn * (BETA_NOT * s2) + gc * cra[j];
    }
    *(float2*)&Smix[idx] = (float2){out[0], out[1]};
}

// ---------------------------------------------------------------------------
// Final projection via n64 core, 128x64 tiles (validated round 12: 96 blocks
// instead of 48 — proj_mfma left 81% of CUs idle; net ~ -16 µs).
// ---------------------------------------------------------------------------
__global__ __launch_bounds__(256) void proj_n64(
    const bf16* __restrict__ yc, const bf16* __restrict__ pwt,
    const void* __restrict__ xraw, void* __restrict__ out)
{
    constexpr int K = Dc;  // 512
    constexpr int N = Dc;  // 512
    __shared__ unsigned short Asm[128 * 72];
    __shared__ unsigned short Bsm[64 * 72];
    __shared__ int is32s;
    if (threadIdx.x == 0) is32s = sniff_is_fp32(xraw);

    const bf16* A  = yc  + (long)(blockIdx.y * 128) * K;
    const bf16* Bt = pwt + (long)(blockIdx.x * 64) * K;

    N64Acc R;
    n64_core(A, Bt, K, Asm, Bsm, R);   // internal barriers publish is32s

    const int is32 = is32s;
    const int tid = threadIdx.x;
    const int wave = tid >> 6, lane = tid & 63, q = lane >> 4, ln = lane & 15;
#pragma unroll
    for (int mt = 0; mt < 2; ++mt) {
#pragma unroll
        for (int nt = 0; nt < 4; ++nt) {
            const int col  = blockIdx.x * 64 + nt * 16 + ln;
            const int rowb = blockIdx.y * 128 + wave * 32 + mt * 16 + q * 4;
#pragma unroll
            for (int r = 0; r < 4; ++r) {
                const long o = (long)(rowb + r) * N + col;
                if (is32) ((float*)out)[o] = R.acc[mt][nt][r];
                else      ((bf16*)out)[o] = __float2bfloat16(R.acc[mt][nt][r]);
            }
        }
    }
}

// ---------------------------------------------------------------------------
extern "C" void kernel_launch(void* const* d_in, const int* in_sizes, int n_in,
                              void* d_out, int out_size, void* d_ws, size_t ws_size,
                              hipStream_t stream)
{
    const size_t HD   = (size_t)BHc * Nc * DKc;   // 786432
    const size_t HDh  = HD / 2;                   // float-slots for HD bf16
    const size_t MAT  = (size_t)Nc * Nc;          // 589824
    const size_t MATS = (size_t)BHc * MAT;        // 9437184
    const long   HSTR = (long)Nc * DKc;           // 49152 per-head stride

    float* ws = (float*)d_ws;
    size_t off = 0;
    auto alloc = [&](size_t n) { float* p = ws + off; off += n; return p; };

    bf16* xb  = (bf16*)alloc(HDh);
    bf16* w1b = (bf16*)alloc(HDh);   // w1b/w2b adjacent -> merged transpose
    bf16* w2b = (bf16*)alloc(HDh);
    bf16* w1t = (bf16*)alloc(HDh);
    bf16* w2t = (bf16*)alloc(HDh);
    bf16* pwb = (bf16*)alloc((size_t)Dc * Dc / 2);
    bf16* pwt = (bf16*)alloc((size_t)Dc * Dc / 2);
    float* smallf = alloc(256);
    // q1|q2 and k1|k2 adjacent -> single merged S-GEMM launch (32 heads)
    bf16* q1b = (bf16*)alloc(HDh); bf16* q2b = (bf16*)alloc(HDh);
    bf16* k1b = (bf16*)alloc(HDh); bf16* k2b = (bf16*)alloc(HDh);
    bf16* v1b = (bf16*)alloc(HDh); bf16* v2b = (bf16*)alloc(HDh);  // adjacent
    bf16* v1t = (bf16*)alloc(HDh); bf16* v2t = (bf16*)alloc(HDh);  // adjacent
    bf16* trt = (bf16*)alloc(HDh);
    float* S1   = alloc(MATS);       // S1/S2 adjacent -> merged softmax + S-GEMM
    float* S2   = alloc(MATS);
    float* Smix = alloc(MATS);       // region reused: A1tb|A2tb, then Smix
    bf16* A1b = (bf16*)alloc(MATS / 2);  // A1b/A2b adjacent
    bf16* A2b = (bf16*)alloc(MATS / 2);
    bf16* Crb = (bf16*)alloc(MATS / 2);  // Crb/Clb adjacent (merged launch)
    bf16* Clb = (bf16*)alloc(MATS / 2);
    bf16* yb1 = (bf16*)alloc(HDh);
    bf16* yc  = (bf16*)alloc(HDh);

    // aliases into dead regions
    bf16* A1tb = (bf16*)Smix;            // live steps 3-4 (dead once gates writes Smix)
    bf16* A2tb = ((bf16*)Smix) + MATS;
    bf16* Ab   = (bf16*)S1;              // S1 dead after gates

    const size_t NEED_BYTES = off * sizeof(float);
    if (ws_size < NEED_BYTES) {
        fill_sentinel<<<dim3(3072), 256, 0, stream>>>((unsigned short*)d_out);
        return;
    }

    // 0. normalize inputs
    convert_all<<<dim3(3072), 256, 0, stream>>>(
        d_in[0], d_in[1], d_in[2], d_in[3], d_in[4], d_in[5], d_in[6], d_in[7],
        d_in[8], xb, w1b, w2b, pwb, smallf);

    // 1. merged W transposes; pw transpose; merged QKV; merged v transposes
    transpose_bf16<<<dim3(24, 8, 2), 256, 0, stream>>>(
        (const unsigned short*)w1b, (unsigned short*)w1t, Dc, 3 * Dc, (long)HD, (long)HD);
    transpose_bf16<<<dim3(8, 8, 1), 256, 0, stream>>>(
        (const unsigned short*)pwb, (unsigned short*)pwt, Dc, Dc, 0, 0);
    qkv_mfma<<<dim3(12, 12, 2), 256, 0, stream>>>(
        xb, w1t, w2t, q1b, k1b, v1b, q2b, k2b, v2b);
    transpose_bf16<<<dim3(1, 12, 2 * BHc), 256, 0, stream>>>(
        (const unsigned short*)v1b, (unsigned short*)v1t, Nc, DKc, HSTR, HSTR);

    // 2. S = scale * q @ k^T — single 32-batch launch
    gemm_nt_mfma<0, float><<<dim3(6, 6, 2 * BHc), 256, 0, stream>>>(
        q1b, k1b, S1, Nc, Nc, DKc, HSTR, HSTR, (long)MAT, SCALE);

    // 3. merged softmax S1|S2 -> A1b|A2b; merged transposes -> A1tb|A2tb
    softmax_rows<bf16><<<2 * BHc * Nc, 256, 0, stream>>>(S1, A1b);
    transpose_bf16<<<dim3(12, 12, 2 * BHc), 256, 0, stream>>>(
        (const unsigned short*)A1b, (unsigned short*)A1tb, Nc, Nc, (long)MAT, (long)MAT);

    // 4. Cr|Cl in ONE 32-batch launch (Bt batch = z^16; C regions adjacent)
    gemm_nt_mfma<1, bf16, 1><<<dim3(6, 6, 2 * BHc), 256, 0, stream>>>(
        A1b, A1tb, Crb, Nc, Nc, Nc, (long)MAT, (long)MAT, (long)MAT, 1.f);

    // 5. gates + Smix (round-9 structure + packed-fp32 pair math)
    gates_smix<<<dim3(24, 48, BHc), 256, 0, stream>>>(S1, S2, Crb, Clb, Smix, smallf);

    // 6. A = softmax(Smix) -> bf16 (into S1 alias)
    softmax_rows<bf16><<<BHc * Nc, 256, 0, stream>>>(Smix, Ab);

    // 7. merged: transport = A2 @ v2 -> trt (transposed epilogue, z<16)
    //            y_base   = A  @ v1 -> yb1 (z>=16)
    gemm_n64_pair<<<dim3(1, 6, 2 * BHc), 256, 0, stream>>>(
        A2b, v2t, trt, Ab, v1t, yb1, Nc, Nc, (long)MAT, HSTR, HSTR);

    // 8. y_chain GEMM with fused combine + permute -> yc
    gemm_n64_combine<<<dim3(1, 6, BHc), 256, 0, stream>>>(
        A1b, trt, yb1, smallf, yc, Nc, Nc, (long)MAT, HSTR);

    // 9. proj via n64 core, 128x64 tiles (96 blocks)
    proj_n64<<<dim3(8, 12, 1), 256, 0, stream>>>(yc, pwt, d_in[0], d_out);
}

// Round 4
// 420.972 us; speedup vs baseline: 1.1732x; 1.0242x over previous
//
#include <hip/hip_runtime.h>
#include <hip/hip_bf16.h>
#include <math.h>

typedef __hip_bfloat16 bf16;
typedef __attribute__((ext_vector_type(8))) short short8;   // 8 bf16 (4 VGPRs)
typedef __attribute__((ext_vector_type(4))) float f32x4;
typedef __attribute__((ext_vector_type(2))) float f32x2;
#define DEVINL __device__ __forceinline__

constexpr int Bc  = 2;
constexpr int Nc  = 768;
constexpr int Dc  = 512;
constexpr int Hc  = 8;
constexpr int DKc = 64;
constexpr int BHc = Bc * Hc;
constexpr float SCALE    = 0.125f;   // 1/sqrt(64)
constexpr float EPSF     = 1e-6f;
constexpr float BETA_NOT = 0.5f;

DEVINL float ldf(const float* p, long i) { return p[i]; }
DEVINL float ldf(const bf16* p, long i) { return __bfloat162float(p[i]); }
DEVINL void stf(float* p, long i, float v) { p[i] = v; }
DEVINL void stf(bf16* p, long i, float v) { p[i] = __float2bfloat16(v); }

DEVINL float sigf(float x) { return __fdividef(1.f, 1.f + __expf(-x)); }

// packed fp32 pair helpers — backend selects v_pk_fma_f32/v_pk_mul_f32 (r3:
// validated -41% on gates_smix).
DEVINL f32x2 fma2(f32x2 a, f32x2 b, f32x2 c) { return __builtin_elementwise_fma(a, b, c); }
DEVINL f32x2 splat2(float x) { return (f32x2){x, x}; }
// guard-free transcendentals (libm exp2f adds a denormal guard: +13% in r2)
DEVINL float vexp2(float x) { float r; asm("v_exp_f32 %0, %1" : "=v"(r) : "v"(x)); return r; }
DEVINL float vrcp(float x)  { float r; asm("v_rcp_f32 %0, %1" : "=v"(r) : "v"(x)); return r; }
DEVINL float vlog2(float x) { float r; asm("v_log_f32 %0, %1" : "=v"(r) : "v"(x)); return r; }

// async global->LDS, 16B per lane; LDS dest = wave-uniform base + lane*16.
DEVINL void gl_lds16(const void* g, void* l) {
    __builtin_amdgcn_global_load_lds(
        (const __attribute__((address_space(1))) void*)g,
        (__attribute__((address_space(3))) void*)l, 16, 0, 0);
}

// ---------------------------------------------------------------------------
// Dtype sniffer — vectorized (validated round 9).
// ---------------------------------------------------------------------------
DEVINL int sniff_is_fp32(const void* xraw) {
    const uint4* p4 = (const uint4*)xraw;
    float mx = 0.f;
#pragma unroll
    for (int j = 0; j < 16; ++j) {
        const uint4 u = p4[j];
        const unsigned w[4] = {u.x, u.y, u.z, u.w};
#pragma unroll
        for (int t = 0; t < 4; ++t) {
            mx = fmaxf(mx, fabsf(__uint_as_float((w[t] & 0xffffu) << 16)));
            mx = fmaxf(mx, fabsf(__uint_as_float(w[t] & 0xffff0000u)));
        }
    }
    return mx > 1000.f ? 1 : 0;
}

DEVINL float cvt_elem(const void* s, long j, int is32) {
    return is32 ? ((const float*)s)[j]
                : __bfloat162float(((const bf16*)s)[j]);
}

// smallf layout (round 15 — PAIR-DUPLICATED for v_pk operand broadcast):
//   [u*24 + 2k+{0,1}]  = w1[u][k]          k=0..5   (12 floats)
//   [u*24 + 12..13]    = b1[u] pair
//   [u*24 + 14..15]    = pad
//   [u*24 + 16 + 2o+{0,1}] = conv2_w[o][u] o=0..3   (8 floats)
//   [384..391]  conv2_b[o] pairs
//   [392..393]  chain_logit pair          (combine reads [392])
__global__ __launch_bounds__(256) void convert_all(
    const void* x, const void* w1, const void* w2, const void* pw,
    const void* c1w, const void* c1b, const void* c2w, const void* c2b,
    const void* ch,
    bf16* xb, bf16* w1b, bf16* w2b, bf16* pwb, float* smallf)
{
    __shared__ int is32s;
    if (threadIdx.x == 0) is32s = sniff_is_fp32(x);
    __syncthreads();
    const int is32 = is32s;
    const long i = (long)blockIdx.x * 256 + threadIdx.x;
    if (i < (long)Bc * Nc * Dc) {
        xb[i]  = __float2bfloat16(cvt_elem(x,  i, is32));
        w1b[i] = __float2bfloat16(cvt_elem(w1, i, is32));
        w2b[i] = __float2bfloat16(cvt_elem(w2, i, is32));
    }
    if (i < (long)Dc * Dc) pwb[i] = __float2bfloat16(cvt_elem(pw, i, is32));
    if (i < 384) {
        const int u = (int)i / 24, k = (int)i % 24;
        float v = 0.f;
        if (k < 12)      v = cvt_elem(c1w, u * 6 + (k >> 1), is32);
        else if (k < 14) v = cvt_elem(c1b, u, is32);
        else if (k >= 16) { const int o = (k - 16) >> 1; v = cvt_elem(c2w, o * 16 + u, is32); }
        smallf[i] = v;
    } else if (i < 392) smallf[i] = cvt_elem(c2b, ((int)i - 384) >> 1, is32);
    else if (i < 394) smallf[i] = cvt_elem(ch, 0, is32);
    else if (i < 512) smallf[i] = 0.f;
}

__global__ __launch_bounds__(256) void fill_sentinel(unsigned short* o) {
    const long i = (long)blockIdx.x * 256 + threadIdx.x;
    if (i < (long)Bc * Nc * Dc) o[i] = 0x40E0;  // bf16 7.0
}

// ---------------------------------------------------------------------------
// Generic bf16 transpose, 64x64 tiles: dst[c][r] = src[r][c]; src is (R,C).
// ---------------------------------------------------------------------------
__global__ __launch_bounds__(256) void transpose_bf16(
    const unsigned short* __restrict__ src, unsigned short* __restrict__ dst,
    int R, int C, long sS, long sD)
{
    __shared__ unsigned short tile[64][68];
    const unsigned short* s = src + (long)blockIdx.z * sS;
    unsigned short* d = dst + (long)blockIdx.z * sD;
    const int r0 = blockIdx.y * 64, c0 = blockIdx.x * 64;
    const int t = threadIdx.x;
    const int lr = t >> 4, lc4 = (t & 15) * 4;
#pragma unroll
    for (int i = 0; i < 4; ++i) {
        int r = lr + i * 16;
        *(uint2*)&tile[r][lc4] = *(const uint2*)&s[(long)(r0 + r) * C + c0 + lc4];
    }
    __syncthreads();
#pragma unroll
    for (int i = 0; i < 4; ++i) {
        int r = lr + i * 16;
        unsigned short v[4];
#pragma unroll
        for (int j = 0; j < 4; ++j) v[j] = tile[lc4 + j][r];
        *(uint2*)&d[(long)(c0 + r) * R + r0 + lc4] = *(uint2*)v;
    }
}

// ---------------------------------------------------------------------------
// MFMA bf16 NT GEMM with global_load_lds staging (validated rounds 6-11):
// C = A(M,K) @ Bt(N,K)^T. 128x128 tile, BK=32.
// XORB: B batch index = z^16 (merged Cr/Cl trick; adjacency-dependent).
// ---------------------------------------------------------------------------
template <int EPI, typename TC, int XORB = 0>
__global__ __launch_bounds__(256) void gemm_nt_mfma(
    const bf16* __restrict__ Ag, const bf16* __restrict__ Btg,
    TC* __restrict__ Cg, int M, int N, int K,
    long sA, long sB, long sC, float alpha)
{
    __shared__ unsigned short Asm[128 * 32];
    __shared__ unsigned short Bsm[128 * 32];

    const int tid  = threadIdx.x;
    const int wv   = tid >> 6;
    const int lane = tid & 63;
    const int q    = lane >> 4;
    const int ln   = lane & 15;
    const int wm   = wv & 1;
    const int wn   = wv >> 1;

    const int zb = XORB ? ((int)blockIdx.z ^ 16) : (int)blockIdx.z;
    const bf16* A  = Ag  + (long)blockIdx.z * sA + (long)(blockIdx.y * 128) * K;
    const bf16* Bt = Btg + (long)zb * sB + (long)(blockIdx.x * 128) * K;
    TC*         C  = Cg  + (long)blockIdx.z * sC;

    const int sr = lane >> 2, sc = lane & 3;
    const bf16* gA0 = A  + (long)(wv * 32 + sr)      * K + sc * 8;
    const bf16* gA1 = A  + (long)(wv * 32 + 16 + sr) * K + sc * 8;
    const bf16* gB0 = Bt + (long)(wv * 32 + sr)      * K + sc * 8;
    const bf16* gB1 = Bt + (long)(wv * 32 + 16 + sr) * K + sc * 8;
    unsigned short* lA0 = &Asm[(wv * 32)      * 32];
    unsigned short* lA1 = &Asm[(wv * 32 + 16) * 32];
    unsigned short* lB0 = &Bsm[(wv * 32)      * 32];
    unsigned short* lB1 = &Bsm[(wv * 32 + 16) * 32];

    f32x4 acc[4][4];
#pragma unroll
    for (int i = 0; i < 4; ++i)
#pragma unroll
        for (int j = 0; j < 4; ++j)
            acc[i][j] = (f32x4){0.f, 0.f, 0.f, 0.f};

    for (int k0 = 0; k0 < K; k0 += 32) {
        __syncthreads();
        gl_lds16(gA0 + k0, lA0);
        gl_lds16(gA1 + k0, lA1);
        gl_lds16(gB0 + k0, lB0);
        gl_lds16(gB1 + k0, lB1);
        __syncthreads();

        short8 af[4], bfr[4];
#pragma unroll
        for (int mt = 0; mt < 4; ++mt) {
            int m = wm * 64 + mt * 16 + ln;
            af[mt] = *(const short8*)&Asm[m * 32 + q * 8];
        }
#pragma unroll
        for (int nt = 0; nt < 4; ++nt) {
            int n = wn * 64 + nt * 16 + ln;
            bfr[nt] = *(const short8*)&Bsm[n * 32 + q * 8];
        }
#pragma unroll
        for (int mt = 0; mt < 4; ++mt)
#pragma unroll
            for (int nt = 0; nt < 4; ++nt)
                acc[mt][nt] = __builtin_amdgcn_mfma_f32_16x16x32_bf16(
                    af[mt], bfr[nt], acc[mt][nt], 0, 0, 0);
    }

#pragma unroll
    for (int mt = 0; mt < 4; ++mt) {
#pragma unroll
        for (int nt = 0; nt < 4; ++nt) {
            const int col = blockIdx.x * 128 + wn * 64 + nt * 16 + ln;
            const int rowb = blockIdx.y * 128 + wm * 64 + mt * 16 + q * 4;
#pragma unroll
            for (int r = 0; r < 4; ++r) {
                float v = acc[mt][nt][r] * alpha;
                if (EPI == 1) v = __logf(fmaxf(v, 0.f) + EPSF);
                stf(C, (long)(rowb + r) * N + col, v);
            }
        }
    }
}

// ---------------------------------------------------------------------------
// QKV via MFMA, merged sets (validated rounds 6-11).
// ---------------------------------------------------------------------------
__global__ __launch_bounds__(256) void qkv_mfma(
    const bf16* __restrict__ X,
    const bf16* __restrict__ w1t, const bf16* __restrict__ w2t,
    bf16* __restrict__ q1, bf16* __restrict__ k1, bf16* __restrict__ v1,
    bf16* __restrict__ q2, bf16* __restrict__ k2, bf16* __restrict__ v2)
{
    constexpr int K = Dc;  // 512
    __shared__ unsigned short Asm[128 * 32];
    __shared__ unsigned short Bsm[128 * 32];

    const int tid  = threadIdx.x;
    const int wv   = tid >> 6;
    const int lane = tid & 63;
    const int q    = lane >> 4;
    const int ln   = lane & 15;
    const int wm   = wv & 1;
    const int wn   = wv >> 1;
    const int set  = blockIdx.z;

    const bf16* Wt = set ? w2t : w1t;
    bf16* Q  = set ? q2 : q1;
    bf16* Ko = set ? k2 : k1;
    bf16* V  = set ? v2 : v1;

    const bf16* A  = X  + (long)(blockIdx.y * 128) * K;
    const bf16* Bt = Wt + (long)(blockIdx.x * 128) * K;

    const int sr = lane >> 2, sc = lane & 3;
    const bf16* gA0 = A  + (long)(wv * 32 + sr)      * K + sc * 8;
    const bf16* gA1 = A  + (long)(wv * 32 + 16 + sr) * K + sc * 8;
    const bf16* gB0 = Bt + (long)(wv * 32 + sr)      * K + sc * 8;
    const bf16* gB1 = Bt + (long)(wv * 32 + 16 + sr) * K + sc * 8;
    unsigned short* lA0 = &Asm[(wv * 32)      * 32];
    unsigned short* lA1 = &Asm[(wv * 32 + 16) * 32];
    unsigned short* lB0 = &Bsm[(wv * 32)      * 32];
    unsigned short* lB1 = &Bsm[(wv * 32 + 16) * 32];

    f32x4 acc[4][4];
#pragma unroll
    for (int i = 0; i < 4; ++i)
#pragma unroll
        for (int j = 0; j < 4; ++j)
            acc[i][j] = (f32x4){0.f, 0.f, 0.f, 0.f};

    for (int k0 = 0; k0 < K; k0 += 32) {
        __syncthreads();
        gl_lds16(gA0 + k0, lA0);
        gl_lds16(gA1 + k0, lA1);
        gl_lds16(gB0 + k0, lB0);
        gl_lds16(gB1 + k0, lB1);
        __syncthreads();

        short8 af[4], bfr[4];
#pragma unroll
        for (int mt = 0; mt < 4; ++mt) {
            int m = wm * 64 + mt * 16 + ln;
            af[mt] = *(const short8*)&Asm[m * 32 + q * 8];
        }
#pragma unroll
        for (int nt = 0; nt < 4; ++nt) {
            int n = wn * 64 + nt * 16 + ln;
            bfr[nt] = *(const short8*)&Bsm[n * 32 + q * 8];
        }
#pragma unroll
        for (int mt = 0; mt < 4; ++mt)
#pragma unroll
            for (int nt = 0; nt < 4; ++nt)
                acc[mt][nt] = __builtin_amdgcn_mfma_f32_16x16x32_bf16(
                    af[mt], bfr[nt], acc[mt][nt], 0, 0, 0);
    }

#pragma unroll
    for (int mt = 0; mt < 4; ++mt) {
#pragma unroll
        for (int nt = 0; nt < 4; ++nt) {
            const int col  = blockIdx.x * 128 + wn * 64 + nt * 16 + ln;
            const int rowb = blockIdx.y * 128 + wm * 64 + mt * 16 + q * 4;
            const int t = col >> 9;
            const int h = (col >> 6) & 7;
            const int dk = col & 63;
            bf16* dst = (t == 0) ? Q : (t == 1) ? Ko : V;
#pragma unroll
            for (int r = 0; r < 4; ++r) {
                const int row = rowb + r;
                const int b = row >= Nc ? 1 : 0;
                const int n = row - b * Nc;
                dst[(((long)b * Hc + h) * Nc + n) * DKc + dk] =
                    __float2bfloat16(acc[mt][nt][r]);
            }
        }
    }
}

// ---------------------------------------------------------------------------
// MFMA bf16 NT narrow GEMM core (validated): acc = A(128,K) @ Bt(64,K)^T.
// ---------------------------------------------------------------------------
struct N64Acc { f32x4 acc[2][4]; };

template <typename DUMMY = void>
DEVINL void n64_core(const bf16* A, const bf16* Bt, int K,
                     unsigned short* Asm, unsigned short* Bsm, N64Acc& R)
{
    const int tid  = threadIdx.x;
    const int wave = tid >> 6;
    const int lane = tid & 63;
    const int q    = lane >> 4;
    const int ln   = lane & 15;

    const int sr = tid >> 3, k8 = tid & 7;
    const bf16* pa[4];
    const bf16* pb[2];
    int wa[4], wb[2];
#pragma unroll
    for (int i = 0; i < 4; ++i) {
        pa[i] = A + (long)(sr + i * 32) * K + k8 * 8;
        wa[i] = (sr + i * 32) * 72 + k8 * 8;
    }
#pragma unroll
    for (int i = 0; i < 2; ++i) {
        pb[i] = Bt + (long)(sr + i * 32) * K + k8 * 8;
        wb[i] = (sr + i * 32) * 72 + k8 * 8;
    }

#pragma unroll
    for (int i = 0; i < 2; ++i)
#pragma unroll
        for (int j = 0; j < 4; ++j)
            R.acc[i][j] = (f32x4){0.f, 0.f, 0.f, 0.f};

    for (int k0 = 0; k0 < K; k0 += 64) {
        uint4 va[4], vb[2];
#pragma unroll
        for (int i = 0; i < 4; ++i) va[i] = *(const uint4*)(pa[i] + k0);
#pragma unroll
        for (int i = 0; i < 2; ++i) vb[i] = *(const uint4*)(pb[i] + k0);
        __syncthreads();
#pragma unroll
        for (int i = 0; i < 4; ++i) *(uint4*)&Asm[wa[i]] = va[i];
#pragma unroll
        for (int i = 0; i < 2; ++i) *(uint4*)&Bsm[wb[i]] = vb[i];
        __syncthreads();

#pragma unroll
        for (int kc = 0; kc < 2; ++kc) {
            short8 af[2], bfr[4];
#pragma unroll
            for (int mt = 0; mt < 2; ++mt) {
                int m = wave * 32 + mt * 16 + ln;
                af[mt] = *(const short8*)&Asm[m * 72 + kc * 32 + q * 8];
            }
#pragma unroll
            for (int nt = 0; nt < 4; ++nt) {
                int n = nt * 16 + ln;
                bfr[nt] = *(const short8*)&Bsm[n * 72 + kc * 32 + q * 8];
            }
#pragma unroll
            for (int mt = 0; mt < 2; ++mt)
#pragma unroll
                for (int nt = 0; nt < 4; ++nt)
                    R.acc[mt][nt] = __builtin_amdgcn_mfma_f32_16x16x32_bf16(
                        af[mt], bfr[nt], R.acc[mt][nt], 0, 0, 0);
        }
    }
}

// ---------------------------------------------------------------------------
// Merged pair launch (validated round 11):
//   z <  16: transport = A2 @ v2t -> written TRANSPOSED (64 x Nc) straight to
//            trt via an LDS transpose in the epilogue.
//   z >= 16: y_base = A @ v1t -> normal (Nc x 64) write to yb1.
// ---------------------------------------------------------------------------
__global__ __launch_bounds__(256) void gemm_n64_pair(
    const bf16* __restrict__ A0g, const bf16* __restrict__ B0g, bf16* __restrict__ C0tg,
    const bf16* __restrict__ A1g, const bf16* __restrict__ B1g, bf16* __restrict__ C1g,
    int M, int K, long sA, long sB, long sC)
{
    __shared__ unsigned short Asm[128 * 72];
    __shared__ unsigned short Bsm[64 * 72];

    const int zz = blockIdx.z & 15;
    const int second = blockIdx.z >> 4;
    const bf16* A  = (second ? A1g : A0g) + (long)zz * sA + (long)(blockIdx.y * 128) * K;
    const bf16* Bt = (second ? B1g : B0g) + (long)zz * sB;

    N64Acc R;
    n64_core(A, Bt, K, Asm, Bsm, R);

    const int tid = threadIdx.x;
    const int wave = tid >> 6, lane = tid & 63, q = lane >> 4, ln = lane & 15;

    if (second) {
        bf16* C = C1g + (long)zz * sC;
#pragma unroll
        for (int mt = 0; mt < 2; ++mt) {
#pragma unroll
            for (int nt = 0; nt < 4; ++nt) {
                const int col  = nt * 16 + ln;
                const int rowb = blockIdx.y * 128 + wave * 32 + mt * 16 + q * 4;
#pragma unroll
                for (int r = 0; r < 4; ++r)
                    C[(long)(rowb + r) * 64 + col] = __float2bfloat16(R.acc[mt][nt][r]);
            }
        }
    } else {
        // stage C tile into Asm as [dk][n] (stride 136 -> 16B-aligned rows)
        __syncthreads();   // all waves done reading Asm from the K loop
#pragma unroll
        for (int mt = 0; mt < 2; ++mt) {
#pragma unroll
            for (int nt = 0; nt < 4; ++nt) {
                const int col = nt * 16 + ln;                 // dk
                const int rwb = wave * 32 + mt * 16 + q * 4;  // n within tile
#pragma unroll
                for (int r = 0; r < 4; ++r)
                    *(bf16*)&Asm[col * 136 + rwb + r] = __float2bfloat16(R.acc[mt][nt][r]);
            }
        }
        __syncthreads();
        bf16* Ct = C0tg + (long)zz * sC;
        const int dk  = tid >> 2;
        const int nc0 = (tid & 3) * 32;
        const int gn0 = blockIdx.y * 128;
#pragma unroll
        for (int c8 = 0; c8 < 4; ++c8) {
            uint4 v = *(const uint4*)&Asm[dk * 136 + nc0 + c8 * 8];
            *(uint4*)&Ct[(long)dk * Nc + gn0 + nc0 + c8 * 8] = v;
        }
    }
}

// y_chain GEMM with fused combine + permute (validated rounds 9-11).
__global__ __launch_bounds__(256) void gemm_n64_combine(
    const bf16* __restrict__ A1b, const bf16* __restrict__ trt,
    const bf16* __restrict__ yb1, const float* __restrict__ smallf,
    bf16* __restrict__ yc, int M, int K, long sA, long sB)
{
    __shared__ unsigned short Asm[128 * 72];
    __shared__ unsigned short Bsm[64 * 72];

    const int bh = blockIdx.z;
    const bf16* A  = A1b + (long)bh * sA + (long)(blockIdx.y * 128) * K;
    const bf16* Bt = trt + (long)bh * sB;

    N64Acc R;
    n64_core(A, Bt, K, Asm, Bsm, R);

    const float w = sigf(smallf[392]);
    const int b = bh >> 3, h = bh & 7;
    const long yb1base = (long)bh * Nc * DKc;

    const int tid = threadIdx.x;
    const int wave = tid >> 6, lane = tid & 63, q = lane >> 4, ln = lane & 15;
#pragma unroll
    for (int mt = 0; mt < 2; ++mt) {
#pragma unroll
        for (int nt = 0; nt < 4; ++nt) {
            const int col  = nt * 16 + ln;
            const int rowb = blockIdx.y * 128 + wave * 32 + mt * 16 + q * 4;
#pragma unroll
            for (int r = 0; r < 4; ++r) {
                const int n = rowb + r;
                const float base = __bfloat162float(yb1[yb1base + (long)n * 64 + col]);
                yc[((long)(b * Nc + n)) * Dc + h * DKc + col] =
                    __float2bfloat16(base + w * R.acc[mt][nt][r]);
            }
        }
    }
}

// ---------------------------------------------------------------------------
// Row softmax over width 768 (validated).
// ---------------------------------------------------------------------------
template <typename TO>
__global__ __launch_bounds__(256) void softmax_rows(const float* src, TO* dst)
{
    __shared__ float red[4];
    const long row = blockIdx.x;
    const float* s = src + row * Nc;
    TO* d = dst + row * Nc;
    const int tid = threadIdx.x;

    float v[3];
    float m = -1e30f;
#pragma unroll
    for (int i = 0; i < 3; ++i) { v[i] = s[tid + i * 256]; m = fmaxf(m, v[i]); }

#pragma unroll
    for (int off = 32; off > 0; off >>= 1) m = fmaxf(m, __shfl_down(m, off, 64));
    if ((tid & 63) == 0) red[tid >> 6] = m;
    __syncthreads();
    if (tid == 0) {
        float mm = red[0];
        for (int w = 1; w < 4; ++w) mm = fmaxf(mm, red[w]);
        red[0] = mm;
    }
    __syncthreads();
    m = red[0];
    __syncthreads();

    float e[3];
    float sum = 0.f;
#pragma unroll
    for (int i = 0; i < 3; ++i) { e[i] = __expf(v[i] - m); sum += e[i]; }
#pragma unroll
    for (int off = 32; off > 0; off >>= 1) sum += __shfl_down(sum, off, 64);
    if ((tid & 63) == 0) red[tid >> 6] = sum;
    __syncthreads();
    if (tid == 0) red[0] = red[0] + red[1] + red[2] + red[3];
    __syncthreads();
    const float inv = 1.f / fmaxf(red[0], 1e-30f);
#pragma unroll
    for (int i = 0; i < 3; ++i) stf(d, tid + i * 256, e[i] * inv);
}

// ---------------------------------------------------------------------------
// Gate network + Smix — round 15: round-9 structure + r3's pk-pair math, with
// (a) pair-duplicated weights in LDS (ds_read_b128 lands {w,w} operand pairs
//     directly -> no v_mov splat broadcasts feeding v_pk_fma_f32), and
// (b) fully packed epilogue (sigmoids, logaddexp, mix as f32x2, guard-free
//     v_exp/v_rcp/v_log with base-2 folds — value-identical math).
// Kernel is VALU-issue-bound (r0/r2/r3 A/B chain); must stay VGPR<=64.
// ---------------------------------------------------------------------------
__global__ __launch_bounds__(256) void gates_smix(
    const float* __restrict__ S1g, const float* __restrict__ S2g,
    const bf16* __restrict__ Crg, const bf16* __restrict__ Clg,
    float* __restrict__ Smixg, const float* __restrict__ smallf)
{
    __shared__ float t1t[32][17], t2t[32][17];
    __shared__ float cs[400];

    const long mat = (long)blockIdx.z * Nc * Nc;
    const float* S1 = S1g + mat;
    const float* S2 = S2g + mat;
    const unsigned short* Cr = (const unsigned short*)Crg + mat;
    const unsigned short* Cl = (const unsigned short*)Clg + mat;
    float* Smix = Smixg + mat;

    const int tid = threadIdx.x;
    cs[tid] = smallf[tid];
    if (tid < 144) cs[tid + 256] = smallf[tid + 256];

    const int n0 = blockIdx.y * 16, m0 = blockIdx.x * 32;
    {   // transposed tiles: S[m0..m0+31][n0..n0+15], coalesced float2 loads
        const int r = tid >> 3, c2 = (tid & 7) * 2;
        const float2 a = *(const float2*)&S1[(long)(m0 + r) * Nc + n0 + c2];
        const float2 b = *(const float2*)&S2[(long)(m0 + r) * Nc + n0 + c2];
        t1t[r][c2] = a.x; t1t[r][c2 + 1] = a.y;
        t2t[r][c2] = b.x; t2t[r][c2 + 1] = b.y;
    }
    __syncthreads();

    const int tx = tid & 15, ty = tid >> 4;
    const int n = n0 + ty;
    const long idx = (long)n * Nc + m0 + tx * 2;

    const float2 s1v = *(const float2*)&S1[idx];
    const float2 s2v = *(const float2*)&S2[idx];
    const unsigned cru = *(const unsigned*)&Cr[idx];   // idx even -> 4B aligned
    const unsigned clu = *(const unsigned*)&Cl[idx];

    const f32x2 s1a = {s1v.x, s1v.y};
    const f32x2 s2a = {s2v.x, s2v.y};
    const f32x2 cra = {__uint_as_float((cru & 0xffffu) << 16),
                       __uint_as_float(cru & 0xffff0000u)};
    const f32x2 cla = {__uint_as_float((clu & 0xffffu) << 16),
                       __uint_as_float(clu & 0xffff0000u)};
    const f32x2 s1t = {t1t[tx * 2][ty], t1t[tx * 2 + 1][ty]};
    const f32x2 s2t = {t2t[tx * 2][ty], t2t[tx * 2 + 1][ty]};

    f32x2 g0 = *(const f32x2*)&cs[384];
    f32x2 g1 = *(const f32x2*)&cs[386];
    f32x2 g2 = *(const f32x2*)&cs[388];
    f32x2 g3 = *(const f32x2*)&cs[390];

    const f32x2 gc1  = splat2(-2.30220902f);   // gelu c1 * log2e
    const f32x2 gc3  = splat2(-0.10294357f);   // gelu c3 * log2e
    const f32x2 one2 = splat2(1.f);

#pragma unroll
    for (int u = 0; u < 16; ++u) {
        const f32x2* cw = (const f32x2*)&cs[u * 24];
        // cw[0..5]={w0..w5 pairs}, cw[6]={b1,b1}, cw[8..11]={w2t[0..3] pairs}
        f32x2 h = cw[6];
        h = fma2(s1a, cw[0], h);
        h = fma2(s2a, cw[1], h);
        h = fma2(s1t, cw[2], h);
        h = fma2(s2t, cw[3], h);
        h = fma2(cra, cw[4], h);
        h = fma2(cla, cw[5], h);
        const f32x2 hh = h * h;
        const f32x2 z2 = h * fma2(hh, gc3, gc1);
        f32x2 e;  e[0]  = vexp2(z2[0]); e[1]  = vexp2(z2[1]);
        const f32x2 d = one2 + e;
        f32x2 rc; rc[0] = vrcp(d[0]);   rc[1] = vrcp(d[1]);
        const f32x2 hid = h * rc;
        g0 = fma2(hid, cw[8],  g0);
        g1 = fma2(hid, cw[9],  g1);
        g2 = fma2(hid, cw[10], g2);
        g3 = fma2(hid, cw[11], g3);
    }

    // ---- packed epilogue: 4 sigmoid pairs + logaddexp pair + mix ----
    const f32x2 nl2e = splat2(-1.44269504f);
    const f32x2 ln2v = splat2(0.69314718f);
    auto sig2 = [&](f32x2 x) -> f32x2 {
        const f32x2 t = x * nl2e;
        f32x2 e;  e[0] = vexp2(t[0]); e[1] = vexp2(t[1]);
        const f32x2 d = one2 + e;
        f32x2 r;  r[0] = vrcp(d[0]);  r[1] = vrcp(d[1]);
        return r;
    };
    const f32x2 ga2 = sig2(g0);
    const f32x2 go2 = sig2(g1);
    const f32x2 gn2 = sig2(g2);
    const f32x2 gc2 = sig2(g3);

    const f32x2 dd = s1a - s2a;
    f32x2 ad; ad[0] = fabsf(dd[0]); ad[1] = fabsf(dd[1]);
    const f32x2 t2 = ad * nl2e;                       // -|d| * log2e
    f32x2 ee; ee[0] = vexp2(t2[0]); ee[1] = vexp2(t2[1]);
    const f32x2 lp = one2 + ee;
    f32x2 lg; lg[0] = vlog2(lp[0]); lg[1] = vlog2(lp[1]);
    const f32x2 mx2 = __builtin_elementwise_max(s1a, s2a);
    const f32x2 lae = fma2(lg, ln2v, mx2);            // logaddexp(s1,s2)

    f32x2 o2 = s1a;
    o2 = fma2(ga2, s2a, o2);
    o2 = fma2(go2, lae - s1a, o2);
    o2 = fma2(gn2, s2a * splat2(-BETA_NOT), o2);
    o2 = fma2(gc2, cra, o2);
    *(float2*)&Smix[idx] = (float2){o2[0], o2[1]};
}

// ---------------------------------------------------------------------------
// Final projection via n64 core, 128x64 tiles (validated round 12: 96 blocks
// instead of 48 — proj_mfma left 81% of CUs idle; net ~ -16 µs).
// ---------------------------------------------------------------------------
__global__ __launch_bounds__(256) void proj_n64(
    const bf16* __restrict__ yc, const bf16* __restrict__ pwt,
    const void* __restrict__ xraw, void* __restrict__ out)
{
    constexpr int K = Dc;  // 512
    constexpr int N = Dc;  // 512
    __shared__ unsigned short Asm[128 * 72];
    __shared__ unsigned short Bsm[64 * 72];
    __shared__ int is32s;
    if (threadIdx.x == 0) is32s = sniff_is_fp32(xraw);

    const bf16* A  = yc  + (long)(blockIdx.y * 128) * K;
    const bf16* Bt = pwt + (long)(blockIdx.x * 64) * K;

    N64Acc R;
    n64_core(A, Bt, K, Asm, Bsm, R);   // internal barriers publish is32s

    const int is32 = is32s;
    const int tid = threadIdx.x;
    const int wave = tid >> 6, lane = tid & 63, q = lane >> 4, ln = lane & 15;
#pragma unroll
    for (int mt = 0; mt < 2; ++mt) {
#pragma unroll
        for (int nt = 0; nt < 4; ++nt) {
            const int col  = blockIdx.x * 64 + nt * 16 + ln;
            const int rowb = blockIdx.y * 128 + wave * 32 + mt * 16 + q * 4;
#pragma unroll
            for (int r = 0; r < 4; ++r) {
                const long o = (long)(rowb + r) * N + col;
                if (is32) ((float*)out)[o] = R.acc[mt][nt][r];
                else      ((bf16*)out)[o] = __float2bfloat16(R.acc[mt][nt][r]);
            }
        }
    }
}

// ---------------------------------------------------------------------------
extern "C" void kernel_launch(void* const* d_in, const int* in_sizes, int n_in,
                              void* d_out, int out_size, void* d_ws, size_t ws_size,
                              hipStream_t stream)
{
    const size_t HD   = (size_t)BHc * Nc * DKc;   // 786432
    const size_t HDh  = HD / 2;                   // float-slots for HD bf16
    const size_t MAT  = (size_t)Nc * Nc;          // 589824
    const size_t MATS = (size_t)BHc * MAT;        // 9437184
    const long   HSTR = (long)Nc * DKc;           // 49152 per-head stride

    float* ws = (float*)d_ws;
    size_t off = 0;
    auto alloc = [&](size_t n) { float* p = ws + off; off += n; return p; };

    bf16* xb  = (bf16*)alloc(HDh);
    bf16* w1b = (bf16*)alloc(HDh);   // w1b/w2b adjacent -> merged transpose
    bf16* w2b = (bf16*)alloc(HDh);
    bf16* w1t = (bf16*)alloc(HDh);
    bf16* w2t = (bf16*)alloc(HDh);
    bf16* pwb = (bf16*)alloc((size_t)Dc * Dc / 2);
    bf16* pwt = (bf16*)alloc((size_t)Dc * Dc / 2);
    float* smallf = alloc(512);
    // q1|q2 and k1|k2 adjacent -> single merged S-GEMM launch (32 heads)
    bf16* q1b = (bf16*)alloc(HDh); bf16* q2b = (bf16*)alloc(HDh);
    bf16* k1b = (bf16*)alloc(HDh); bf16* k2b = (bf16*)alloc(HDh);
    bf16* v1b = (bf16*)alloc(HDh); bf16* v2b = (bf16*)alloc(HDh);  // adjacent
    bf16* v1t = (bf16*)alloc(HDh); bf16* v2t = (bf16*)alloc(HDh);  // adjacent
    bf16* trt = (bf16*)alloc(HDh);
    float* S1   = alloc(MATS);       // S1/S2 adjacent -> merged softmax + S-GEMM
    float* S2   = alloc(MATS);
    float* Smix = alloc(MATS);       // region reused: A1tb|A2tb, then Smix
    bf16* A1b = (bf16*)alloc(MATS / 2);  // A1b/A2b adjacent
    bf16* A2b = (bf16*)alloc(MATS / 2);
    bf16* Crb = (bf16*)alloc(MATS / 2);  // Crb/Clb adjacent (merged launch)
    bf16* Clb = (bf16*)alloc(MATS / 2);
    bf16* yb1 = (bf16*)alloc(HDh);
    bf16* yc  = (bf16*)alloc(HDh);

    // aliases into dead regions
    bf16* A1tb = (bf16*)Smix;            // live steps 3-4 (dead once gates writes Smix)
    bf16* A2tb = ((bf16*)Smix) + MATS;
    bf16* Ab   = (bf16*)S1;              // S1 dead after gates

    const size_t NEED_BYTES = off * sizeof(float);
    if (ws_size < NEED_BYTES) {
        fill_sentinel<<<dim3(3072), 256, 0, stream>>>((unsigned short*)d_out);
        return;
    }

    // 0. normalize inputs
    convert_all<<<dim3(3072), 256, 0, stream>>>(
        d_in[0], d_in[1], d_in[2], d_in[3], d_in[4], d_in[5], d_in[6], d_in[7],
        d_in[8], xb, w1b, w2b, pwb, smallf);

    // 1. merged W transposes; pw transpose; merged QKV; merged v transposes
    transpose_bf16<<<dim3(24, 8, 2), 256, 0, stream>>>(
        (const unsigned short*)w1b, (unsigned short*)w1t, Dc, 3 * Dc, (long)HD, (long)HD);
    transpose_bf16<<<dim3(8, 8, 1), 256, 0, stream>>>(
        (const unsigned short*)pwb, (unsigned short*)pwt, Dc, Dc, 0, 0);
    qkv_mfma<<<dim3(12, 12, 2), 256, 0, stream>>>(
        xb, w1t, w2t, q1b, k1b, v1b, q2b, k2b, v2b);
    transpose_bf16<<<dim3(1, 12, 2 * BHc), 256, 0, stream>>>(
        (const unsigned short*)v1b, (unsigned short*)v1t, Nc, DKc, HSTR, HSTR);

    // 2. S = scale * q @ k^T — single 32-batch launch
    gemm_nt_mfma<0, float><<<dim3(6, 6, 2 * BHc), 256, 0, stream>>>(
        q1b, k1b, S1, Nc, Nc, DKc, HSTR, HSTR, (long)MAT, SCALE);

    // 3. merged softmax S1|S2 -> A1b|A2b; merged transposes -> A1tb|A2tb
    softmax_rows<bf16><<<2 * BHc * Nc, 256, 0, stream>>>(S1, A1b);
    transpose_bf16<<<dim3(12, 12, 2 * BHc), 256, 0, stream>>>(
        (const unsigned short*)A1b, (unsigned short*)A1tb, Nc, Nc, (long)MAT, (long)MAT);

    // 4. Cr|Cl in ONE 32-batch launch (Bt batch = z^16; C regions adjacent)
    gemm_nt_mfma<1, bf16, 1><<<dim3(6, 6, 2 * BHc), 256, 0, stream>>>(
        A1b, A1tb, Crb, Nc, Nc, Nc, (long)MAT, (long)MAT, (long)MAT, 1.f);

    // 5. gates + Smix (pair-duplicated weights + packed epilogue)
    gates_smix<<<dim3(24, 48, BHc), 256, 0, stream>>>(S1, S2, Crb, Clb, Smix, smallf);

    // 6. A = softmax(Smix) -> bf16 (into S1 alias)
    softmax_rows<bf16><<<BHc * Nc, 256, 0, stream>>>(Smix, Ab);

    // 7. merged: transport = A2 @ v2 -> trt (transposed epilogue, z<16)
    //            y_base   = A  @ v1 -> yb1 (z>=16)
    gemm_n64_pair<<<dim3(1, 6, 2 * BHc), 256, 0, stream>>>(
        A2b, v2t, trt, Ab, v1t, yb1, Nc, Nc, (long)MAT, HSTR, HSTR);

    // 8. y_chain GEMM with fused combine + permute -> yc
    gemm_n64_combine<<<dim3(1, 6, BHc), 256, 0, stream>>>(
        A1b, trt, yb1, smallf, yc, Nc, Nc, (long)MAT, HSTR);

    // 9. proj via n64 core, 128x64 tiles (96 blocks)
    proj_n64<<<dim3(8, 12, 1), 256, 0, stream>>>(yc, pwt, d_in[0], d_out);
}

// Round 5
// 407.052 us; speedup vs baseline: 1.2133x; 1.0342x over previous
//
#include <hip/hip_runtime.h>
#include <hip/hip_bf16.h>
#include <math.h>

typedef __hip_bfloat16 bf16;
typedef __attribute__((ext_vector_type(8))) short short8;   // 8 bf16 (4 VGPRs)
typedef __attribute__((ext_vector_type(4))) float f32x4;
typedef __attribute__((ext_vector_type(2))) float f32x2;
#define DEVINL __device__ __forceinline__

constexpr int Bc  = 2;
constexpr int Nc  = 768;
constexpr int Dc  = 512;
constexpr int Hc  = 8;
constexpr int DKc = 64;
constexpr int BHc = Bc * Hc;
constexpr float SCALE    = 0.125f;   // 1/sqrt(64)
constexpr float EPSF     = 1e-6f;
constexpr float BETA_NOT = 0.5f;

DEVINL float ldf(const float* p, long i) { return p[i]; }
DEVINL float ldf(const bf16* p, long i) { return __bfloat162float(p[i]); }
DEVINL void stf(float* p, long i, float v) { p[i] = v; }
DEVINL void stf(bf16* p, long i, float v) { p[i] = __float2bfloat16(v); }

DEVINL float sigf(float x) { return __fdividef(1.f, 1.f + __expf(-x)); }

// packed fp32 pair helpers — backend selects v_pk_fma_f32/v_pk_mul_f32 (r3:
// validated -41% on gates_smix; r4 pair-dup operands -12%).
DEVINL f32x2 fma2(f32x2 a, f32x2 b, f32x2 c) { return __builtin_elementwise_fma(a, b, c); }
DEVINL f32x2 splat2(float x) { return (f32x2){x, x}; }
// guard-free transcendentals (libm exp2f adds a denormal guard: +13% in r2)
DEVINL float vexp2(float x) { float r; asm("v_exp_f32 %0, %1" : "=v"(r) : "v"(x)); return r; }
DEVINL float vrcp(float x)  { float r; asm("v_rcp_f32 %0, %1" : "=v"(r) : "v"(x)); return r; }
DEVINL float vlog2(float x) { float r; asm("v_log_f32 %0, %1" : "=v"(r) : "v"(x)); return r; }

// async global->LDS, 16B per lane; LDS dest = wave-uniform base + lane*16.
DEVINL void gl_lds16(const void* g, void* l) {
    __builtin_amdgcn_global_load_lds(
        (const __attribute__((address_space(1))) void*)g,
        (__attribute__((address_space(3))) void*)l, 16, 0, 0);
}

// ---------------------------------------------------------------------------
// Dtype sniffer — vectorized (validated round 9).
// ---------------------------------------------------------------------------
DEVINL int sniff_is_fp32(const void* xraw) {
    const uint4* p4 = (const uint4*)xraw;
    float mx = 0.f;
#pragma unroll
    for (int j = 0; j < 16; ++j) {
        const uint4 u = p4[j];
        const unsigned w[4] = {u.x, u.y, u.z, u.w};
#pragma unroll
        for (int t = 0; t < 4; ++t) {
            mx = fmaxf(mx, fabsf(__uint_as_float((w[t] & 0xffffu) << 16)));
            mx = fmaxf(mx, fabsf(__uint_as_float(w[t] & 0xffff0000u)));
        }
    }
    return mx > 1000.f ? 1 : 0;
}

DEVINL float cvt_elem(const void* s, long j, int is32) {
    return is32 ? ((const float*)s)[j]
                : __bfloat162float(((const bf16*)s)[j]);
}

// smallf layout (round 15 — PAIR-DUPLICATED; round 16 reads it via uniform
// scalar loads, no LDS staging):
//   [u*24 + 2k+{0,1}]  = w1[u][k]          k=0..5   (12 floats)
//   [u*24 + 12..13]    = b1[u] pair
//   [u*24 + 14..15]    = pad
//   [u*24 + 16 + 2o+{0,1}] = conv2_w[o][u] o=0..3   (8 floats)
//   [384..391]  conv2_b[o] pairs
//   [392..393]  chain_logit pair          (combine reads [392])
__global__ __launch_bounds__(256) void convert_all(
    const void* x, const void* w1, const void* w2, const void* pw,
    const void* c1w, const void* c1b, const void* c2w, const void* c2b,
    const void* ch,
    bf16* xb, bf16* w1b, bf16* w2b, bf16* pwb, float* smallf)
{
    __shared__ int is32s;
    if (threadIdx.x == 0) is32s = sniff_is_fp32(x);
    __syncthreads();
    const int is32 = is32s;
    const long i = (long)blockIdx.x * 256 + threadIdx.x;
    if (i < (long)Bc * Nc * Dc) {
        xb[i]  = __float2bfloat16(cvt_elem(x,  i, is32));
        w1b[i] = __float2bfloat16(cvt_elem(w1, i, is32));
        w2b[i] = __float2bfloat16(cvt_elem(w2, i, is32));
    }
    if (i < (long)Dc * Dc) pwb[i] = __float2bfloat16(cvt_elem(pw, i, is32));
    if (i < 384) {
        const int u = (int)i / 24, k = (int)i % 24;
        float v = 0.f;
        if (k < 12)      v = cvt_elem(c1w, u * 6 + (k >> 1), is32);
        else if (k < 14) v = cvt_elem(c1b, u, is32);
        else if (k >= 16) { const int o = (k - 16) >> 1; v = cvt_elem(c2w, o * 16 + u, is32); }
        smallf[i] = v;
    } else if (i < 392) smallf[i] = cvt_elem(c2b, ((int)i - 384) >> 1, is32);
    else if (i < 394) smallf[i] = cvt_elem(ch, 0, is32);
    else if (i < 512) smallf[i] = 0.f;
}

__global__ __launch_bounds__(256) void fill_sentinel(unsigned short* o) {
    const long i = (long)blockIdx.x * 256 + threadIdx.x;
    if (i < (long)Bc * Nc * Dc) o[i] = 0x40E0;  // bf16 7.0
}

// ---------------------------------------------------------------------------
// Generic bf16 transpose, 64x64 tiles: dst[c][r] = src[r][c]; src is (R,C).
// ---------------------------------------------------------------------------
__global__ __launch_bounds__(256) void transpose_bf16(
    const unsigned short* __restrict__ src, unsigned short* __restrict__ dst,
    int R, int C, long sS, long sD)
{
    __shared__ unsigned short tile[64][68];
    const unsigned short* s = src + (long)blockIdx.z * sS;
    unsigned short* d = dst + (long)blockIdx.z * sD;
    const int r0 = blockIdx.y * 64, c0 = blockIdx.x * 64;
    const int t = threadIdx.x;
    const int lr = t >> 4, lc4 = (t & 15) * 4;
#pragma unroll
    for (int i = 0; i < 4; ++i) {
        int r = lr + i * 16;
        *(uint2*)&tile[r][lc4] = *(const uint2*)&s[(long)(r0 + r) * C + c0 + lc4];
    }
    __syncthreads();
#pragma unroll
    for (int i = 0; i < 4; ++i) {
        int r = lr + i * 16;
        unsigned short v[4];
#pragma unroll
        for (int j = 0; j < 4; ++j) v[j] = tile[lc4 + j][r];
        *(uint2*)&d[(long)(c0 + r) * R + r0 + lc4] = *(uint2*)v;
    }
}

// ---------------------------------------------------------------------------
// MFMA bf16 NT GEMM with global_load_lds staging (validated rounds 6-11):
// C = A(M,K) @ Bt(N,K)^T. 128x128 tile, BK=32.
// XORB: B batch index = z^16 (merged Cr/Cl trick; adjacency-dependent).
// ---------------------------------------------------------------------------
template <int EPI, typename TC, int XORB = 0>
__global__ __launch_bounds__(256) void gemm_nt_mfma(
    const bf16* __restrict__ Ag, const bf16* __restrict__ Btg,
    TC* __restrict__ Cg, int M, int N, int K,
    long sA, long sB, long sC, float alpha)
{
    __shared__ unsigned short Asm[128 * 32];
    __shared__ unsigned short Bsm[128 * 32];

    const int tid  = threadIdx.x;
    const int wv   = tid >> 6;
    const int lane = tid & 63;
    const int q    = lane >> 4;
    const int ln   = lane & 15;
    const int wm   = wv & 1;
    const int wn   = wv >> 1;

    const int zb = XORB ? ((int)blockIdx.z ^ 16) : (int)blockIdx.z;
    const bf16* A  = Ag  + (long)blockIdx.z * sA + (long)(blockIdx.y * 128) * K;
    const bf16* Bt = Btg + (long)zb * sB + (long)(blockIdx.x * 128) * K;
    TC*         C  = Cg  + (long)blockIdx.z * sC;

    const int sr = lane >> 2, sc = lane & 3;
    const bf16* gA0 = A  + (long)(wv * 32 + sr)      * K + sc * 8;
    const bf16* gA1 = A  + (long)(wv * 32 + 16 + sr) * K + sc * 8;
    const bf16* gB0 = Bt + (long)(wv * 32 + sr)      * K + sc * 8;
    const bf16* gB1 = Bt + (long)(wv * 32 + 16 + sr) * K + sc * 8;
    unsigned short* lA0 = &Asm[(wv * 32)      * 32];
    unsigned short* lA1 = &Asm[(wv * 32 + 16) * 32];
    unsigned short* lB0 = &Bsm[(wv * 32)      * 32];
    unsigned short* lB1 = &Bsm[(wv * 32 + 16) * 32];

    f32x4 acc[4][4];
#pragma unroll
    for (int i = 0; i < 4; ++i)
#pragma unroll
        for (int j = 0; j < 4; ++j)
            acc[i][j] = (f32x4){0.f, 0.f, 0.f, 0.f};

    for (int k0 = 0; k0 < K; k0 += 32) {
        __syncthreads();
        gl_lds16(gA0 + k0, lA0);
        gl_lds16(gA1 + k0, lA1);
        gl_lds16(gB0 + k0, lB0);
        gl_lds16(gB1 + k0, lB1);
        __syncthreads();

        short8 af[4], bfr[4];
#pragma unroll
        for (int mt = 0; mt < 4; ++mt) {
            int m = wm * 64 + mt * 16 + ln;
            af[mt] = *(const short8*)&Asm[m * 32 + q * 8];
        }
#pragma unroll
        for (int nt = 0; nt < 4; ++nt) {
            int n = wn * 64 + nt * 16 + ln;
            bfr[nt] = *(const short8*)&Bsm[n * 32 + q * 8];
        }
#pragma unroll
        for (int mt = 0; mt < 4; ++mt)
#pragma unroll
            for (int nt = 0; nt < 4; ++nt)
                acc[mt][nt] = __builtin_amdgcn_mfma_f32_16x16x32_bf16(
                    af[mt], bfr[nt], acc[mt][nt], 0, 0, 0);
    }

#pragma unroll
    for (int mt = 0; mt < 4; ++mt) {
#pragma unroll
        for (int nt = 0; nt < 4; ++nt) {
            const int col = blockIdx.x * 128 + wn * 64 + nt * 16 + ln;
            const int rowb = blockIdx.y * 128 + wm * 64 + mt * 16 + q * 4;
#pragma unroll
            for (int r = 0; r < 4; ++r) {
                float v = acc[mt][nt][r] * alpha;
                if (EPI == 1) v = __logf(fmaxf(v, 0.f) + EPSF);
                stf(C, (long)(rowb + r) * N + col, v);
            }
        }
    }
}

// ---------------------------------------------------------------------------
// QKV via MFMA, merged sets (validated rounds 6-11).
// ---------------------------------------------------------------------------
__global__ __launch_bounds__(256) void qkv_mfma(
    const bf16* __restrict__ X,
    const bf16* __restrict__ w1t, const bf16* __restrict__ w2t,
    bf16* __restrict__ q1, bf16* __restrict__ k1, bf16* __restrict__ v1,
    bf16* __restrict__ q2, bf16* __restrict__ k2, bf16* __restrict__ v2)
{
    constexpr int K = Dc;  // 512
    __shared__ unsigned short Asm[128 * 32];
    __shared__ unsigned short Bsm[128 * 32];

    const int tid  = threadIdx.x;
    const int wv   = tid >> 6;
    const int lane = tid & 63;
    const int q    = lane >> 4;
    const int ln   = lane & 15;
    const int wm   = wv & 1;
    const int wn   = wv >> 1;
    const int set  = blockIdx.z;

    const bf16* Wt = set ? w2t : w1t;
    bf16* Q  = set ? q2 : q1;
    bf16* Ko = set ? k2 : k1;
    bf16* V  = set ? v2 : v1;

    const bf16* A  = X  + (long)(blockIdx.y * 128) * K;
    const bf16* Bt = Wt + (long)(blockIdx.x * 128) * K;

    const int sr = lane >> 2, sc = lane & 3;
    const bf16* gA0 = A  + (long)(wv * 32 + sr)      * K + sc * 8;
    const bf16* gA1 = A  + (long)(wv * 32 + 16 + sr) * K + sc * 8;
    const bf16* gB0 = Bt + (long)(wv * 32 + sr)      * K + sc * 8;
    const bf16* gB1 = Bt + (long)(wv * 32 + 16 + sr) * K + sc * 8;
    unsigned short* lA0 = &Asm[(wv * 32)      * 32];
    unsigned short* lA1 = &Asm[(wv * 32 + 16) * 32];
    unsigned short* lB0 = &Bsm[(wv * 32)      * 32];
    unsigned short* lB1 = &Bsm[(wv * 32 + 16) * 32];

    f32x4 acc[4][4];
#pragma unroll
    for (int i = 0; i < 4; ++i)
#pragma unroll
        for (int j = 0; j < 4; ++j)
            acc[i][j] = (f32x4){0.f, 0.f, 0.f, 0.f};

    for (int k0 = 0; k0 < K; k0 += 32) {
        __syncthreads();
        gl_lds16(gA0 + k0, lA0);
        gl_lds16(gA1 + k0, lA1);
        gl_lds16(gB0 + k0, lB0);
        gl_lds16(gB1 + k0, lB1);
        __syncthreads();

        short8 af[4], bfr[4];
#pragma unroll
        for (int mt = 0; mt < 4; ++mt) {
            int m = wm * 64 + mt * 16 + ln;
            af[mt] = *(const short8*)&Asm[m * 32 + q * 8];
        }
#pragma unroll
        for (int nt = 0; nt < 4; ++nt) {
            int n = wn * 64 + nt * 16 + ln;
            bfr[nt] = *(const short8*)&Bsm[n * 32 + q * 8];
        }
#pragma unroll
        for (int mt = 0; mt < 4; ++mt)
#pragma unroll
            for (int nt = 0; nt < 4; ++nt)
                acc[mt][nt] = __builtin_amdgcn_mfma_f32_16x16x32_bf16(
                    af[mt], bfr[nt], acc[mt][nt], 0, 0, 0);
    }

#pragma unroll
    for (int mt = 0; mt < 4; ++mt) {
#pragma unroll
        for (int nt = 0; nt < 4; ++nt) {
            const int col  = blockIdx.x * 128 + wn * 64 + nt * 16 + ln;
            const int rowb = blockIdx.y * 128 + wm * 64 + mt * 16 + q * 4;
            const int t = col >> 9;
            const int h = (col >> 6) & 7;
            const int dk = col & 63;
            bf16* dst = (t == 0) ? Q : (t == 1) ? Ko : V;
#pragma unroll
            for (int r = 0; r < 4; ++r) {
                const int row = rowb + r;
                const int b = row >= Nc ? 1 : 0;
                const int n = row - b * Nc;
                dst[(((long)b * Hc + h) * Nc + n) * DKc + dk] =
                    __float2bfloat16(acc[mt][nt][r]);
            }
        }
    }
}

// ---------------------------------------------------------------------------
// MFMA bf16 NT narrow GEMM core (validated): acc = A(128,K) @ Bt(64,K)^T.
// ---------------------------------------------------------------------------
struct N64Acc { f32x4 acc[2][4]; };

template <typename DUMMY = void>
DEVINL void n64_core(const bf16* A, const bf16* Bt, int K,
                     unsigned short* Asm, unsigned short* Bsm, N64Acc& R)
{
    const int tid  = threadIdx.x;
    const int wave = tid >> 6;
    const int lane = tid & 63;
    const int q    = lane >> 4;
    const int ln   = lane & 15;

    const int sr = tid >> 3, k8 = tid & 7;
    const bf16* pa[4];
    const bf16* pb[2];
    int wa[4], wb[2];
#pragma unroll
    for (int i = 0; i < 4; ++i) {
        pa[i] = A + (long)(sr + i * 32) * K + k8 * 8;
        wa[i] = (sr + i * 32) * 72 + k8 * 8;
    }
#pragma unroll
    for (int i = 0; i < 2; ++i) {
        pb[i] = Bt + (long)(sr + i * 32) * K + k8 * 8;
        wb[i] = (sr + i * 32) * 72 + k8 * 8;
    }

#pragma unroll
    for (int i = 0; i < 2; ++i)
#pragma unroll
        for (int j = 0; j < 4; ++j)
            R.acc[i][j] = (f32x4){0.f, 0.f, 0.f, 0.f};

    for (int k0 = 0; k0 < K; k0 += 64) {
        uint4 va[4], vb[2];
#pragma unroll
        for (int i = 0; i < 4; ++i) va[i] = *(const uint4*)(pa[i] + k0);
#pragma unroll
        for (int i = 0; i < 2; ++i) vb[i] = *(const uint4*)(pb[i] + k0);
        __syncthreads();
#pragma unroll
        for (int i = 0; i < 4; ++i) *(uint4*)&Asm[wa[i]] = va[i];
#pragma unroll
        for (int i = 0; i < 2; ++i) *(uint4*)&Bsm[wb[i]] = vb[i];
        __syncthreads();

#pragma unroll
        for (int kc = 0; kc < 2; ++kc) {
            short8 af[2], bfr[4];
#pragma unroll
            for (int mt = 0; mt < 2; ++mt) {
                int m = wave * 32 + mt * 16 + ln;
                af[mt] = *(const short8*)&Asm[m * 72 + kc * 32 + q * 8];
            }
#pragma unroll
            for (int nt = 0; nt < 4; ++nt) {
                int n = nt * 16 + ln;
                bfr[nt] = *(const short8*)&Bsm[n * 72 + kc * 32 + q * 8];
            }
#pragma unroll
            for (int mt = 0; mt < 2; ++mt)
#pragma unroll
                for (int nt = 0; nt < 4; ++nt)
                    R.acc[mt][nt] = __builtin_amdgcn_mfma_f32_16x16x32_bf16(
                        af[mt], bfr[nt], R.acc[mt][nt], 0, 0, 0);
        }
    }
}

// ---------------------------------------------------------------------------
// Merged pair launch (validated round 11):
//   z <  16: transport = A2 @ v2t -> written TRANSPOSED (64 x Nc) straight to
//            trt via an LDS transpose in the epilogue.
//   z >= 16: y_base = A @ v1t -> normal (Nc x 64) write to yb1.
// ---------------------------------------------------------------------------
__global__ __launch_bounds__(256) void gemm_n64_pair(
    const bf16* __restrict__ A0g, const bf16* __restrict__ B0g, bf16* __restrict__ C0tg,
    const bf16* __restrict__ A1g, const bf16* __restrict__ B1g, bf16* __restrict__ C1g,
    int M, int K, long sA, long sB, long sC)
{
    __shared__ unsigned short Asm[128 * 72];
    __shared__ unsigned short Bsm[64 * 72];

    const int zz = blockIdx.z & 15;
    const int second = blockIdx.z >> 4;
    const bf16* A  = (second ? A1g : A0g) + (long)zz * sA + (long)(blockIdx.y * 128) * K;
    const bf16* Bt = (second ? B1g : B0g) + (long)zz * sB;

    N64Acc R;
    n64_core(A, Bt, K, Asm, Bsm, R);

    const int tid = threadIdx.x;
    const int wave = tid >> 6, lane = tid & 63, q = lane >> 4, ln = lane & 15;

    if (second) {
        bf16* C = C1g + (long)zz * sC;
#pragma unroll
        for (int mt = 0; mt < 2; ++mt) {
#pragma unroll
            for (int nt = 0; nt < 4; ++nt) {
                const int col  = nt * 16 + ln;
                const int rowb = blockIdx.y * 128 + wave * 32 + mt * 16 + q * 4;
#pragma unroll
                for (int r = 0; r < 4; ++r)
                    C[(long)(rowb + r) * 64 + col] = __float2bfloat16(R.acc[mt][nt][r]);
            }
        }
    } else {
        // stage C tile into Asm as [dk][n] (stride 136 -> 16B-aligned rows)
        __syncthreads();   // all waves done reading Asm from the K loop
#pragma unroll
        for (int mt = 0; mt < 2; ++mt) {
#pragma unroll
            for (int nt = 0; nt < 4; ++nt) {
                const int col = nt * 16 + ln;                 // dk
                const int rwb = wave * 32 + mt * 16 + q * 4;  // n within tile
#pragma unroll
                for (int r = 0; r < 4; ++r)
                    *(bf16*)&Asm[col * 136 + rwb + r] = __float2bfloat16(R.acc[mt][nt][r]);
            }
        }
        __syncthreads();
        bf16* Ct = C0tg + (long)zz * sC;
        const int dk  = tid >> 2;
        const int nc0 = (tid & 3) * 32;
        const int gn0 = blockIdx.y * 128;
#pragma unroll
        for (int c8 = 0; c8 < 4; ++c8) {
            uint4 v = *(const uint4*)&Asm[dk * 136 + nc0 + c8 * 8];
            *(uint4*)&Ct[(long)dk * Nc + gn0 + nc0 + c8 * 8] = v;
        }
    }
}

// y_chain GEMM with fused combine + permute (validated rounds 9-11).
__global__ __launch_bounds__(256) void gemm_n64_combine(
    const bf16* __restrict__ A1b, const bf16* __restrict__ trt,
    const bf16* __restrict__ yb1, const float* __restrict__ smallf,
    bf16* __restrict__ yc, int M, int K, long sA, long sB)
{
    __shared__ unsigned short Asm[128 * 72];
    __shared__ unsigned short Bsm[64 * 72];

    const int bh = blockIdx.z;
    const bf16* A  = A1b + (long)bh * sA + (long)(blockIdx.y * 128) * K;
    const bf16* Bt = trt + (long)bh * sB;

    N64Acc R;
    n64_core(A, Bt, K, Asm, Bsm, R);

    const float w = sigf(smallf[392]);
    const int b = bh >> 3, h = bh & 7;
    const long yb1base = (long)bh * Nc * DKc;

    const int tid = threadIdx.x;
    const int wave = tid >> 6, lane = tid & 63, q = lane >> 4, ln = lane & 15;
#pragma unroll
    for (int mt = 0; mt < 2; ++mt) {
#pragma unroll
        for (int nt = 0; nt < 4; ++nt) {
            const int col  = nt * 16 + ln;
            const int rowb = blockIdx.y * 128 + wave * 32 + mt * 16 + q * 4;
#pragma unroll
            for (int r = 0; r < 4; ++r) {
                const int n = rowb + r;
                const float base = __bfloat162float(yb1[yb1base + (long)n * 64 + col]);
                yc[((long)(b * Nc + n)) * Dc + h * DKc + col] =
                    __float2bfloat16(base + w * R.acc[mt][nt][r]);
            }
        }
    }
}

// ---------------------------------------------------------------------------
// Row softmax over width 768 — round 16: wave-per-row (4 rows/block).
// No LDS, no __syncthreads; float4 loads, __shfl_xor reductions, packed
// bf16 stores. Replaces the 1-row/block 5-barrier version.
// ---------------------------------------------------------------------------
__global__ __launch_bounds__(256) void softmax_rows_w(
    const float* __restrict__ src, bf16* __restrict__ dst)
{
    const int wid  = threadIdx.x >> 6;
    const int lane = threadIdx.x & 63;
    const long row = (long)blockIdx.x * 4 + wid;
    const float* s = src + row * Nc;

    float4 v[3];
#pragma unroll
    for (int i = 0; i < 3; ++i)
        v[i] = *(const float4*)&s[i * 256 + lane * 4];

    float m = -1e30f;
#pragma unroll
    for (int i = 0; i < 3; ++i)
        m = fmaxf(m, fmaxf(fmaxf(v[i].x, v[i].y), fmaxf(v[i].z, v[i].w)));
#pragma unroll
    for (int off = 32; off > 0; off >>= 1)
        m = fmaxf(m, __shfl_xor(m, off, 64));

    float e[12];
    float sum = 0.f;
#pragma unroll
    for (int i = 0; i < 3; ++i) {
        e[i * 4 + 0] = __expf(v[i].x - m);
        e[i * 4 + 1] = __expf(v[i].y - m);
        e[i * 4 + 2] = __expf(v[i].z - m);
        e[i * 4 + 3] = __expf(v[i].w - m);
        sum += e[i * 4 + 0] + e[i * 4 + 1] + e[i * 4 + 2] + e[i * 4 + 3];
    }
#pragma unroll
    for (int off = 32; off > 0; off >>= 1)
        sum += __shfl_xor(sum, off, 64);

    const float inv = 1.f / fmaxf(sum, 1e-30f);
    unsigned short* d = (unsigned short*)dst + row * Nc;
#pragma unroll
    for (int i = 0; i < 3; ++i) {
        unsigned short o[4];
#pragma unroll
        for (int j = 0; j < 4; ++j) {
            const bf16 b = __float2bfloat16(e[i * 4 + j] * inv);
            o[j] = *(const unsigned short*)&b;
        }
        *(uint2*)&d[i * 256 + lane * 4] = *(const uint2*)o;
    }
}

// ---------------------------------------------------------------------------
// Gate network + Smix — round 16: r4 structure/math, but weights read from
// GLOBAL smallf with wave-uniform addresses (compiler scalarizes to s_load;
// VOP3P consumes the SGPR pair directly). Removes ~96 wave-uniform DS reads
// per thread-pair — LDS is per-CU shared, the wrong storage class for
// block-invariant constants. Tile staging (per-lane varying) stays in LDS.
// ---------------------------------------------------------------------------
__global__ __launch_bounds__(256) void gates_smix(
    const float* __restrict__ S1g, const float* __restrict__ S2g,
    const bf16* __restrict__ Crg, const bf16* __restrict__ Clg,
    float* __restrict__ Smixg, const float* __restrict__ smallf)
{
    __shared__ float t1t[32][17], t2t[32][17];

    const long mat = (long)blockIdx.z * Nc * Nc;
    const float* S1 = S1g + mat;
    const float* S2 = S2g + mat;
    const unsigned short* Cr = (const unsigned short*)Crg + mat;
    const unsigned short* Cl = (const unsigned short*)Clg + mat;
    float* Smix = Smixg + mat;

    const int tid = threadIdx.x;

    const int n0 = blockIdx.y * 16, m0 = blockIdx.x * 32;
    {   // transposed tiles: S[m0..m0+31][n0..n0+15], coalesced float2 loads
        const int r = tid >> 3, c2 = (tid & 7) * 2;
        const float2 a = *(const float2*)&S1[(long)(m0 + r) * Nc + n0 + c2];
        const float2 b = *(const float2*)&S2[(long)(m0 + r) * Nc + n0 + c2];
        t1t[r][c2] = a.x; t1t[r][c2 + 1] = a.y;
        t2t[r][c2] = b.x; t2t[r][c2 + 1] = b.y;
    }
    __syncthreads();

    const int tx = tid & 15, ty = tid >> 4;
    const int n = n0 + ty;
    const long idx = (long)n * Nc + m0 + tx * 2;

    const float2 s1v = *(const float2*)&S1[idx];
    const float2 s2v = *(const float2*)&S2[idx];
    const unsigned cru = *(const unsigned*)&Cr[idx];   // idx even -> 4B aligned
    const unsigned clu = *(const unsigned*)&Cl[idx];

    const f32x2 s1a = {s1v.x, s1v.y};
    const f32x2 s2a = {s2v.x, s2v.y};
    const f32x2 cra = {__uint_as_float((cru & 0xffffu) << 16),
                       __uint_as_float(cru & 0xffff0000u)};
    const f32x2 cla = {__uint_as_float((clu & 0xffffu) << 16),
                       __uint_as_float(clu & 0xffff0000u)};
    const f32x2 s1t = {t1t[tx * 2][ty], t1t[tx * 2 + 1][ty]};
    const f32x2 s2t = {t2t[tx * 2][ty], t2t[tx * 2 + 1][ty]};

    f32x2 g0 = *(const f32x2*)&smallf[384];
    f32x2 g1 = *(const f32x2*)&smallf[386];
    f32x2 g2 = *(const f32x2*)&smallf[388];
    f32x2 g3 = *(const f32x2*)&smallf[390];

    const f32x2 gc1  = splat2(-2.30220902f);   // gelu c1 * log2e
    const f32x2 gc3  = splat2(-0.10294357f);   // gelu c3 * log2e
    const f32x2 one2 = splat2(1.f);

#pragma unroll
    for (int u = 0; u < 16; ++u) {
        const f32x2* cw = (const f32x2*)&smallf[u * 24];
        // cw[0..5]={w0..w5 pairs}, cw[6]={b1,b1}, cw[8..11]={w2t[0..3] pairs}
        f32x2 h = cw[6];
        h = fma2(s1a, cw[0], h);
        h = fma2(s2a, cw[1], h);
        h = fma2(s1t, cw[2], h);
        h = fma2(s2t, cw[3], h);
        h = fma2(cra, cw[4], h);
        h = fma2(cla, cw[5], h);
        const f32x2 hh = h * h;
        const f32x2 z2 = h * fma2(hh, gc3, gc1);
        f32x2 e;  e[0]  = vexp2(z2[0]); e[1]  = vexp2(z2[1]);
        const f32x2 d = one2 + e;
        f32x2 rc; rc[0] = vrcp(d[0]);   rc[1] = vrcp(d[1]);
        const f32x2 hid = h * rc;
        g0 = fma2(hid, cw[8],  g0);
        g1 = fma2(hid, cw[9],  g1);
        g2 = fma2(hid, cw[10], g2);
        g3 = fma2(hid, cw[11], g3);
    }

    // ---- packed epilogue: 4 sigmoid pairs + logaddexp pair + mix ----
    const f32x2 nl2e = splat2(-1.44269504f);
    const f32x2 ln2v = splat2(0.69314718f);
    auto sig2 = [&](f32x2 x) -> f32x2 {
        const f32x2 t = x * nl2e;
        f32x2 e;  e[0] = vexp2(t[0]); e[1] = vexp2(t[1]);
        const f32x2 d = one2 + e;
        f32x2 r;  r[0] = vrcp(d[0]);  r[1] = vrcp(d[1]);
        return r;
    };
    const f32x2 ga2 = sig2(g0);
    const f32x2 go2 = sig2(g1);
    const f32x2 gn2 = sig2(g2);
    const f32x2 gc2 = sig2(g3);

    const f32x2 dd = s1a - s2a;
    f32x2 ad; ad[0] = fabsf(dd[0]); ad[1] = fabsf(dd[1]);
    const f32x2 t2 = ad * nl2e;                       // -|d| * log2e
    f32x2 ee; ee[0] = vexp2(t2[0]); ee[1] = vexp2(t2[1]);
    const f32x2 lp = one2 + ee;
    f32x2 lg; lg[0] = vlog2(lp[0]); lg[1] = vlog2(lp[1]);
    const f32x2 mx2 = __builtin_elementwise_max(s1a, s2a);
    const f32x2 lae = fma2(lg, ln2v, mx2);            // logaddexp(s1,s2)

    f32x2 o2 = s1a;
    o2 = fma2(ga2, s2a, o2);
    o2 = fma2(go2, lae - s1a, o2);
    o2 = fma2(gn2, s2a * splat2(-BETA_NOT), o2);
    o2 = fma2(gc2, cra, o2);
    *(float2*)&Smix[idx] = (float2){o2[0], o2[1]};
}

// ---------------------------------------------------------------------------
// Final projection via n64 core, 128x64 tiles (validated round 12: 96 blocks
// instead of 48 — proj_mfma left 81% of CUs idle; net ~ -16 µs).
// ---------------------------------------------------------------------------
__global__ __launch_bounds__(256) void proj_n64(
    const bf16* __restrict__ yc, const bf16* __restrict__ pwt,
    const void* __restrict__ xraw, void* __restrict__ out)
{
    constexpr int K = Dc;  // 512
    constexpr int N = Dc;  // 512
    __shared__ unsigned short Asm[128 * 72];
    __shared__ unsigned short Bsm[64 * 72];
    __shared__ int is32s;
    if (threadIdx.x == 0) is32s = sniff_is_fp32(xraw);

    const bf16* A  = yc  + (long)(blockIdx.y * 128) * K;
    const bf16* Bt = pwt + (long)(blockIdx.x * 64) * K;

    N64Acc R;
    n64_core(A, Bt, K, Asm, Bsm, R);   // internal barriers publish is32s

    const int is32 = is32s;
    const int tid = threadIdx.x;
    const int wave = tid >> 6, lane = tid & 63, q = lane >> 4, ln = lane & 15;
#pragma unroll
    for (int mt = 0; mt < 2; ++mt) {
#pragma unroll
        for (int nt = 0; nt < 4; ++nt) {
            const int col  = blockIdx.x * 64 + nt * 16 + ln;
            const int rowb = blockIdx.y * 128 + wave * 32 + mt * 16 + q * 4;
#pragma unroll
            for (int r = 0; r < 4; ++r) {
                const long o = (long)(rowb + r) * N + col;
                if (is32) ((float*)out)[o] = R.acc[mt][nt][r];
                else      ((bf16*)out)[o] = __float2bfloat16(R.acc[mt][nt][r]);
            }
        }
    }
}

// ---------------------------------------------------------------------------
extern "C" void kernel_launch(void* const* d_in, const int* in_sizes, int n_in,
                              void* d_out, int out_size, void* d_ws, size_t ws_size,
                              hipStream_t stream)
{
    const size_t HD   = (size_t)BHc * Nc * DKc;   // 786432
    const size_t HDh  = HD / 2;                   // float-slots for HD bf16
    const size_t MAT  = (size_t)Nc * Nc;          // 589824
    const size_t MATS = (size_t)BHc * MAT;        // 9437184
    const long   HSTR = (long)Nc * DKc;           // 49152 per-head stride

    float* ws = (float*)d_ws;
    size_t off = 0;
    auto alloc = [&](size_t n) { float* p = ws + off; off += n; return p; };

    bf16* xb  = (bf16*)alloc(HDh);
    bf16* w1b = (bf16*)alloc(HDh);   // w1b/w2b adjacent -> merged transpose
    bf16* w2b = (bf16*)alloc(HDh);
    bf16* w1t = (bf16*)alloc(HDh);
    bf16* w2t = (bf16*)alloc(HDh);
    bf16* pwb = (bf16*)alloc((size_t)Dc * Dc / 2);
    bf16* pwt = (bf16*)alloc((size_t)Dc * Dc / 2);
    float* smallf = alloc(512);
    // q1|q2 and k1|k2 adjacent -> single merged S-GEMM launch (32 heads)
    bf16* q1b = (bf16*)alloc(HDh); bf16* q2b = (bf16*)alloc(HDh);
    bf16* k1b = (bf16*)alloc(HDh); bf16* k2b = (bf16*)alloc(HDh);
    bf16* v1b = (bf16*)alloc(HDh); bf16* v2b = (bf16*)alloc(HDh);  // adjacent
    bf16* v1t = (bf16*)alloc(HDh); bf16* v2t = (bf16*)alloc(HDh);  // adjacent
    bf16* trt = (bf16*)alloc(HDh);
    float* S1   = alloc(MATS);       // S1/S2 adjacent -> merged softmax + S-GEMM
    float* S2   = alloc(MATS);
    float* Smix = alloc(MATS);       // region reused: A1tb|A2tb, then Smix
    bf16* A1b = (bf16*)alloc(MATS / 2);  // A1b/A2b adjacent
    bf16* A2b = (bf16*)alloc(MATS / 2);
    bf16* Crb = (bf16*)alloc(MATS / 2);  // Crb/Clb adjacent (merged launch)
    bf16* Clb = (bf16*)alloc(MATS / 2);
    bf16* yb1 = (bf16*)alloc(HDh);
    bf16* yc  = (bf16*)alloc(HDh);

    // aliases into dead regions
    bf16* A1tb = (bf16*)Smix;            // live steps 3-4 (dead once gates writes Smix)
    bf16* A2tb = ((bf16*)Smix) + MATS;
    bf16* Ab   = (bf16*)S1;              // S1 dead after gates

    const size_t NEED_BYTES = off * sizeof(float);
    if (ws_size < NEED_BYTES) {
        fill_sentinel<<<dim3(3072), 256, 0, stream>>>((unsigned short*)d_out);
        return;
    }

    // 0. normalize inputs
    convert_all<<<dim3(3072), 256, 0, stream>>>(
        d_in[0], d_in[1], d_in[2], d_in[3], d_in[4], d_in[5], d_in[6], d_in[7],
        d_in[8], xb, w1b, w2b, pwb, smallf);

    // 1. merged W transposes; pw transpose; merged QKV; merged v transposes
    transpose_bf16<<<dim3(24, 8, 2), 256, 0, stream>>>(
        (const unsigned short*)w1b, (unsigned short*)w1t, Dc, 3 * Dc, (long)HD, (long)HD);
    transpose_bf16<<<dim3(8, 8, 1), 256, 0, stream>>>(
        (const unsigned short*)pwb, (unsigned short*)pwt, Dc, Dc, 0, 0);
    qkv_mfma<<<dim3(12, 12, 2), 256, 0, stream>>>(
        xb, w1t, w2t, q1b, k1b, v1b, q2b, k2b, v2b);
    transpose_bf16<<<dim3(1, 12, 2 * BHc), 256, 0, stream>>>(
        (const unsigned short*)v1b, (unsigned short*)v1t, Nc, DKc, HSTR, HSTR);

    // 2. S = scale * q @ k^T — single 32-batch launch
    gemm_nt_mfma<0, float><<<dim3(6, 6, 2 * BHc), 256, 0, stream>>>(
        q1b, k1b, S1, Nc, Nc, DKc, HSTR, HSTR, (long)MAT, SCALE);

    // 3. merged softmax S1|S2 -> A1b|A2b (wave-per-row); merged transposes
    softmax_rows_w<<<(2 * BHc * Nc) / 4, 256, 0, stream>>>(S1, A1b);
    transpose_bf16<<<dim3(12, 12, 2 * BHc), 256, 0, stream>>>(
        (const unsigned short*)A1b, (unsigned short*)A1tb, Nc, Nc, (long)MAT, (long)MAT);

    // 4. Cr|Cl in ONE 32-batch launch (Bt batch = z^16; C regions adjacent)
    gemm_nt_mfma<1, bf16, 1><<<dim3(6, 6, 2 * BHc), 256, 0, stream>>>(
        A1b, A1tb, Crb, Nc, Nc, Nc, (long)MAT, (long)MAT, (long)MAT, 1.f);

    // 5. gates + Smix (scalar-load weights + packed epilogue)
    gates_smix<<<dim3(24, 48, BHc), 256, 0, stream>>>(S1, S2, Crb, Clb, Smix, smallf);

    // 6. A = softmax(Smix) -> bf16 (into S1 alias, wave-per-row)
    softmax_rows_w<<<(BHc * Nc) / 4, 256, 0, stream>>>(Smix, Ab);

    // 7. merged: transport = A2 @ v2 -> trt (transposed epilogue, z<16)
    //            y_base   = A  @ v1 -> yb1 (z>=16)
    gemm_n64_pair<<<dim3(1, 6, 2 * BHc), 256, 0, stream>>>(
        A2b, v2t, trt, Ab, v1t, yb1, Nc, Nc, (long)MAT, HSTR, HSTR);

    // 8. y_chain GEMM with fused combine + permute -> yc
    gemm_n64_combine<<<dim3(1, 6, BHc), 256, 0, stream>>>(
        A1b, trt, yb1, smallf, yc, Nc, Nc, (long)MAT, HSTR);

    // 9. proj via n64 core, 128x64 tiles (96 blocks)
    proj_n64<<<dim3(8, 12, 1), 256, 0, stream>>>(yc, pwt, d_in[0], d_out);
}

// Round 6
// 385.053 us; speedup vs baseline: 1.2826x; 1.0571x over previous
//
#include <hip/hip_runtime.h>
#include <hip/hip_bf16.h>
#include <math.h>

typedef __hip_bfloat16 bf16;
typedef __attribute__((ext_vector_type(8))) short short8;   // 8 bf16 (4 VGPRs)
typedef __attribute__((ext_vector_type(4))) float f32x4;
typedef __attribute__((ext_vector_type(2))) float f32x2;
#define DEVINL __device__ __forceinline__

constexpr int Bc  = 2;
constexpr int Nc  = 768;
constexpr int Dc  = 512;
constexpr int Hc  = 8;
constexpr int DKc = 64;
constexpr int BHc = Bc * Hc;
constexpr float SCALE    = 0.125f;   // 1/sqrt(64)
constexpr float EPSF     = 1e-6f;
constexpr float BETA_NOT = 0.5f;

DEVINL float ldf(const float* p, long i) { return p[i]; }
DEVINL float ldf(const bf16* p, long i) { return __bfloat162float(p[i]); }
DEVINL void stf(float* p, long i, float v) { p[i] = v; }
DEVINL void stf(bf16* p, long i, float v) { p[i] = __float2bfloat16(v); }

DEVINL float sigf(float x) { return __fdividef(1.f, 1.f + __expf(-x)); }

// packed fp32 pair helpers — backend selects v_pk_fma_f32/v_pk_mul_f32 (r3:
// validated -41% on gates_smix; r4 pair-dup operands -12%; r5 s_load weights).
DEVINL f32x2 fma2(f32x2 a, f32x2 b, f32x2 c) { return __builtin_elementwise_fma(a, b, c); }
DEVINL f32x2 splat2(float x) { return (f32x2){x, x}; }
// guard-free transcendentals (libm exp2f adds a denormal guard: +13% in r2)
DEVINL float vexp2(float x) { float r; asm("v_exp_f32 %0, %1" : "=v"(r) : "v"(x)); return r; }
DEVINL float vrcp(float x)  { float r; asm("v_rcp_f32 %0, %1" : "=v"(r) : "v"(x)); return r; }
DEVINL float vlog2(float x) { float r; asm("v_log_f32 %0, %1" : "=v"(r) : "v"(x)); return r; }

// async global->LDS, 16B per lane; LDS dest = wave-uniform base + lane*16.
DEVINL void gl_lds16(const void* g, void* l) {
    __builtin_amdgcn_global_load_lds(
        (const __attribute__((address_space(1))) void*)g,
        (__attribute__((address_space(3))) void*)l, 16, 0, 0);
}

// ---------------------------------------------------------------------------
// Dtype sniffer — vectorized (validated round 9).
// ---------------------------------------------------------------------------
DEVINL int sniff_is_fp32(const void* xraw) {
    const uint4* p4 = (const uint4*)xraw;
    float mx = 0.f;
#pragma unroll
    for (int j = 0; j < 16; ++j) {
        const uint4 u = p4[j];
        const unsigned w[4] = {u.x, u.y, u.z, u.w};
#pragma unroll
        for (int t = 0; t < 4; ++t) {
            mx = fmaxf(mx, fabsf(__uint_as_float((w[t] & 0xffffu) << 16)));
            mx = fmaxf(mx, fabsf(__uint_as_float(w[t] & 0xffff0000u)));
        }
    }
    return mx > 1000.f ? 1 : 0;
}

DEVINL float cvt_elem(const void* s, long j, int is32) {
    return is32 ? ((const float*)s)[j]
                : __bfloat162float(((const bf16*)s)[j]);
}

// smallf layout (round 15 — PAIR-DUPLICATED; read via uniform scalar loads):
//   [u*24 + 2k+{0,1}]  = w1[u][k]          k=0..5   (12 floats)
//   [u*24 + 12..13]    = b1[u] pair
//   [u*24 + 14..15]    = pad
//   [u*24 + 16 + 2o+{0,1}] = conv2_w[o][u] o=0..3   (8 floats)
//   [384..391]  conv2_b[o] pairs
//   [392..393]  chain_logit pair          (combine reads [392])
__global__ __launch_bounds__(256) void convert_all(
    const void* x, const void* w1, const void* w2, const void* pw,
    const void* c1w, const void* c1b, const void* c2w, const void* c2b,
    const void* ch,
    bf16* xb, bf16* w1b, bf16* w2b, bf16* pwb, float* smallf)
{
    __shared__ int is32s;
    if (threadIdx.x == 0) is32s = sniff_is_fp32(x);
    __syncthreads();
    const int is32 = is32s;
    const long i = (long)blockIdx.x * 256 + threadIdx.x;
    if (i < (long)Bc * Nc * Dc) {
        xb[i]  = __float2bfloat16(cvt_elem(x,  i, is32));
        w1b[i] = __float2bfloat16(cvt_elem(w1, i, is32));
        w2b[i] = __float2bfloat16(cvt_elem(w2, i, is32));
    }
    if (i < (long)Dc * Dc) pwb[i] = __float2bfloat16(cvt_elem(pw, i, is32));
    if (i < 384) {
        const int u = (int)i / 24, k = (int)i % 24;
        float v = 0.f;
        if (k < 12)      v = cvt_elem(c1w, u * 6 + (k >> 1), is32);
        else if (k < 14) v = cvt_elem(c1b, u, is32);
        else if (k >= 16) { const int o = (k - 16) >> 1; v = cvt_elem(c2w, o * 16 + u, is32); }
        smallf[i] = v;
    } else if (i < 392) smallf[i] = cvt_elem(c2b, ((int)i - 384) >> 1, is32);
    else if (i < 394) smallf[i] = cvt_elem(ch, 0, is32);
    else if (i < 512) smallf[i] = 0.f;
}

__global__ __launch_bounds__(256) void fill_sentinel(unsigned short* o) {
    const long i = (long)blockIdx.x * 256 + threadIdx.x;
    if (i < (long)Bc * Nc * Dc) o[i] = 0x40E0;  // bf16 7.0
}

// ---------------------------------------------------------------------------
// Generic bf16 transpose, 64x64 tiles: dst[c][r] = src[r][c]; src is (R,C).
// ---------------------------------------------------------------------------
__global__ __launch_bounds__(256) void transpose_bf16(
    const unsigned short* __restrict__ src, unsigned short* __restrict__ dst,
    int R, int C, long sS, long sD)
{
    __shared__ unsigned short tile[64][68];
    const unsigned short* s = src + (long)blockIdx.z * sS;
    unsigned short* d = dst + (long)blockIdx.z * sD;
    const int r0 = blockIdx.y * 64, c0 = blockIdx.x * 64;
    const int t = threadIdx.x;
    const int lr = t >> 4, lc4 = (t & 15) * 4;
#pragma unroll
    for (int i = 0; i < 4; ++i) {
        int r = lr + i * 16;
        *(uint2*)&tile[r][lc4] = *(const uint2*)&s[(long)(r0 + r) * C + c0 + lc4];
    }
    __syncthreads();
#pragma unroll
    for (int i = 0; i < 4; ++i) {
        int r = lr + i * 16;
        unsigned short v[4];
#pragma unroll
        for (int j = 0; j < 4; ++j) v[j] = tile[lc4 + j][r];
        *(uint2*)&d[(long)(c0 + r) * R + r0 + lc4] = *(uint2*)v;
    }
}

// ---------------------------------------------------------------------------
// MFMA bf16 NT GEMM with global_load_lds staging.
// Round 17 additions:
//  - bank-conflict XOR swizzle (rule: both-sides-or-neither with gl_lds —
//    pre-swizzled global SOURCE col-block sc^(sr&3), swizzled READ q^(ln&3)).
//    Was 8-way conflict (64B row stride, all even lanes on one bank group).
//  - XCDSWZ: 1-D grid 1152 = 8 xcd * (4 batch * 36 tile); batch pinned to
//    one XCD so its 2.36 MB working set stays in that XCD's 4 MB L2.
//  - RAW: also store pre-log C (z<16) for the y_chain associativity path.
// ---------------------------------------------------------------------------
template <int EPI, typename TC, int XORB = 0, int XCDSWZ = 0, int RAW = 0>
__global__ __launch_bounds__(256) void gemm_nt_mfma(
    const bf16* __restrict__ Ag, const bf16* __restrict__ Btg,
    TC* __restrict__ Cg, bf16* __restrict__ Craw, int M, int N, int K,
    long sA, long sB, long sC, float alpha)
{
    __shared__ unsigned short Asm[128 * 32];
    __shared__ unsigned short Bsm[128 * 32];

    int bx, by, bz;
    if (XCDSWZ) {
        const int wg = blockIdx.x;
        const int xcd = wg & 7, t = wg >> 3;
        bz = xcd + 8 * (t / 36);
        const int tile = t % 36;
        bx = tile % 6; by = tile / 6;
    } else { bx = blockIdx.x; by = blockIdx.y; bz = blockIdx.z; }

    const int tid  = threadIdx.x;
    const int wv   = tid >> 6;
    const int lane = tid & 63;
    const int q    = lane >> 4;
    const int ln   = lane & 15;
    const int wm   = wv & 1;
    const int wn   = wv >> 1;

    const int zb = XORB ? (bz ^ 16) : bz;
    const bf16* A  = Ag  + (long)bz * sA + (long)(by * 128) * K;
    const bf16* Bt = Btg + (long)zb * sB + (long)(bx * 128) * K;
    TC*         C  = Cg  + (long)bz * sC;

    const int sr = lane >> 2, sc = lane & 3;
    const int scs = sc ^ (sr & 3);          // source col-block pre-swizzle
    const bf16* gA0 = A  + (long)(wv * 32 + sr)      * K + scs * 8;
    const bf16* gA1 = A  + (long)(wv * 32 + 16 + sr) * K + scs * 8;
    const bf16* gB0 = Bt + (long)(wv * 32 + sr)      * K + scs * 8;
    const bf16* gB1 = Bt + (long)(wv * 32 + 16 + sr) * K + scs * 8;
    unsigned short* lA0 = &Asm[(wv * 32)      * 32];
    unsigned short* lA1 = &Asm[(wv * 32 + 16) * 32];
    unsigned short* lB0 = &Bsm[(wv * 32)      * 32];
    unsigned short* lB1 = &Bsm[(wv * 32 + 16) * 32];

    f32x4 acc[4][4];
#pragma unroll
    for (int i = 0; i < 4; ++i)
#pragma unroll
        for (int j = 0; j < 4; ++j)
            acc[i][j] = (f32x4){0.f, 0.f, 0.f, 0.f};

    const int qs = (q ^ (ln & 3)) * 8;      // swizzled read block

    for (int k0 = 0; k0 < K; k0 += 32) {
        __syncthreads();
        gl_lds16(gA0 + k0, lA0);
        gl_lds16(gA1 + k0, lA1);
        gl_lds16(gB0 + k0, lB0);
        gl_lds16(gB1 + k0, lB1);
        __syncthreads();

        short8 af[4], bfr[4];
#pragma unroll
        for (int mt = 0; mt < 4; ++mt) {
            int m = wm * 64 + mt * 16 + ln;
            af[mt] = *(const short8*)&Asm[m * 32 + qs];
        }
#pragma unroll
        for (int nt = 0; nt < 4; ++nt) {
            int n = wn * 64 + nt * 16 + ln;
            bfr[nt] = *(const short8*)&Bsm[n * 32 + qs];
        }
#pragma unroll
        for (int mt = 0; mt < 4; ++mt)
#pragma unroll
            for (int nt = 0; nt < 4; ++nt)
                acc[mt][nt] = __builtin_amdgcn_mfma_f32_16x16x32_bf16(
                    af[mt], bfr[nt], acc[mt][nt], 0, 0, 0);
    }

#pragma unroll
    for (int mt = 0; mt < 4; ++mt) {
#pragma unroll
        for (int nt = 0; nt < 4; ++nt) {
            const int col = bx * 128 + wn * 64 + nt * 16 + ln;
            const int rowb = by * 128 + wm * 64 + mt * 16 + q * 4;
#pragma unroll
            for (int r = 0; r < 4; ++r) {
                float vraw = acc[mt][nt][r] * alpha;
                if (RAW) {
                    if (bz < 16)
                        Craw[(long)bz * M * N + (long)(rowb + r) * N + col] =
                            __float2bfloat16(vraw);
                }
                float v = vraw;
                if (EPI == 1) v = __logf(fmaxf(v, 0.f) + EPSF);
                stf(C, (long)(rowb + r) * N + col, v);
            }
        }
    }
}

// ---------------------------------------------------------------------------
// QKV via MFMA, merged sets (r17: same bank-conflict XOR swizzle).
// ---------------------------------------------------------------------------
__global__ __launch_bounds__(256) void qkv_mfma(
    const bf16* __restrict__ X,
    const bf16* __restrict__ w1t, const bf16* __restrict__ w2t,
    bf16* __restrict__ q1, bf16* __restrict__ k1, bf16* __restrict__ v1,
    bf16* __restrict__ q2, bf16* __restrict__ k2, bf16* __restrict__ v2)
{
    constexpr int K = Dc;  // 512
    __shared__ unsigned short Asm[128 * 32];
    __shared__ unsigned short Bsm[128 * 32];

    const int tid  = threadIdx.x;
    const int wv   = tid >> 6;
    const int lane = tid & 63;
    const int q    = lane >> 4;
    const int ln   = lane & 15;
    const int wm   = wv & 1;
    const int wn   = wv >> 1;
    const int set  = blockIdx.z;

    const bf16* Wt = set ? w2t : w1t;
    bf16* Q  = set ? q2 : q1;
    bf16* Ko = set ? k2 : k1;
    bf16* V  = set ? v2 : v1;

    const bf16* A  = X  + (long)(blockIdx.y * 128) * K;
    const bf16* Bt = Wt + (long)(blockIdx.x * 128) * K;

    const int sr = lane >> 2, sc = lane & 3;
    const int scs = sc ^ (sr & 3);
    const bf16* gA0 = A  + (long)(wv * 32 + sr)      * K + scs * 8;
    const bf16* gA1 = A  + (long)(wv * 32 + 16 + sr) * K + scs * 8;
    const bf16* gB0 = Bt + (long)(wv * 32 + sr)      * K + scs * 8;
    const bf16* gB1 = Bt + (long)(wv * 32 + 16 + sr) * K + scs * 8;
    unsigned short* lA0 = &Asm[(wv * 32)      * 32];
    unsigned short* lA1 = &Asm[(wv * 32 + 16) * 32];
    unsigned short* lB0 = &Bsm[(wv * 32)      * 32];
    unsigned short* lB1 = &Bsm[(wv * 32 + 16) * 32];

    f32x4 acc[4][4];
#pragma unroll
    for (int i = 0; i < 4; ++i)
#pragma unroll
        for (int j = 0; j < 4; ++j)
            acc[i][j] = (f32x4){0.f, 0.f, 0.f, 0.f};

    const int qs = (q ^ (ln & 3)) * 8;

    for (int k0 = 0; k0 < K; k0 += 32) {
        __syncthreads();
        gl_lds16(gA0 + k0, lA0);
        gl_lds16(gA1 + k0, lA1);
        gl_lds16(gB0 + k0, lB0);
        gl_lds16(gB1 + k0, lB1);
        __syncthreads();

        short8 af[4], bfr[4];
#pragma unroll
        for (int mt = 0; mt < 4; ++mt) {
            int m = wm * 64 + mt * 16 + ln;
            af[mt] = *(const short8*)&Asm[m * 32 + qs];
        }
#pragma unroll
        for (int nt = 0; nt < 4; ++nt) {
            int n = wn * 64 + nt * 16 + ln;
            bfr[nt] = *(const short8*)&Bsm[n * 32 + qs];
        }
#pragma unroll
        for (int mt = 0; mt < 4; ++mt)
#pragma unroll
            for (int nt = 0; nt < 4; ++nt)
                acc[mt][nt] = __builtin_amdgcn_mfma_f32_16x16x32_bf16(
                    af[mt], bfr[nt], acc[mt][nt], 0, 0, 0);
    }

#pragma unroll
    for (int mt = 0; mt < 4; ++mt) {
#pragma unroll
        for (int nt = 0; nt < 4; ++nt) {
            const int col  = blockIdx.x * 128 + wn * 64 + nt * 16 + ln;
            const int rowb = blockIdx.y * 128 + wm * 64 + mt * 16 + q * 4;
            const int t = col >> 9;
            const int h = (col >> 6) & 7;
            const int dk = col & 63;
            bf16* dst = (t == 0) ? Q : (t == 1) ? Ko : V;
#pragma unroll
            for (int r = 0; r < 4; ++r) {
                const int row = rowb + r;
                const int b = row >= Nc ? 1 : 0;
                const int n = row - b * Nc;
                dst[(((long)b * Hc + h) * Nc + n) * DKc + dk] =
                    __float2bfloat16(acc[mt][nt][r]);
            }
        }
    }
}

// ---------------------------------------------------------------------------
// MFMA bf16 NT narrow GEMM core (validated): acc = A(128,K) @ Bt(64,K)^T.
// Reg-staged, stride-72 LDS (conflict-free by construction).
// ---------------------------------------------------------------------------
struct N64Acc { f32x4 acc[2][4]; };

template <typename DUMMY = void>
DEVINL void n64_core(const bf16* A, const bf16* Bt, int K,
                     unsigned short* Asm, unsigned short* Bsm, N64Acc& R)
{
    const int tid  = threadIdx.x;
    const int wave = tid >> 6;
    const int lane = tid & 63;
    const int q    = lane >> 4;
    const int ln   = lane & 15;

    const int sr = tid >> 3, k8 = tid & 7;
    const bf16* pa[4];
    const bf16* pb[2];
    int wa[4], wb[2];
#pragma unroll
    for (int i = 0; i < 4; ++i) {
        pa[i] = A + (long)(sr + i * 32) * K + k8 * 8;
        wa[i] = (sr + i * 32) * 72 + k8 * 8;
    }
#pragma unroll
    for (int i = 0; i < 2; ++i) {
        pb[i] = Bt + (long)(sr + i * 32) * K + k8 * 8;
        wb[i] = (sr + i * 32) * 72 + k8 * 8;
    }

#pragma unroll
    for (int i = 0; i < 2; ++i)
#pragma unroll
        for (int j = 0; j < 4; ++j)
            R.acc[i][j] = (f32x4){0.f, 0.f, 0.f, 0.f};

    for (int k0 = 0; k0 < K; k0 += 64) {
        uint4 va[4], vb[2];
#pragma unroll
        for (int i = 0; i < 4; ++i) va[i] = *(const uint4*)(pa[i] + k0);
#pragma unroll
        for (int i = 0; i < 2; ++i) vb[i] = *(const uint4*)(pb[i] + k0);
        __syncthreads();
#pragma unroll
        for (int i = 0; i < 4; ++i) *(uint4*)&Asm[wa[i]] = va[i];
#pragma unroll
        for (int i = 0; i < 2; ++i) *(uint4*)&Bsm[wb[i]] = vb[i];
        __syncthreads();

#pragma unroll
        for (int kc = 0; kc < 2; ++kc) {
            short8 af[2], bfr[4];
#pragma unroll
            for (int mt = 0; mt < 2; ++mt) {
                int m = wave * 32 + mt * 16 + ln;
                af[mt] = *(const short8*)&Asm[m * 72 + kc * 32 + q * 8];
            }
#pragma unroll
            for (int nt = 0; nt < 4; ++nt) {
                int n = nt * 16 + ln;
                bfr[nt] = *(const short8*)&Bsm[n * 72 + kc * 32 + q * 8];
            }
#pragma unroll
            for (int mt = 0; mt < 2; ++mt)
#pragma unroll
                for (int nt = 0; nt < 4; ++nt)
                    R.acc[mt][nt] = __builtin_amdgcn_mfma_f32_16x16x32_bf16(
                        af[mt], bfr[nt], R.acc[mt][nt], 0, 0, 0);
        }
    }
}

// ---------------------------------------------------------------------------
// Merged pair launch (Path-B fallback only; validated round 11).
// ---------------------------------------------------------------------------
__global__ __launch_bounds__(256) void gemm_n64_pair(
    const bf16* __restrict__ A0g, const bf16* __restrict__ B0g, bf16* __restrict__ C0tg,
    const bf16* __restrict__ A1g, const bf16* __restrict__ B1g, bf16* __restrict__ C1g,
    int M, int K, long sA, long sB, long sC)
{
    __shared__ unsigned short Asm[128 * 72];
    __shared__ unsigned short Bsm[64 * 72];

    const int zz = blockIdx.z & 15;
    const int second = blockIdx.z >> 4;
    const bf16* A  = (second ? A1g : A0g) + (long)zz * sA + (long)(blockIdx.y * 128) * K;
    const bf16* Bt = (second ? B1g : B0g) + (long)zz * sB;

    N64Acc R;
    n64_core(A, Bt, K, Asm, Bsm, R);

    const int tid = threadIdx.x;
    const int wave = tid >> 6, lane = tid & 63, q = lane >> 4, ln = lane & 15;

    if (second) {
        bf16* C = C1g + (long)zz * sC;
#pragma unroll
        for (int mt = 0; mt < 2; ++mt) {
#pragma unroll
            for (int nt = 0; nt < 4; ++nt) {
                const int col  = nt * 16 + ln;
                const int rowb = blockIdx.y * 128 + wave * 32 + mt * 16 + q * 4;
#pragma unroll
                for (int r = 0; r < 4; ++r)
                    C[(long)(rowb + r) * 64 + col] = __float2bfloat16(R.acc[mt][nt][r]);
            }
        }
    } else {
        __syncthreads();
#pragma unroll
        for (int mt = 0; mt < 2; ++mt) {
#pragma unroll
            for (int nt = 0; nt < 4; ++nt) {
                const int col = nt * 16 + ln;
                const int rwb = wave * 32 + mt * 16 + q * 4;
#pragma unroll
                for (int r = 0; r < 4; ++r)
                    *(bf16*)&Asm[col * 136 + rwb + r] = __float2bfloat16(R.acc[mt][nt][r]);
            }
        }
        __syncthreads();
        bf16* Ct = C0tg + (long)zz * sC;
        const int dk  = tid >> 2;
        const int nc0 = (tid & 3) * 32;
        const int gn0 = blockIdx.y * 128;
#pragma unroll
        for (int c8 = 0; c8 < 4; ++c8) {
            uint4 v = *(const uint4*)&Asm[dk * 136 + nc0 + c8 * 8];
            *(uint4*)&Ct[(long)dk * Nc + gn0 + nc0 + c8 * 8] = v;
        }
    }
}

// y_base-only n64 GEMM (Path A): C = A @ Bt^T, plain (Nc x 64) store.
__global__ __launch_bounds__(256) void gemm_n64_yb(
    const bf16* __restrict__ Ag, const bf16* __restrict__ Btg,
    bf16* __restrict__ Cg, int M, int K, long sA, long sB, long sC)
{
    __shared__ unsigned short Asm[128 * 72];
    __shared__ unsigned short Bsm[64 * 72];

    const int zz = blockIdx.z;
    const bf16* A  = Ag + (long)zz * sA + (long)(blockIdx.y * 128) * K;
    const bf16* Bt = Btg + (long)zz * sB;

    N64Acc R;
    n64_core(A, Bt, K, Asm, Bsm, R);

    bf16* C = Cg + (long)zz * sC;
    const int tid = threadIdx.x;
    const int wave = tid >> 6, lane = tid & 63, q = lane >> 4, ln = lane & 15;
#pragma unroll
    for (int mt = 0; mt < 2; ++mt) {
#pragma unroll
        for (int nt = 0; nt < 4; ++nt) {
            const int col  = nt * 16 + ln;
            const int rowb = blockIdx.y * 128 + wave * 32 + mt * 16 + q * 4;
#pragma unroll
            for (int r = 0; r < 4; ++r)
                C[(long)(rowb + r) * 64 + col] = __float2bfloat16(R.acc[mt][nt][r]);
        }
    }
}

// y_chain GEMM with fused combine + permute. Path A: A = raw C_right
// (associativity: y_chain = (A1@A2)@v2), Bt = v2t. Path B: A=A1b, Bt=trt.
__global__ __launch_bounds__(256) void gemm_n64_combine(
    const bf16* __restrict__ A1b, const bf16* __restrict__ trt,
    const bf16* __restrict__ yb1, const float* __restrict__ smallf,
    bf16* __restrict__ yc, int M, int K, long sA, long sB)
{
    __shared__ unsigned short Asm[128 * 72];
    __shared__ unsigned short Bsm[64 * 72];

    const int bh = blockIdx.z;
    const bf16* A  = A1b + (long)bh * sA + (long)(blockIdx.y * 128) * K;
    const bf16* Bt = trt + (long)bh * sB;

    N64Acc R;
    n64_core(A, Bt, K, Asm, Bsm, R);

    const float w = sigf(smallf[392]);
    const int b = bh >> 3, h = bh & 7;
    const long yb1base = (long)bh * Nc * DKc;

    const int tid = threadIdx.x;
    const int wave = tid >> 6, lane = tid & 63, q = lane >> 4, ln = lane & 15;
#pragma unroll
    for (int mt = 0; mt < 2; ++mt) {
#pragma unroll
        for (int nt = 0; nt < 4; ++nt) {
            const int col  = nt * 16 + ln;
            const int rowb = blockIdx.y * 128 + wave * 32 + mt * 16 + q * 4;
#pragma unroll
            for (int r = 0; r < 4; ++r) {
                const int n = rowb + r;
                const float base = __bfloat162float(yb1[yb1base + (long)n * 64 + col]);
                yc[((long)(b * Nc + n)) * Dc + h * DKc + col] =
                    __float2bfloat16(base + w * R.acc[mt][nt][r]);
            }
        }
    }
}

// ---------------------------------------------------------------------------
// Row softmax over width 768 — wave-per-row (validated round 16).
// ---------------------------------------------------------------------------
__global__ __launch_bounds__(256) void softmax_rows_w(
    const float* __restrict__ src, bf16* __restrict__ dst)
{
    const int wid  = threadIdx.x >> 6;
    const int lane = threadIdx.x & 63;
    const long row = (long)blockIdx.x * 4 + wid;
    const float* s = src + row * Nc;

    float4 v[3];
#pragma unroll
    for (int i = 0; i < 3; ++i)
        v[i] = *(const float4*)&s[i * 256 + lane * 4];

    float m = -1e30f;
#pragma unroll
    for (int i = 0; i < 3; ++i)
        m = fmaxf(m, fmaxf(fmaxf(v[i].x, v[i].y), fmaxf(v[i].z, v[i].w)));
#pragma unroll
    for (int off = 32; off > 0; off >>= 1)
        m = fmaxf(m, __shfl_xor(m, off, 64));

    float e[12];
    float sum = 0.f;
#pragma unroll
    for (int i = 0; i < 3; ++i) {
        e[i * 4 + 0] = __expf(v[i].x - m);
        e[i * 4 + 1] = __expf(v[i].y - m);
        e[i * 4 + 2] = __expf(v[i].z - m);
        e[i * 4 + 3] = __expf(v[i].w - m);
        sum += e[i * 4 + 0] + e[i * 4 + 1] + e[i * 4 + 2] + e[i * 4 + 3];
    }
#pragma unroll
    for (int off = 32; off > 0; off >>= 1)
        sum += __shfl_xor(sum, off, 64);

    const float inv = 1.f / fmaxf(sum, 1e-30f);
    unsigned short* d = (unsigned short*)dst + row * Nc;
#pragma unroll
    for (int i = 0; i < 3; ++i) {
        unsigned short o[4];
#pragma unroll
        for (int j = 0; j < 4; ++j) {
            const bf16 b = __float2bfloat16(e[i * 4 + j] * inv);
            o[j] = *(const unsigned short*)&b;
        }
        *(uint2*)&d[i * 256 + lane * 4] = *(const uint2*)o;
    }
}

// ---------------------------------------------------------------------------
// Gate network + Smix — validated round 16 version (s_load weights, packed
// pair math, guard-free transcendentals). VALU-issue-bound; VGPR 32.
// ---------------------------------------------------------------------------
__global__ __launch_bounds__(256) void gates_smix(
    const float* __restrict__ S1g, const float* __restrict__ S2g,
    const bf16* __restrict__ Crg, const bf16* __restrict__ Clg,
    float* __restrict__ Smixg, const float* __restrict__ smallf)
{
    __shared__ float t1t[32][17], t2t[32][17];

    const long mat = (long)blockIdx.z * Nc * Nc;
    const float* S1 = S1g + mat;
    const float* S2 = S2g + mat;
    const unsigned short* Cr = (const unsigned short*)Crg + mat;
    const unsigned short* Cl = (const unsigned short*)Clg + mat;
    float* Smix = Smixg + mat;

    const int tid = threadIdx.x;

    const int n0 = blockIdx.y * 16, m0 = blockIdx.x * 32;
    {   // transposed tiles: S[m0..m0+31][n0..n0+15], coalesced float2 loads
        const int r = tid >> 3, c2 = (tid & 7) * 2;
        const float2 a = *(const float2*)&S1[(long)(m0 + r) * Nc + n0 + c2];
        const float2 b = *(const float2*)&S2[(long)(m0 + r) * Nc + n0 + c2];
        t1t[r][c2] = a.x; t1t[r][c2 + 1] = a.y;
        t2t[r][c2] = b.x; t2t[r][c2 + 1] = b.y;
    }
    __syncthreads();

    const int tx = tid & 15, ty = tid >> 4;
    const int n = n0 + ty;
    const long idx = (long)n * Nc + m0 + tx * 2;

    const float2 s1v = *(const float2*)&S1[idx];
    const float2 s2v = *(const float2*)&S2[idx];
    const unsigned cru = *(const unsigned*)&Cr[idx];   // idx even -> 4B aligned
    const unsigned clu = *(const unsigned*)&Cl[idx];

    const f32x2 s1a = {s1v.x, s1v.y};
    const f32x2 s2a = {s2v.x, s2v.y};
    const f32x2 cra = {__uint_as_float((cru & 0xffffu) << 16),
                       __uint_as_float(cru & 0xffff0000u)};
    const f32x2 cla = {__uint_as_float((clu & 0xffffu) << 16),
                       __uint_as_float(clu & 0xffff0000u)};
    const f32x2 s1t = {t1t[tx * 2][ty], t1t[tx * 2 + 1][ty]};
    const f32x2 s2t = {t2t[tx * 2][ty], t2t[tx * 2 + 1][ty]};

    f32x2 g0 = *(const f32x2*)&smallf[384];
    f32x2 g1 = *(const f32x2*)&smallf[386];
    f32x2 g2 = *(const f32x2*)&smallf[388];
    f32x2 g3 = *(const f32x2*)&smallf[390];

    const f32x2 gc1  = splat2(-2.30220902f);   // gelu c1 * log2e
    const f32x2 gc3  = splat2(-0.10294357f);   // gelu c3 * log2e
    const f32x2 one2 = splat2(1.f);

#pragma unroll
    for (int u = 0; u < 16; ++u) {
        const f32x2* cw = (const f32x2*)&smallf[u * 24];
        f32x2 h = cw[6];
        h = fma2(s1a, cw[0], h);
        h = fma2(s2a, cw[1], h);
        h = fma2(s1t, cw[2], h);
        h = fma2(s2t, cw[3], h);
        h = fma2(cra, cw[4], h);
        h = fma2(cla, cw[5], h);
        const f32x2 hh = h * h;
        const f32x2 z2 = h * fma2(hh, gc3, gc1);
        f32x2 e;  e[0]  = vexp2(z2[0]); e[1]  = vexp2(z2[1]);
        const f32x2 d = one2 + e;
        f32x2 rc; rc[0] = vrcp(d[0]);   rc[1] = vrcp(d[1]);
        const f32x2 hid = h * rc;
        g0 = fma2(hid, cw[8],  g0);
        g1 = fma2(hid, cw[9],  g1);
        g2 = fma2(hid, cw[10], g2);
        g3 = fma2(hid, cw[11], g3);
    }

    const f32x2 nl2e = splat2(-1.44269504f);
    const f32x2 ln2v = splat2(0.69314718f);
    auto sig2 = [&](f32x2 x) -> f32x2 {
        const f32x2 t = x * nl2e;
        f32x2 e;  e[0] = vexp2(t[0]); e[1] = vexp2(t[1]);
        const f32x2 d = one2 + e;
        f32x2 r;  r[0] = vrcp(d[0]);  r[1] = vrcp(d[1]);
        return r;
    };
    const f32x2 ga2 = sig2(g0);
    const f32x2 go2 = sig2(g1);
    const f32x2 gn2 = sig2(g2);
    const f32x2 gc2 = sig2(g3);

    const f32x2 dd = s1a - s2a;
    f32x2 ad; ad[0] = fabsf(dd[0]); ad[1] = fabsf(dd[1]);
    const f32x2 t2 = ad * nl2e;                       // -|d| * log2e
    f32x2 ee; ee[0] = vexp2(t2[0]); ee[1] = vexp2(t2[1]);
    const f32x2 lp = one2 + ee;
    f32x2 lg; lg[0] = vlog2(lp[0]); lg[1] = vlog2(lp[1]);
    const f32x2 mx2 = __builtin_elementwise_max(s1a, s2a);
    const f32x2 lae = fma2(lg, ln2v, mx2);            // logaddexp(s1,s2)

    f32x2 o2 = s1a;
    o2 = fma2(ga2, s2a, o2);
    o2 = fma2(go2, lae - s1a, o2);
    o2 = fma2(gn2, s2a * splat2(-BETA_NOT), o2);
    o2 = fma2(gc2, cra, o2);
    *(float2*)&Smix[idx] = (float2){o2[0], o2[1]};
}

// ---------------------------------------------------------------------------
// Final projection via n64 core, 128x64 tiles (validated round 12).
// ---------------------------------------------------------------------------
__global__ __launch_bounds__(256) void proj_n64(
    const bf16* __restrict__ yc, const bf16* __restrict__ pwt,
    const void* __restrict__ xraw, void* __restrict__ out)
{
    constexpr int K = Dc;  // 512
    constexpr int N = Dc;  // 512
    __shared__ unsigned short Asm[128 * 72];
    __shared__ unsigned short Bsm[64 * 72];
    __shared__ int is32s;
    if (threadIdx.x == 0) is32s = sniff_is_fp32(xraw);

    const bf16* A  = yc  + (long)(blockIdx.y * 128) * K;
    const bf16* Bt = pwt + (long)(blockIdx.x * 64) * K;

    N64Acc R;
    n64_core(A, Bt, K, Asm, Bsm, R);   // internal barriers publish is32s

    const int is32 = is32s;
    const int tid = threadIdx.x;
    const int wave = tid >> 6, lane = tid & 63, q = lane >> 4, ln = lane & 15;
#pragma unroll
    for (int mt = 0; mt < 2; ++mt) {
#pragma unroll
        for (int nt = 0; nt < 4; ++nt) {
            const int col  = blockIdx.x * 64 + nt * 16 + ln;
            const int rowb = blockIdx.y * 128 + wave * 32 + mt * 16 + q * 4;
#pragma unroll
            for (int r = 0; r < 4; ++r) {
                const long o = (long)(rowb + r) * N + col;
                if (is32) ((float*)out)[o] = R.acc[mt][nt][r];
                else      ((bf16*)out)[o] = __float2bfloat16(R.acc[mt][nt][r]);
            }
        }
    }
}

// ---------------------------------------------------------------------------
extern "C" void kernel_launch(void* const* d_in, const int* in_sizes, int n_in,
                              void* d_out, int out_size, void* d_ws, size_t ws_size,
                              hipStream_t stream)
{
    const size_t HD   = (size_t)BHc * Nc * DKc;   // 786432
    const size_t HDh  = HD / 2;                   // float-slots for HD bf16
    const size_t MAT  = (size_t)Nc * Nc;          // 589824
    const size_t MATS = (size_t)BHc * MAT;        // 9437184
    const long   HSTR = (long)Nc * DKc;           // 49152 per-head stride

    float* ws = (float*)d_ws;
    size_t off = 0;
    auto alloc = [&](size_t n) { float* p = ws + off; off += n; return p; };

    bf16* xb  = (bf16*)alloc(HDh);
    bf16* w1b = (bf16*)alloc(HDh);   // w1b/w2b adjacent -> merged transpose
    bf16* w2b = (bf16*)alloc(HDh);
    bf16* w1t = (bf16*)alloc(HDh);
    bf16* w2t = (bf16*)alloc(HDh);
    bf16* pwb = (bf16*)alloc((size_t)Dc * Dc / 2);
    bf16* pwt = (bf16*)alloc((size_t)Dc * Dc / 2);
    float* smallf = alloc(512);
    // q1|q2 and k1|k2 adjacent -> single merged S-GEMM launch (32 heads)
    bf16* q1b = (bf16*)alloc(HDh); bf16* q2b = (bf16*)alloc(HDh);
    bf16* k1b = (bf16*)alloc(HDh); bf16* k2b = (bf16*)alloc(HDh);
    bf16* v1b = (bf16*)alloc(HDh); bf16* v2b = (bf16*)alloc(HDh);  // adjacent
    bf16* v1t = (bf16*)alloc(HDh); bf16* v2t = (bf16*)alloc(HDh);  // adjacent
    bf16* trt = (bf16*)alloc(HDh);
    float* S1   = alloc(MATS);       // S1/S2 adjacent -> merged softmax + S-GEMM
    float* S2   = alloc(MATS);
    float* Smix = alloc(MATS);       // region reused: A1tb|A2tb, then Smix
    bf16* A1b = (bf16*)alloc(MATS / 2);  // A1b/A2b adjacent
    bf16* A2b = (bf16*)alloc(MATS / 2);
    bf16* Crb = (bf16*)alloc(MATS / 2);  // Crb/Clb adjacent (merged launch)
    bf16* Clb = (bf16*)alloc(MATS / 2);
    bf16* yb1 = (bf16*)alloc(HDh);
    bf16* yc  = (bf16*)alloc(HDh);

    const size_t NEED_BASE = off * sizeof(float);
    bf16* Crawb = (bf16*)alloc(MATS / 2);          // raw C_right (Path A only)
    const size_t NEED_A = off * sizeof(float);
    const int pathA = ws_size >= NEED_A;

    // aliases into dead regions
    bf16* A1tb = (bf16*)Smix;            // live steps 3-4 (dead once gates writes Smix)
    bf16* A2tb = ((bf16*)Smix) + MATS;
    bf16* Ab   = (bf16*)S1;              // S1 dead after gates

    if (ws_size < NEED_BASE) {
        fill_sentinel<<<dim3(3072), 256, 0, stream>>>((unsigned short*)d_out);
        return;
    }

    // 0. normalize inputs
    convert_all<<<dim3(3072), 256, 0, stream>>>(
        d_in[0], d_in[1], d_in[2], d_in[3], d_in[4], d_in[5], d_in[6], d_in[7],
        d_in[8], xb, w1b, w2b, pwb, smallf);

    // 1. merged W transposes; pw transpose; merged QKV; merged v transposes
    transpose_bf16<<<dim3(24, 8, 2), 256, 0, stream>>>(
        (const unsigned short*)w1b, (unsigned short*)w1t, Dc, 3 * Dc, (long)HD, (long)HD);
    transpose_bf16<<<dim3(8, 8, 1), 256, 0, stream>>>(
        (const unsigned short*)pwb, (unsigned short*)pwt, Dc, Dc, 0, 0);
    qkv_mfma<<<dim3(12, 12, 2), 256, 0, stream>>>(
        xb, w1t, w2t, q1b, k1b, v1b, q2b, k2b, v2b);
    transpose_bf16<<<dim3(1, 12, 2 * BHc), 256, 0, stream>>>(
        (const unsigned short*)v1b, (unsigned short*)v1t, Nc, DKc, HSTR, HSTR);

    // 2. S = scale * q @ k^T — single 32-batch launch
    gemm_nt_mfma<0, float><<<dim3(6, 6, 2 * BHc), 256, 0, stream>>>(
        q1b, k1b, S1, nullptr, Nc, Nc, DKc, HSTR, HSTR, (long)MAT, SCALE);

    // 3. merged softmax S1|S2 -> A1b|A2b (wave-per-row); merged transposes
    softmax_rows_w<<<(2 * BHc * Nc) / 4, 256, 0, stream>>>(S1, A1b);
    transpose_bf16<<<dim3(12, 12, 2 * BHc), 256, 0, stream>>>(
        (const unsigned short*)A1b, (unsigned short*)A1tb, Nc, Nc, (long)MAT, (long)MAT);

    // 4. Cr|Cl in ONE 32-batch launch; XCD-pinned 1-D grid (1152 = 8*4*36);
    //    Path A also stores raw C_right for the associativity y_chain.
    if (pathA)
        gemm_nt_mfma<1, bf16, 1, 1, 1><<<dim3(1152), 256, 0, stream>>>(
            A1b, A1tb, Crb, Crawb, Nc, Nc, Nc, (long)MAT, (long)MAT, (long)MAT, 1.f);
    else
        gemm_nt_mfma<1, bf16, 1, 1, 0><<<dim3(1152), 256, 0, stream>>>(
            A1b, A1tb, Crb, nullptr, Nc, Nc, Nc, (long)MAT, (long)MAT, (long)MAT, 1.f);

    // 5. gates + Smix
    gates_smix<<<dim3(24, 48, BHc), 256, 0, stream>>>(S1, S2, Crb, Clb, Smix, smallf);

    // 6. A = softmax(Smix) -> bf16 (into S1 alias, wave-per-row)
    softmax_rows_w<<<(BHc * Nc) / 4, 256, 0, stream>>>(Smix, Ab);

    if (pathA) {
        // 7a. y_base = A @ v1 -> yb1
        gemm_n64_yb<<<dim3(1, 6, BHc), 256, 0, stream>>>(
            Ab, v1t, yb1, Nc, Nc, (long)MAT, HSTR, HSTR);
        // 7b. y_chain = C_right @ v2 (associativity), fused combine -> yc
        gemm_n64_combine<<<dim3(1, 6, BHc), 256, 0, stream>>>(
            Crawb, v2t, yb1, smallf, yc, Nc, Nc, (long)MAT, HSTR);
    } else {
        // Path B fallback (round-5 structure)
        gemm_n64_pair<<<dim3(1, 6, 2 * BHc), 256, 0, stream>>>(
            A2b, v2t, trt, Ab, v1t, yb1, Nc, Nc, (long)MAT, HSTR, HSTR);
        gemm_n64_combine<<<dim3(1, 6, BHc), 256, 0, stream>>>(
            A1b, trt, yb1, smallf, yc, Nc, Nc, (long)MAT, HSTR);
    }

    // 9. proj via n64 core, 128x64 tiles (96 blocks)
    proj_n64<<<dim3(8, 12, 1), 256, 0, stream>>>(yc, pwt, d_in[0], d_out);
}

// Round 7
// 383.404 us; speedup vs baseline: 1.2882x; 1.0043x over previous
//
#include <hip/hip_runtime.h>
#include <hip/hip_bf16.h>
#include <math.h>

typedef __hip_bfloat16 bf16;
typedef __attribute__((ext_vector_type(8))) short short8;   // 8 bf16 (4 VGPRs)
typedef __attribute__((ext_vector_type(4))) float f32x4;
typedef __attribute__((ext_vector_type(2))) float f32x2;
#define DEVINL __device__ __forceinline__

constexpr int Bc  = 2;
constexpr int Nc  = 768;
constexpr int Dc  = 512;
constexpr int Hc  = 8;
constexpr int DKc = 64;
constexpr int BHc = Bc * Hc;
constexpr float SCALE    = 0.125f;   // 1/sqrt(64)
constexpr float EPSF     = 1e-6f;
constexpr float BETA_NOT = 0.5f;

DEVINL float ldf(const float* p, long i) { return p[i]; }
DEVINL float ldf(const bf16* p, long i) { return __bfloat162float(p[i]); }
DEVINL void stf(float* p, long i, float v) { p[i] = v; }
DEVINL void stf(bf16* p, long i, float v) { p[i] = __float2bfloat16(v); }

DEVINL float sigf(float x) { return __fdividef(1.f, 1.f + __expf(-x)); }

// packed fp32 pair helpers — backend selects v_pk_fma_f32/v_pk_mul_f32 (r3:
// validated -41% on gates_smix; r4 pair-dup operands -12%; r5 s_load weights).
DEVINL f32x2 fma2(f32x2 a, f32x2 b, f32x2 c) { return __builtin_elementwise_fma(a, b, c); }
DEVINL f32x2 splat2(float x) { return (f32x2){x, x}; }
// guard-free transcendentals (libm exp2f adds a denormal guard: +13% in r2)
DEVINL float vexp2(float x) { float r; asm("v_exp_f32 %0, %1" : "=v"(r) : "v"(x)); return r; }
DEVINL float vrcp(float x)  { float r; asm("v_rcp_f32 %0, %1" : "=v"(r) : "v"(x)); return r; }
DEVINL float vlog2(float x) { float r; asm("v_log_f32 %0, %1" : "=v"(r) : "v"(x)); return r; }

// async global->LDS, 16B per lane; LDS dest = wave-uniform base + lane*16.
DEVINL void gl_lds16(const void* g, void* l) {
    __builtin_amdgcn_global_load_lds(
        (const __attribute__((address_space(1))) void*)g,
        (__attribute__((address_space(3))) void*)l, 16, 0, 0);
}

// ---------------------------------------------------------------------------
// Dtype sniffer — vectorized (validated round 9).
// ---------------------------------------------------------------------------
DEVINL int sniff_is_fp32(const void* xraw) {
    const uint4* p4 = (const uint4*)xraw;
    float mx = 0.f;
#pragma unroll
    for (int j = 0; j < 16; ++j) {
        const uint4 u = p4[j];
        const unsigned w[4] = {u.x, u.y, u.z, u.w};
#pragma unroll
        for (int t = 0; t < 4; ++t) {
            mx = fmaxf(mx, fabsf(__uint_as_float((w[t] & 0xffffu) << 16)));
            mx = fmaxf(mx, fabsf(__uint_as_float(w[t] & 0xffff0000u)));
        }
    }
    return mx > 1000.f ? 1 : 0;
}

DEVINL float cvt_elem(const void* s, long j, int is32) {
    return is32 ? ((const float*)s)[j]
                : __bfloat162float(((const bf16*)s)[j]);
}

// smallf layout (round 15 — PAIR-DUPLICATED; read via uniform scalar loads):
//   [u*24 + 2k+{0,1}]  = w1[u][k]          k=0..5   (12 floats)
//   [u*24 + 12..13]    = b1[u] pair
//   [u*24 + 14..15]    = pad
//   [u*24 + 16 + 2o+{0,1}] = conv2_w[o][u] o=0..3   (8 floats)
//   [384..391]  conv2_b[o] pairs
//   [392..393]  chain_logit pair          (combine reads [392])
__global__ __launch_bounds__(256) void convert_all(
    const void* x, const void* w1, const void* w2, const void* pw,
    const void* c1w, const void* c1b, const void* c2w, const void* c2b,
    const void* ch,
    bf16* xb, bf16* w1b, bf16* w2b, bf16* pwb, float* smallf)
{
    __shared__ int is32s;
    if (threadIdx.x == 0) is32s = sniff_is_fp32(x);
    __syncthreads();
    const int is32 = is32s;
    const long i = (long)blockIdx.x * 256 + threadIdx.x;
    if (i < (long)Bc * Nc * Dc) {
        xb[i]  = __float2bfloat16(cvt_elem(x,  i, is32));
        w1b[i] = __float2bfloat16(cvt_elem(w1, i, is32));
        w2b[i] = __float2bfloat16(cvt_elem(w2, i, is32));
    }
    if (i < (long)Dc * Dc) pwb[i] = __float2bfloat16(cvt_elem(pw, i, is32));
    if (i < 384) {
        const int u = (int)i / 24, k = (int)i % 24;
        float v = 0.f;
        if (k < 12)      v = cvt_elem(c1w, u * 6 + (k >> 1), is32);
        else if (k < 14) v = cvt_elem(c1b, u, is32);
        else if (k >= 16) { const int o = (k - 16) >> 1; v = cvt_elem(c2w, o * 16 + u, is32); }
        smallf[i] = v;
    } else if (i < 392) smallf[i] = cvt_elem(c2b, ((int)i - 384) >> 1, is32);
    else if (i < 394) smallf[i] = cvt_elem(ch, 0, is32);
    else if (i < 512) smallf[i] = 0.f;
}

__global__ __launch_bounds__(256) void fill_sentinel(unsigned short* o) {
    const long i = (long)blockIdx.x * 256 + threadIdx.x;
    if (i < (long)Bc * Nc * Dc) o[i] = 0x40E0;  // bf16 7.0
}

// ---------------------------------------------------------------------------
// Generic bf16 transpose, 64x64 tiles: dst[c][r] = src[r][c]; src is (R,C).
// ---------------------------------------------------------------------------
__global__ __launch_bounds__(256) void transpose_bf16(
    const unsigned short* __restrict__ src, unsigned short* __restrict__ dst,
    int R, int C, long sS, long sD)
{
    __shared__ unsigned short tile[64][68];
    const unsigned short* s = src + (long)blockIdx.z * sS;
    unsigned short* d = dst + (long)blockIdx.z * sD;
    const int r0 = blockIdx.y * 64, c0 = blockIdx.x * 64;
    const int t = threadIdx.x;
    const int lr = t >> 4, lc4 = (t & 15) * 4;
#pragma unroll
    for (int i = 0; i < 4; ++i) {
        int r = lr + i * 16;
        *(uint2*)&tile[r][lc4] = *(const uint2*)&s[(long)(r0 + r) * C + c0 + lc4];
    }
    __syncthreads();
#pragma unroll
    for (int i = 0; i < 4; ++i) {
        int r = lr + i * 16;
        unsigned short v[4];
#pragma unroll
        for (int j = 0; j < 4; ++j) v[j] = tile[lc4 + j][r];
        *(uint2*)&d[(long)(c0 + r) * R + r0 + lc4] = *(uint2*)v;
    }
}

// ---------------------------------------------------------------------------
// MFMA bf16 NT GEMM with global_load_lds staging.
// Round 19: 2-PHASE double-buffered K-loop (T3-lite). r6 showed step-4 is
// latency-bound (busy 41% of 99 µs): the old 1-phase loop exposed the full
// load latency every K-step with only ~2 blocks/CU of TLP. Now: issue next
// tile's stage into buf^1, compute current buf, ONE __syncthreads (its
// vmcnt(0) drain covers the just-issued loads). Barriers/step 2 -> 1.
//  - XCDSWZ: 1-D grid 1152 = 8 xcd * (4 batch * 36 tile) — kept (FETCH 5x
//    cut, r6). RAW: also store pre-log C (z<16) for associativity y_chain.
//  - read-XOR swizzle kept (r6: conflict-count-neutral, cost-free).
// ---------------------------------------------------------------------------
template <int EPI, typename TC, int XORB = 0, int XCDSWZ = 0, int RAW = 0>
__global__ __launch_bounds__(256) void gemm_nt_mfma(
    const bf16* __restrict__ Ag, const bf16* __restrict__ Btg,
    TC* __restrict__ Cg, bf16* __restrict__ Craw, int M, int N, int K,
    long sA, long sB, long sC, float alpha)
{
    __shared__ unsigned short Asm[2 * 128 * 32];
    __shared__ unsigned short Bsm[2 * 128 * 32];
    constexpr int BUF = 128 * 32;   // elements per buffer

    int bx, by, bz;
    if (XCDSWZ) {
        const int wg = blockIdx.x;
        const int xcd = wg & 7, t = wg >> 3;
        bz = xcd + 8 * (t / 36);
        const int tile = t % 36;
        bx = tile % 6; by = tile / 6;
    } else { bx = blockIdx.x; by = blockIdx.y; bz = blockIdx.z; }

    const int tid  = threadIdx.x;
    const int wv   = tid >> 6;
    const int lane = tid & 63;
    const int q    = lane >> 4;
    const int ln   = lane & 15;
    const int wm   = wv & 1;
    const int wn   = wv >> 1;

    const int zb = XORB ? (bz ^ 16) : bz;
    const bf16* A  = Ag  + (long)bz * sA + (long)(by * 128) * K;
    const bf16* Bt = Btg + (long)zb * sB + (long)(bx * 128) * K;
    TC*         C  = Cg  + (long)bz * sC;

    const int sr = lane >> 2, sc = lane & 3;
    const int scs = sc ^ (sr & 3);          // source col-block pre-swizzle
    const bf16* gA0 = A  + (long)(wv * 32 + sr)      * K + scs * 8;
    const bf16* gA1 = A  + (long)(wv * 32 + 16 + sr) * K + scs * 8;
    const bf16* gB0 = Bt + (long)(wv * 32 + sr)      * K + scs * 8;
    const bf16* gB1 = Bt + (long)(wv * 32 + 16 + sr) * K + scs * 8;
    unsigned short* lA0 = &Asm[(wv * 32)      * 32];
    unsigned short* lA1 = &Asm[(wv * 32 + 16) * 32];
    unsigned short* lB0 = &Bsm[(wv * 32)      * 32];
    unsigned short* lB1 = &Bsm[(wv * 32 + 16) * 32];

    f32x4 acc[4][4];
#pragma unroll
    for (int i = 0; i < 4; ++i)
#pragma unroll
        for (int j = 0; j < 4; ++j)
            acc[i][j] = (f32x4){0.f, 0.f, 0.f, 0.f};

    const int qs = (q ^ (ln & 3)) * 8;      // swizzled read block

    // prologue: stage K-tile 0 into buffer 0, drain, sync
    gl_lds16(gA0, lA0);
    gl_lds16(gA1, lA1);
    gl_lds16(gB0, lB0);
    gl_lds16(gB1, lB1);
    __syncthreads();

    int cur = 0;
    for (int k0 = 0; k0 < K; k0 += 32) {
        const int nxt = cur ^ 1;
        if (k0 + 32 < K) {                  // issue NEXT tile's loads (async)
            const int no = nxt * BUF;
            gl_lds16(gA0 + k0 + 32, lA0 + no);
            gl_lds16(gA1 + k0 + 32, lA1 + no);
            gl_lds16(gB0 + k0 + 32, lB0 + no);
            gl_lds16(gB1 + k0 + 32, lB1 + no);
        }

        const unsigned short* Ac = &Asm[cur * BUF];
        const unsigned short* Bc = &Bsm[cur * BUF];
        short8 af[4], bfr[4];
#pragma unroll
        for (int mt = 0; mt < 4; ++mt) {
            int m = wm * 64 + mt * 16 + ln;
            af[mt] = *(const short8*)&Ac[m * 32 + qs];
        }
#pragma unroll
        for (int nt = 0; nt < 4; ++nt) {
            int n = wn * 64 + nt * 16 + ln;
            bfr[nt] = *(const short8*)&Bc[n * 32 + qs];
        }
#pragma unroll
        for (int mt = 0; mt < 4; ++mt)
#pragma unroll
            for (int nt = 0; nt < 4; ++nt)
                acc[mt][nt] = __builtin_amdgcn_mfma_f32_16x16x32_bf16(
                    af[mt], bfr[nt], acc[mt][nt], 0, 0, 0);

        __syncthreads();   // vmcnt(0) drain of next-tile loads + wave sync
        cur = nxt;
    }

#pragma unroll
    for (int mt = 0; mt < 4; ++mt) {
#pragma unroll
        for (int nt = 0; nt < 4; ++nt) {
            const int col = bx * 128 + wn * 64 + nt * 16 + ln;
            const int rowb = by * 128 + wm * 64 + mt * 16 + q * 4;
#pragma unroll
            for (int r = 0; r < 4; ++r) {
                float vraw = acc[mt][nt][r] * alpha;
                if (RAW) {
                    if (bz < 16)
                        Craw[(long)bz * M * N + (long)(rowb + r) * N + col] =
                            __float2bfloat16(vraw);
                }
                float v = vraw;
                if (EPI == 1) v = __logf(fmaxf(v, 0.f) + EPSF);
                stf(C, (long)(rowb + r) * N + col, v);
            }
        }
    }
}

// ---------------------------------------------------------------------------
// QKV via MFMA, merged sets — round 19: same 2-phase double-buffered K-loop.
// ---------------------------------------------------------------------------
__global__ __launch_bounds__(256) void qkv_mfma(
    const bf16* __restrict__ X,
    const bf16* __restrict__ w1t, const bf16* __restrict__ w2t,
    bf16* __restrict__ q1, bf16* __restrict__ k1, bf16* __restrict__ v1,
    bf16* __restrict__ q2, bf16* __restrict__ k2, bf16* __restrict__ v2)
{
    constexpr int K = Dc;  // 512
    __shared__ unsigned short Asm[2 * 128 * 32];
    __shared__ unsigned short Bsm[2 * 128 * 32];
    constexpr int BUF = 128 * 32;

    const int tid  = threadIdx.x;
    const int wv   = tid >> 6;
    const int lane = tid & 63;
    const int q    = lane >> 4;
    const int ln   = lane & 15;
    const int wm   = wv & 1;
    const int wn   = wv >> 1;
    const int set  = blockIdx.z;

    const bf16* Wt = set ? w2t : w1t;
    bf16* Q  = set ? q2 : q1;
    bf16* Ko = set ? k2 : k1;
    bf16* V  = set ? v2 : v1;

    const bf16* A  = X  + (long)(blockIdx.y * 128) * K;
    const bf16* Bt = Wt + (long)(blockIdx.x * 128) * K;

    const int sr = lane >> 2, sc = lane & 3;
    const int scs = sc ^ (sr & 3);
    const bf16* gA0 = A  + (long)(wv * 32 + sr)      * K + scs * 8;
    const bf16* gA1 = A  + (long)(wv * 32 + 16 + sr) * K + scs * 8;
    const bf16* gB0 = Bt + (long)(wv * 32 + sr)      * K + scs * 8;
    const bf16* gB1 = Bt + (long)(wv * 32 + 16 + sr) * K + scs * 8;
    unsigned short* lA0 = &Asm[(wv * 32)      * 32];
    unsigned short* lA1 = &Asm[(wv * 32 + 16) * 32];
    unsigned short* lB0 = &Bsm[(wv * 32)      * 32];
    unsigned short* lB1 = &Bsm[(wv * 32 + 16) * 32];

    f32x4 acc[4][4];
#pragma unroll
    for (int i = 0; i < 4; ++i)
#pragma unroll
        for (int j = 0; j < 4; ++j)
            acc[i][j] = (f32x4){0.f, 0.f, 0.f, 0.f};

    const int qs = (q ^ (ln & 3)) * 8;

    gl_lds16(gA0, lA0);
    gl_lds16(gA1, lA1);
    gl_lds16(gB0, lB0);
    gl_lds16(gB1, lB1);
    __syncthreads();

    int cur = 0;
    for (int k0 = 0; k0 < K; k0 += 32) {
        const int nxt = cur ^ 1;
        if (k0 + 32 < K) {
            const int no = nxt * BUF;
            gl_lds16(gA0 + k0 + 32, lA0 + no);
            gl_lds16(gA1 + k0 + 32, lA1 + no);
            gl_lds16(gB0 + k0 + 32, lB0 + no);
            gl_lds16(gB1 + k0 + 32, lB1 + no);
        }

        const unsigned short* Ac = &Asm[cur * BUF];
        const unsigned short* Bc = &Bsm[cur * BUF];
        short8 af[4], bfr[4];
#pragma unroll
        for (int mt = 0; mt < 4; ++mt) {
            int m = wm * 64 + mt * 16 + ln;
            af[mt] = *(const short8*)&Ac[m * 32 + qs];
        }
#pragma unroll
        for (int nt = 0; nt < 4; ++nt) {
            int n = wn * 64 + nt * 16 + ln;
            bfr[nt] = *(const short8*)&Bc[n * 32 + qs];
        }
#pragma unroll
        for (int mt = 0; mt < 4; ++mt)
#pragma unroll
            for (int nt = 0; nt < 4; ++nt)
                acc[mt][nt] = __builtin_amdgcn_mfma_f32_16x16x32_bf16(
                    af[mt], bfr[nt], acc[mt][nt], 0, 0, 0);

        __syncthreads();
        cur = nxt;
    }

#pragma unroll
    for (int mt = 0; mt < 4; ++mt) {
#pragma unroll
        for (int nt = 0; nt < 4; ++nt) {
            const int col  = blockIdx.x * 128 + wn * 64 + nt * 16 + ln;
            const int rowb = blockIdx.y * 128 + wm * 64 + mt * 16 + q * 4;
            const int t = col >> 9;
            const int h = (col >> 6) & 7;
            const int dk = col & 63;
            bf16* dst = (t == 0) ? Q : (t == 1) ? Ko : V;
#pragma unroll
            for (int r = 0; r < 4; ++r) {
                const int row = rowb + r;
                const int b = row >= Nc ? 1 : 0;
                const int n = row - b * Nc;
                dst[(((long)b * Hc + h) * Nc + n) * DKc + dk] =
                    __float2bfloat16(acc[mt][nt][r]);
            }
        }
    }
}

// ---------------------------------------------------------------------------
// MFMA bf16 NT narrow GEMM core (validated): acc = A(128,K) @ Bt(64,K)^T.
// Reg-staged, stride-72 LDS (conflict-free by construction).
// ---------------------------------------------------------------------------
struct N64Acc { f32x4 acc[2][4]; };

template <typename DUMMY = void>
DEVINL void n64_core(const bf16* A, const bf16* Bt, int K,
                     unsigned short* Asm, unsigned short* Bsm, N64Acc& R)
{
    const int tid  = threadIdx.x;
    const int wave = tid >> 6;
    const int lane = tid & 63;
    const int q    = lane >> 4;
    const int ln   = lane & 15;

    const int sr = tid >> 3, k8 = tid & 7;
    const bf16* pa[4];
    const bf16* pb[2];
    int wa[4], wb[2];
#pragma unroll
    for (int i = 0; i < 4; ++i) {
        pa[i] = A + (long)(sr + i * 32) * K + k8 * 8;
        wa[i] = (sr + i * 32) * 72 + k8 * 8;
    }
#pragma unroll
    for (int i = 0; i < 2; ++i) {
        pb[i] = Bt + (long)(sr + i * 32) * K + k8 * 8;
        wb[i] = (sr + i * 32) * 72 + k8 * 8;
    }

#pragma unroll
    for (int i = 0; i < 2; ++i)
#pragma unroll
        for (int j = 0; j < 4; ++j)
            R.acc[i][j] = (f32x4){0.f, 0.f, 0.f, 0.f};

    for (int k0 = 0; k0 < K; k0 += 64) {
        uint4 va[4], vb[2];
#pragma unroll
        for (int i = 0; i < 4; ++i) va[i] = *(const uint4*)(pa[i] + k0);
#pragma unroll
        for (int i = 0; i < 2; ++i) vb[i] = *(const uint4*)(pb[i] + k0);
        __syncthreads();
#pragma unroll
        for (int i = 0; i < 4; ++i) *(uint4*)&Asm[wa[i]] = va[i];
#pragma unroll
        for (int i = 0; i < 2; ++i) *(uint4*)&Bsm[wb[i]] = vb[i];
        __syncthreads();

#pragma unroll
        for (int kc = 0; kc < 2; ++kc) {
            short8 af[2], bfr[4];
#pragma unroll
            for (int mt = 0; mt < 2; ++mt) {
                int m = wave * 32 + mt * 16 + ln;
                af[mt] = *(const short8*)&Asm[m * 72 + kc * 32 + q * 8];
            }
#pragma unroll
            for (int nt = 0; nt < 4; ++nt) {
                int n = nt * 16 + ln;
                bfr[nt] = *(const short8*)&Bsm[n * 72 + kc * 32 + q * 8];
            }
#pragma unroll
            for (int mt = 0; mt < 2; ++mt)
#pragma unroll
                for (int nt = 0; nt < 4; ++nt)
                    R.acc[mt][nt] = __builtin_amdgcn_mfma_f32_16x16x32_bf16(
                        af[mt], bfr[nt], R.acc[mt][nt], 0, 0, 0);
        }
    }
}

// ---------------------------------------------------------------------------
// Merged pair launch (Path-B fallback only; validated round 11).
// ---------------------------------------------------------------------------
__global__ __launch_bounds__(256) void gemm_n64_pair(
    const bf16* __restrict__ A0g, const bf16* __restrict__ B0g, bf16* __restrict__ C0tg,
    const bf16* __restrict__ A1g, const bf16* __restrict__ B1g, bf16* __restrict__ C1g,
    int M, int K, long sA, long sB, long sC)
{
    __shared__ unsigned short Asm[128 * 72];
    __shared__ unsigned short Bsm[64 * 72];

    const int zz = blockIdx.z & 15;
    const int second = blockIdx.z >> 4;
    const bf16* A  = (second ? A1g : A0g) + (long)zz * sA + (long)(blockIdx.y * 128) * K;
    const bf16* Bt = (second ? B1g : B0g) + (long)zz * sB;

    N64Acc R;
    n64_core(A, Bt, K, Asm, Bsm, R);

    const int tid = threadIdx.x;
    const int wave = tid >> 6, lane = tid & 63, q = lane >> 4, ln = lane & 15;

    if (second) {
        bf16* C = C1g + (long)zz * sC;
#pragma unroll
        for (int mt = 0; mt < 2; ++mt) {
#pragma unroll
            for (int nt = 0; nt < 4; ++nt) {
                const int col  = nt * 16 + ln;
                const int rowb = blockIdx.y * 128 + wave * 32 + mt * 16 + q * 4;
#pragma unroll
                for (int r = 0; r < 4; ++r)
                    C[(long)(rowb + r) * 64 + col] = __float2bfloat16(R.acc[mt][nt][r]);
            }
        }
    } else {
        __syncthreads();
#pragma unroll
        for (int mt = 0; mt < 2; ++mt) {
#pragma unroll
            for (int nt = 0; nt < 4; ++nt) {
                const int col = nt * 16 + ln;
                const int rwb = wave * 32 + mt * 16 + q * 4;
#pragma unroll
                for (int r = 0; r < 4; ++r)
                    *(bf16*)&Asm[col * 136 + rwb + r] = __float2bfloat16(R.acc[mt][nt][r]);
            }
        }
        __syncthreads();
        bf16* Ct = C0tg + (long)zz * sC;
        const int dk  = tid >> 2;
        const int nc0 = (tid & 3) * 32;
        const int gn0 = blockIdx.y * 128;
#pragma unroll
        for (int c8 = 0; c8 < 4; ++c8) {
            uint4 v = *(const uint4*)&Asm[dk * 136 + nc0 + c8 * 8];
            *(uint4*)&Ct[(long)dk * Nc + gn0 + nc0 + c8 * 8] = v;
        }
    }
}

// y_base-only n64 GEMM (Path A): C = A @ Bt^T, plain (Nc x 64) store.
__global__ __launch_bounds__(256) void gemm_n64_yb(
    const bf16* __restrict__ Ag, const bf16* __restrict__ Btg,
    bf16* __restrict__ Cg, int M, int K, long sA, long sB, long sC)
{
    __shared__ unsigned short Asm[128 * 72];
    __shared__ unsigned short Bsm[64 * 72];

    const int zz = blockIdx.z;
    const bf16* A  = Ag + (long)zz * sA + (long)(blockIdx.y * 128) * K;
    const bf16* Bt = Btg + (long)zz * sB;

    N64Acc R;
    n64_core(A, Bt, K, Asm, Bsm, R);

    bf16* C = Cg + (long)zz * sC;
    const int tid = threadIdx.x;
    const int wave = tid >> 6, lane = tid & 63, q = lane >> 4, ln = lane & 15;
#pragma unroll
    for (int mt = 0; mt < 2; ++mt) {
#pragma unroll
        for (int nt = 0; nt < 4; ++nt) {
            const int col  = nt * 16 + ln;
            const int rowb = blockIdx.y * 128 + wave * 32 + mt * 16 + q * 4;
#pragma unroll
            for (int r = 0; r < 4; ++r)
                C[(long)(rowb + r) * 64 + col] = __float2bfloat16(R.acc[mt][nt][r]);
        }
    }
}

// y_chain GEMM with fused combine + permute. Path A: A = raw C_right
// (associativity: y_chain = (A1@A2)@v2), Bt = v2t. Path B: A=A1b, Bt=trt.
__global__ __launch_bounds__(256) void gemm_n64_combine(
    const bf16* __restrict__ A1b, const bf16* __restrict__ trt,
    const bf16* __restrict__ yb1, const float* __restrict__ smallf,
    bf16* __restrict__ yc, int M, int K, long sA, long sB)
{
    __shared__ unsigned short Asm[128 * 72];
    __shared__ unsigned short Bsm[64 * 72];

    const int bh = blockIdx.z;
    const bf16* A  = A1b + (long)bh * sA + (long)(blockIdx.y * 128) * K;
    const bf16* Bt = trt + (long)bh * sB;

    N64Acc R;
    n64_core(A, Bt, K, Asm, Bsm, R);

    const float w = sigf(smallf[392]);
    const int b = bh >> 3, h = bh & 7;
    const long yb1base = (long)bh * Nc * DKc;

    const int tid = threadIdx.x;
    const int wave = tid >> 6, lane = tid & 63, q = lane >> 4, ln = lane & 15;
#pragma unroll
    for (int mt = 0; mt < 2; ++mt) {
#pragma unroll
        for (int nt = 0; nt < 4; ++nt) {
            const int col  = nt * 16 + ln;
            const int rowb = blockIdx.y * 128 + wave * 32 + mt * 16 + q * 4;
#pragma unroll
            for (int r = 0; r < 4; ++r) {
                const int n = rowb + r;
                const float base = __bfloat162float(yb1[yb1base + (long)n * 64 + col]);
                yc[((long)(b * Nc + n)) * Dc + h * DKc + col] =
                    __float2bfloat16(base + w * R.acc[mt][nt][r]);
            }
        }
    }
}

// ---------------------------------------------------------------------------
// Row softmax over width 768 — wave-per-row (validated round 16).
// ---------------------------------------------------------------------------
__global__ __launch_bounds__(256) void softmax_rows_w(
    const float* __restrict__ src, bf16* __restrict__ dst)
{
    const int wid  = threadIdx.x >> 6;
    const int lane = threadIdx.x & 63;
    const long row = (long)blockIdx.x * 4 + wid;
    const float* s = src + row * Nc;

    float4 v[3];
#pragma unroll
    for (int i = 0; i < 3; ++i)
        v[i] = *(const float4*)&s[i * 256 + lane * 4];

    float m = -1e30f;
#pragma unroll
    for (int i = 0; i < 3; ++i)
        m = fmaxf(m, fmaxf(fmaxf(v[i].x, v[i].y), fmaxf(v[i].z, v[i].w)));
#pragma unroll
    for (int off = 32; off > 0; off >>= 1)
        m = fmaxf(m, __shfl_xor(m, off, 64));

    float e[12];
    float sum = 0.f;
#pragma unroll
    for (int i = 0; i < 3; ++i) {
        e[i * 4 + 0] = __expf(v[i].x - m);
        e[i * 4 + 1] = __expf(v[i].y - m);
        e[i * 4 + 2] = __expf(v[i].z - m);
        e[i * 4 + 3] = __expf(v[i].w - m);
        sum += e[i * 4 + 0] + e[i * 4 + 1] + e[i * 4 + 2] + e[i * 4 + 3];
    }
#pragma unroll
    for (int off = 32; off > 0; off >>= 1)
        sum += __shfl_xor(sum, off, 64);

    const float inv = 1.f / fmaxf(sum, 1e-30f);
    unsigned short* d = (unsigned short*)dst + row * Nc;
#pragma unroll
    for (int i = 0; i < 3; ++i) {
        unsigned short o[4];
#pragma unroll
        for (int j = 0; j < 4; ++j) {
            const bf16 b = __float2bfloat16(e[i * 4 + j] * inv);
            o[j] = *(const unsigned short*)&b;
        }
        *(uint2*)&d[i * 256 + lane * 4] = *(const uint2*)o;
    }
}

// ---------------------------------------------------------------------------
// Gate network + Smix — validated round 16 version (s_load weights, packed
// pair math, guard-free transcendentals). VALU-issue-bound; VGPR 32.
// ---------------------------------------------------------------------------
__global__ __launch_bounds__(256) void gates_smix(
    const float* __restrict__ S1g, const float* __restrict__ S2g,
    const bf16* __restrict__ Crg, const bf16* __restrict__ Clg,
    float* __restrict__ Smixg, const float* __restrict__ smallf)
{
    __shared__ float t1t[32][17], t2t[32][17];

    const long mat = (long)blockIdx.z * Nc * Nc;
    const float* S1 = S1g + mat;
    const float* S2 = S2g + mat;
    const unsigned short* Cr = (const unsigned short*)Crg + mat;
    const unsigned short* Cl = (const unsigned short*)Clg + mat;
    float* Smix = Smixg + mat;

    const int tid = threadIdx.x;

    const int n0 = blockIdx.y * 16, m0 = blockIdx.x * 32;
    {   // transposed tiles: S[m0..m0+31][n0..n0+15], coalesced float2 loads
        const int r = tid >> 3, c2 = (tid & 7) * 2;
        const float2 a = *(const float2*)&S1[(long)(m0 + r) * Nc + n0 + c2];
        const float2 b = *(const float2*)&S2[(long)(m0 + r) * Nc + n0 + c2];
        t1t[r][c2] = a.x; t1t[r][c2 + 1] = a.y;
        t2t[r][c2] = b.x; t2t[r][c2 + 1] = b.y;
    }
    __syncthreads();

    const int tx = tid & 15, ty = tid >> 4;
    const int n = n0 + ty;
    const long idx = (long)n * Nc + m0 + tx * 2;

    const float2 s1v = *(const float2*)&S1[idx];
    const float2 s2v = *(const float2*)&S2[idx];
    const unsigned cru = *(const unsigned*)&Cr[idx];   // idx even -> 4B aligned
    const unsigned clu = *(const unsigned*)&Cl[idx];

    const f32x2 s1a = {s1v.x, s1v.y};
    const f32x2 s2a = {s2v.x, s2v.y};
    const f32x2 cra = {__uint_as_float((cru & 0xffffu) << 16),
                       __uint_as_float(cru & 0xffff0000u)};
    const f32x2 cla = {__uint_as_float((clu & 0xffffu) << 16),
                       __uint_as_float(clu & 0xffff0000u)};
    const f32x2 s1t = {t1t[tx * 2][ty], t1t[tx * 2 + 1][ty]};
    const f32x2 s2t = {t2t[tx * 2][ty], t2t[tx * 2 + 1][ty]};

    f32x2 g0 = *(const f32x2*)&smallf[384];
    f32x2 g1 = *(const f32x2*)&smallf[386];
    f32x2 g2 = *(const f32x2*)&smallf[388];
    f32x2 g3 = *(const f32x2*)&smallf[390];

    const f32x2 gc1  = splat2(-2.30220902f);   // gelu c1 * log2e
    const f32x2 gc3  = splat2(-0.10294357f);   // gelu c3 * log2e
    const f32x2 one2 = splat2(1.f);

#pragma unroll
    for (int u = 0; u < 16; ++u) {
        const f32x2* cw = (const f32x2*)&smallf[u * 24];
        f32x2 h = cw[6];
        h = fma2(s1a, cw[0], h);
        h = fma2(s2a, cw[1], h);
        h = fma2(s1t, cw[2], h);
        h = fma2(s2t, cw[3], h);
        h = fma2(cra, cw[4], h);
        h = fma2(cla, cw[5], h);
        const f32x2 hh = h * h;
        const f32x2 z2 = h * fma2(hh, gc3, gc1);
        f32x2 e;  e[0]  = vexp2(z2[0]); e[1]  = vexp2(z2[1]);
        const f32x2 d = one2 + e;
        f32x2 rc; rc[0] = vrcp(d[0]);   rc[1] = vrcp(d[1]);
        const f32x2 hid = h * rc;
        g0 = fma2(hid, cw[8],  g0);
        g1 = fma2(hid, cw[9],  g1);
        g2 = fma2(hid, cw[10], g2);
        g3 = fma2(hid, cw[11], g3);
    }

    const f32x2 nl2e = splat2(-1.44269504f);
    const f32x2 ln2v = splat2(0.69314718f);
    auto sig2 = [&](f32x2 x) -> f32x2 {
        const f32x2 t = x * nl2e;
        f32x2 e;  e[0] = vexp2(t[0]); e[1] = vexp2(t[1]);
        const f32x2 d = one2 + e;
        f32x2 r;  r[0] = vrcp(d[0]);  r[1] = vrcp(d[1]);
        return r;
    };
    const f32x2 ga2 = sig2(g0);
    const f32x2 go2 = sig2(g1);
    const f32x2 gn2 = sig2(g2);
    const f32x2 gc2 = sig2(g3);

    const f32x2 dd = s1a - s2a;
    f32x2 ad; ad[0] = fabsf(dd[0]); ad[1] = fabsf(dd[1]);
    const f32x2 t2 = ad * nl2e;                       // -|d| * log2e
    f32x2 ee; ee[0] = vexp2(t2[0]); ee[1] = vexp2(t2[1]);
    const f32x2 lp = one2 + ee;
    f32x2 lg; lg[0] = vlog2(lp[0]); lg[1] = vlog2(lp[1]);
    const f32x2 mx2 = __builtin_elementwise_max(s1a, s2a);
    const f32x2 lae = fma2(lg, ln2v, mx2);            // logaddexp(s1,s2)

    f32x2 o2 = s1a;
    o2 = fma2(ga2, s2a, o2);
    o2 = fma2(go2, lae - s1a, o2);
    o2 = fma2(gn2, s2a * splat2(-BETA_NOT), o2);
    o2 = fma2(gc2, cra, o2);
    *(float2*)&Smix[idx] = (float2){o2[0], o2[1]};
}

// ---------------------------------------------------------------------------
// Final projection via n64 core, 128x64 tiles (validated round 12).
// ---------------------------------------------------------------------------
__global__ __launch_bounds__(256) void proj_n64(
    const bf16* __restrict__ yc, const bf16* __restrict__ pwt,
    const void* __restrict__ xraw, void* __restrict__ out)
{
    constexpr int K = Dc;  // 512
    constexpr int N = Dc;  // 512
    __shared__ unsigned short Asm[128 * 72];
    __shared__ unsigned short Bsm[64 * 72];
    __shared__ int is32s;
    if (threadIdx.x == 0) is32s = sniff_is_fp32(xraw);

    const bf16* A  = yc  + (long)(blockIdx.y * 128) * K;
    const bf16* Bt = pwt + (long)(blockIdx.x * 64) * K;

    N64Acc R;
    n64_core(A, Bt, K, Asm, Bsm, R);   // internal barriers publish is32s

    const int is32 = is32s;
    const int tid = threadIdx.x;
    const int wave = tid >> 6, lane = tid & 63, q = lane >> 4, ln = lane & 15;
#pragma unroll
    for (int mt = 0; mt < 2; ++mt) {
#pragma unroll
        for (int nt = 0; nt < 4; ++nt) {
            const int col  = blockIdx.x * 64 + nt * 16 + ln;
            const int rowb = blockIdx.y * 128 + wave * 32 + mt * 16 + q * 4;
#pragma unroll
            for (int r = 0; r < 4; ++r) {
                const long o = (long)(rowb + r) * N + col;
                if (is32) ((float*)out)[o] = R.acc[mt][nt][r];
                else      ((bf16*)out)[o] = __float2bfloat16(R.acc[mt][nt][r]);
            }
        }
    }
}

// ---------------------------------------------------------------------------
extern "C" void kernel_launch(void* const* d_in, const int* in_sizes, int n_in,
                              void* d_out, int out_size, void* d_ws, size_t ws_size,
                              hipStream_t stream)
{
    const size_t HD   = (size_t)BHc * Nc * DKc;   // 786432
    const size_t HDh  = HD / 2;                   // float-slots for HD bf16
    const size_t MAT  = (size_t)Nc * Nc;          // 589824
    const size_t MATS = (size_t)BHc * MAT;        // 9437184
    const long   HSTR = (long)Nc * DKc;           // 49152 per-head stride

    float* ws = (float*)d_ws;
    size_t off = 0;
    auto alloc = [&](size_t n) { float* p = ws + off; off += n; return p; };

    bf16* xb  = (bf16*)alloc(HDh);
    bf16* w1b = (bf16*)alloc(HDh);   // w1b/w2b adjacent -> merged transpose
    bf16* w2b = (bf16*)alloc(HDh);
    bf16* w1t = (bf16*)alloc(HDh);
    bf16* w2t = (bf16*)alloc(HDh);
    bf16* pwb = (bf16*)alloc((size_t)Dc * Dc / 2);
    bf16* pwt = (bf16*)alloc((size_t)Dc * Dc / 2);
    float* smallf = alloc(512);
    // q1|q2 and k1|k2 adjacent -> single merged S-GEMM launch (32 heads)
    bf16* q1b = (bf16*)alloc(HDh); bf16* q2b = (bf16*)alloc(HDh);
    bf16* k1b = (bf16*)alloc(HDh); bf16* k2b = (bf16*)alloc(HDh);
    bf16* v1b = (bf16*)alloc(HDh); bf16* v2b = (bf16*)alloc(HDh);  // adjacent
    bf16* v1t = (bf16*)alloc(HDh); bf16* v2t = (bf16*)alloc(HDh);  // adjacent
    bf16* trt = (bf16*)alloc(HDh);
    float* S1   = alloc(MATS);       // S1/S2 adjacent -> merged softmax + S-GEMM
    float* S2   = alloc(MATS);
    float* Smix = alloc(MATS);       // region reused: A1tb|A2tb, then Smix
    bf16* A1b = (bf16*)alloc(MATS / 2);  // A1b/A2b adjacent
    bf16* A2b = (bf16*)alloc(MATS / 2);
    bf16* Crb = (bf16*)alloc(MATS / 2);  // Crb/Clb adjacent (merged launch)
    bf16* Clb = (bf16*)alloc(MATS / 2);
    bf16* yb1 = (bf16*)alloc(HDh);
    bf16* yc  = (bf16*)alloc(HDh);

    const size_t NEED_BASE = off * sizeof(float);
    bf16* Crawb = (bf16*)alloc(MATS / 2);          // raw C_right (Path A only)
    const size_t NEED_A = off * sizeof(float);
    const int pathA = ws_size >= NEED_A;

    // aliases into dead regions
    bf16* A1tb = (bf16*)Smix;            // live steps 3-4 (dead once gates writes Smix)
    bf16* A2tb = ((bf16*)Smix) + MATS;
    bf16* Ab   = (bf16*)S1;              // S1 dead after gates

    if (ws_size < NEED_BASE) {
        fill_sentinel<<<dim3(3072), 256, 0, stream>>>((unsigned short*)d_out);
        return;
    }

    // 0. normalize inputs
    convert_all<<<dim3(3072), 256, 0, stream>>>(
        d_in[0], d_in[1], d_in[2], d_in[3], d_in[4], d_in[5], d_in[6], d_in[7],
        d_in[8], xb, w1b, w2b, pwb, smallf);

    // 1. merged W transposes; pw transpose; merged QKV; merged v transposes
    transpose_bf16<<<dim3(24, 8, 2), 256, 0, stream>>>(
        (const unsigned short*)w1b, (unsigned short*)w1t, Dc, 3 * Dc, (long)HD, (long)HD);
    transpose_bf16<<<dim3(8, 8, 1), 256, 0, stream>>>(
        (const unsigned short*)pwb, (unsigned short*)pwt, Dc, Dc, 0, 0);
    qkv_mfma<<<dim3(12, 12, 2), 256, 0, stream>>>(
        xb, w1t, w2t, q1b, k1b, v1b, q2b, k2b, v2b);
    transpose_bf16<<<dim3(1, 12, 2 * BHc), 256, 0, stream>>>(
        (const unsigned short*)v1b, (unsigned short*)v1t, Nc, DKc, HSTR, HSTR);

    // 2. S = scale * q @ k^T — single 32-batch launch (2-phase K-loop)
    gemm_nt_mfma<0, float><<<dim3(6, 6, 2 * BHc), 256, 0, stream>>>(
        q1b, k1b, S1, nullptr, Nc, Nc, DKc, HSTR, HSTR, (long)MAT, SCALE);

    // 3. merged softmax S1|S2 -> A1b|A2b (wave-per-row); merged transposes
    softmax_rows_w<<<(2 * BHc * Nc) / 4, 256, 0, stream>>>(S1, A1b);
    transpose_bf16<<<dim3(12, 12, 2 * BHc), 256, 0, stream>>>(
        (const unsigned short*)A1b, (unsigned short*)A1tb, Nc, Nc, (long)MAT, (long)MAT);

    // 4. Cr|Cl in ONE 32-batch launch; XCD-pinned 1-D grid (1152 = 8*4*36);
    //    2-phase double-buffered K-loop; Path A also stores raw C_right.
    if (pathA)
        gemm_nt_mfma<1, bf16, 1, 1, 1><<<dim3(1152), 256, 0, stream>>>(
            A1b, A1tb, Crb, Crawb, Nc, Nc, Nc, (long)MAT, (long)MAT, (long)MAT, 1.f);
    else
        gemm_nt_mfma<1, bf16, 1, 1, 0><<<dim3(1152), 256, 0, stream>>>(
            A1b, A1tb, Crb, nullptr, Nc, Nc, Nc, (long)MAT, (long)MAT, (long)MAT, 1.f);

    // 5. gates + Smix
    gates_smix<<<dim3(24, 48, BHc), 256, 0, stream>>>(S1, S2, Crb, Clb, Smix, smallf);

    // 6. A = softmax(Smix) -> bf16 (into S1 alias, wave-per-row)
    softmax_rows_w<<<(BHc * Nc) / 4, 256, 0, stream>>>(Smix, Ab);

    if (pathA) {
        // 7a. y_base = A @ v1 -> yb1
        gemm_n64_yb<<<dim3(1, 6, BHc), 256, 0, stream>>>(
            Ab, v1t, yb1, Nc, Nc, (long)MAT, HSTR, HSTR);
        // 7b. y_chain = C_right @ v2 (associativity), fused combine -> yc
        gemm_n64_combine<<<dim3(1, 6, BHc), 256, 0, stream>>>(
            Crawb, v2t, yb1, smallf, yc, Nc, Nc, (long)MAT, HSTR);
    } else {
        // Path B fallback (round-5 structure)
        gemm_n64_pair<<<dim3(1, 6, 2 * BHc), 256, 0, stream>>>(
            A2b, v2t, trt, Ab, v1t, yb1, Nc, Nc, (long)MAT, HSTR, HSTR);
        gemm_n64_combine<<<dim3(1, 6, BHc), 256, 0, stream>>>(
            A1b, trt, yb1, smallf, yc, Nc, Nc, (long)MAT, HSTR);
    }

    // 9. proj via n64 core, 128x64 tiles (96 blocks)
    proj_n64<<<dim3(8, 12, 1), 256, 0, stream>>>(yc, pwt, d_in[0], d_out);
}

// Round 8
// 368.961 us; speedup vs baseline: 1.3386x; 1.0391x over previous
//
#include <hip/hip_runtime.h>
#include <hip/hip_bf16.h>
#include <math.h>

typedef __hip_bfloat16 bf16;
typedef __attribute__((ext_vector_type(8))) short short8;   // 8 bf16 (4 VGPRs)
typedef __attribute__((ext_vector_type(4))) float f32x4;
typedef __attribute__((ext_vector_type(2))) float f32x2;
#define DEVINL __device__ __forceinline__

constexpr int Bc  = 2;
constexpr int Nc  = 768;
constexpr int Dc  = 512;
constexpr int Hc  = 8;
constexpr int DKc = 64;
constexpr int BHc = Bc * Hc;
constexpr float SCALE    = 0.125f;   // 1/sqrt(64)
constexpr float EPSF     = 1e-6f;
constexpr float BETA_NOT = 0.5f;

DEVINL float ldf(const float* p, long i) { return p[i]; }
DEVINL float ldf(const bf16* p, long i) { return __bfloat162float(p[i]); }
DEVINL void stf(float* p, long i, float v) { p[i] = v; }
DEVINL void stf(bf16* p, long i, float v) { p[i] = __float2bfloat16(v); }

DEVINL float sigf(float x) { return __fdividef(1.f, 1.f + __expf(-x)); }

// packed fp32 pair helpers — backend selects v_pk_fma_f32/v_pk_mul_f32 (r3:
// validated -41% on gates_smix; r4 pair-dup operands -12%; r5 s_load weights).
DEVINL f32x2 fma2(f32x2 a, f32x2 b, f32x2 c) { return __builtin_elementwise_fma(a, b, c); }
DEVINL f32x2 splat2(float x) { return (f32x2){x, x}; }
// guard-free transcendentals (libm exp2f adds a denormal guard: +13% in r2)
DEVINL float vexp2(float x) { float r; asm("v_exp_f32 %0, %1" : "=v"(r) : "v"(x)); return r; }
DEVINL float vrcp(float x)  { float r; asm("v_rcp_f32 %0, %1" : "=v"(r) : "v"(x)); return r; }
DEVINL float vlog2(float x) { float r; asm("v_log_f32 %0, %1" : "=v"(r) : "v"(x)); return r; }

// async global->LDS, 16B per lane; LDS dest = wave-uniform base + lane*16.
DEVINL void gl_lds16(const void* g, void* l) {
    __builtin_amdgcn_global_load_lds(
        (const __attribute__((address_space(1))) void*)g,
        (__attribute__((address_space(3))) void*)l, 16, 0, 0);
}

// ---------------------------------------------------------------------------
// Dtype sniffer — vectorized (validated round 9).
// ---------------------------------------------------------------------------
DEVINL int sniff_is_fp32(const void* xraw) {
    const uint4* p4 = (const uint4*)xraw;
    float mx = 0.f;
#pragma unroll
    for (int j = 0; j < 16; ++j) {
        const uint4 u = p4[j];
        const unsigned w[4] = {u.x, u.y, u.z, u.w};
#pragma unroll
        for (int t = 0; t < 4; ++t) {
            mx = fmaxf(mx, fabsf(__uint_as_float((w[t] & 0xffffu) << 16)));
            mx = fmaxf(mx, fabsf(__uint_as_float(w[t] & 0xffff0000u)));
        }
    }
    return mx > 1000.f ? 1 : 0;
}

DEVINL float cvt_elem(const void* s, long j, int is32) {
    return is32 ? ((const float*)s)[j]
                : __bfloat162float(((const bf16*)s)[j]);
}

// smallf layout (round 15 — PAIR-DUPLICATED; read via uniform scalar loads):
//   [u*24 + 2k+{0,1}]  = w1[u][k]          k=0..5   (12 floats)
//   [u*24 + 12..13]    = b1[u] pair
//   [u*24 + 14..15]    = pad
//   [u*24 + 16 + 2o+{0,1}] = conv2_w[o][u] o=0..3   (8 floats)
//   [384..391]  conv2_b[o] pairs
//   [392..393]  chain_logit pair          (combine reads [392])
__global__ __launch_bounds__(256) void convert_all(
    const void* x, const void* w1, const void* w2, const void* pw,
    const void* c1w, const void* c1b, const void* c2w, const void* c2b,
    const void* ch,
    bf16* xb, bf16* w1b, bf16* w2b, bf16* pwb, float* smallf)
{
    __shared__ int is32s;
    if (threadIdx.x == 0) is32s = sniff_is_fp32(x);
    __syncthreads();
    const int is32 = is32s;
    const long i = (long)blockIdx.x * 256 + threadIdx.x;
    if (i < (long)Bc * Nc * Dc) {
        xb[i]  = __float2bfloat16(cvt_elem(x,  i, is32));
        w1b[i] = __float2bfloat16(cvt_elem(w1, i, is32));
        w2b[i] = __float2bfloat16(cvt_elem(w2, i, is32));
    }
    if (i < (long)Dc * Dc) pwb[i] = __float2bfloat16(cvt_elem(pw, i, is32));
    if (i < 384) {
        const int u = (int)i / 24, k = (int)i % 24;
        float v = 0.f;
        if (k < 12)      v = cvt_elem(c1w, u * 6 + (k >> 1), is32);
        else if (k < 14) v = cvt_elem(c1b, u, is32);
        else if (k >= 16) { const int o = (k - 16) >> 1; v = cvt_elem(c2w, o * 16 + u, is32); }
        smallf[i] = v;
    } else if (i < 392) smallf[i] = cvt_elem(c2b, ((int)i - 384) >> 1, is32);
    else if (i < 394) smallf[i] = cvt_elem(ch, 0, is32);
    else if (i < 512) smallf[i] = 0.f;
}

__global__ __launch_bounds__(256) void fill_sentinel(unsigned short* o) {
    const long i = (long)blockIdx.x * 256 + threadIdx.x;
    if (i < (long)Bc * Nc * Dc) o[i] = 0x40E0;  // bf16 7.0
}

// ---------------------------------------------------------------------------
// Generic bf16 transpose, 64x64 tiles: dst[c][r] = src[r][c]; src is (R,C).
// ---------------------------------------------------------------------------
__global__ __launch_bounds__(256) void transpose_bf16(
    const unsigned short* __restrict__ src, unsigned short* __restrict__ dst,
    int R, int C, long sS, long sD)
{
    __shared__ unsigned short tile[64][68];
    const unsigned short* s = src + (long)blockIdx.z * sS;
    unsigned short* d = dst + (long)blockIdx.z * sD;
    const int r0 = blockIdx.y * 64, c0 = blockIdx.x * 64;
    const int t = threadIdx.x;
    const int lr = t >> 4, lc4 = (t & 15) * 4;
#pragma unroll
    for (int i = 0; i < 4; ++i) {
        int r = lr + i * 16;
        *(uint2*)&tile[r][lc4] = *(const uint2*)&s[(long)(r0 + r) * C + c0 + lc4];
    }
    __syncthreads();
#pragma unroll
    for (int i = 0; i < 4; ++i) {
        int r = lr + i * 16;
        unsigned short v[4];
#pragma unroll
        for (int j = 0; j < 4; ++j) v[j] = tile[lc4 + j][r];
        *(uint2*)&d[(long)(c0 + r) * R + r0 + lc4] = *(uint2*)v;
    }
}

// ---------------------------------------------------------------------------
// MFMA bf16 NT GEMM — 2-phase double-buffered K-loop (validated r7: step-4
// 99 -> <78 µs; latency-bound 1-phase loop was the cause).
//  - XCDSWZ: 1-D grid 1152 = 8 xcd * (4 batch * 36 tile) — FETCH 5x cut (r6).
//  - RAW: also store pre-log C (z<16) for associativity y_chain.
//  - read-XOR swizzle kept (r6: conflict-count-neutral, cost-free).
// ---------------------------------------------------------------------------
template <int EPI, typename TC, int XORB = 0, int XCDSWZ = 0, int RAW = 0>
__global__ __launch_bounds__(256) void gemm_nt_mfma(
    const bf16* __restrict__ Ag, const bf16* __restrict__ Btg,
    TC* __restrict__ Cg, bf16* __restrict__ Craw, int M, int N, int K,
    long sA, long sB, long sC, float alpha)
{
    __shared__ unsigned short Asm[2 * 128 * 32];
    __shared__ unsigned short Bsm[2 * 128 * 32];
    constexpr int BUF = 128 * 32;   // elements per buffer

    int bx, by, bz;
    if (XCDSWZ) {
        const int wg = blockIdx.x;
        const int xcd = wg & 7, t = wg >> 3;
        bz = xcd + 8 * (t / 36);
        const int tile = t % 36;
        bx = tile % 6; by = tile / 6;
    } else { bx = blockIdx.x; by = blockIdx.y; bz = blockIdx.z; }

    const int tid  = threadIdx.x;
    const int wv   = tid >> 6;
    const int lane = tid & 63;
    const int q    = lane >> 4;
    const int ln   = lane & 15;
    const int wm   = wv & 1;
    const int wn   = wv >> 1;

    const int zb = XORB ? (bz ^ 16) : bz;
    const bf16* A  = Ag  + (long)bz * sA + (long)(by * 128) * K;
    const bf16* Bt = Btg + (long)zb * sB + (long)(bx * 128) * K;
    TC*         C  = Cg  + (long)bz * sC;

    const int sr = lane >> 2, sc = lane & 3;
    const int scs = sc ^ (sr & 3);          // source col-block pre-swizzle
    const bf16* gA0 = A  + (long)(wv * 32 + sr)      * K + scs * 8;
    const bf16* gA1 = A  + (long)(wv * 32 + 16 + sr) * K + scs * 8;
    const bf16* gB0 = Bt + (long)(wv * 32 + sr)      * K + scs * 8;
    const bf16* gB1 = Bt + (long)(wv * 32 + 16 + sr) * K + scs * 8;
    unsigned short* lA0 = &Asm[(wv * 32)      * 32];
    unsigned short* lA1 = &Asm[(wv * 32 + 16) * 32];
    unsigned short* lB0 = &Bsm[(wv * 32)      * 32];
    unsigned short* lB1 = &Bsm[(wv * 32 + 16) * 32];

    f32x4 acc[4][4];
#pragma unroll
    for (int i = 0; i < 4; ++i)
#pragma unroll
        for (int j = 0; j < 4; ++j)
            acc[i][j] = (f32x4){0.f, 0.f, 0.f, 0.f};

    const int qs = (q ^ (ln & 3)) * 8;      // swizzled read block

    // prologue: stage K-tile 0 into buffer 0, drain, sync
    gl_lds16(gA0, lA0);
    gl_lds16(gA1, lA1);
    gl_lds16(gB0, lB0);
    gl_lds16(gB1, lB1);
    __syncthreads();

    int cur = 0;
    for (int k0 = 0; k0 < K; k0 += 32) {
        const int nxt = cur ^ 1;
        if (k0 + 32 < K) {                  // issue NEXT tile's loads (async)
            const int no = nxt * BUF;
            gl_lds16(gA0 + k0 + 32, lA0 + no);
            gl_lds16(gA1 + k0 + 32, lA1 + no);
            gl_lds16(gB0 + k0 + 32, lB0 + no);
            gl_lds16(gB1 + k0 + 32, lB1 + no);
        }

        const unsigned short* Ac = &Asm[cur * BUF];
        const unsigned short* Bc = &Bsm[cur * BUF];
        short8 af[4], bfr[4];
#pragma unroll
        for (int mt = 0; mt < 4; ++mt) {
            int m = wm * 64 + mt * 16 + ln;
            af[mt] = *(const short8*)&Ac[m * 32 + qs];
        }
#pragma unroll
        for (int nt = 0; nt < 4; ++nt) {
            int n = wn * 64 + nt * 16 + ln;
            bfr[nt] = *(const short8*)&Bc[n * 32 + qs];
        }
#pragma unroll
        for (int mt = 0; mt < 4; ++mt)
#pragma unroll
            for (int nt = 0; nt < 4; ++nt)
                acc[mt][nt] = __builtin_amdgcn_mfma_f32_16x16x32_bf16(
                    af[mt], bfr[nt], acc[mt][nt], 0, 0, 0);

        __syncthreads();   // vmcnt(0) drain of next-tile loads + wave sync
        cur = nxt;
    }

#pragma unroll
    for (int mt = 0; mt < 4; ++mt) {
#pragma unroll
        for (int nt = 0; nt < 4; ++nt) {
            const int col = bx * 128 + wn * 64 + nt * 16 + ln;
            const int rowb = by * 128 + wm * 64 + mt * 16 + q * 4;
#pragma unroll
            for (int r = 0; r < 4; ++r) {
                float vraw = acc[mt][nt][r] * alpha;
                if (RAW) {
                    if (bz < 16)
                        Craw[(long)bz * M * N + (long)(rowb + r) * N + col] =
                            __float2bfloat16(vraw);
                }
                float v = vraw;
                if (EPI == 1) v = __logf(fmaxf(v, 0.f) + EPSF);
                stf(C, (long)(rowb + r) * N + col, v);
            }
        }
    }
}

// ---------------------------------------------------------------------------
// QKV via MFMA, merged sets — 2-phase double-buffered K-loop (r7).
// ---------------------------------------------------------------------------
__global__ __launch_bounds__(256) void qkv_mfma(
    const bf16* __restrict__ X,
    const bf16* __restrict__ w1t, const bf16* __restrict__ w2t,
    bf16* __restrict__ q1, bf16* __restrict__ k1, bf16* __restrict__ v1,
    bf16* __restrict__ q2, bf16* __restrict__ k2, bf16* __restrict__ v2)
{
    constexpr int K = Dc;  // 512
    __shared__ unsigned short Asm[2 * 128 * 32];
    __shared__ unsigned short Bsm[2 * 128 * 32];
    constexpr int BUF = 128 * 32;

    const int tid  = threadIdx.x;
    const int wv   = tid >> 6;
    const int lane = tid & 63;
    const int q    = lane >> 4;
    const int ln   = lane & 15;
    const int wm   = wv & 1;
    const int wn   = wv >> 1;
    const int set  = blockIdx.z;

    const bf16* Wt = set ? w2t : w1t;
    bf16* Q  = set ? q2 : q1;
    bf16* Ko = set ? k2 : k1;
    bf16* V  = set ? v2 : v1;

    const bf16* A  = X  + (long)(blockIdx.y * 128) * K;
    const bf16* Bt = Wt + (long)(blockIdx.x * 128) * K;

    const int sr = lane >> 2, sc = lane & 3;
    const int scs = sc ^ (sr & 3);
    const bf16* gA0 = A  + (long)(wv * 32 + sr)      * K + scs * 8;
    const bf16* gA1 = A  + (long)(wv * 32 + 16 + sr) * K + scs * 8;
    const bf16* gB0 = Bt + (long)(wv * 32 + sr)      * K + scs * 8;
    const bf16* gB1 = Bt + (long)(wv * 32 + 16 + sr) * K + scs * 8;
    unsigned short* lA0 = &Asm[(wv * 32)      * 32];
    unsigned short* lA1 = &Asm[(wv * 32 + 16) * 32];
    unsigned short* lB0 = &Bsm[(wv * 32)      * 32];
    unsigned short* lB1 = &Bsm[(wv * 32 + 16) * 32];

    f32x4 acc[4][4];
#pragma unroll
    for (int i = 0; i < 4; ++i)
#pragma unroll
        for (int j = 0; j < 4; ++j)
            acc[i][j] = (f32x4){0.f, 0.f, 0.f, 0.f};

    const int qs = (q ^ (ln & 3)) * 8;

    gl_lds16(gA0, lA0);
    gl_lds16(gA1, lA1);
    gl_lds16(gB0, lB0);
    gl_lds16(gB1, lB1);
    __syncthreads();

    int cur = 0;
    for (int k0 = 0; k0 < K; k0 += 32) {
        const int nxt = cur ^ 1;
        if (k0 + 32 < K) {
            const int no = nxt * BUF;
            gl_lds16(gA0 + k0 + 32, lA0 + no);
            gl_lds16(gA1 + k0 + 32, lA1 + no);
            gl_lds16(gB0 + k0 + 32, lB0 + no);
            gl_lds16(gB1 + k0 + 32, lB1 + no);
        }

        const unsigned short* Ac = &Asm[cur * BUF];
        const unsigned short* Bc = &Bsm[cur * BUF];
        short8 af[4], bfr[4];
#pragma unroll
        for (int mt = 0; mt < 4; ++mt) {
            int m = wm * 64 + mt * 16 + ln;
            af[mt] = *(const short8*)&Ac[m * 32 + qs];
        }
#pragma unroll
        for (int nt = 0; nt < 4; ++nt) {
            int n = wn * 64 + nt * 16 + ln;
            bfr[nt] = *(const short8*)&Bc[n * 32 + qs];
        }
#pragma unroll
        for (int mt = 0; mt < 4; ++mt)
#pragma unroll
            for (int nt = 0; nt < 4; ++nt)
                acc[mt][nt] = __builtin_amdgcn_mfma_f32_16x16x32_bf16(
                    af[mt], bfr[nt], acc[mt][nt], 0, 0, 0);

        __syncthreads();
        cur = nxt;
    }

#pragma unroll
    for (int mt = 0; mt < 4; ++mt) {
#pragma unroll
        for (int nt = 0; nt < 4; ++nt) {
            const int col  = blockIdx.x * 128 + wn * 64 + nt * 16 + ln;
            const int rowb = blockIdx.y * 128 + wm * 64 + mt * 16 + q * 4;
            const int t = col >> 9;
            const int h = (col >> 6) & 7;
            const int dk = col & 63;
            bf16* dst = (t == 0) ? Q : (t == 1) ? Ko : V;
#pragma unroll
            for (int r = 0; r < 4; ++r) {
                const int row = rowb + r;
                const int b = row >= Nc ? 1 : 0;
                const int n = row - b * Nc;
                dst[(((long)b * Hc + h) * Nc + n) * DKc + dk] =
                    __float2bfloat16(acc[mt][nt][r]);
            }
        }
    }
}

// ---------------------------------------------------------------------------
// MFMA bf16 NT narrow GEMM core (validated): acc = A(128,K) @ Bt(64,K)^T.
// Reg-staged, stride-72 LDS (conflict-free by construction).
// ---------------------------------------------------------------------------
struct N64Acc { f32x4 acc[2][4]; };

template <typename DUMMY = void>
DEVINL void n64_core(const bf16* A, const bf16* Bt, int K,
                     unsigned short* Asm, unsigned short* Bsm, N64Acc& R)
{
    const int tid  = threadIdx.x;
    const int wave = tid >> 6;
    const int lane = tid & 63;
    const int q    = lane >> 4;
    const int ln   = lane & 15;

    const int sr = tid >> 3, k8 = tid & 7;
    const bf16* pa[4];
    const bf16* pb[2];
    int wa[4], wb[2];
#pragma unroll
    for (int i = 0; i < 4; ++i) {
        pa[i] = A + (long)(sr + i * 32) * K + k8 * 8;
        wa[i] = (sr + i * 32) * 72 + k8 * 8;
    }
#pragma unroll
    for (int i = 0; i < 2; ++i) {
        pb[i] = Bt + (long)(sr + i * 32) * K + k8 * 8;
        wb[i] = (sr + i * 32) * 72 + k8 * 8;
    }

#pragma unroll
    for (int i = 0; i < 2; ++i)
#pragma unroll
        for (int j = 0; j < 4; ++j)
            R.acc[i][j] = (f32x4){0.f, 0.f, 0.f, 0.f};

    for (int k0 = 0; k0 < K; k0 += 64) {
        uint4 va[4], vb[2];
#pragma unroll
        for (int i = 0; i < 4; ++i) va[i] = *(const uint4*)(pa[i] + k0);
#pragma unroll
        for (int i = 0; i < 2; ++i) vb[i] = *(const uint4*)(pb[i] + k0);
        __syncthreads();
#pragma unroll
        for (int i = 0; i < 4; ++i) *(uint4*)&Asm[wa[i]] = va[i];
#pragma unroll
        for (int i = 0; i < 2; ++i) *(uint4*)&Bsm[wb[i]] = vb[i];
        __syncthreads();

#pragma unroll
        for (int kc = 0; kc < 2; ++kc) {
            short8 af[2], bfr[4];
#pragma unroll
            for (int mt = 0; mt < 2; ++mt) {
                int m = wave * 32 + mt * 16 + ln;
                af[mt] = *(const short8*)&Asm[m * 72 + kc * 32 + q * 8];
            }
#pragma unroll
            for (int nt = 0; nt < 4; ++nt) {
                int n = nt * 16 + ln;
                bfr[nt] = *(const short8*)&Bsm[n * 72 + kc * 32 + q * 8];
            }
#pragma unroll
            for (int mt = 0; mt < 2; ++mt)
#pragma unroll
                for (int nt = 0; nt < 4; ++nt)
                    R.acc[mt][nt] = __builtin_amdgcn_mfma_f32_16x16x32_bf16(
                        af[mt], bfr[nt], R.acc[mt][nt], 0, 0, 0);
        }
    }
}

// ---------------------------------------------------------------------------
// Merged pair launch (Path-B fallback only; validated round 11).
// ---------------------------------------------------------------------------
__global__ __launch_bounds__(256) void gemm_n64_pair(
    const bf16* __restrict__ A0g, const bf16* __restrict__ B0g, bf16* __restrict__ C0tg,
    const bf16* __restrict__ A1g, const bf16* __restrict__ B1g, bf16* __restrict__ C1g,
    int M, int K, long sA, long sB, long sC)
{
    __shared__ unsigned short Asm[128 * 72];
    __shared__ unsigned short Bsm[64 * 72];

    const int zz = blockIdx.z & 15;
    const int second = blockIdx.z >> 4;
    const bf16* A  = (second ? A1g : A0g) + (long)zz * sA + (long)(blockIdx.y * 128) * K;
    const bf16* Bt = (second ? B1g : B0g) + (long)zz * sB;

    N64Acc R;
    n64_core(A, Bt, K, Asm, Bsm, R);

    const int tid = threadIdx.x;
    const int wave = tid >> 6, lane = tid & 63, q = lane >> 4, ln = lane & 15;

    if (second) {
        bf16* C = C1g + (long)zz * sC;
#pragma unroll
        for (int mt = 0; mt < 2; ++mt) {
#pragma unroll
            for (int nt = 0; nt < 4; ++nt) {
                const int col  = nt * 16 + ln;
                const int rowb = blockIdx.y * 128 + wave * 32 + mt * 16 + q * 4;
#pragma unroll
                for (int r = 0; r < 4; ++r)
                    C[(long)(rowb + r) * 64 + col] = __float2bfloat16(R.acc[mt][nt][r]);
            }
        }
    } else {
        __syncthreads();
#pragma unroll
        for (int mt = 0; mt < 2; ++mt) {
#pragma unroll
            for (int nt = 0; nt < 4; ++nt) {
                const int col = nt * 16 + ln;
                const int rwb = wave * 32 + mt * 16 + q * 4;
#pragma unroll
                for (int r = 0; r < 4; ++r)
                    *(bf16*)&Asm[col * 136 + rwb + r] = __float2bfloat16(R.acc[mt][nt][r]);
            }
        }
        __syncthreads();
        bf16* Ct = C0tg + (long)zz * sC;
        const int dk  = tid >> 2;
        const int nc0 = (tid & 3) * 32;
        const int gn0 = blockIdx.y * 128;
#pragma unroll
        for (int c8 = 0; c8 < 4; ++c8) {
            uint4 v = *(const uint4*)&Asm[dk * 136 + nc0 + c8 * 8];
            *(uint4*)&Ct[(long)dk * Nc + gn0 + nc0 + c8 * 8] = v;
        }
    }
}

// ---------------------------------------------------------------------------
// Round 20: merged y kernel (Path A). One block computes BOTH
//   R1 = A (softmax-Smix) @ v1t   and   R2 = C_right_raw @ v2t
// then writes yc = R1 + w*R2 directly (f32 combine, single bf16 round).
// Replaces gemm_n64_yb + gemm_n64_combine: one 96-block launch instead of
// two (each 37% CU-occupancy), and kills the yb1 bf16 round-trip.
// ---------------------------------------------------------------------------
__global__ __launch_bounds__(256) void gemm_n64_both(
    const bf16* __restrict__ Ab, const bf16* __restrict__ v1t,
    const bf16* __restrict__ Craw, const bf16* __restrict__ v2t,
    const float* __restrict__ smallf, bf16* __restrict__ yc,
    int K, long sA, long sB)
{
    __shared__ unsigned short Asm[128 * 72];
    __shared__ unsigned short Bsm[64 * 72];

    const int bh = blockIdx.z;
    const long arow = (long)(blockIdx.y * 128) * K;

    N64Acc R1;
    n64_core(Ab + (long)bh * sA + arow, v1t + (long)bh * sB, K, Asm, Bsm, R1);
    // n64_core's first internal __syncthreads (before LDS writes) separates
    // the previous call's trailing LDS reads — no extra barrier needed.
    N64Acc R2;
    n64_core(Craw + (long)bh * sA + arow, v2t + (long)bh * sB, K, Asm, Bsm, R2);

    const float w = sigf(smallf[392]);
    const int b = bh >> 3, h = bh & 7;

    const int tid = threadIdx.x;
    const int wave = tid >> 6, lane = tid & 63, q = lane >> 4, ln = lane & 15;
#pragma unroll
    for (int mt = 0; mt < 2; ++mt) {
#pragma unroll
        for (int nt = 0; nt < 4; ++nt) {
            const int col  = nt * 16 + ln;
            const int rowb = blockIdx.y * 128 + wave * 32 + mt * 16 + q * 4;
#pragma unroll
            for (int r = 0; r < 4; ++r) {
                const int n = rowb + r;
                yc[((long)(b * Nc + n)) * Dc + h * DKc + col] =
                    __float2bfloat16(R1.acc[mt][nt][r] + w * R2.acc[mt][nt][r]);
            }
        }
    }
}

// y_chain GEMM with fused combine + permute (Path-B fallback only).
__global__ __launch_bounds__(256) void gemm_n64_combine(
    const bf16* __restrict__ A1b, const bf16* __restrict__ trt,
    const bf16* __restrict__ yb1, const float* __restrict__ smallf,
    bf16* __restrict__ yc, int M, int K, long sA, long sB)
{
    __shared__ unsigned short Asm[128 * 72];
    __shared__ unsigned short Bsm[64 * 72];

    const int bh = blockIdx.z;
    const bf16* A  = A1b + (long)bh * sA + (long)(blockIdx.y * 128) * K;
    const bf16* Bt = trt + (long)bh * sB;

    N64Acc R;
    n64_core(A, Bt, K, Asm, Bsm, R);

    const float w = sigf(smallf[392]);
    const int b = bh >> 3, h = bh & 7;
    const long yb1base = (long)bh * Nc * DKc;

    const int tid = threadIdx.x;
    const int wave = tid >> 6, lane = tid & 63, q = lane >> 4, ln = lane & 15;
#pragma unroll
    for (int mt = 0; mt < 2; ++mt) {
#pragma unroll
        for (int nt = 0; nt < 4; ++nt) {
            const int col  = nt * 16 + ln;
            const int rowb = blockIdx.y * 128 + wave * 32 + mt * 16 + q * 4;
#pragma unroll
            for (int r = 0; r < 4; ++r) {
                const int n = rowb + r;
                const float base = __bfloat162float(yb1[yb1base + (long)n * 64 + col]);
                yc[((long)(b * Nc + n)) * Dc + h * DKc + col] =
                    __float2bfloat16(base + w * R.acc[mt][nt][r]);
            }
        }
    }
}

// Path-B y_base GEMM (fallback only).
__global__ __launch_bounds__(256) void gemm_n64_yb(
    const bf16* __restrict__ Ag, const bf16* __restrict__ Btg,
    bf16* __restrict__ Cg, int M, int K, long sA, long sB, long sC)
{
    __shared__ unsigned short Asm[128 * 72];
    __shared__ unsigned short Bsm[64 * 72];

    const int zz = blockIdx.z;
    const bf16* A  = Ag + (long)zz * sA + (long)(blockIdx.y * 128) * K;
    const bf16* Bt = Btg + (long)zz * sB;

    N64Acc R;
    n64_core(A, Bt, K, Asm, Bsm, R);

    bf16* C = Cg + (long)zz * sC;
    const int tid = threadIdx.x;
    const int wave = tid >> 6, lane = tid & 63, q = lane >> 4, ln = lane & 15;
#pragma unroll
    for (int mt = 0; mt < 2; ++mt) {
#pragma unroll
        for (int nt = 0; nt < 4; ++nt) {
            const int col  = nt * 16 + ln;
            const int rowb = blockIdx.y * 128 + wave * 32 + mt * 16 + q * 4;
#pragma unroll
            for (int r = 0; r < 4; ++r)
                C[(long)(rowb + r) * 64 + col] = __float2bfloat16(R.acc[mt][nt][r]);
        }
    }
}

// ---------------------------------------------------------------------------
// Row softmax over width 768 — wave-per-row (validated round 16).
// ---------------------------------------------------------------------------
__global__ __launch_bounds__(256) void softmax_rows_w(
    const float* __restrict__ src, bf16* __restrict__ dst)
{
    const int wid  = threadIdx.x >> 6;
    const int lane = threadIdx.x & 63;
    const long row = (long)blockIdx.x * 4 + wid;
    const float* s = src + row * Nc;

    float4 v[3];
#pragma unroll
    for (int i = 0; i < 3; ++i)
        v[i] = *(const float4*)&s[i * 256 + lane * 4];

    float m = -1e30f;
#pragma unroll
    for (int i = 0; i < 3; ++i)
        m = fmaxf(m, fmaxf(fmaxf(v[i].x, v[i].y), fmaxf(v[i].z, v[i].w)));
#pragma unroll
    for (int off = 32; off > 0; off >>= 1)
        m = fmaxf(m, __shfl_xor(m, off, 64));

    float e[12];
    float sum = 0.f;
#pragma unroll
    for (int i = 0; i < 3; ++i) {
        e[i * 4 + 0] = __expf(v[i].x - m);
        e[i * 4 + 1] = __expf(v[i].y - m);
        e[i * 4 + 2] = __expf(v[i].z - m);
        e[i * 4 + 3] = __expf(v[i].w - m);
        sum += e[i * 4 + 0] + e[i * 4 + 1] + e[i * 4 + 2] + e[i * 4 + 3];
    }
#pragma unroll
    for (int off = 32; off > 0; off >>= 1)
        sum += __shfl_xor(sum, off, 64);

    const float inv = 1.f / fmaxf(sum, 1e-30f);
    unsigned short* d = (unsigned short*)dst + row * Nc;
#pragma unroll
    for (int i = 0; i < 3; ++i) {
        unsigned short o[4];
#pragma unroll
        for (int j = 0; j < 4; ++j) {
            const bf16 b = __float2bfloat16(e[i * 4 + j] * inv);
            o[j] = *(const unsigned short*)&b;
        }
        *(uint2*)&d[i * 256 + lane * 4] = *(const uint2*)o;
    }
}

// ---------------------------------------------------------------------------
// Gate network + Smix — round 20: 4 elems/thread (two pk-pair streams) for
// trans-pipe ILP. r1's 4-elem failure was VGPR 92 from LDS-staged weight
// float4s; weights are now SGPR (s_load, r5) so state stays ~56-64 VGPR.
// Grid (12, 48, 16): 64-wide m tile, 16 n rows.
// ---------------------------------------------------------------------------
__global__ __launch_bounds__(256) void gates_smix(
    const float* __restrict__ S1g, const float* __restrict__ S2g,
    const bf16* __restrict__ Crg, const bf16* __restrict__ Clg,
    float* __restrict__ Smixg, const float* __restrict__ smallf)
{
    __shared__ float t1t[64][17], t2t[64][17];

    const long mat = (long)blockIdx.z * Nc * Nc;
    const float* S1 = S1g + mat;
    const float* S2 = S2g + mat;
    const unsigned short* Cr = (const unsigned short*)Crg + mat;
    const unsigned short* Cl = (const unsigned short*)Clg + mat;
    float* Smix = Smixg + mat;

    const int tid = threadIdx.x;

    const int n0 = blockIdx.y * 16, m0 = blockIdx.x * 64;
    {   // transposed tiles: S[m0..m0+63][n0..n0+15], coalesced float4 loads
        const int r = tid >> 2, c4 = (tid & 3) * 4;
        const float4 a = *(const float4*)&S1[(long)(m0 + r) * Nc + n0 + c4];
        const float4 b = *(const float4*)&S2[(long)(m0 + r) * Nc + n0 + c4];
        t1t[r][c4] = a.x; t1t[r][c4 + 1] = a.y; t1t[r][c4 + 2] = a.z; t1t[r][c4 + 3] = a.w;
        t2t[r][c4] = b.x; t2t[r][c4 + 1] = b.y; t2t[r][c4 + 2] = b.z; t2t[r][c4 + 3] = b.w;
    }
    __syncthreads();

    const int tx = tid & 15, ty = tid >> 4;
    const int n = n0 + ty;
    const long idx = (long)n * Nc + m0 + tx * 4;

    const float4 s1v = *(const float4*)&S1[idx];
    const float4 s2v = *(const float4*)&S2[idx];
    const uint2 cru = *(const uint2*)&Cr[idx];
    const uint2 clu = *(const uint2*)&Cl[idx];

    // two packed pair streams: p=0 -> elems {0,1}, p=1 -> elems {2,3}
    f32x2 s1a[2] = {{s1v.x, s1v.y}, {s1v.z, s1v.w}};
    f32x2 s2a[2] = {{s2v.x, s2v.y}, {s2v.z, s2v.w}};
    f32x2 cra[2] = {{__uint_as_float((cru.x & 0xffffu) << 16),
                     __uint_as_float(cru.x & 0xffff0000u)},
                    {__uint_as_float((cru.y & 0xffffu) << 16),
                     __uint_as_float(cru.y & 0xffff0000u)}};
    f32x2 cla[2] = {{__uint_as_float((clu.x & 0xffffu) << 16),
                     __uint_as_float(clu.x & 0xffff0000u)},
                    {__uint_as_float((clu.y & 0xffffu) << 16),
                     __uint_as_float(clu.y & 0xffff0000u)}};
    f32x2 s1t[2], s2t[2];
#pragma unroll
    for (int p = 0; p < 2; ++p) {
        s1t[p] = (f32x2){t1t[tx * 4 + 2 * p][ty], t1t[tx * 4 + 2 * p + 1][ty]};
        s2t[p] = (f32x2){t2t[tx * 4 + 2 * p][ty], t2t[tx * 4 + 2 * p + 1][ty]};
    }

    f32x2 g0[2], g1[2], g2[2], g3[2];
#pragma unroll
    for (int p = 0; p < 2; ++p) {
        g0[p] = *(const f32x2*)&smallf[384];
        g1[p] = *(const f32x2*)&smallf[386];
        g2[p] = *(const f32x2*)&smallf[388];
        g3[p] = *(const f32x2*)&smallf[390];
    }

    const f32x2 gc1  = splat2(-2.30220902f);   // gelu c1 * log2e
    const f32x2 gc3  = splat2(-0.10294357f);   // gelu c3 * log2e
    const f32x2 one2 = splat2(1.f);

#pragma unroll
    for (int u = 0; u < 16; ++u) {
        const f32x2* cw = (const f32x2*)&smallf[u * 24];
#pragma unroll
        for (int p = 0; p < 2; ++p) {
            f32x2 h = cw[6];
            h = fma2(s1a[p], cw[0], h);
            h = fma2(s2a[p], cw[1], h);
            h = fma2(s1t[p], cw[2], h);
            h = fma2(s2t[p], cw[3], h);
            h = fma2(cra[p], cw[4], h);
            h = fma2(cla[p], cw[5], h);
            const f32x2 hh = h * h;
            const f32x2 z2 = h * fma2(hh, gc3, gc1);
            f32x2 e;  e[0]  = vexp2(z2[0]); e[1]  = vexp2(z2[1]);
            const f32x2 d = one2 + e;
            f32x2 rc; rc[0] = vrcp(d[0]);   rc[1] = vrcp(d[1]);
            const f32x2 hid = h * rc;
            g0[p] = fma2(hid, cw[8],  g0[p]);
            g1[p] = fma2(hid, cw[9],  g1[p]);
            g2[p] = fma2(hid, cw[10], g2[p]);
            g3[p] = fma2(hid, cw[11], g3[p]);
        }
    }

    const f32x2 nl2e = splat2(-1.44269504f);
    const f32x2 ln2v = splat2(0.69314718f);
    auto sig2 = [&](f32x2 x) -> f32x2 {
        const f32x2 t = x * nl2e;
        f32x2 e;  e[0] = vexp2(t[0]); e[1] = vexp2(t[1]);
        const f32x2 d = one2 + e;
        f32x2 r;  r[0] = vrcp(d[0]);  r[1] = vrcp(d[1]);
        return r;
    };

    float4 outv;
    float* outp = &outv.x;
#pragma unroll
    for (int p = 0; p < 2; ++p) {
        const f32x2 ga2 = sig2(g0[p]);
        const f32x2 go2 = sig2(g1[p]);
        const f32x2 gn2 = sig2(g2[p]);
        const f32x2 gc2 = sig2(g3[p]);

        const f32x2 dd = s1a[p] - s2a[p];
        f32x2 ad; ad[0] = fabsf(dd[0]); ad[1] = fabsf(dd[1]);
        const f32x2 t2 = ad * nl2e;                   // -|d| * log2e
        f32x2 ee; ee[0] = vexp2(t2[0]); ee[1] = vexp2(t2[1]);
        const f32x2 lp = one2 + ee;
        f32x2 lg; lg[0] = vlog2(lp[0]); lg[1] = vlog2(lp[1]);
        const f32x2 mx2 = __builtin_elementwise_max(s1a[p], s2a[p]);
        const f32x2 lae = fma2(lg, ln2v, mx2);        // logaddexp(s1,s2)

        f32x2 o2 = s1a[p];
        o2 = fma2(ga2, s2a[p], o2);
        o2 = fma2(go2, lae - s1a[p], o2);
        o2 = fma2(gn2, s2a[p] * splat2(-BETA_NOT), o2);
        o2 = fma2(gc2, cra[p], o2);
        outp[2 * p]     = o2[0];
        outp[2 * p + 1] = o2[1];
    }
    *(float4*)&Smix[idx] = outv;
}

// ---------------------------------------------------------------------------
// Final projection via n64 core, 128x64 tiles (validated round 12).
// ---------------------------------------------------------------------------
__global__ __launch_bounds__(256) void proj_n64(
    const bf16* __restrict__ yc, const bf16* __restrict__ pwt,
    const void* __restrict__ xraw, void* __restrict__ out)
{
    constexpr int K = Dc;  // 512
    constexpr int N = Dc;  // 512
    __shared__ unsigned short Asm[128 * 72];
    __shared__ unsigned short Bsm[64 * 72];
    __shared__ int is32s;
    if (threadIdx.x == 0) is32s = sniff_is_fp32(xraw);

    const bf16* A  = yc  + (long)(blockIdx.y * 128) * K;
    const bf16* Bt = pwt + (long)(blockIdx.x * 64) * K;

    N64Acc R;
    n64_core(A, Bt, K, Asm, Bsm, R);   // internal barriers publish is32s

    const int is32 = is32s;
    const int tid = threadIdx.x;
    const int wave = tid >> 6, lane = tid & 63, q = lane >> 4, ln = lane & 15;
#pragma unroll
    for (int mt = 0; mt < 2; ++mt) {
#pragma unroll
        for (int nt = 0; nt < 4; ++nt) {
            const int col  = blockIdx.x * 64 + nt * 16 + ln;
            const int rowb = blockIdx.y * 128 + wave * 32 + mt * 16 + q * 4;
#pragma unroll
            for (int r = 0; r < 4; ++r) {
                const long o = (long)(rowb + r) * N + col;
                if (is32) ((float*)out)[o] = R.acc[mt][nt][r];
                else      ((bf16*)out)[o] = __float2bfloat16(R.acc[mt][nt][r]);
            }
        }
    }
}

// ---------------------------------------------------------------------------
extern "C" void kernel_launch(void* const* d_in, const int* in_sizes, int n_in,
                              void* d_out, int out_size, void* d_ws, size_t ws_size,
                              hipStream_t stream)
{
    const size_t HD   = (size_t)BHc * Nc * DKc;   // 786432
    const size_t HDh  = HD / 2;                   // float-slots for HD bf16
    const size_t MAT  = (size_t)Nc * Nc;          // 589824
    const size_t MATS = (size_t)BHc * MAT;        // 9437184
    const long   HSTR = (long)Nc * DKc;           // 49152 per-head stride

    float* ws = (float*)d_ws;
    size_t off = 0;
    auto alloc = [&](size_t n) { float* p = ws + off; off += n; return p; };

    bf16* xb  = (bf16*)alloc(HDh);
    bf16* w1b = (bf16*)alloc(HDh);   // w1b/w2b adjacent -> merged transpose
    bf16* w2b = (bf16*)alloc(HDh);
    bf16* w1t = (bf16*)alloc(HDh);
    bf16* w2t = (bf16*)alloc(HDh);
    bf16* pwb = (bf16*)alloc((size_t)Dc * Dc / 2);
    bf16* pwt = (bf16*)alloc((size_t)Dc * Dc / 2);
    float* smallf = alloc(512);
    // q1|q2 and k1|k2 adjacent -> single merged S-GEMM launch (32 heads)
    bf16* q1b = (bf16*)alloc(HDh); bf16* q2b = (bf16*)alloc(HDh);
    bf16* k1b = (bf16*)alloc(HDh); bf16* k2b = (bf16*)alloc(HDh);
    bf16* v1b = (bf16*)alloc(HDh); bf16* v2b = (bf16*)alloc(HDh);  // adjacent
    bf16* v1t = (bf16*)alloc(HDh); bf16* v2t = (bf16*)alloc(HDh);  // adjacent
    bf16* trt = (bf16*)alloc(HDh);
    float* S1   = alloc(MATS);       // S1/S2 adjacent -> merged softmax + S-GEMM
    float* S2   = alloc(MATS);
    float* Smix = alloc(MATS);       // region reused: A1tb|A2tb, then Smix
    bf16* A1b = (bf16*)alloc(MATS / 2);  // A1b/A2b adjacent
    bf16* A2b = (bf16*)alloc(MATS / 2);
    bf16* Crb = (bf16*)alloc(MATS / 2);  // Crb/Clb adjacent (merged launch)
    bf16* Clb = (bf16*)alloc(MATS / 2);
    bf16* yb1 = (bf16*)alloc(HDh);
    bf16* yc  = (bf16*)alloc(HDh);

    const size_t NEED_BASE = off * sizeof(float);
    bf16* Crawb = (bf16*)alloc(MATS / 2);          // raw C_right (Path A only)
    const size_t NEED_A = off * sizeof(float);
    const int pathA = ws_size >= NEED_A;

    // aliases into dead regions
    bf16* A1tb = (bf16*)Smix;            // live steps 3-4 (dead once gates writes Smix)
    bf16* A2tb = ((bf16*)Smix) + MATS;
    bf16* Ab   = (bf16*)S1;              // S1 dead after gates

    if (ws_size < NEED_BASE) {
        fill_sentinel<<<dim3(3072), 256, 0, stream>>>((unsigned short*)d_out);
        return;
    }

    // 0. normalize inputs
    convert_all<<<dim3(3072), 256, 0, stream>>>(
        d_in[0], d_in[1], d_in[2], d_in[3], d_in[4], d_in[5], d_in[6], d_in[7],
        d_in[8], xb, w1b, w2b, pwb, smallf);

    // 1. merged W transposes; pw transpose; merged QKV; merged v transposes
    transpose_bf16<<<dim3(24, 8, 2), 256, 0, stream>>>(
        (const unsigned short*)w1b, (unsigned short*)w1t, Dc, 3 * Dc, (long)HD, (long)HD);
    transpose_bf16<<<dim3(8, 8, 1), 256, 0, stream>>>(
        (const unsigned short*)pwb, (unsigned short*)pwt, Dc, Dc, 0, 0);
    qkv_mfma<<<dim3(12, 12, 2), 256, 0, stream>>>(
        xb, w1t, w2t, q1b, k1b, v1b, q2b, k2b, v2b);
    transpose_bf16<<<dim3(1, 12, 2 * BHc), 256, 0, stream>>>(
        (const unsigned short*)v1b, (unsigned short*)v1t, Nc, DKc, HSTR, HSTR);

    // 2. S = scale * q @ k^T — single 32-batch launch (2-phase K-loop)
    gemm_nt_mfma<0, float><<<dim3(6, 6, 2 * BHc), 256, 0, stream>>>(
        q1b, k1b, S1, nullptr, Nc, Nc, DKc, HSTR, HSTR, (long)MAT, SCALE);

    // 3. merged softmax S1|S2 -> A1b|A2b (wave-per-row); merged transposes
    softmax_rows_w<<<(2 * BHc * Nc) / 4, 256, 0, stream>>>(S1, A1b);
    transpose_bf16<<<dim3(12, 12, 2 * BHc), 256, 0, stream>>>(
        (const unsigned short*)A1b, (unsigned short*)A1tb, Nc, Nc, (long)MAT, (long)MAT);

    // 4. Cr|Cl in ONE 32-batch launch; XCD-pinned 1-D grid (1152 = 8*4*36);
    //    2-phase double-buffered K-loop; Path A also stores raw C_right.
    if (pathA)
        gemm_nt_mfma<1, bf16, 1, 1, 1><<<dim3(1152), 256, 0, stream>>>(
            A1b, A1tb, Crb, Crawb, Nc, Nc, Nc, (long)MAT, (long)MAT, (long)MAT, 1.f);
    else
        gemm_nt_mfma<1, bf16, 1, 1, 0><<<dim3(1152), 256, 0, stream>>>(
            A1b, A1tb, Crb, nullptr, Nc, Nc, Nc, (long)MAT, (long)MAT, (long)MAT, 1.f);

    // 5. gates + Smix (4 elems/thread, two pk-pair streams)
    gates_smix<<<dim3(12, 48, BHc), 256, 0, stream>>>(S1, S2, Crb, Clb, Smix, smallf);

    // 6. A = softmax(Smix) -> bf16 (into S1 alias, wave-per-row)
    softmax_rows_w<<<(BHc * Nc) / 4, 256, 0, stream>>>(Smix, Ab);

    if (pathA) {
        // 7. merged y: yc = (A @ v1) + w * (C_right_raw @ v2), one launch
        gemm_n64_both<<<dim3(1, 6, BHc), 256, 0, stream>>>(
            Ab, v1t, Crawb, v2t, smallf, yc, Nc, (long)MAT, HSTR);
    } else {
        // Path B fallback (round-5 structure)
        gemm_n64_pair<<<dim3(1, 6, 2 * BHc), 256, 0, stream>>>(
            A2b, v2t, trt, Ab, v1t, yb1, Nc, Nc, (long)MAT, HSTR, HSTR);
        gemm_n64_combine<<<dim3(1, 6, BHc), 256, 0, stream>>>(
            A1b, trt, yb1, smallf, yc, Nc, Nc, (long)MAT, HSTR);
    }

    // 9. proj via n64 core, 128x64 tiles (96 blocks)
    proj_n64<<<dim3(8, 12, 1), 256, 0, stream>>>(yc, pwt, d_in[0], d_out);
}

// Round 9
// 345.711 us; speedup vs baseline: 1.4286x; 1.0673x over previous
//
#include <hip/hip_runtime.h>
#include <hip/hip_bf16.h>
#include <math.h>

typedef __hip_bfloat16 bf16;
typedef __attribute__((ext_vector_type(8))) short short8;   // 8 bf16 (4 VGPRs)
typedef __attribute__((ext_vector_type(4))) float f32x4;
typedef __attribute__((ext_vector_type(2))) float f32x2;
#define DEVINL __device__ __forceinline__

constexpr int Bc  = 2;
constexpr int Nc  = 768;
constexpr int Dc  = 512;
constexpr int Hc  = 8;
constexpr int DKc = 64;
constexpr int BHc = Bc * Hc;
constexpr float SCALE    = 0.125f;   // 1/sqrt(64)
constexpr float EPSF     = 1e-6f;
constexpr float BETA_NOT = 0.5f;

DEVINL float ldf(const float* p, long i) { return p[i]; }
DEVINL float ldf(const bf16* p, long i) { return __bfloat162float(p[i]); }
DEVINL void stf(float* p, long i, float v) { p[i] = v; }
DEVINL void stf(bf16* p, long i, float v) { p[i] = __float2bfloat16(v); }

DEVINL float sigf(float x) { return __fdividef(1.f, 1.f + __expf(-x)); }

// packed fp32 pair helpers — backend selects v_pk_fma_f32/v_pk_mul_f32 (r3:
// validated -41% on gates_smix; r4 pair-dup operands -12%; r5 s_load weights).
DEVINL f32x2 fma2(f32x2 a, f32x2 b, f32x2 c) { return __builtin_elementwise_fma(a, b, c); }
DEVINL f32x2 splat2(float x) { return (f32x2){x, x}; }
// guard-free transcendentals (libm exp2f adds a denormal guard: +13% in r2)
DEVINL float vexp2(float x) { float r; asm("v_exp_f32 %0, %1" : "=v"(r) : "v"(x)); return r; }
DEVINL float vrcp(float x)  { float r; asm("v_rcp_f32 %0, %1" : "=v"(r) : "v"(x)); return r; }
DEVINL float vlog2(float x) { float r; asm("v_log_f32 %0, %1" : "=v"(r) : "v"(x)); return r; }

// async global->LDS, 16B per lane; LDS dest = wave-uniform base + lane*16.
DEVINL void gl_lds16(const void* g, void* l) {
    __builtin_amdgcn_global_load_lds(
        (const __attribute__((address_space(1))) void*)g,
        (__attribute__((address_space(3))) void*)l, 16, 0, 0);
}

// ---------------------------------------------------------------------------
// Dtype sniffer — vectorized (validated round 9).
// ---------------------------------------------------------------------------
DEVINL int sniff_is_fp32(const void* xraw) {
    const uint4* p4 = (const uint4*)xraw;
    float mx = 0.f;
#pragma unroll
    for (int j = 0; j < 16; ++j) {
        const uint4 u = p4[j];
        const unsigned w[4] = {u.x, u.y, u.z, u.w};
#pragma unroll
        for (int t = 0; t < 4; ++t) {
            mx = fmaxf(mx, fabsf(__uint_as_float((w[t] & 0xffffu) << 16)));
            mx = fmaxf(mx, fabsf(__uint_as_float(w[t] & 0xffff0000u)));
        }
    }
    return mx > 1000.f ? 1 : 0;
}

DEVINL float cvt_elem(const void* s, long j, int is32) {
    return is32 ? ((const float*)s)[j]
                : __bfloat162float(((const bf16*)s)[j]);
}

// smallf layout (round 15 — PAIR-DUPLICATED; read via uniform scalar loads):
//   [u*24 + 2k+{0,1}]  = w1[u][k]          k=0..5   (12 floats)
//   [u*24 + 12..13]    = b1[u] pair
//   [u*24 + 14..15]    = pad
//   [u*24 + 16 + 2o+{0,1}] = conv2_w[o][u] o=0..3   (8 floats)
//   [384..391]  conv2_b[o] pairs
//   [392..393]  chain_logit pair          (combine reads [392])
__global__ __launch_bounds__(256) void convert_all(
    const void* x, const void* w1, const void* w2, const void* pw,
    const void* c1w, const void* c1b, const void* c2w, const void* c2b,
    const void* ch,
    bf16* xb, bf16* w1b, bf16* w2b, bf16* pwb, float* smallf)
{
    __shared__ int is32s;
    if (threadIdx.x == 0) is32s = sniff_is_fp32(x);
    __syncthreads();
    const int is32 = is32s;
    const long i = (long)blockIdx.x * 256 + threadIdx.x;
    if (i < (long)Bc * Nc * Dc) {
        xb[i]  = __float2bfloat16(cvt_elem(x,  i, is32));
        w1b[i] = __float2bfloat16(cvt_elem(w1, i, is32));
        w2b[i] = __float2bfloat16(cvt_elem(w2, i, is32));
    }
    if (i < (long)Dc * Dc) pwb[i] = __float2bfloat16(cvt_elem(pw, i, is32));
    if (i < 384) {
        const int u = (int)i / 24, k = (int)i % 24;
        float v = 0.f;
        if (k < 12)      v = cvt_elem(c1w, u * 6 + (k >> 1), is32);
        else if (k < 14) v = cvt_elem(c1b, u, is32);
        else if (k >= 16) { const int o = (k - 16) >> 1; v = cvt_elem(c2w, o * 16 + u, is32); }
        smallf[i] = v;
    } else if (i < 392) smallf[i] = cvt_elem(c2b, ((int)i - 384) >> 1, is32);
    else if (i < 394) smallf[i] = cvt_elem(ch, 0, is32);
    else if (i < 512) smallf[i] = 0.f;
}

__global__ __launch_bounds__(256) void fill_sentinel(unsigned short* o) {
    const long i = (long)blockIdx.x * 256 + threadIdx.x;
    if (i < (long)Bc * Nc * Dc) o[i] = 0x40E0;  // bf16 7.0
}

// ---------------------------------------------------------------------------
// Generic bf16 transpose, 64x64 tiles: dst[c][r] = src[r][c]; src is (R,C).
// ---------------------------------------------------------------------------
__global__ __launch_bounds__(256) void transpose_bf16(
    const unsigned short* __restrict__ src, unsigned short* __restrict__ dst,
    int R, int C, long sS, long sD)
{
    __shared__ unsigned short tile[64][68];
    const unsigned short* s = src + (long)blockIdx.z * sS;
    unsigned short* d = dst + (long)blockIdx.z * sD;
    const int r0 = blockIdx.y * 64, c0 = blockIdx.x * 64;
    const int t = threadIdx.x;
    const int lr = t >> 4, lc4 = (t & 15) * 4;
#pragma unroll
    for (int i = 0; i < 4; ++i) {
        int r = lr + i * 16;
        *(uint2*)&tile[r][lc4] = *(const uint2*)&s[(long)(r0 + r) * C + c0 + lc4];
    }
    __syncthreads();
#pragma unroll
    for (int i = 0; i < 4; ++i) {
        int r = lr + i * 16;
        unsigned short v[4];
#pragma unroll
        for (int j = 0; j < 4; ++j) v[j] = tile[lc4 + j][r];
        *(uint2*)&d[(long)(c0 + r) * R + r0 + lc4] = *(uint2*)v;
    }
}

// ---------------------------------------------------------------------------
// MFMA bf16 NT GEMM — 2-phase double-buffered K-loop (validated r7: step-4
// 99 -> <78 µs; latency-bound 1-phase loop was the cause).
//  - XCDSWZ: 1-D grid 1152 = 8 xcd * (4 batch * 36 tile) — FETCH 5x cut (r6).
//  - RAW: also store pre-log C (z<16) for associativity y_chain.
//  - read-XOR swizzle kept (r6: conflict-count-neutral, cost-free).
// ---------------------------------------------------------------------------
template <int EPI, typename TC, int XORB = 0, int XCDSWZ = 0, int RAW = 0>
__global__ __launch_bounds__(256) void gemm_nt_mfma(
    const bf16* __restrict__ Ag, const bf16* __restrict__ Btg,
    TC* __restrict__ Cg, bf16* __restrict__ Craw, int M, int N, int K,
    long sA, long sB, long sC, float alpha)
{
    __shared__ unsigned short Asm[2 * 128 * 32];
    __shared__ unsigned short Bsm[2 * 128 * 32];
    constexpr int BUF = 128 * 32;   // elements per buffer

    int bx, by, bz;
    if (XCDSWZ) {
        const int wg = blockIdx.x;
        const int xcd = wg & 7, t = wg >> 3;
        bz = xcd + 8 * (t / 36);
        const int tile = t % 36;
        bx = tile % 6; by = tile / 6;
    } else { bx = blockIdx.x; by = blockIdx.y; bz = blockIdx.z; }

    const int tid  = threadIdx.x;
    const int wv   = tid >> 6;
    const int lane = tid & 63;
    const int q    = lane >> 4;
    const int ln   = lane & 15;
    const int wm   = wv & 1;
    const int wn   = wv >> 1;

    const int zb = XORB ? (bz ^ 16) : bz;
    const bf16* A  = Ag  + (long)bz * sA + (long)(by * 128) * K;
    const bf16* Bt = Btg + (long)zb * sB + (long)(bx * 128) * K;
    TC*         C  = Cg  + (long)bz * sC;

    const int sr = lane >> 2, sc = lane & 3;
    const int scs = sc ^ (sr & 3);          // source col-block pre-swizzle
    const bf16* gA0 = A  + (long)(wv * 32 + sr)      * K + scs * 8;
    const bf16* gA1 = A  + (long)(wv * 32 + 16 + sr) * K + scs * 8;
    const bf16* gB0 = Bt + (long)(wv * 32 + sr)      * K + scs * 8;
    const bf16* gB1 = Bt + (long)(wv * 32 + 16 + sr) * K + scs * 8;
    unsigned short* lA0 = &Asm[(wv * 32)      * 32];
    unsigned short* lA1 = &Asm[(wv * 32 + 16) * 32];
    unsigned short* lB0 = &Bsm[(wv * 32)      * 32];
    unsigned short* lB1 = &Bsm[(wv * 32 + 16) * 32];

    f32x4 acc[4][4];
#pragma unroll
    for (int i = 0; i < 4; ++i)
#pragma unroll
        for (int j = 0; j < 4; ++j)
            acc[i][j] = (f32x4){0.f, 0.f, 0.f, 0.f};

    const int qs = (q ^ (ln & 3)) * 8;      // swizzled read block

    // prologue: stage K-tile 0 into buffer 0, drain, sync
    gl_lds16(gA0, lA0);
    gl_lds16(gA1, lA1);
    gl_lds16(gB0, lB0);
    gl_lds16(gB1, lB1);
    __syncthreads();

    int cur = 0;
    for (int k0 = 0; k0 < K; k0 += 32) {
        const int nxt = cur ^ 1;
        if (k0 + 32 < K) {                  // issue NEXT tile's loads (async)
            const int no = nxt * BUF;
            gl_lds16(gA0 + k0 + 32, lA0 + no);
            gl_lds16(gA1 + k0 + 32, lA1 + no);
            gl_lds16(gB0 + k0 + 32, lB0 + no);
            gl_lds16(gB1 + k0 + 32, lB1 + no);
        }

        const unsigned short* Ac = &Asm[cur * BUF];
        const unsigned short* Bc = &Bsm[cur * BUF];
        short8 af[4], bfr[4];
#pragma unroll
        for (int mt = 0; mt < 4; ++mt) {
            int m = wm * 64 + mt * 16 + ln;
            af[mt] = *(const short8*)&Ac[m * 32 + qs];
        }
#pragma unroll
        for (int nt = 0; nt < 4; ++nt) {
            int n = wn * 64 + nt * 16 + ln;
            bfr[nt] = *(const short8*)&Bc[n * 32 + qs];
        }
#pragma unroll
        for (int mt = 0; mt < 4; ++mt)
#pragma unroll
            for (int nt = 0; nt < 4; ++nt)
                acc[mt][nt] = __builtin_amdgcn_mfma_f32_16x16x32_bf16(
                    af[mt], bfr[nt], acc[mt][nt], 0, 0, 0);

        __syncthreads();   // vmcnt(0) drain of next-tile loads + wave sync
        cur = nxt;
    }

#pragma unroll
    for (int mt = 0; mt < 4; ++mt) {
#pragma unroll
        for (int nt = 0; nt < 4; ++nt) {
            const int col = bx * 128 + wn * 64 + nt * 16 + ln;
            const int rowb = by * 128 + wm * 64 + mt * 16 + q * 4;
#pragma unroll
            for (int r = 0; r < 4; ++r) {
                float vraw = acc[mt][nt][r] * alpha;
                if (RAW) {
                    if (bz < 16)
                        Craw[(long)bz * M * N + (long)(rowb + r) * N + col] =
                            __float2bfloat16(vraw);
                }
                float v = vraw;
                if (EPI == 1) v = __logf(fmaxf(v, 0.f) + EPSF);
                stf(C, (long)(rowb + r) * N + col, v);
            }
        }
    }
}

// ---------------------------------------------------------------------------
// QKV via MFMA, merged sets — 2-phase double-buffered K-loop (r7).
// ---------------------------------------------------------------------------
__global__ __launch_bounds__(256) void qkv_mfma(
    const bf16* __restrict__ X,
    const bf16* __restrict__ w1t, const bf16* __restrict__ w2t,
    bf16* __restrict__ q1, bf16* __restrict__ k1, bf16* __restrict__ v1,
    bf16* __restrict__ q2, bf16* __restrict__ k2, bf16* __restrict__ v2)
{
    constexpr int K = Dc;  // 512
    __shared__ unsigned short Asm[2 * 128 * 32];
    __shared__ unsigned short Bsm[2 * 128 * 32];
    constexpr int BUF = 128 * 32;

    const int tid  = threadIdx.x;
    const int wv   = tid >> 6;
    const int lane = tid & 63;
    const int q    = lane >> 4;
    const int ln   = lane & 15;
    const int wm   = wv & 1;
    const int wn   = wv >> 1;
    const int set  = blockIdx.z;

    const bf16* Wt = set ? w2t : w1t;
    bf16* Q  = set ? q2 : q1;
    bf16* Ko = set ? k2 : k1;
    bf16* V  = set ? v2 : v1;

    const bf16* A  = X  + (long)(blockIdx.y * 128) * K;
    const bf16* Bt = Wt + (long)(blockIdx.x * 128) * K;

    const int sr = lane >> 2, sc = lane & 3;
    const int scs = sc ^ (sr & 3);
    const bf16* gA0 = A  + (long)(wv * 32 + sr)      * K + scs * 8;
    const bf16* gA1 = A  + (long)(wv * 32 + 16 + sr) * K + scs * 8;
    const bf16* gB0 = Bt + (long)(wv * 32 + sr)      * K + scs * 8;
    const bf16* gB1 = Bt + (long)(wv * 32 + 16 + sr) * K + scs * 8;
    unsigned short* lA0 = &Asm[(wv * 32)      * 32];
    unsigned short* lA1 = &Asm[(wv * 32 + 16) * 32];
    unsigned short* lB0 = &Bsm[(wv * 32)      * 32];
    unsigned short* lB1 = &Bsm[(wv * 32 + 16) * 32];

    f32x4 acc[4][4];
#pragma unroll
    for (int i = 0; i < 4; ++i)
#pragma unroll
        for (int j = 0; j < 4; ++j)
            acc[i][j] = (f32x4){0.f, 0.f, 0.f, 0.f};

    const int qs = (q ^ (ln & 3)) * 8;

    gl_lds16(gA0, lA0);
    gl_lds16(gA1, lA1);
    gl_lds16(gB0, lB0);
    gl_lds16(gB1, lB1);
    __syncthreads();

    int cur = 0;
    for (int k0 = 0; k0 < K; k0 += 32) {
        const int nxt = cur ^ 1;
        if (k0 + 32 < K) {
            const int no = nxt * BUF;
            gl_lds16(gA0 + k0 + 32, lA0 + no);
            gl_lds16(gA1 + k0 + 32, lA1 + no);
            gl_lds16(gB0 + k0 + 32, lB0 + no);
            gl_lds16(gB1 + k0 + 32, lB1 + no);
        }

        const unsigned short* Ac = &Asm[cur * BUF];
        const unsigned short* Bc = &Bsm[cur * BUF];
        short8 af[4], bfr[4];
#pragma unroll
        for (int mt = 0; mt < 4; ++mt) {
            int m = wm * 64 + mt * 16 + ln;
            af[mt] = *(const short8*)&Ac[m * 32 + qs];
        }
#pragma unroll
        for (int nt = 0; nt < 4; ++nt) {
            int n = wn * 64 + nt * 16 + ln;
            bfr[nt] = *(const short8*)&Bc[n * 32 + qs];
        }
#pragma unroll
        for (int mt = 0; mt < 4; ++mt)
#pragma unroll
            for (int nt = 0; nt < 4; ++nt)
                acc[mt][nt] = __builtin_amdgcn_mfma_f32_16x16x32_bf16(
                    af[mt], bfr[nt], acc[mt][nt], 0, 0, 0);

        __syncthreads();
        cur = nxt;
    }

#pragma unroll
    for (int mt = 0; mt < 4; ++mt) {
#pragma unroll
        for (int nt = 0; nt < 4; ++nt) {
            const int col  = blockIdx.x * 128 + wn * 64 + nt * 16 + ln;
            const int rowb = blockIdx.y * 128 + wm * 64 + mt * 16 + q * 4;
            const int t = col >> 9;
            const int h = (col >> 6) & 7;
            const int dk = col & 63;
            bf16* dst = (t == 0) ? Q : (t == 1) ? Ko : V;
#pragma unroll
            for (int r = 0; r < 4; ++r) {
                const int row = rowb + r;
                const int b = row >= Nc ? 1 : 0;
                const int n = row - b * Nc;
                dst[(((long)b * Hc + h) * Nc + n) * DKc + dk] =
                    __float2bfloat16(acc[mt][nt][r]);
            }
        }
    }
}

// ---------------------------------------------------------------------------
// MFMA bf16 NT narrow GEMM core (validated): acc = A(128,K) @ Bt(64,K)^T.
// Reg-staged, stride-72 LDS (conflict-free by construction).
// ---------------------------------------------------------------------------
struct N64Acc { f32x4 acc[2][4]; };

template <typename DUMMY = void>
DEVINL void n64_core(const bf16* A, const bf16* Bt, int K,
                     unsigned short* Asm, unsigned short* Bsm, N64Acc& R)
{
    const int tid  = threadIdx.x;
    const int wave = tid >> 6;
    const int lane = tid & 63;
    const int q    = lane >> 4;
    const int ln   = lane & 15;

    const int sr = tid >> 3, k8 = tid & 7;
    const bf16* pa[4];
    const bf16* pb[2];
    int wa[4], wb[2];
#pragma unroll
    for (int i = 0; i < 4; ++i) {
        pa[i] = A + (long)(sr + i * 32) * K + k8 * 8;
        wa[i] = (sr + i * 32) * 72 + k8 * 8;
    }
#pragma unroll
    for (int i = 0; i < 2; ++i) {
        pb[i] = Bt + (long)(sr + i * 32) * K + k8 * 8;
        wb[i] = (sr + i * 32) * 72 + k8 * 8;
    }

#pragma unroll
    for (int i = 0; i < 2; ++i)
#pragma unroll
        for (int j = 0; j < 4; ++j)
            R.acc[i][j] = (f32x4){0.f, 0.f, 0.f, 0.f};

    for (int k0 = 0; k0 < K; k0 += 64) {
        uint4 va[4], vb[2];
#pragma unroll
        for (int i = 0; i < 4; ++i) va[i] = *(const uint4*)(pa[i] + k0);
#pragma unroll
        for (int i = 0; i < 2; ++i) vb[i] = *(const uint4*)(pb[i] + k0);
        __syncthreads();
#pragma unroll
        for (int i = 0; i < 4; ++i) *(uint4*)&Asm[wa[i]] = va[i];
#pragma unroll
        for (int i = 0; i < 2; ++i) *(uint4*)&Bsm[wb[i]] = vb[i];
        __syncthreads();

#pragma unroll
        for (int kc = 0; kc < 2; ++kc) {
            short8 af[2], bfr[4];
#pragma unroll
            for (int mt = 0; mt < 2; ++mt) {
                int m = wave * 32 + mt * 16 + ln;
                af[mt] = *(const short8*)&Asm[m * 72 + kc * 32 + q * 8];
            }
#pragma unroll
            for (int nt = 0; nt < 4; ++nt) {
                int n = nt * 16 + ln;
                bfr[nt] = *(const short8*)&Bsm[n * 72 + kc * 32 + q * 8];
            }
#pragma unroll
            for (int mt = 0; mt < 2; ++mt)
#pragma unroll
                for (int nt = 0; nt < 4; ++nt)
                    R.acc[mt][nt] = __builtin_amdgcn_mfma_f32_16x16x32_bf16(
                        af[mt], bfr[nt], R.acc[mt][nt], 0, 0, 0);
        }
    }
}

// ---------------------------------------------------------------------------
// Round 21: HALF-HEIGHT n64 core — acc = A(64,K) @ Bt(64,K)^T. 4 waves x 16
// rows, acc[4], 18 KB LDS. Same reg-staged stride-72 pattern. Purpose:
// double the grid of the 96-block y/proj launches (37% -> 75% CU coverage).
// ---------------------------------------------------------------------------
struct N64hAcc { f32x4 acc[4]; };

template <typename DUMMY = void>
DEVINL void n64h_core(const bf16* A, const bf16* Bt, int K,
                      unsigned short* Asm, unsigned short* Bsm, N64hAcc& R)
{
    const int tid  = threadIdx.x;
    const int wave = tid >> 6;
    const int lane = tid & 63;
    const int q    = lane >> 4;
    const int ln   = lane & 15;

    const int sr = tid >> 3, k8 = tid & 7;   // sr 0..31, k8 0..7
    const bf16* pa[2];
    const bf16* pb[2];
    int wa[2], wb[2];
#pragma unroll
    for (int i = 0; i < 2; ++i) {
        pa[i] = A  + (long)(sr + i * 32) * K + k8 * 8;
        wa[i] = (sr + i * 32) * 72 + k8 * 8;
        pb[i] = Bt + (long)(sr + i * 32) * K + k8 * 8;
        wb[i] = wa[i];
    }

#pragma unroll
    for (int j = 0; j < 4; ++j)
        R.acc[j] = (f32x4){0.f, 0.f, 0.f, 0.f};

    for (int k0 = 0; k0 < K; k0 += 64) {
        uint4 va[2], vb[2];
#pragma unroll
        for (int i = 0; i < 2; ++i) va[i] = *(const uint4*)(pa[i] + k0);
#pragma unroll
        for (int i = 0; i < 2; ++i) vb[i] = *(const uint4*)(pb[i] + k0);
        __syncthreads();
#pragma unroll
        for (int i = 0; i < 2; ++i) *(uint4*)&Asm[wa[i]] = va[i];
#pragma unroll
        for (int i = 0; i < 2; ++i) *(uint4*)&Bsm[wb[i]] = vb[i];
        __syncthreads();

#pragma unroll
        for (int kc = 0; kc < 2; ++kc) {
            short8 af;
            af = *(const short8*)&Asm[(wave * 16 + ln) * 72 + kc * 32 + q * 8];
            short8 bfr[4];
#pragma unroll
            for (int nt = 0; nt < 4; ++nt) {
                int n = nt * 16 + ln;
                bfr[nt] = *(const short8*)&Bsm[n * 72 + kc * 32 + q * 8];
            }
#pragma unroll
            for (int nt = 0; nt < 4; ++nt)
                R.acc[nt] = __builtin_amdgcn_mfma_f32_16x16x32_bf16(
                    af, bfr[nt], R.acc[nt], 0, 0, 0);
        }
    }
}

// ---------------------------------------------------------------------------
// Merged pair launch (Path-B fallback only; validated round 11).
// ---------------------------------------------------------------------------
__global__ __launch_bounds__(256) void gemm_n64_pair(
    const bf16* __restrict__ A0g, const bf16* __restrict__ B0g, bf16* __restrict__ C0tg,
    const bf16* __restrict__ A1g, const bf16* __restrict__ B1g, bf16* __restrict__ C1g,
    int M, int K, long sA, long sB, long sC)
{
    __shared__ unsigned short Asm[128 * 72];
    __shared__ unsigned short Bsm[64 * 72];

    const int zz = blockIdx.z & 15;
    const int second = blockIdx.z >> 4;
    const bf16* A  = (second ? A1g : A0g) + (long)zz * sA + (long)(blockIdx.y * 128) * K;
    const bf16* Bt = (second ? B1g : B0g) + (long)zz * sB;

    N64Acc R;
    n64_core(A, Bt, K, Asm, Bsm, R);

    const int tid = threadIdx.x;
    const int wave = tid >> 6, lane = tid & 63, q = lane >> 4, ln = lane & 15;

    if (second) {
        bf16* C = C1g + (long)zz * sC;
#pragma unroll
        for (int mt = 0; mt < 2; ++mt) {
#pragma unroll
            for (int nt = 0; nt < 4; ++nt) {
                const int col  = nt * 16 + ln;
                const int rowb = blockIdx.y * 128 + wave * 32 + mt * 16 + q * 4;
#pragma unroll
                for (int r = 0; r < 4; ++r)
                    C[(long)(rowb + r) * 64 + col] = __float2bfloat16(R.acc[mt][nt][r]);
            }
        }
    } else {
        __syncthreads();
#pragma unroll
        for (int mt = 0; mt < 2; ++mt) {
#pragma unroll
            for (int nt = 0; nt < 4; ++nt) {
                const int col = nt * 16 + ln;
                const int rwb = wave * 32 + mt * 16 + q * 4;
#pragma unroll
                for (int r = 0; r < 4; ++r)
                    *(bf16*)&Asm[col * 136 + rwb + r] = __float2bfloat16(R.acc[mt][nt][r]);
            }
        }
        __syncthreads();
        bf16* Ct = C0tg + (long)zz * sC;
        const int dk  = tid >> 2;
        const int nc0 = (tid & 3) * 32;
        const int gn0 = blockIdx.y * 128;
#pragma unroll
        for (int c8 = 0; c8 < 4; ++c8) {
            uint4 v = *(const uint4*)&Asm[dk * 136 + nc0 + c8 * 8];
            *(uint4*)&Ct[(long)dk * Nc + gn0 + nc0 + c8 * 8] = v;
        }
    }
}

// ---------------------------------------------------------------------------
// Round 21: merged y kernel, half-height tiles (Path A). Grid (1,12,16) =
// 192 blocks. Per block: R1 = A(64 rows)@v1t, R2 = Craw(64 rows)@v2t, write
// yc = R1 + w*R2 (f32 combine, single bf16 round).
// ---------------------------------------------------------------------------
__global__ __launch_bounds__(256) void gemm_n64_both_h(
    const bf16* __restrict__ Ab, const bf16* __restrict__ v1t,
    const bf16* __restrict__ Craw, const bf16* __restrict__ v2t,
    const float* __restrict__ smallf, bf16* __restrict__ yc,
    int K, long sA, long sB)
{
    __shared__ unsigned short Asm[64 * 72];
    __shared__ unsigned short Bsm[64 * 72];

    const int bh = blockIdx.z;
    const long arow = (long)(blockIdx.y * 64) * K;

    N64hAcc R1;
    n64h_core(Ab + (long)bh * sA + arow, v1t + (long)bh * sB, K, Asm, Bsm, R1);
    // n64h_core's first internal __syncthreads (before LDS writes) orders the
    // previous call's trailing LDS reads — no extra barrier needed.
    N64hAcc R2;
    n64h_core(Craw + (long)bh * sA + arow, v2t + (long)bh * sB, K, Asm, Bsm, R2);

    const float w = sigf(smallf[392]);
    const int b = bh >> 3, h = bh & 7;

    const int tid = threadIdx.x;
    const int wave = tid >> 6, lane = tid & 63, q = lane >> 4, ln = lane & 15;
#pragma unroll
    for (int nt = 0; nt < 4; ++nt) {
        const int col  = nt * 16 + ln;
        const int rowb = blockIdx.y * 64 + wave * 16 + q * 4;
#pragma unroll
        for (int r = 0; r < 4; ++r) {
            const int n = rowb + r;
            yc[((long)(b * Nc + n)) * Dc + h * DKc + col] =
                __float2bfloat16(R1.acc[nt][r] + w * R2.acc[nt][r]);
        }
    }
}

// y_chain GEMM with fused combine + permute (Path-B fallback only).
__global__ __launch_bounds__(256) void gemm_n64_combine(
    const bf16* __restrict__ A1b, const bf16* __restrict__ trt,
    const bf16* __restrict__ yb1, const float* __restrict__ smallf,
    bf16* __restrict__ yc, int M, int K, long sA, long sB)
{
    __shared__ unsigned short Asm[128 * 72];
    __shared__ unsigned short Bsm[64 * 72];

    const int bh = blockIdx.z;
    const bf16* A  = A1b + (long)bh * sA + (long)(blockIdx.y * 128) * K;
    const bf16* Bt = trt + (long)bh * sB;

    N64Acc R;
    n64_core(A, Bt, K, Asm, Bsm, R);

    const float w = sigf(smallf[392]);
    const int b = bh >> 3, h = bh & 7;
    const long yb1base = (long)bh * Nc * DKc;

    const int tid = threadIdx.x;
    const int wave = tid >> 6, lane = tid & 63, q = lane >> 4, ln = lane & 15;
#pragma unroll
    for (int mt = 0; mt < 2; ++mt) {
#pragma unroll
        for (int nt = 0; nt < 4; ++nt) {
            const int col  = nt * 16 + ln;
            const int rowb = blockIdx.y * 128 + wave * 32 + mt * 16 + q * 4;
#pragma unroll
            for (int r = 0; r < 4; ++r) {
                const int n = rowb + r;
                const float base = __bfloat162float(yb1[yb1base + (long)n * 64 + col]);
                yc[((long)(b * Nc + n)) * Dc + h * DKc + col] =
                    __float2bfloat16(base + w * R.acc[mt][nt][r]);
            }
        }
    }
}

// Path-B y_base GEMM (fallback only).
__global__ __launch_bounds__(256) void gemm_n64_yb(
    const bf16* __restrict__ Ag, const bf16* __restrict__ Btg,
    bf16* __restrict__ Cg, int M, int K, long sA, long sB, long sC)
{
    __shared__ unsigned short Asm[128 * 72];
    __shared__ unsigned short Bsm[64 * 72];

    const int zz = blockIdx.z;
    const bf16* A  = Ag + (long)zz * sA + (long)(blockIdx.y * 128) * K;
    const bf16* Bt = Btg + (long)zz * sB;

    N64Acc R;
    n64_core(A, Bt, K, Asm, Bsm, R);

    bf16* C = Cg + (long)zz * sC;
    const int tid = threadIdx.x;
    const int wave = tid >> 6, lane = tid & 63, q = lane >> 4, ln = lane & 15;
#pragma unroll
    for (int mt = 0; mt < 2; ++mt) {
#pragma unroll
        for (int nt = 0; nt < 4; ++nt) {
            const int col  = nt * 16 + ln;
            const int rowb = blockIdx.y * 128 + wave * 32 + mt * 16 + q * 4;
#pragma unroll
            for (int r = 0; r < 4; ++r)
                C[(long)(rowb + r) * 64 + col] = __float2bfloat16(R.acc[mt][nt][r]);
        }
    }
}

// ---------------------------------------------------------------------------
// Row softmax over width 768 — wave-per-row (validated round 16).
// ---------------------------------------------------------------------------
__global__ __launch_bounds__(256) void softmax_rows_w(
    const float* __restrict__ src, bf16* __restrict__ dst)
{
    const int wid  = threadIdx.x >> 6;
    const int lane = threadIdx.x & 63;
    const long row = (long)blockIdx.x * 4 + wid;
    const float* s = src + row * Nc;

    float4 v[3];
#pragma unroll
    for (int i = 0; i < 3; ++i)
        v[i] = *(const float4*)&s[i * 256 + lane * 4];

    float m = -1e30f;
#pragma unroll
    for (int i = 0; i < 3; ++i)
        m = fmaxf(m, fmaxf(fmaxf(v[i].x, v[i].y), fmaxf(v[i].z, v[i].w)));
#pragma unroll
    for (int off = 32; off > 0; off >>= 1)
        m = fmaxf(m, __shfl_xor(m, off, 64));

    float e[12];
    float sum = 0.f;
#pragma unroll
    for (int i = 0; i < 3; ++i) {
        e[i * 4 + 0] = __expf(v[i].x - m);
        e[i * 4 + 1] = __expf(v[i].y - m);
        e[i * 4 + 2] = __expf(v[i].z - m);
        e[i * 4 + 3] = __expf(v[i].w - m);
        sum += e[i * 4 + 0] + e[i * 4 + 1] + e[i * 4 + 2] + e[i * 4 + 3];
    }
#pragma unroll
    for (int off = 32; off > 0; off >>= 1)
        sum += __shfl_xor(sum, off, 64);

    const float inv = 1.f / fmaxf(sum, 1e-30f);
    unsigned short* d = (unsigned short*)dst + row * Nc;
#pragma unroll
    for (int i = 0; i < 3; ++i) {
        unsigned short o[4];
#pragma unroll
        for (int j = 0; j < 4; ++j) {
            const bf16 b = __float2bfloat16(e[i * 4 + j] * inv);
            o[j] = *(const unsigned short*)&b;
        }
        *(uint2*)&d[i * 256 + lane * 4] = *(const uint2*)o;
    }
}

// ---------------------------------------------------------------------------
// Gate network + Smix — round 21: EXACT r7-validated 2-elem body (77.8 µs).
// r8's 4-elem variant was null-to-negative (80.6 µs, FETCH +14 MB) — gates
// is at its mixed-regime plateau; reverted and frozen.
// ---------------------------------------------------------------------------
__global__ __launch_bounds__(256) void gates_smix(
    const float* __restrict__ S1g, const float* __restrict__ S2g,
    const bf16* __restrict__ Crg, const bf16* __restrict__ Clg,
    float* __restrict__ Smixg, const float* __restrict__ smallf)
{
    __shared__ float t1t[32][17], t2t[32][17];

    const long mat = (long)blockIdx.z * Nc * Nc;
    const float* S1 = S1g + mat;
    const float* S2 = S2g + mat;
    const unsigned short* Cr = (const unsigned short*)Crg + mat;
    const unsigned short* Cl = (const unsigned short*)Clg + mat;
    float* Smix = Smixg + mat;

    const int tid = threadIdx.x;

    const int n0 = blockIdx.y * 16, m0 = blockIdx.x * 32;
    {   // transposed tiles: S[m0..m0+31][n0..n0+15], coalesced float2 loads
        const int r = tid >> 3, c2 = (tid & 7) * 2;
        const float2 a = *(const float2*)&S1[(long)(m0 + r) * Nc + n0 + c2];
        const float2 b = *(const float2*)&S2[(long)(m0 + r) * Nc + n0 + c2];
        t1t[r][c2] = a.x; t1t[r][c2 + 1] = a.y;
        t2t[r][c2] = b.x; t2t[r][c2 + 1] = b.y;
    }
    __syncthreads();

    const int tx = tid & 15, ty = tid >> 4;
    const int n = n0 + ty;
    const long idx = (long)n * Nc + m0 + tx * 2;

    const float2 s1v = *(const float2*)&S1[idx];
    const float2 s2v = *(const float2*)&S2[idx];
    const unsigned cru = *(const unsigned*)&Cr[idx];   // idx even -> 4B aligned
    const unsigned clu = *(const unsigned*)&Cl[idx];

    const f32x2 s1a = {s1v.x, s1v.y};
    const f32x2 s2a = {s2v.x, s2v.y};
    const f32x2 cra = {__uint_as_float((cru & 0xffffu) << 16),
                       __uint_as_float(cru & 0xffff0000u)};
    const f32x2 cla = {__uint_as_float((clu & 0xffffu) << 16),
                       __uint_as_float(clu & 0xffff0000u)};
    const f32x2 s1t = {t1t[tx * 2][ty], t1t[tx * 2 + 1][ty]};
    const f32x2 s2t = {t2t[tx * 2][ty], t2t[tx * 2 + 1][ty]};

    f32x2 g0 = *(const f32x2*)&smallf[384];
    f32x2 g1 = *(const f32x2*)&smallf[386];
    f32x2 g2 = *(const f32x2*)&smallf[388];
    f32x2 g3 = *(const f32x2*)&smallf[390];

    const f32x2 gc1  = splat2(-2.30220902f);   // gelu c1 * log2e
    const f32x2 gc3  = splat2(-0.10294357f);   // gelu c3 * log2e
    const f32x2 one2 = splat2(1.f);

#pragma unroll
    for (int u = 0; u < 16; ++u) {
        const f32x2* cw = (const f32x2*)&smallf[u * 24];
        f32x2 h = cw[6];
        h = fma2(s1a, cw[0], h);
        h = fma2(s2a, cw[1], h);
        h = fma2(s1t, cw[2], h);
        h = fma2(s2t, cw[3], h);
        h = fma2(cra, cw[4], h);
        h = fma2(cla, cw[5], h);
        const f32x2 hh = h * h;
        const f32x2 z2 = h * fma2(hh, gc3, gc1);
        f32x2 e;  e[0]  = vexp2(z2[0]); e[1]  = vexp2(z2[1]);
        const f32x2 d = one2 + e;
        f32x2 rc; rc[0] = vrcp(d[0]);   rc[1] = vrcp(d[1]);
        const f32x2 hid = h * rc;
        g0 = fma2(hid, cw[8],  g0);
        g1 = fma2(hid, cw[9],  g1);
        g2 = fma2(hid, cw[10], g2);
        g3 = fma2(hid, cw[11], g3);
    }

    const f32x2 nl2e = splat2(-1.44269504f);
    const f32x2 ln2v = splat2(0.69314718f);
    auto sig2 = [&](f32x2 x) -> f32x2 {
        const f32x2 t = x * nl2e;
        f32x2 e;  e[0] = vexp2(t[0]); e[1] = vexp2(t[1]);
        const f32x2 d = one2 + e;
        f32x2 r;  r[0] = vrcp(d[0]);  r[1] = vrcp(d[1]);
        return r;
    };
    const f32x2 ga2 = sig2(g0);
    const f32x2 go2 = sig2(g1);
    const f32x2 gn2 = sig2(g2);
    const f32x2 gc2 = sig2(g3);

    const f32x2 dd = s1a - s2a;
    f32x2 ad; ad[0] = fabsf(dd[0]); ad[1] = fabsf(dd[1]);
    const f32x2 t2 = ad * nl2e;                       // -|d| * log2e
    f32x2 ee; ee[0] = vexp2(t2[0]); ee[1] = vexp2(t2[1]);
    const f32x2 lp = one2 + ee;
    f32x2 lg; lg[0] = vlog2(lp[0]); lg[1] = vlog2(lp[1]);
    const f32x2 mx2 = __builtin_elementwise_max(s1a, s2a);
    const f32x2 lae = fma2(lg, ln2v, mx2);            // logaddexp(s1,s2)

    f32x2 o2 = s1a;
    o2 = fma2(ga2, s2a, o2);
    o2 = fma2(go2, lae - s1a, o2);
    o2 = fma2(gn2, s2a * splat2(-BETA_NOT), o2);
    o2 = fma2(gc2, cra, o2);
    *(float2*)&Smix[idx] = (float2){o2[0], o2[1]};
}

// ---------------------------------------------------------------------------
// Round 21: final projection, half-height tiles — grid (8, 24) = 192 blocks
// (was 96 at 37% CU coverage).
// ---------------------------------------------------------------------------
__global__ __launch_bounds__(256) void proj_n64h(
    const bf16* __restrict__ yc, const bf16* __restrict__ pwt,
    const void* __restrict__ xraw, void* __restrict__ out)
{
    constexpr int K = Dc;  // 512
    constexpr int N = Dc;  // 512
    __shared__ unsigned short Asm[64 * 72];
    __shared__ unsigned short Bsm[64 * 72];
    __shared__ int is32s;
    if (threadIdx.x == 0) is32s = sniff_is_fp32(xraw);

    const bf16* A  = yc  + (long)(blockIdx.y * 64) * K;
    const bf16* Bt = pwt + (long)(blockIdx.x * 64) * K;

    N64hAcc R;
    n64h_core(A, Bt, K, Asm, Bsm, R);   // internal barriers publish is32s

    const int is32 = is32s;
    const int tid = threadIdx.x;
    const int wave = tid >> 6, lane = tid & 63, q = lane >> 4, ln = lane & 15;
#pragma unroll
    for (int nt = 0; nt < 4; ++nt) {
        const int col  = blockIdx.x * 64 + nt * 16 + ln;
        const int rowb = blockIdx.y * 64 + wave * 16 + q * 4;
#pragma unroll
        for (int r = 0; r < 4; ++r) {
            const long o = (long)(rowb + r) * N + col;
            if (is32) ((float*)out)[o] = R.acc[nt][r];
            else      ((bf16*)out)[o] = __float2bfloat16(R.acc[nt][r]);
        }
    }
}

// ---------------------------------------------------------------------------
extern "C" void kernel_launch(void* const* d_in, const int* in_sizes, int n_in,
                              void* d_out, int out_size, void* d_ws, size_t ws_size,
                              hipStream_t stream)
{
    const size_t HD   = (size_t)BHc * Nc * DKc;   // 786432
    const size_t HDh  = HD / 2;                   // float-slots for HD bf16
    const size_t MAT  = (size_t)Nc * Nc;          // 589824
    const size_t MATS = (size_t)BHc * MAT;        // 9437184
    const long   HSTR = (long)Nc * DKc;           // 49152 per-head stride

    float* ws = (float*)d_ws;
    size_t off = 0;
    auto alloc = [&](size_t n) { float* p = ws + off; off += n; return p; };

    bf16* xb  = (bf16*)alloc(HDh);
    bf16* w1b = (bf16*)alloc(HDh);   // w1b/w2b adjacent -> merged transpose
    bf16* w2b = (bf16*)alloc(HDh);
    bf16* w1t = (bf16*)alloc(HDh);
    bf16* w2t = (bf16*)alloc(HDh);
    bf16* pwb = (bf16*)alloc((size_t)Dc * Dc / 2);
    bf16* pwt = (bf16*)alloc((size_t)Dc * Dc / 2);
    float* smallf = alloc(512);
    // q1|q2 and k1|k2 adjacent -> single merged S-GEMM launch (32 heads)
    bf16* q1b = (bf16*)alloc(HDh); bf16* q2b = (bf16*)alloc(HDh);
    bf16* k1b = (bf16*)alloc(HDh); bf16* k2b = (bf16*)alloc(HDh);
    bf16* v1b = (bf16*)alloc(HDh); bf16* v2b = (bf16*)alloc(HDh);  // adjacent
    bf16* v1t = (bf16*)alloc(HDh); bf16* v2t = (bf16*)alloc(HDh);  // adjacent
    bf16* trt = (bf16*)alloc(HDh);
    float* S1   = alloc(MATS);       // S1/S2 adjacent -> merged softmax + S-GEMM
    float* S2   = alloc(MATS);
    float* Smix = alloc(MATS);       // region reused: A1tb|A2tb, then Smix
    bf16* A1b = (bf16*)alloc(MATS / 2);  // A1b/A2b adjacent
    bf16* A2b = (bf16*)alloc(MATS / 2);
    bf16* Crb = (bf16*)alloc(MATS / 2);  // Crb/Clb adjacent (merged launch)
    bf16* Clb = (bf16*)alloc(MATS / 2);
    bf16* yb1 = (bf16*)alloc(HDh);
    bf16* yc  = (bf16*)alloc(HDh);

    const size_t NEED_BASE = off * sizeof(float);
    bf16* Crawb = (bf16*)alloc(MATS / 2);          // raw C_right (Path A only)
    const size_t NEED_A = off * sizeof(float);
    const int pathA = ws_size >= NEED_A;

    // aliases into dead regions
    bf16* A1tb = (bf16*)Smix;            // live steps 3-4 (dead once gates writes Smix)
    bf16* A2tb = ((bf16*)Smix) + MATS;
    bf16* Ab   = (bf16*)S1;              // S1 dead after gates

    if (ws_size < NEED_BASE) {
        fill_sentinel<<<dim3(3072), 256, 0, stream>>>((unsigned short*)d_out);
        return;
    }

    // 0. normalize inputs
    convert_all<<<dim3(3072), 256, 0, stream>>>(
        d_in[0], d_in[1], d_in[2], d_in[3], d_in[4], d_in[5], d_in[6], d_in[7],
        d_in[8], xb, w1b, w2b, pwb, smallf);

    // 1. merged W transposes; pw transpose; merged QKV; merged v transposes
    transpose_bf16<<<dim3(24, 8, 2), 256, 0, stream>>>(
        (const unsigned short*)w1b, (unsigned short*)w1t, Dc, 3 * Dc, (long)HD, (long)HD);
    transpose_bf16<<<dim3(8, 8, 1), 256, 0, stream>>>(
        (const unsigned short*)pwb, (unsigned short*)pwt, Dc, Dc, 0, 0);
    qkv_mfma<<<dim3(12, 12, 2), 256, 0, stream>>>(
        xb, w1t, w2t, q1b, k1b, v1b, q2b, k2b, v2b);
    transpose_bf16<<<dim3(1, 12, 2 * BHc), 256, 0, stream>>>(
        (const unsigned short*)v1b, (unsigned short*)v1t, Nc, DKc, HSTR, HSTR);

    // 2. S = scale * q @ k^T — single 32-batch launch (2-phase K-loop)
    gemm_nt_mfma<0, float><<<dim3(6, 6, 2 * BHc), 256, 0, stream>>>(
        q1b, k1b, S1, nullptr, Nc, Nc, DKc, HSTR, HSTR, (long)MAT, SCALE);

    // 3. merged softmax S1|S2 -> A1b|A2b (wave-per-row); merged transposes
    softmax_rows_w<<<(2 * BHc * Nc) / 4, 256, 0, stream>>>(S1, A1b);
    transpose_bf16<<<dim3(12, 12, 2 * BHc), 256, 0, stream>>>(
        (const unsigned short*)A1b, (unsigned short*)A1tb, Nc, Nc, (long)MAT, (long)MAT);

    // 4. Cr|Cl in ONE 32-batch launch; XCD-pinned 1-D grid (1152 = 8*4*36);
    //    2-phase double-buffered K-loop; Path A also stores raw C_right.
    if (pathA)
        gemm_nt_mfma<1, bf16, 1, 1, 1><<<dim3(1152), 256, 0, stream>>>(
            A1b, A1tb, Crb, Crawb, Nc, Nc, Nc, (long)MAT, (long)MAT, (long)MAT, 1.f);
    else
        gemm_nt_mfma<1, bf16, 1, 1, 0><<<dim3(1152), 256, 0, stream>>>(
            A1b, A1tb, Crb, nullptr, Nc, Nc, Nc, (long)MAT, (long)MAT, (long)MAT, 1.f);

    // 5. gates + Smix (r7-validated 2-elem body)
    gates_smix<<<dim3(24, 48, BHc), 256, 0, stream>>>(S1, S2, Crb, Clb, Smix, smallf);

    // 6. A = softmax(Smix) -> bf16 (into S1 alias, wave-per-row)
    softmax_rows_w<<<(BHc * Nc) / 4, 256, 0, stream>>>(Smix, Ab);

    if (pathA) {
        // 7. merged y, half-height tiles: 192 blocks (was 96 @ 37% CUs)
        gemm_n64_both_h<<<dim3(1, 12, BHc), 256, 0, stream>>>(
            Ab, v1t, Crawb, v2t, smallf, yc, Nc, (long)MAT, HSTR);
    } else {
        // Path B fallback (round-5 structure)
        gemm_n64_pair<<<dim3(1, 6, 2 * BHc), 256, 0, stream>>>(
            A2b, v2t, trt, Ab, v1t, yb1, Nc, Nc, (long)MAT, HSTR, HSTR);
        gemm_n64_combine<<<dim3(1, 6, BHc), 256, 0, stream>>>(
            A1b, trt, yb1, smallf, yc, Nc, Nc, (long)MAT, HSTR);
    }

    // 9. proj, half-height tiles: 192 blocks (was 96)
    proj_n64h<<<dim3(8, 24, 1), 256, 0, stream>>>(yc, pwt, d_in[0], d_out);
}

// Round 10
// 331.630 us; speedup vs baseline: 1.4893x; 1.0425x over previous
//
#include <hip/hip_runtime.h>
#include <hip/hip_bf16.h>
#include <math.h>

typedef __hip_bfloat16 bf16;
typedef __attribute__((ext_vector_type(8))) short short8;   // 8 bf16 (4 VGPRs)
typedef __attribute__((ext_vector_type(4))) float f32x4;
typedef __attribute__((ext_vector_type(2))) float f32x2;
#define DEVINL __device__ __forceinline__

constexpr int Bc  = 2;
constexpr int Nc  = 768;
constexpr int Dc  = 512;
constexpr int Hc  = 8;
constexpr int DKc = 64;
constexpr int BHc = Bc * Hc;
constexpr float SCALE    = 0.125f;   // 1/sqrt(64)
constexpr float EPSF     = 1e-6f;
constexpr float BETA_NOT = 0.5f;

DEVINL float ldf(const float* p, long i) { return p[i]; }
DEVINL float ldf(const bf16* p, long i) { return __bfloat162float(p[i]); }
DEVINL void stf(float* p, long i, float v) { p[i] = v; }
DEVINL void stf(bf16* p, long i, float v) { p[i] = __float2bfloat16(v); }

DEVINL float sigf(float x) { return __fdividef(1.f, 1.f + __expf(-x)); }

// packed fp32 pair helpers — backend selects v_pk_fma_f32/v_pk_mul_f32 (r3:
// validated -41% on gates_smix; r4 pair-dup operands -12%; r5 s_load weights).
DEVINL f32x2 fma2(f32x2 a, f32x2 b, f32x2 c) { return __builtin_elementwise_fma(a, b, c); }
DEVINL f32x2 splat2(float x) { return (f32x2){x, x}; }
// guard-free transcendentals (libm exp2f adds a denormal guard: +13% in r2)
DEVINL float vexp2(float x) { float r; asm("v_exp_f32 %0, %1" : "=v"(r) : "v"(x)); return r; }
DEVINL float vrcp(float x)  { float r; asm("v_rcp_f32 %0, %1" : "=v"(r) : "v"(x)); return r; }
DEVINL float vlog2(float x) { float r; asm("v_log_f32 %0, %1" : "=v"(r) : "v"(x)); return r; }

// async global->LDS, 16B per lane; LDS dest = wave-uniform base + lane*16.
DEVINL void gl_lds16(const void* g, void* l) {
    __builtin_amdgcn_global_load_lds(
        (const __attribute__((address_space(1))) void*)g,
        (__attribute__((address_space(3))) void*)l, 16, 0, 0);
}

// ---------------------------------------------------------------------------
// Dtype sniffer — vectorized (validated round 9).
// ---------------------------------------------------------------------------
DEVINL int sniff_is_fp32(const void* xraw) {
    const uint4* p4 = (const uint4*)xraw;
    float mx = 0.f;
#pragma unroll
    for (int j = 0; j < 16; ++j) {
        const uint4 u = p4[j];
        const unsigned w[4] = {u.x, u.y, u.z, u.w};
#pragma unroll
        for (int t = 0; t < 4; ++t) {
            mx = fmaxf(mx, fabsf(__uint_as_float((w[t] & 0xffffu) << 16)));
            mx = fmaxf(mx, fabsf(__uint_as_float(w[t] & 0xffff0000u)));
        }
    }
    return mx > 1000.f ? 1 : 0;
}

DEVINL float cvt_elem(const void* s, long j, int is32) {
    return is32 ? ((const float*)s)[j]
                : __bfloat162float(((const bf16*)s)[j]);
}

// smallf layout (round 15 — PAIR-DUPLICATED; read via uniform scalar loads):
//   [u*24 + 2k+{0,1}]  = w1[u][k]          k=0..5   (12 floats)
//   [u*24 + 12..13]    = b1[u] pair
//   [u*24 + 14..15]    = pad
//   [u*24 + 16 + 2o+{0,1}] = conv2_w[o][u] o=0..3   (8 floats)
//   [384..391]  conv2_b[o] pairs
//   [392..393]  chain_logit pair          (combine reads [392])
__global__ __launch_bounds__(256) void convert_all(
    const void* x, const void* w1, const void* w2, const void* pw,
    const void* c1w, const void* c1b, const void* c2w, const void* c2b,
    const void* ch,
    bf16* xb, bf16* w1b, bf16* w2b, bf16* pwb, float* smallf)
{
    __shared__ int is32s;
    if (threadIdx.x == 0) is32s = sniff_is_fp32(x);
    __syncthreads();
    const int is32 = is32s;
    const long i = (long)blockIdx.x * 256 + threadIdx.x;
    if (i < (long)Bc * Nc * Dc) {
        xb[i]  = __float2bfloat16(cvt_elem(x,  i, is32));
        w1b[i] = __float2bfloat16(cvt_elem(w1, i, is32));
        w2b[i] = __float2bfloat16(cvt_elem(w2, i, is32));
    }
    if (i < (long)Dc * Dc) pwb[i] = __float2bfloat16(cvt_elem(pw, i, is32));
    if (i < 384) {
        const int u = (int)i / 24, k = (int)i % 24;
        float v = 0.f;
        if (k < 12)      v = cvt_elem(c1w, u * 6 + (k >> 1), is32);
        else if (k < 14) v = cvt_elem(c1b, u, is32);
        else if (k >= 16) { const int o = (k - 16) >> 1; v = cvt_elem(c2w, o * 16 + u, is32); }
        smallf[i] = v;
    } else if (i < 392) smallf[i] = cvt_elem(c2b, ((int)i - 384) >> 1, is32);
    else if (i < 394) smallf[i] = cvt_elem(ch, 0, is32);
    else if (i < 512) smallf[i] = 0.f;
}

__global__ __launch_bounds__(256) void fill_sentinel(unsigned short* o) {
    const long i = (long)blockIdx.x * 256 + threadIdx.x;
    if (i < (long)Bc * Nc * Dc) o[i] = 0x40E0;  // bf16 7.0
}

// ---------------------------------------------------------------------------
// Generic bf16 transpose, 64x64 tiles: dst[c][r] = src[r][c]; src is (R,C).
// ---------------------------------------------------------------------------
__global__ __launch_bounds__(256) void transpose_bf16(
    const unsigned short* __restrict__ src, unsigned short* __restrict__ dst,
    int R, int C, long sS, long sD)
{
    __shared__ unsigned short tile[64][68];
    const unsigned short* s = src + (long)blockIdx.z * sS;
    unsigned short* d = dst + (long)blockIdx.z * sD;
    const int r0 = blockIdx.y * 64, c0 = blockIdx.x * 64;
    const int t = threadIdx.x;
    const int lr = t >> 4, lc4 = (t & 15) * 4;
#pragma unroll
    for (int i = 0; i < 4; ++i) {
        int r = lr + i * 16;
        *(uint2*)&tile[r][lc4] = *(const uint2*)&s[(long)(r0 + r) * C + c0 + lc4];
    }
    __syncthreads();
#pragma unroll
    for (int i = 0; i < 4; ++i) {
        int r = lr + i * 16;
        unsigned short v[4];
#pragma unroll
        for (int j = 0; j < 4; ++j) v[j] = tile[lc4 + j][r];
        *(uint2*)&d[(long)(c0 + r) * R + r0 + lc4] = *(uint2*)v;
    }
}

// ---------------------------------------------------------------------------
// Round 22: FUSED S-GEMM + row softmax + A-transpose.
// Block = 16 rows x 768 cols, K = 64. Replaces step-2 GEMM, softmax3, and
// the A-transpose launch: acc stays live through softmax (no S re-read,
// -75 MB) and the A strip is staged in LDS then written transposed
// (-75 MB round trip, -1 launch). B staged n64-style (stride 72, 3 chunks
// of 256 rows); A^T stage aliases the B buffer after the K loop.
// Grid 1536 = 8 xcd * (4 z-group * 48 row-tiles), z pinned to XCD.
// ---------------------------------------------------------------------------
__global__ __launch_bounds__(256) void sgemm_softmax(
    const bf16* __restrict__ qg, const bf16* __restrict__ kg,
    float* __restrict__ Sg, bf16* __restrict__ Ag_, bf16* __restrict__ Atg)
{
    __shared__ unsigned short Bsm[256 * 72];   // 36 KB; aliased for A^T stage
    __shared__ unsigned short Asm16[16 * 72];  // 2.25 KB
    __shared__ float red[4][16];

    const int wg  = blockIdx.x;
    const int xcd = wg & 7, tt = wg >> 3;
    const int z   = xcd + 8 * (tt / 48);
    const int by  = tt % 48;
    const long MAT = (long)Nc * Nc;

    const bf16* Q  = qg + (long)z * (Nc * DKc) + (long)(by * 16) * DKc;
    const bf16* Km = kg + (long)z * (Nc * DKc);
    float* S  = Sg  + (long)z * MAT + (long)(by * 16) * Nc;
    bf16*  A  = Ag_ + (long)z * MAT + (long)(by * 16) * Nc;
    bf16*  At = Atg + (long)z * MAT;           // write At[m][by*16 + n]

    const int tid  = threadIdx.x;
    const int wv   = tid >> 6;
    const int lane = tid & 63;
    const int q    = lane >> 4;
    const int ln   = lane & 15;
    const int sr   = tid >> 3, k8 = tid & 7;

    // stage Q tile (16 x 64) — covered by the first barrier in the chunk loop
    if (tid < 128) {
        const int row = tid >> 3, kk = tid & 7;
        *(uint4*)&Asm16[row * 72 + kk * 8] = *(const uint4*)&Q[row * 64 + kk * 8];
    }

    f32x4 acc[12];
#pragma unroll
    for (int j = 0; j < 12; ++j) acc[j] = (f32x4){0.f, 0.f, 0.f, 0.f};

    for (int c = 0; c < 3; ++c) {
        __syncthreads();   // prev chunk's Bsm reads done (and Q stage at c=0)
#pragma unroll
        for (int i = 0; i < 8; ++i) {
            const int row = sr + i * 32;
            *(uint4*)&Bsm[row * 72 + k8 * 8] =
                *(const uint4*)&Km[(long)(c * 256 + row) * 64 + k8 * 8];
        }
        __syncthreads();
#pragma unroll
        for (int kc = 0; kc < 2; ++kc) {
            const short8 af = *(const short8*)&Asm16[ln * 72 + kc * 32 + q * 8];
#pragma unroll
            for (int t = 0; t < 4; ++t) {
                const int nl = wv * 64 + t * 16 + ln;
                const short8 bfr = *(const short8*)&Bsm[nl * 72 + kc * 32 + q * 8];
                acc[c * 4 + t] = __builtin_amdgcn_mfma_f32_16x16x32_bf16(
                    af, bfr, acc[c * 4 + t], 0, 0, 0);
            }
        }
    }

    // scale, store S, track row max (C/D layout: row = q*4+r, col = ... + ln)
    float mrow[4] = {-1e30f, -1e30f, -1e30f, -1e30f};
#pragma unroll
    for (int j = 0; j < 12; ++j) {
        const int c = j >> 2, t = j & 3;
        const int col = c * 256 + wv * 64 + t * 16 + ln;
#pragma unroll
        for (int r = 0; r < 4; ++r) {
            const float v = acc[j][r] * SCALE;
            acc[j][r] = v;
            S[(long)(q * 4 + r) * Nc + col] = v;
            mrow[r] = fmaxf(mrow[r], v);
        }
    }
#pragma unroll
    for (int off = 8; off > 0; off >>= 1)
#pragma unroll
        for (int r = 0; r < 4; ++r)
            mrow[r] = fmaxf(mrow[r], __shfl_xor(mrow[r], off, 16));
    if (ln == 0)
#pragma unroll
        for (int r = 0; r < 4; ++r) red[wv][q * 4 + r] = mrow[r];
    __syncthreads();
    float m4[4];
#pragma unroll
    for (int r = 0; r < 4; ++r)
        m4[r] = fmaxf(fmaxf(red[0][q * 4 + r], red[1][q * 4 + r]),
                      fmaxf(red[2][q * 4 + r], red[3][q * 4 + r]));
    __syncthreads();   // before red reuse for sums

    float srow[4] = {0.f, 0.f, 0.f, 0.f};
#pragma unroll
    for (int j = 0; j < 12; ++j)
#pragma unroll
        for (int r = 0; r < 4; ++r) {
            const float e = __expf(acc[j][r] - m4[r]);
            acc[j][r] = e;
            srow[r] += e;
        }
#pragma unroll
    for (int off = 8; off > 0; off >>= 1)
#pragma unroll
        for (int r = 0; r < 4; ++r)
            srow[r] += __shfl_xor(srow[r], off, 16);
    if (ln == 0)
#pragma unroll
        for (int r = 0; r < 4; ++r) red[wv][q * 4 + r] = srow[r];
    __syncthreads();
    float inv[4];
#pragma unroll
    for (int r = 0; r < 4; ++r)
        inv[r] = 1.f / fmaxf(red[0][q * 4 + r] + red[1][q * 4 + r] +
                             red[2][q * 4 + r] + red[3][q * 4 + r], 1e-30f);

    // write A (row-major bf16) and stage A^T in LDS [768][20] (aliases Bsm)
    unsigned short* ATl = Bsm;   // 768*20*2 = 30.7 KB <= 36 KB
#pragma unroll
    for (int j = 0; j < 12; ++j) {
        const int c = j >> 2, t = j & 3;
        const int col = c * 256 + wv * 64 + t * 16 + ln;
#pragma unroll
        for (int r = 0; r < 4; ++r) {
            const bf16 b = __float2bfloat16(acc[j][r] * inv[r]);
            const unsigned short u = *(const unsigned short*)&b;
            A[(long)(q * 4 + r) * Nc + col] = *(const bf16*)&u;
            ATl[col * 20 + q * 4 + r] = u;
        }
    }
    __syncthreads();
    // cooperative transposed write: 768 rows m, 16 bf16 (32 B) each
#pragma unroll
    for (int s = 0; s < 3; ++s) {
        const int m = tid + s * 256;
        uint2 v0 = *(const uint2*)&ATl[m * 20 + 0];
        uint2 v1 = *(const uint2*)&ATl[m * 20 + 4];
        uint2 v2 = *(const uint2*)&ATl[m * 20 + 8];
        uint2 v3 = *(const uint2*)&ATl[m * 20 + 12];
        unsigned short* d = (unsigned short*)&At[(long)m * Nc + by * 16];
        *(uint2*)&d[0]  = v0;
        *(uint2*)&d[4]  = v1;
        *(uint2*)&d[8]  = v2;
        *(uint2*)&d[12] = v3;
    }
}

// ---------------------------------------------------------------------------
// MFMA bf16 NT GEMM — 2-phase double-buffered K-loop (validated r7: step-4
// 99 -> <78 µs; latency-bound 1-phase loop was the cause).
//  - XCDSWZ: 1-D grid 1152 = 8 xcd * (4 batch * 36 tile) — FETCH 5x cut (r6).
//  - RAW: also store pre-log C (z<16) for associativity y_chain.
//  - read-XOR swizzle kept (r6: conflict-count-neutral, cost-free).
// ---------------------------------------------------------------------------
template <int EPI, typename TC, int XORB = 0, int XCDSWZ = 0, int RAW = 0>
__global__ __launch_bounds__(256) void gemm_nt_mfma(
    const bf16* __restrict__ Ag, const bf16* __restrict__ Btg,
    TC* __restrict__ Cg, bf16* __restrict__ Craw, int M, int N, int K,
    long sA, long sB, long sC, float alpha)
{
    __shared__ unsigned short Asm[2 * 128 * 32];
    __shared__ unsigned short Bsm[2 * 128 * 32];
    constexpr int BUF = 128 * 32;   // elements per buffer

    int bx, by, bz;
    if (XCDSWZ) {
        const int wg = blockIdx.x;
        const int xcd = wg & 7, t = wg >> 3;
        bz = xcd + 8 * (t / 36);
        const int tile = t % 36;
        bx = tile % 6; by = tile / 6;
    } else { bx = blockIdx.x; by = blockIdx.y; bz = blockIdx.z; }

    const int tid  = threadIdx.x;
    const int wv   = tid >> 6;
    const int lane = tid & 63;
    const int q    = lane >> 4;
    const int ln   = lane & 15;
    const int wm   = wv & 1;
    const int wn   = wv >> 1;

    const int zb = XORB ? (bz ^ 16) : bz;
    const bf16* A  = Ag  + (long)bz * sA + (long)(by * 128) * K;
    const bf16* Bt = Btg + (long)zb * sB + (long)(bx * 128) * K;
    TC*         C  = Cg  + (long)bz * sC;

    const int sr = lane >> 2, sc = lane & 3;
    const int scs = sc ^ (sr & 3);          // source col-block pre-swizzle
    const bf16* gA0 = A  + (long)(wv * 32 + sr)      * K + scs * 8;
    const bf16* gA1 = A  + (long)(wv * 32 + 16 + sr) * K + scs * 8;
    const bf16* gB0 = Bt + (long)(wv * 32 + sr)      * K + scs * 8;
    const bf16* gB1 = Bt + (long)(wv * 32 + 16 + sr) * K + scs * 8;
    unsigned short* lA0 = &Asm[(wv * 32)      * 32];
    unsigned short* lA1 = &Asm[(wv * 32 + 16) * 32];
    unsigned short* lB0 = &Bsm[(wv * 32)      * 32];
    unsigned short* lB1 = &Bsm[(wv * 32 + 16) * 32];

    f32x4 acc[4][4];
#pragma unroll
    for (int i = 0; i < 4; ++i)
#pragma unroll
        for (int j = 0; j < 4; ++j)
            acc[i][j] = (f32x4){0.f, 0.f, 0.f, 0.f};

    const int qs = (q ^ (ln & 3)) * 8;      // swizzled read block

    // prologue: stage K-tile 0 into buffer 0, drain, sync
    gl_lds16(gA0, lA0);
    gl_lds16(gA1, lA1);
    gl_lds16(gB0, lB0);
    gl_lds16(gB1, lB1);
    __syncthreads();

    int cur = 0;
    for (int k0 = 0; k0 < K; k0 += 32) {
        const int nxt = cur ^ 1;
        if (k0 + 32 < K) {                  // issue NEXT tile's loads (async)
            const int no = nxt * BUF;
            gl_lds16(gA0 + k0 + 32, lA0 + no);
            gl_lds16(gA1 + k0 + 32, lA1 + no);
            gl_lds16(gB0 + k0 + 32, lB0 + no);
            gl_lds16(gB1 + k0 + 32, lB1 + no);
        }

        const unsigned short* Ac = &Asm[cur * BUF];
        const unsigned short* Bc = &Bsm[cur * BUF];
        short8 af[4], bfr[4];
#pragma unroll
        for (int mt = 0; mt < 4; ++mt) {
            int m = wm * 64 + mt * 16 + ln;
            af[mt] = *(const short8*)&Ac[m * 32 + qs];
        }
#pragma unroll
        for (int nt = 0; nt < 4; ++nt) {
            int n = wn * 64 + nt * 16 + ln;
            bfr[nt] = *(const short8*)&Bc[n * 32 + qs];
        }
#pragma unroll
        for (int mt = 0; mt < 4; ++mt)
#pragma unroll
            for (int nt = 0; nt < 4; ++nt)
                acc[mt][nt] = __builtin_amdgcn_mfma_f32_16x16x32_bf16(
                    af[mt], bfr[nt], acc[mt][nt], 0, 0, 0);

        __syncthreads();   // vmcnt(0) drain of next-tile loads + wave sync
        cur = nxt;
    }

#pragma unroll
    for (int mt = 0; mt < 4; ++mt) {
#pragma unroll
        for (int nt = 0; nt < 4; ++nt) {
            const int col = bx * 128 + wn * 64 + nt * 16 + ln;
            const int rowb = by * 128 + wm * 64 + mt * 16 + q * 4;
#pragma unroll
            for (int r = 0; r < 4; ++r) {
                float vraw = acc[mt][nt][r] * alpha;
                if (RAW) {
                    if (bz < 16)
                        Craw[(long)bz * M * N + (long)(rowb + r) * N + col] =
                            __float2bfloat16(vraw);
                }
                float v = vraw;
                if (EPI == 1) v = __logf(fmaxf(v, 0.f) + EPSF);
                stf(C, (long)(rowb + r) * N + col, v);
            }
        }
    }
}

// ---------------------------------------------------------------------------
// QKV via MFMA, merged sets — 2-phase double-buffered K-loop (r7).
// ---------------------------------------------------------------------------
__global__ __launch_bounds__(256) void qkv_mfma(
    const bf16* __restrict__ X,
    const bf16* __restrict__ w1t, const bf16* __restrict__ w2t,
    bf16* __restrict__ q1, bf16* __restrict__ k1, bf16* __restrict__ v1,
    bf16* __restrict__ q2, bf16* __restrict__ k2, bf16* __restrict__ v2)
{
    constexpr int K = Dc;  // 512
    __shared__ unsigned short Asm[2 * 128 * 32];
    __shared__ unsigned short Bsm[2 * 128 * 32];
    constexpr int BUF = 128 * 32;

    const int tid  = threadIdx.x;
    const int wv   = tid >> 6;
    const int lane = tid & 63;
    const int q    = lane >> 4;
    const int ln   = lane & 15;
    const int wm   = wv & 1;
    const int wn   = wv >> 1;
    const int set  = blockIdx.z;

    const bf16* Wt = set ? w2t : w1t;
    bf16* Q  = set ? q2 : q1;
    bf16* Ko = set ? k2 : k1;
    bf16* V  = set ? v2 : v1;

    const bf16* A  = X  + (long)(blockIdx.y * 128) * K;
    const bf16* Bt = Wt + (long)(blockIdx.x * 128) * K;

    const int sr = lane >> 2, sc = lane & 3;
    const int scs = sc ^ (sr & 3);
    const bf16* gA0 = A  + (long)(wv * 32 + sr)      * K + scs * 8;
    const bf16* gA1 = A  + (long)(wv * 32 + 16 + sr) * K + scs * 8;
    const bf16* gB0 = Bt + (long)(wv * 32 + sr)      * K + scs * 8;
    const bf16* gB1 = Bt + (long)(wv * 32 + 16 + sr) * K + scs * 8;
    unsigned short* lA0 = &Asm[(wv * 32)      * 32];
    unsigned short* lA1 = &Asm[(wv * 32 + 16) * 32];
    unsigned short* lB0 = &Bsm[(wv * 32)      * 32];
    unsigned short* lB1 = &Bsm[(wv * 32 + 16) * 32];

    f32x4 acc[4][4];
#pragma unroll
    for (int i = 0; i < 4; ++i)
#pragma unroll
        for (int j = 0; j < 4; ++j)
            acc[i][j] = (f32x4){0.f, 0.f, 0.f, 0.f};

    const int qs = (q ^ (ln & 3)) * 8;

    gl_lds16(gA0, lA0);
    gl_lds16(gA1, lA1);
    gl_lds16(gB0, lB0);
    gl_lds16(gB1, lB1);
    __syncthreads();

    int cur = 0;
    for (int k0 = 0; k0 < K; k0 += 32) {
        const int nxt = cur ^ 1;
        if (k0 + 32 < K) {
            const int no = nxt * BUF;
            gl_lds16(gA0 + k0 + 32, lA0 + no);
            gl_lds16(gA1 + k0 + 32, lA1 + no);
            gl_lds16(gB0 + k0 + 32, lB0 + no);
            gl_lds16(gB1 + k0 + 32, lB1 + no);
        }

        const unsigned short* Ac = &Asm[cur * BUF];
        const unsigned short* Bc = &Bsm[cur * BUF];
        short8 af[4], bfr[4];
#pragma unroll
        for (int mt = 0; mt < 4; ++mt) {
            int m = wm * 64 + mt * 16 + ln;
            af[mt] = *(const short8*)&Ac[m * 32 + qs];
        }
#pragma unroll
        for (int nt = 0; nt < 4; ++nt) {
            int n = wn * 64 + nt * 16 + ln;
            bfr[nt] = *(const short8*)&Bc[n * 32 + qs];
        }
#pragma unroll
        for (int mt = 0; mt < 4; ++mt)
#pragma unroll
            for (int nt = 0; nt < 4; ++nt)
                acc[mt][nt] = __builtin_amdgcn_mfma_f32_16x16x32_bf16(
                    af[mt], bfr[nt], acc[mt][nt], 0, 0, 0);

        __syncthreads();
        cur = nxt;
    }

#pragma unroll
    for (int mt = 0; mt < 4; ++mt) {
#pragma unroll
        for (int nt = 0; nt < 4; ++nt) {
            const int col  = blockIdx.x * 128 + wn * 64 + nt * 16 + ln;
            const int rowb = blockIdx.y * 128 + wm * 64 + mt * 16 + q * 4;
            const int t = col >> 9;
            const int h = (col >> 6) & 7;
            const int dk = col & 63;
            bf16* dst = (t == 0) ? Q : (t == 1) ? Ko : V;
#pragma unroll
            for (int r = 0; r < 4; ++r) {
                const int row = rowb + r;
                const int b = row >= Nc ? 1 : 0;
                const int n = row - b * Nc;
                dst[(((long)b * Hc + h) * Nc + n) * DKc + dk] =
                    __float2bfloat16(acc[mt][nt][r]);
            }
        }
    }
}

// ---------------------------------------------------------------------------
// MFMA bf16 NT narrow GEMM core (validated): acc = A(128,K) @ Bt(64,K)^T.
// ---------------------------------------------------------------------------
struct N64Acc { f32x4 acc[2][4]; };

template <typename DUMMY = void>
DEVINL void n64_core(const bf16* A, const bf16* Bt, int K,
                     unsigned short* Asm, unsigned short* Bsm, N64Acc& R)
{
    const int tid  = threadIdx.x;
    const int wave = tid >> 6;
    const int lane = tid & 63;
    const int q    = lane >> 4;
    const int ln   = lane & 15;

    const int sr = tid >> 3, k8 = tid & 7;
    const bf16* pa[4];
    const bf16* pb[2];
    int wa[4], wb[2];
#pragma unroll
    for (int i = 0; i < 4; ++i) {
        pa[i] = A + (long)(sr + i * 32) * K + k8 * 8;
        wa[i] = (sr + i * 32) * 72 + k8 * 8;
    }
#pragma unroll
    for (int i = 0; i < 2; ++i) {
        pb[i] = Bt + (long)(sr + i * 32) * K + k8 * 8;
        wb[i] = (sr + i * 32) * 72 + k8 * 8;
    }

#pragma unroll
    for (int i = 0; i < 2; ++i)
#pragma unroll
        for (int j = 0; j < 4; ++j)
            R.acc[i][j] = (f32x4){0.f, 0.f, 0.f, 0.f};

    for (int k0 = 0; k0 < K; k0 += 64) {
        uint4 va[4], vb[2];
#pragma unroll
        for (int i = 0; i < 4; ++i) va[i] = *(const uint4*)(pa[i] + k0);
#pragma unroll
        for (int i = 0; i < 2; ++i) vb[i] = *(const uint4*)(pb[i] + k0);
        __syncthreads();
#pragma unroll
        for (int i = 0; i < 4; ++i) *(uint4*)&Asm[wa[i]] = va[i];
#pragma unroll
        for (int i = 0; i < 2; ++i) *(uint4*)&Bsm[wb[i]] = vb[i];
        __syncthreads();

#pragma unroll
        for (int kc = 0; kc < 2; ++kc) {
            short8 af[2], bfr[4];
#pragma unroll
            for (int mt = 0; mt < 2; ++mt) {
                int m = wave * 32 + mt * 16 + ln;
                af[mt] = *(const short8*)&Asm[m * 72 + kc * 32 + q * 8];
            }
#pragma unroll
            for (int nt = 0; nt < 4; ++nt) {
                int n = nt * 16 + ln;
                bfr[nt] = *(const short8*)&Bsm[n * 72 + kc * 32 + q * 8];
            }
#pragma unroll
            for (int mt = 0; mt < 2; ++mt)
#pragma unroll
                for (int nt = 0; nt < 4; ++nt)
                    R.acc[mt][nt] = __builtin_amdgcn_mfma_f32_16x16x32_bf16(
                        af[mt], bfr[nt], R.acc[mt][nt], 0, 0, 0);
        }
    }
}

// ---------------------------------------------------------------------------
// Round 21: HALF-HEIGHT n64 core — acc = A(64,K) @ Bt(64,K)^T. 4 waves x 16
// rows, acc[4], 18 KB LDS (validated r9: 96->192-block y/proj launches).
// ---------------------------------------------------------------------------
struct N64hAcc { f32x4 acc[4]; };

template <typename DUMMY = void>
DEVINL void n64h_core(const bf16* A, const bf16* Bt, int K,
                      unsigned short* Asm, unsigned short* Bsm, N64hAcc& R)
{
    const int tid  = threadIdx.x;
    const int wave = tid >> 6;
    const int lane = tid & 63;
    const int q    = lane >> 4;
    const int ln   = lane & 15;

    const int sr = tid >> 3, k8 = tid & 7;   // sr 0..31, k8 0..7
    const bf16* pa[2];
    const bf16* pb[2];
    int wa[2], wb[2];
#pragma unroll
    for (int i = 0; i < 2; ++i) {
        pa[i] = A  + (long)(sr + i * 32) * K + k8 * 8;
        wa[i] = (sr + i * 32) * 72 + k8 * 8;
        pb[i] = Bt + (long)(sr + i * 32) * K + k8 * 8;
        wb[i] = wa[i];
    }

#pragma unroll
    for (int j = 0; j < 4; ++j)
        R.acc[j] = (f32x4){0.f, 0.f, 0.f, 0.f};

    for (int k0 = 0; k0 < K; k0 += 64) {
        uint4 va[2], vb[2];
#pragma unroll
        for (int i = 0; i < 2; ++i) va[i] = *(const uint4*)(pa[i] + k0);
#pragma unroll
        for (int i = 0; i < 2; ++i) vb[i] = *(const uint4*)(pb[i] + k0);
        __syncthreads();
#pragma unroll
        for (int i = 0; i < 2; ++i) *(uint4*)&Asm[wa[i]] = va[i];
#pragma unroll
        for (int i = 0; i < 2; ++i) *(uint4*)&Bsm[wb[i]] = vb[i];
        __syncthreads();

#pragma unroll
        for (int kc = 0; kc < 2; ++kc) {
            short8 af;
            af = *(const short8*)&Asm[(wave * 16 + ln) * 72 + kc * 32 + q * 8];
            short8 bfr[4];
#pragma unroll
            for (int nt = 0; nt < 4; ++nt) {
                int n = nt * 16 + ln;
                bfr[nt] = *(const short8*)&Bsm[n * 72 + kc * 32 + q * 8];
            }
#pragma unroll
            for (int nt = 0; nt < 4; ++nt)
                R.acc[nt] = __builtin_amdgcn_mfma_f32_16x16x32_bf16(
                    af, bfr[nt], R.acc[nt], 0, 0, 0);
        }
    }
}

// ---------------------------------------------------------------------------
// Merged pair launch (Path-B fallback only; validated round 11).
// ---------------------------------------------------------------------------
__global__ __launch_bounds__(256) void gemm_n64_pair(
    const bf16* __restrict__ A0g, const bf16* __restrict__ B0g, bf16* __restrict__ C0tg,
    const bf16* __restrict__ A1g, const bf16* __restrict__ B1g, bf16* __restrict__ C1g,
    int M, int K, long sA, long sB, long sC)
{
    __shared__ unsigned short Asm[128 * 72];
    __shared__ unsigned short Bsm[64 * 72];

    const int zz = blockIdx.z & 15;
    const int second = blockIdx.z >> 4;
    const bf16* A  = (second ? A1g : A0g) + (long)zz * sA + (long)(blockIdx.y * 128) * K;
    const bf16* Bt = (second ? B1g : B0g) + (long)zz * sB;

    N64Acc R;
    n64_core(A, Bt, K, Asm, Bsm, R);

    const int tid = threadIdx.x;
    const int wave = tid >> 6, lane = tid & 63, q = lane >> 4, ln = lane & 15;

    if (second) {
        bf16* C = C1g + (long)zz * sC;
#pragma unroll
        for (int mt = 0; mt < 2; ++mt) {
#pragma unroll
            for (int nt = 0; nt < 4; ++nt) {
                const int col  = nt * 16 + ln;
                const int rowb = blockIdx.y * 128 + wave * 32 + mt * 16 + q * 4;
#pragma unroll
                for (int r = 0; r < 4; ++r)
                    C[(long)(rowb + r) * 64 + col] = __float2bfloat16(R.acc[mt][nt][r]);
            }
        }
    } else {
        __syncthreads();
#pragma unroll
        for (int mt = 0; mt < 2; ++mt) {
#pragma unroll
            for (int nt = 0; nt < 4; ++nt) {
                const int col = nt * 16 + ln;
                const int rwb = wave * 32 + mt * 16 + q * 4;
#pragma unroll
                for (int r = 0; r < 4; ++r)
                    *(bf16*)&Asm[col * 136 + rwb + r] = __float2bfloat16(R.acc[mt][nt][r]);
            }
        }
        __syncthreads();
        bf16* Ct = C0tg + (long)zz * sC;
        const int dk  = tid >> 2;
        const int nc0 = (tid & 3) * 32;
        const int gn0 = blockIdx.y * 128;
#pragma unroll
        for (int c8 = 0; c8 < 4; ++c8) {
            uint4 v = *(const uint4*)&Asm[dk * 136 + nc0 + c8 * 8];
            *(uint4*)&Ct[(long)dk * Nc + gn0 + nc0 + c8 * 8] = v;
        }
    }
}

// ---------------------------------------------------------------------------
// Merged y kernel, half-height tiles (Path A; validated r9). 192 blocks.
// ---------------------------------------------------------------------------
__global__ __launch_bounds__(256) void gemm_n64_both_h(
    const bf16* __restrict__ Ab, const bf16* __restrict__ v1t,
    const bf16* __restrict__ Craw, const bf16* __restrict__ v2t,
    const float* __restrict__ smallf, bf16* __restrict__ yc,
    int K, long sA, long sB)
{
    __shared__ unsigned short Asm[64 * 72];
    __shared__ unsigned short Bsm[64 * 72];

    const int bh = blockIdx.z;
    const long arow = (long)(blockIdx.y * 64) * K;

    N64hAcc R1;
    n64h_core(Ab + (long)bh * sA + arow, v1t + (long)bh * sB, K, Asm, Bsm, R1);
    N64hAcc R2;
    n64h_core(Craw + (long)bh * sA + arow, v2t + (long)bh * sB, K, Asm, Bsm, R2);

    const float w = sigf(smallf[392]);
    const int b = bh >> 3, h = bh & 7;

    const int tid = threadIdx.x;
    const int wave = tid >> 6, lane = tid & 63, q = lane >> 4, ln = lane & 15;
#pragma unroll
    for (int nt = 0; nt < 4; ++nt) {
        const int col  = nt * 16 + ln;
        const int rowb = blockIdx.y * 64 + wave * 16 + q * 4;
#pragma unroll
        for (int r = 0; r < 4; ++r) {
            const int n = rowb + r;
            yc[((long)(b * Nc + n)) * Dc + h * DKc + col] =
                __float2bfloat16(R1.acc[nt][r] + w * R2.acc[nt][r]);
        }
    }
}

// y_chain GEMM with fused combine + permute (Path-B fallback only).
__global__ __launch_bounds__(256) void gemm_n64_combine(
    const bf16* __restrict__ A1b, const bf16* __restrict__ trt,
    const bf16* __restrict__ yb1, const float* __restrict__ smallf,
    bf16* __restrict__ yc, int M, int K, long sA, long sB)
{
    __shared__ unsigned short Asm[128 * 72];
    __shared__ unsigned short Bsm[64 * 72];

    const int bh = blockIdx.z;
    const bf16* A  = A1b + (long)bh * sA + (long)(blockIdx.y * 128) * K;
    const bf16* Bt = trt + (long)bh * sB;

    N64Acc R;
    n64_core(A, Bt, K, Asm, Bsm, R);

    const float w = sigf(smallf[392]);
    const int b = bh >> 3, h = bh & 7;
    const long yb1base = (long)bh * Nc * DKc;

    const int tid = threadIdx.x;
    const int wave = tid >> 6, lane = tid & 63, q = lane >> 4, ln = lane & 15;
#pragma unroll
    for (int mt = 0; mt < 2; ++mt) {
#pragma unroll
        for (int nt = 0; nt < 4; ++nt) {
            const int col  = nt * 16 + ln;
            const int rowb = blockIdx.y * 128 + wave * 32 + mt * 16 + q * 4;
#pragma unroll
            for (int r = 0; r < 4; ++r) {
                const int n = rowb + r;
                const float base = __bfloat162float(yb1[yb1base + (long)n * 64 + col]);
                yc[((long)(b * Nc + n)) * Dc + h * DKc + col] =
                    __float2bfloat16(base + w * R.acc[mt][nt][r]);
            }
        }
    }
}

// Path-B y_base GEMM (fallback only).
__global__ __launch_bounds__(256) void gemm_n64_yb(
    const bf16* __restrict__ Ag, const bf16* __restrict__ Btg,
    bf16* __restrict__ Cg, int M, int K, long sA, long sB, long sC)
{
    __shared__ unsigned short Asm[128 * 72];
    __shared__ unsigned short Bsm[64 * 72];

    const int zz = blockIdx.z;
    const bf16* A  = Ag + (long)zz * sA + (long)(blockIdx.y * 128) * K;
    const bf16* Bt = Btg + (long)zz * sB;

    N64Acc R;
    n64_core(A, Bt, K, Asm, Bsm, R);

    bf16* C = Cg + (long)zz * sC;
    const int tid = threadIdx.x;
    const int wave = tid >> 6, lane = tid & 63, q = lane >> 4, ln = lane & 15;
#pragma unroll
    for (int mt = 0; mt < 2; ++mt) {
#pragma unroll
        for (int nt = 0; nt < 4; ++nt) {
            const int col  = nt * 16 + ln;
            const int rowb = blockIdx.y * 128 + wave * 32 + mt * 16 + q * 4;
#pragma unroll
            for (int r = 0; r < 4; ++r)
                C[(long)(rowb + r) * 64 + col] = __float2bfloat16(R.acc[mt][nt][r]);
        }
    }
}

// ---------------------------------------------------------------------------
// Row softmax over width 768 — wave-per-row (validated round 16). Used for
// step-6 (Smix -> A) and Path-B step-3.
// ---------------------------------------------------------------------------
__global__ __launch_bounds__(256) void softmax_rows_w(
    const float* __restrict__ src, bf16* __restrict__ dst)
{
    const int wid  = threadIdx.x >> 6;
    const int lane = threadIdx.x & 63;
    const long row = (long)blockIdx.x * 4 + wid;
    const float* s = src + row * Nc;

    float4 v[3];
#pragma unroll
    for (int i = 0; i < 3; ++i)
        v[i] = *(const float4*)&s[i * 256 + lane * 4];

    float m = -1e30f;
#pragma unroll
    for (int i = 0; i < 3; ++i)
        m = fmaxf(m, fmaxf(fmaxf(v[i].x, v[i].y), fmaxf(v[i].z, v[i].w)));
#pragma unroll
    for (int off = 32; off > 0; off >>= 1)
        m = fmaxf(m, __shfl_xor(m, off, 64));

    float e[12];
    float sum = 0.f;
#pragma unroll
    for (int i = 0; i < 3; ++i) {
        e[i * 4 + 0] = __expf(v[i].x - m);
        e[i * 4 + 1] = __expf(v[i].y - m);
        e[i * 4 + 2] = __expf(v[i].z - m);
        e[i * 4 + 3] = __expf(v[i].w - m);
        sum += e[i * 4 + 0] + e[i * 4 + 1] + e[i * 4 + 2] + e[i * 4 + 3];
    }
#pragma unroll
    for (int off = 32; off > 0; off >>= 1)
        sum += __shfl_xor(sum, off, 64);

    const float inv = 1.f / fmaxf(sum, 1e-30f);
    unsigned short* d = (unsigned short*)dst + row * Nc;
#pragma unroll
    for (int i = 0; i < 3; ++i) {
        unsigned short o[4];
#pragma unroll
        for (int j = 0; j < 4; ++j) {
            const bf16 b = __float2bfloat16(e[i * 4 + j] * inv);
            o[j] = *(const unsigned short*)&b;
        }
        *(uint2*)&d[i * 256 + lane * 4] = *(const uint2*)o;
    }
}

// ---------------------------------------------------------------------------
// Gate network + Smix — r7-validated 2-elem body (77.8 µs plateau; frozen).
// ---------------------------------------------------------------------------
__global__ __launch_bounds__(256) void gates_smix(
    const float* __restrict__ S1g, const float* __restrict__ S2g,
    const bf16* __restrict__ Crg, const bf16* __restrict__ Clg,
    float* __restrict__ Smixg, const float* __restrict__ smallf)
{
    __shared__ float t1t[32][17], t2t[32][17];

    const long mat = (long)blockIdx.z * Nc * Nc;
    const float* S1 = S1g + mat;
    const float* S2 = S2g + mat;
    const unsigned short* Cr = (const unsigned short*)Crg + mat;
    const unsigned short* Cl = (const unsigned short*)Clg + mat;
    float* Smix = Smixg + mat;

    const int tid = threadIdx.x;

    const int n0 = blockIdx.y * 16, m0 = blockIdx.x * 32;
    {   // transposed tiles: S[m0..m0+31][n0..n0+15], coalesced float2 loads
        const int r = tid >> 3, c2 = (tid & 7) * 2;
        const float2 a = *(const float2*)&S1[(long)(m0 + r) * Nc + n0 + c2];
        const float2 b = *(const float2*)&S2[(long)(m0 + r) * Nc + n0 + c2];
        t1t[r][c2] = a.x; t1t[r][c2 + 1] = a.y;
        t2t[r][c2] = b.x; t2t[r][c2 + 1] = b.y;
    }
    __syncthreads();

    const int tx = tid & 15, ty = tid >> 4;
    const int n = n0 + ty;
    const long idx = (long)n * Nc + m0 + tx * 2;

    const float2 s1v = *(const float2*)&S1[idx];
    const float2 s2v = *(const float2*)&S2[idx];
    const unsigned cru = *(const unsigned*)&Cr[idx];   // idx even -> 4B aligned
    const unsigned clu = *(const unsigned*)&Cl[idx];

    const f32x2 s1a = {s1v.x, s1v.y};
    const f32x2 s2a = {s2v.x, s2v.y};
    const f32x2 cra = {__uint_as_float((cru & 0xffffu) << 16),
                       __uint_as_float(cru & 0xffff0000u)};
    const f32x2 cla = {__uint_as_float((clu & 0xffffu) << 16),
                       __uint_as_float(clu & 0xffff0000u)};
    const f32x2 s1t = {t1t[tx * 2][ty], t1t[tx * 2 + 1][ty]};
    const f32x2 s2t = {t2t[tx * 2][ty], t2t[tx * 2 + 1][ty]};

    f32x2 g0 = *(const f32x2*)&smallf[384];
    f32x2 g1 = *(const f32x2*)&smallf[386];
    f32x2 g2 = *(const f32x2*)&smallf[388];
    f32x2 g3 = *(const f32x2*)&smallf[390];

    const f32x2 gc1  = splat2(-2.30220902f);   // gelu c1 * log2e
    const f32x2 gc3  = splat2(-0.10294357f);   // gelu c3 * log2e
    const f32x2 one2 = splat2(1.f);

#pragma unroll
    for (int u = 0; u < 16; ++u) {
        const f32x2* cw = (const f32x2*)&smallf[u * 24];
        f32x2 h = cw[6];
        h = fma2(s1a, cw[0], h);
        h = fma2(s2a, cw[1], h);
        h = fma2(s1t, cw[2], h);
        h = fma2(s2t, cw[3], h);
        h = fma2(cra, cw[4], h);
        h = fma2(cla, cw[5], h);
        const f32x2 hh = h * h;
        const f32x2 z2 = h * fma2(hh, gc3, gc1);
        f32x2 e;  e[0]  = vexp2(z2[0]); e[1]  = vexp2(z2[1]);
        const f32x2 d = one2 + e;
        f32x2 rc; rc[0] = vrcp(d[0]);   rc[1] = vrcp(d[1]);
        const f32x2 hid = h * rc;
        g0 = fma2(hid, cw[8],  g0);
        g1 = fma2(hid, cw[9],  g1);
        g2 = fma2(hid, cw[10], g2);
        g3 = fma2(hid, cw[11], g3);
    }

    const f32x2 nl2e = splat2(-1.44269504f);
    const f32x2 ln2v = splat2(0.69314718f);
    auto sig2 = [&](f32x2 x) -> f32x2 {
        const f32x2 t = x * nl2e;
        f32x2 e;  e[0] = vexp2(t[0]); e[1] = vexp2(t[1]);
        const f32x2 d = one2 + e;
        f32x2 r;  r[0] = vrcp(d[0]);  r[1] = vrcp(d[1]);
        return r;
    };
    const f32x2 ga2 = sig2(g0);
    const f32x2 go2 = sig2(g1);
    const f32x2 gn2 = sig2(g2);
    const f32x2 gc2 = sig2(g3);

    const f32x2 dd = s1a - s2a;
    f32x2 ad; ad[0] = fabsf(dd[0]); ad[1] = fabsf(dd[1]);
    const f32x2 t2 = ad * nl2e;                       // -|d| * log2e
    f32x2 ee; ee[0] = vexp2(t2[0]); ee[1] = vexp2(t2[1]);
    const f32x2 lp = one2 + ee;
    f32x2 lg; lg[0] = vlog2(lp[0]); lg[1] = vlog2(lp[1]);
    const f32x2 mx2 = __builtin_elementwise_max(s1a, s2a);
    const f32x2 lae = fma2(lg, ln2v, mx2);            // logaddexp(s1,s2)

    f32x2 o2 = s1a;
    o2 = fma2(ga2, s2a, o2);
    o2 = fma2(go2, lae - s1a, o2);
    o2 = fma2(gn2, s2a * splat2(-BETA_NOT), o2);
    o2 = fma2(gc2, cra, o2);
    *(float2*)&Smix[idx] = (float2){o2[0], o2[1]};
}

// ---------------------------------------------------------------------------
// Final projection, half-height tiles — 192 blocks (validated r9).
// ---------------------------------------------------------------------------
__global__ __launch_bounds__(256) void proj_n64h(
    const bf16* __restrict__ yc, const bf16* __restrict__ pwt,
    const void* __restrict__ xraw, void* __restrict__ out)
{
    constexpr int K = Dc;  // 512
    constexpr int N = Dc;  // 512
    __shared__ unsigned short Asm[64 * 72];
    __shared__ unsigned short Bsm[64 * 72];
    __shared__ int is32s;
    if (threadIdx.x == 0) is32s = sniff_is_fp32(xraw);

    const bf16* A  = yc  + (long)(blockIdx.y * 64) * K;
    const bf16* Bt = pwt + (long)(blockIdx.x * 64) * K;

    N64hAcc R;
    n64h_core(A, Bt, K, Asm, Bsm, R);   // internal barriers publish is32s

    const int is32 = is32s;
    const int tid = threadIdx.x;
    const int wave = tid >> 6, lane = tid & 63, q = lane >> 4, ln = lane & 15;
#pragma unroll
    for (int nt = 0; nt < 4; ++nt) {
        const int col  = blockIdx.x * 64 + nt * 16 + ln;
        const int rowb = blockIdx.y * 64 + wave * 16 + q * 4;
#pragma unroll
        for (int r = 0; r < 4; ++r) {
            const long o = (long)(rowb + r) * N + col;
            if (is32) ((float*)out)[o] = R.acc[nt][r];
            else      ((bf16*)out)[o] = __float2bfloat16(R.acc[nt][r]);
        }
    }
}

// ---------------------------------------------------------------------------
extern "C" void kernel_launch(void* const* d_in, const int* in_sizes, int n_in,
                              void* d_out, int out_size, void* d_ws, size_t ws_size,
                              hipStream_t stream)
{
    const size_t HD   = (size_t)BHc * Nc * DKc;   // 786432
    const size_t HDh  = HD / 2;                   // float-slots for HD bf16
    const size_t MAT  = (size_t)Nc * Nc;          // 589824
    const size_t MATS = (size_t)BHc * MAT;        // 9437184
    const long   HSTR = (long)Nc * DKc;           // 49152 per-head stride

    float* ws = (float*)d_ws;
    size_t off = 0;
    auto alloc = [&](size_t n) { float* p = ws + off; off += n; return p; };

    bf16* xb  = (bf16*)alloc(HDh);
    bf16* w1b = (bf16*)alloc(HDh);   // w1b/w2b adjacent -> merged transpose
    bf16* w2b = (bf16*)alloc(HDh);
    bf16* w1t = (bf16*)alloc(HDh);
    bf16* w2t = (bf16*)alloc(HDh);
    bf16* pwb = (bf16*)alloc((size_t)Dc * Dc / 2);
    bf16* pwt = (bf16*)alloc((size_t)Dc * Dc / 2);
    float* smallf = alloc(512);
    // q1|q2 and k1|k2 adjacent -> single merged fused-S launch (32 batches)
    bf16* q1b = (bf16*)alloc(HDh); bf16* q2b = (bf16*)alloc(HDh);
    bf16* k1b = (bf16*)alloc(HDh); bf16* k2b = (bf16*)alloc(HDh);
    bf16* v1b = (bf16*)alloc(HDh); bf16* v2b = (bf16*)alloc(HDh);  // adjacent
    bf16* v1t = (bf16*)alloc(HDh); bf16* v2t = (bf16*)alloc(HDh);  // adjacent
    bf16* trt = (bf16*)alloc(HDh);
    float* S1   = alloc(MATS);       // S1/S2 adjacent
    float* S2   = alloc(MATS);
    float* Smix = alloc(MATS);       // region reused: A1tb|A2tb, then Smix
    bf16* A1b = (bf16*)alloc(MATS / 2);  // A1b/A2b adjacent
    bf16* A2b = (bf16*)alloc(MATS / 2);
    bf16* Crb = (bf16*)alloc(MATS / 2);  // Crb/Clb adjacent (merged launch)
    bf16* Clb = (bf16*)alloc(MATS / 2);
    bf16* yb1 = (bf16*)alloc(HDh);
    bf16* yc  = (bf16*)alloc(HDh);

    const size_t NEED_BASE = off * sizeof(float);
    bf16* Crawb = (bf16*)alloc(MATS / 2);          // raw C_right (Path A only)
    const size_t NEED_A = off * sizeof(float);
    const int pathA = ws_size >= NEED_A;

    // aliases into dead regions
    bf16* A1tb = (bf16*)Smix;            // live steps 3-4 (dead once gates writes Smix)
    bf16* A2tb = ((bf16*)Smix) + MATS;
    bf16* Ab   = (bf16*)S1;              // S1 dead after gates

    if (ws_size < NEED_BASE) {
        fill_sentinel<<<dim3(3072), 256, 0, stream>>>((unsigned short*)d_out);
        return;
    }

    // 0. normalize inputs
    convert_all<<<dim3(3072), 256, 0, stream>>>(
        d_in[0], d_in[1], d_in[2], d_in[3], d_in[4], d_in[5], d_in[6], d_in[7],
        d_in[8], xb, w1b, w2b, pwb, smallf);

    // 1. merged W transposes; pw transpose; merged QKV; merged v transposes
    transpose_bf16<<<dim3(24, 8, 2), 256, 0, stream>>>(
        (const unsigned short*)w1b, (unsigned short*)w1t, Dc, 3 * Dc, (long)HD, (long)HD);
    transpose_bf16<<<dim3(8, 8, 1), 256, 0, stream>>>(
        (const unsigned short*)pwb, (unsigned short*)pwt, Dc, Dc, 0, 0);
    qkv_mfma<<<dim3(12, 12, 2), 256, 0, stream>>>(
        xb, w1t, w2t, q1b, k1b, v1b, q2b, k2b, v2b);
    transpose_bf16<<<dim3(1, 12, 2 * BHc), 256, 0, stream>>>(
        (const unsigned short*)v1b, (unsigned short*)v1t, Nc, DKc, HSTR, HSTR);

    // 2+3. FUSED: S = scale*q@k^T, row softmax -> A, A^T — one 1536-block
    //       launch replacing S-GEMM + softmax3 + transposeA (round 22).
    sgemm_softmax<<<dim3(1536), 256, 0, stream>>>(
        q1b, k1b, S1, A1b, A1tb);

    // 4. Cr|Cl in ONE 32-batch launch; XCD-pinned 1-D grid (1152 = 8*4*36);
    //    2-phase double-buffered K-loop; Path A also stores raw C_right.
    if (pathA)
        gemm_nt_mfma<1, bf16, 1, 1, 1><<<dim3(1152), 256, 0, stream>>>(
            A1b, A1tb, Crb, Crawb, Nc, Nc, Nc, (long)MAT, (long)MAT, (long)MAT, 1.f);
    else
        gemm_nt_mfma<1, bf16, 1, 1, 0><<<dim3(1152), 256, 0, stream>>>(
            A1b, A1tb, Crb, nullptr, Nc, Nc, Nc, (long)MAT, (long)MAT, (long)MAT, 1.f);

    // 5. gates + Smix (r7-validated 2-elem body)
    gates_smix<<<dim3(24, 48, BHc), 256, 0, stream>>>(S1, S2, Crb, Clb, Smix, smallf);

    // 6. A = softmax(Smix) -> bf16 (into S1 alias, wave-per-row)
    softmax_rows_w<<<(BHc * Nc) / 4, 256, 0, stream>>>(Smix, Ab);

    if (pathA) {
        // 7. merged y, half-height tiles: 192 blocks
        gemm_n64_both_h<<<dim3(1, 12, BHc), 256, 0, stream>>>(
            Ab, v1t, Crawb, v2t, smallf, yc, Nc, (long)MAT, HSTR);
    } else {
        // Path B fallback (round-5 structure)
        gemm_n64_pair<<<dim3(1, 6, 2 * BHc), 256, 0, stream>>>(
            A2b, v2t, trt, Ab, v1t, yb1, Nc, Nc, (long)MAT, HSTR, HSTR);
        gemm_n64_combine<<<dim3(1, 6, BHc), 256, 0, stream>>>(
            A1b, trt, yb1, smallf, yc, Nc, Nc, (long)MAT, HSTR);
    }

    // 9. proj, half-height tiles: 192 blocks
    proj_n64h<<<dim3(8, 24, 1), 256, 0, stream>>>(yc, pwt, d_in[0], d_out);
}